// Round 2
// baseline (2733.436 us; speedup 1.0000x reference)
//
#include <hip/hip_runtime.h>

#define HD 128
#define GNUM 512

// ======================= device utils =======================
__device__ __forceinline__ void atomicMaxF(float* addr, float v) {
  if ((__float_as_uint(v) >> 31) == 0u)
    atomicMax((int*)addr, __float_as_int(v));           // positive (incl +0)
  else
    atomicMin((unsigned int*)addr, __float_as_uint(v)); // negative (incl -0)
}

// ======================= GEMM: C[N,128] = A[N,128] @ W[128,128] (+Cadd +bias, relu) ===
// 32 rows/block, 256 threads, W staged in LDS in two 64-row K-halves. 48KB LDS.
// NOTE: C and Cadd may alias (element is read before written by the same thread).
__global__ __launch_bounds__(256) void k_gemm128(
    const float* __restrict__ A, const float* __restrict__ W,
    float* C, const float* Cadd,
    const float* __restrict__ bias, int N, int relu)
{
  __shared__ float As[32 * 128];   // 16 KB
  __shared__ float Wk[64 * 128];   // 32 KB
  const int t = threadIdx.x;
  const int row0 = blockIdx.x * 32;

  { // stage A tile (linear float4 copy, zero-pad beyond N)
    const float4* A4 = (const float4*)(A + (size_t)row0 * 128);
    float4* As4 = (float4*)As;
    const int nrow = min(N - row0, 32);
    const int maxf4 = nrow * 32;
#pragma unroll
    for (int i = 0; i < 4; ++i) {
      int f = t + i * 256;
      float4 v = make_float4(0.f, 0.f, 0.f, 0.f);
      if (f < maxf4) v = A4[f];
      As4[f] = v;
    }
  }

  const int tx = t & 31, ty = t >> 5;
  float acc[4][4];
#pragma unroll
  for (int i = 0; i < 4; ++i)
#pragma unroll
    for (int j = 0; j < 4; ++j) acc[i][j] = 0.f;

  for (int p = 0; p < 2; ++p) {
    __syncthreads();
    { // stage W K-half: 8192 floats
      const float4* W4 = (const float4*)(W + p * 64 * 128);
      float4* Wk4 = (float4*)Wk;
#pragma unroll
      for (int i = 0; i < 8; ++i) Wk4[t + i * 256] = W4[t + i * 256];
    }
    __syncthreads();
#pragma unroll 8
    for (int k = 0; k < 64; ++k) {
      const float4 b4 = *(const float4*)(Wk + k * 128 + tx * 4);
      const int kk = p * 64 + k;
      float a[4];
#pragma unroll
      for (int i = 0; i < 4; ++i) a[i] = As[(ty * 4 + i) * 128 + kk];
#pragma unroll
      for (int i = 0; i < 4; ++i) {
        acc[i][0] = fmaf(a[i], b4.x, acc[i][0]);
        acc[i][1] = fmaf(a[i], b4.y, acc[i][1]);
        acc[i][2] = fmaf(a[i], b4.z, acc[i][2]);
        acc[i][3] = fmaf(a[i], b4.w, acc[i][3]);
      }
    }
  }

  // epilogue
  float4 bv = make_float4(0.f, 0.f, 0.f, 0.f);
  if (bias) bv = *(const float4*)(bias + tx * 4);
#pragma unroll
  for (int i = 0; i < 4; ++i) {
    int r = row0 + ty * 4 + i;
    if (r < N) {
      size_t base = (size_t)r * 128 + tx * 4;
      float4 v = make_float4(acc[i][0], acc[i][1], acc[i][2], acc[i][3]);
      if (Cadd) {
        float4 c4 = *(const float4*)(Cadd + base);
        v.x += c4.x; v.y += c4.y; v.z += c4.z; v.w += c4.w;
      }
      if (bias) { v.x += bv.x; v.y += bv.y; v.z += bv.z; v.w += bv.w; }
      if (relu) {
        v.x = fmaxf(v.x, 0.f); v.y = fmaxf(v.y, 0.f);
        v.z = fmaxf(v.z, 0.f); v.w = fmaxf(v.w, 0.f);
      }
      *(float4*)(C + base) = v;
    }
  }
}

// ======================= row dot: out[n] = x[n,:] . a  (one wave / node) ===========
__global__ void k_rowdot(const float* __restrict__ x, const float* __restrict__ a,
                         float* __restrict__ out, int N)
{
  int wid = blockIdx.x * 4 + (threadIdx.x >> 6);
  int lane = threadIdx.x & 63;
  if (wid >= N) return;
  const float* xr = x + (size_t)wid * 128;
  float v = xr[lane] * a[lane] + xr[64 + lane] * a[64 + lane];
#pragma unroll
  for (int o = 32; o > 0; o >>= 1) v += __shfl_down(v, o);
  if (lane == 0) out[wid] = v;
}

// ======================= wvec[i] = sum_j W[i,j]*a[j]  (one block, 128 thr) =========
__global__ void k_matvec_right(const float* __restrict__ W, const float* __restrict__ a,
                               float* __restrict__ wvec)
{
  __shared__ float as[128];
  int i = threadIdx.x;
  as[i] = a[i];
  __syncthreads();
  float v = 0.f;
  for (int j = 0; j < 128; ++j) v = fmaf(W[i * 128 + j], as[j], v);
  wvec[i] = v;
}

// ======================= edge kernels =======================
__global__ void k_count(const int* __restrict__ ed, float* __restrict__ deg, int E) {
  int e = blockIdx.x * 256 + threadIdx.x;
  if (e < E) atomicAdd(&deg[ed[e]], 1.f);
}

__global__ void k_gat_logit(const int* __restrict__ es, const int* __restrict__ ed,
                            const float* __restrict__ as_, const float* __restrict__ ad_,
                            float* __restrict__ elog, float* __restrict__ m, int E)
{
  int e = blockIdx.x * 256 + threadIdx.x;
  if (e >= E) return;
  float v = as_[es[e]] + ad_[ed[e]];
  v = v > 0.f ? v : 0.2f * v;     // leaky_relu 0.2
  elog[e] = v;
  atomicMaxF(&m[ed[e]], v);
}

__global__ void k_gat_exp(const int* __restrict__ ed, float* __restrict__ elog,
                          const float* __restrict__ m, float* __restrict__ z, int E)
{
  int e = blockIdx.x * 256 + threadIdx.x;
  if (e >= E) return;
  int d = ed[e];
  float v = expf(elog[e] - m[d]);
  elog[e] = v;
  atomicAdd(&z[d], v);
}

__global__ void k_gat_scatter(const int* __restrict__ es, const int* __restrict__ ed,
                              const float* __restrict__ elog, const float* __restrict__ z,
                              const float* __restrict__ hs, float* __restrict__ acc, int E)
{
  int e = blockIdx.x * 2 + (threadIdx.x >> 7);
  if (e >= E) return;
  int c = threadIdx.x & 127;
  int si = es[e], di = ed[e];
  float alpha = elog[e] / fmaxf(z[di], 1e-16f);
  atomicAdd(&acc[(size_t)di * 128 + c], alpha * hs[(size_t)si * 128 + c]);
}

__global__ void k_gcn_scatter(const int* __restrict__ es, const int* __restrict__ ed,
                              const float* __restrict__ deg, const float* __restrict__ h,
                              float* __restrict__ acc, int E)
{
  int e = blockIdx.x * 2 + (threadIdx.x >> 7);
  if (e >= E) return;
  int c = threadIdx.x & 127;
  int si = es[e], di = ed[e];
  float nrm = rsqrtf(deg[si] + 1.f) * rsqrtf(deg[di] + 1.f);
  atomicAdd(&acc[(size_t)di * 128 + c], nrm * h[(size_t)si * 128 + c]);
}

__global__ void k_sage_scatter(const int* __restrict__ es, const int* __restrict__ ed,
                               const float* __restrict__ xs, float* __restrict__ agg, int E)
{
  int e = blockIdx.x * 2 + (threadIdx.x >> 7);
  if (e >= E) return;
  int c = threadIdx.x & 127;
  atomicAdd(&agg[(size_t)ed[e] * 128 + c], xs[(size_t)es[e] * 128 + c]);
}

// ======================= elementwise =======================
__global__ void k_mean_div(float* __restrict__ agg, const float* __restrict__ cnt, int N) {
  size_t idx = (size_t)blockIdx.x * 256 + threadIdx.x;
  if (idx >= (size_t)N * 128) return;
  int n = (int)(idx >> 7);
  agg[idx] /= fmaxf(cnt[n], 1.f);
}

// out = relu(acc + rr*h + b1 (+b2))   rr = dis^2 = 1/(deg+1).  out may alias acc.
__global__ void k_combine_gcn(const float* acc, const float* __restrict__ h,
                              const float* __restrict__ deg, const float* __restrict__ b1,
                              const float* __restrict__ b2, float* out, int N)
{
  size_t idx = (size_t)blockIdx.x * 256 + threadIdx.x;
  if (idx >= (size_t)N * 128) return;
  int n = (int)(idx >> 7), c = (int)(idx & 127);
  float r = rsqrtf(deg[n] + 1.f);
  float v = acc[idx] + r * r * h[idx] + b1[c] + (b2 ? b2[c] : 0.f);
  out[idx] = fmaxf(v, 0.f);
}

// out may alias acc.
__global__ void k_combine_bias_relu(const float* acc, const float* __restrict__ b,
                                    float* out, int N)
{
  size_t idx = (size_t)blockIdx.x * 256 + threadIdx.x;
  if (idx >= (size_t)N * 128) return;
  int c = (int)(idx & 127);
  out[idx] = fmaxf(acc[idx] + b[c], 0.f);
}

// ======================= pooling (b sorted -> run-length + atomics) ================
__global__ void k_pool_scan(const float* __restrict__ x, const int* __restrict__ b,
                            float* __restrict__ pool, float* __restrict__ cntg,
                            int N, int col_off)
{
  const int t = threadIdx.x;
  const int c = t & 127;
  const int half = t >> 7;
  const int n0 = blockIdx.x * 256 + half * 128;
  if (n0 >= N) return;
  const int n1 = min(n0 + 128, N);
  float accum = 0.f;
  int cur = b[n0];
  int len = 0;
  for (int n = n0; n < n1; ++n) {
    int g = b[n];
    if (g != cur) {
      atomicAdd(&pool[(size_t)cur * 640 + col_off + c], accum);
      if (c == 0) atomicAdd(&cntg[cur], (float)len);
      accum = 0.f; len = 0; cur = g;
    }
    accum += x[(size_t)n * 128 + c];
    ++len;
  }
  atomicAdd(&pool[(size_t)cur * 640 + col_off + c], accum);
  if (c == 0) atomicAdd(&cntg[cur], (float)len);
}

// ======================= final MLP (one block per graph) =======================
__global__ void k_mlp(const float* __restrict__ pool, const float* __restrict__ cntg,
                      const float* __restrict__ W1, const float* __restrict__ b1,
                      const float* __restrict__ W2, const float* __restrict__ b2,
                      float* __restrict__ out)
{
  __shared__ float emb[640];
  __shared__ float red[128];
  const int g = blockIdx.x, t = threadIdx.x;
  for (int i = t; i < 640; i += 128) {
    int type = i >> 7;
    float cnt = cntg[type * GNUM + g];
    emb[i] = pool[(size_t)g * 640 + i] / fmaxf(cnt, 1.f);
  }
  __syncthreads();
  float acc = b1[t];
  for (int i = 0; i < 640; ++i) acc = fmaf(emb[i], W1[i * 128 + t], acc);
  float h = fmaxf(acc, 0.f);
  red[t] = h * W2[t];
  __syncthreads();
  for (int s = 64; s > 0; s >>= 1) {
    if (t < s) red[t] += red[t + s];
    __syncthreads();
  }
  if (t == 0) out[g] = red[0] + b2[0];
}

// ======================= host =======================
extern "C" void kernel_launch(void* const* d_in, const int* in_sizes, int n_in,
                              void* d_out, int out_size, void* d_ws, size_t ws_size,
                              hipStream_t stream)
{
  auto fin = [&](int i) { return (const float*)d_in[i]; };
  auto iin = [&](int i) { return (const int*)d_in[i]; };

  const float *x_cd = fin(0), *x_seq = fin(1), *x_anno = fin(2), *x_range = fin(3), *x_md = fin(4);
  const int *ei_seq = iin(5), *ei_anno = iin(6), *ei_range = iin(7),
            *ei_comp = iin(8), *ei_cc = iin(9), *ei_mm = iin(10);
  const int *b_cd = iin(11), *b_seq = iin(12), *b_anno = iin(13), *b_range = iin(14), *b_md = iin(15);

  const int N_CD = in_sizes[0] / HD, N_SEQ = in_sizes[1] / HD, N_ANNO = in_sizes[2] / HD,
            N_RANGE = in_sizes[3] / HD, N_MD = in_sizes[4] / HD;
  const int E_seq = in_sizes[5] / 2, E_anno = in_sizes[6] / 2, E_range = in_sizes[7] / 2,
            E_comp = in_sizes[8] / 2, E_cc = in_sizes[9] / 2, E_mm = in_sizes[10] / 2;
  const int N_OTH = max(max(N_SEQ, N_ANNO), N_RANGE);
  const int maxE = max(max(max(E_seq, E_anno), max(E_range, E_comp)), max(E_cc, E_mm));

  auto WLm = [&](int i, int l) { return fin(i) + (size_t)l * HD * HD; };
  auto WLv = [&](int i, int l) { return fin(i) + (size_t)l * HD; };

  // ---- workspace layout (~225 MB) ----
  float* ws = (float*)d_ws;
  size_t off = 0;
  auto alloc = [&](size_t n) { float* p = ws + off; off += (n + 3) & ~(size_t)3; return p; };
  float* xcd1 = alloc((size_t)N_CD * HD);   // L1 CD output (persists through L2)
  float* xmd1 = alloc((size_t)N_MD * HD);   // L1 MD output
  float* xoth = alloc((size_t)N_OTH * HD);  // shared L1 output: seq, then anno, then range
  float* acc  = alloc((size_t)N_CD * HD);   // conv accumulator / L2 output
  float* t1   = alloc((size_t)N_CD * HD);   // hs (GAT) / h (GCN) / agg (SAGE)
  float* eW   = alloc((size_t)maxE);
  float* sAs  = alloc((size_t)N_CD);
  float* sAd  = alloc((size_t)N_CD);
  float* sM   = alloc((size_t)N_CD);
  float* sZ   = alloc((size_t)N_CD);
  float* sDeg = alloc((size_t)N_CD);
  float* wvec = alloc(HD);
  float* pool = alloc((size_t)GNUM * 5 * HD);
  float* cntg = alloc(5 * GNUM);
  (void)n_in;

  if (off * sizeof(float) > ws_size) {
    // Workspace too small: emit zeros instead of faulting (diagnostic fallback).
    hipMemsetAsync(d_out, 0, (size_t)out_size * sizeof(float), stream);
    return;
  }

  auto zero = [&](void* p, size_t bytes) { hipMemsetAsync(p, 0, bytes, stream); };

  auto gemm = [&](const float* A, const float* W, float* C, const float* Cadd,
                  const float* b, int N, int relu) {
    k_gemm128<<<dim3((N + 31) / 32), dim3(256), 0, stream>>>(A, W, C, Cadd, b, N, relu);
  };
  auto rowdot = [&](const float* x, const float* a, float* o, int N) {
    k_rowdot<<<dim3((N + 3) / 4), dim3(256), 0, stream>>>(x, a, o, N);
  };
  auto do_pool = [&](const float* x, const int* b, int N, int type) {
    k_pool_scan<<<dim3((N + 255) / 256), dim3(256), 0, stream>>>(
        x, b, pool, cntg + type * GNUM, N, type * HD);
  };
  auto ew = [&](size_t elems) { return dim3((unsigned)((elems + 255) / 256)); };

  // GAT conv into acc; hs left in t1 (dead after this returns).
  auto gat = [&](const float* xs, const float* xd, const int* ei, int E,
                 int Ns, int Nd, const float* Wsm, const float* Wdm,
                 const float* avs, const float* avd) {
    zero(acc, (size_t)Nd * HD * 4);
    hipMemsetAsync(sM, 0xFF, (size_t)Nd * 4, stream);   // -NaN: any real value replaces it
    zero(sZ, (size_t)Nd * 4);
    gemm(xs, Wsm, t1, nullptr, nullptr, Ns, 0);          // hs
    rowdot(t1, avs, sAs, Ns);                            // hs . a_s
    k_matvec_right<<<1, 128, 0, stream>>>(Wdm, avd, wvec);
    rowdot(xd, wvec, sAd, Nd);                           // x_dst . (Wd@a_d)
    const int *es = ei, *ed = ei + E;
    k_gat_logit<<<ew(E), dim3(256), 0, stream>>>(es, ed, sAs, sAd, eW, sM, E);
    k_gat_exp<<<ew(E), dim3(256), 0, stream>>>(ed, eW, sM, sZ, E);
    k_gat_scatter<<<dim3((E + 1) / 2), dim3(256), 0, stream>>>(es, ed, eW, sZ, t1, acc, E);
  };

  // GCN: deg into sDeg, h into t1, scatter into acc (zeroed first iff fresh).
  auto gcn = [&](const float* x, const int* ei, int E, int N, const float* W, bool fresh) {
    zero(sDeg, (size_t)N * 4);
    k_count<<<ew(E), dim3(256), 0, stream>>>(ei + E, sDeg, E);
    gemm(x, W, t1, nullptr, nullptr, N, 0);
    if (fresh) zero(acc, (size_t)N * HD * 4);
    k_gcn_scatter<<<dim3((E + 1) / 2), dim3(256), 0, stream>>>(ei, ei + E, sDeg, t1, acc, E);
  };

  // SAGE conv -> out = relu(mean@Wl + bl + xself@Wr)
  auto sage = [&](const float* xsrc, const float* xself, const int* ei, int E, int Nd,
                  const float* Wl, const float* bl, const float* Wr, float* out) {
    zero(t1, (size_t)Nd * HD * 4);
    zero(sDeg, (size_t)Nd * 4);
    k_sage_scatter<<<dim3((E + 1) / 2), dim3(256), 0, stream>>>(ei, ei + E, xsrc, t1, E);
    k_count<<<ew(E), dim3(256), 0, stream>>>(ei + E, sDeg, E);
    k_mean_div<<<ew((size_t)Nd * HD), dim3(256), 0, stream>>>(t1, sDeg, Nd);
    gemm(t1, Wl, out, nullptr, nullptr, Nd, 0);
    gemm(xself, Wr, out, out, bl, Nd, 1);   // Cadd aliases C (safe: elementwise)
  };

  zero(pool, (size_t)GNUM * 5 * HD * 4);
  zero(cntg, 5 * GNUM * 4);

  // ---------- L1 CD: GAT(md->cd) + GCN(cd->cd) ----------
  gat(x_md, x_cd, ei_comp, E_comp, N_MD, N_CD, WLm(22, 0), WLm(23, 0), WLv(24, 0), WLv(25, 0));
  gcn(x_cd, ei_cc, E_cc, N_CD, WLm(32, 0), false);
  k_combine_gcn<<<ew((size_t)N_CD * HD), dim3(256), 0, stream>>>(
      acc, t1, sDeg, WLv(33, 0), WLv(26, 0), xcd1, N_CD);
  // ---------- L1 MD: GCN(md->md) ----------
  gcn(x_md, ei_mm, E_mm, N_MD, WLm(34, 0), true);
  k_combine_gcn<<<ew((size_t)N_MD * HD), dim3(256), 0, stream>>>(
      acc, t1, sDeg, WLv(35, 0), nullptr, xmd1, N_MD);
  // ---------- L2 CD ----------
  gat(xmd1, xcd1, ei_comp, E_comp, N_MD, N_CD, WLm(22, 1), WLm(23, 1), WLv(24, 1), WLv(25, 1));
  gcn(xcd1, ei_cc, E_cc, N_CD, WLm(32, 1), false);
  k_combine_gcn<<<ew((size_t)N_CD * HD), dim3(256), 0, stream>>>(
      acc, t1, sDeg, WLv(33, 1), WLv(26, 1), acc, N_CD);
  do_pool(acc, b_cd, N_CD, 0);
  // ---------- L2 MD ----------
  gcn(xmd1, ei_mm, E_mm, N_MD, WLm(34, 1), true);
  k_combine_gcn<<<ew((size_t)N_MD * HD), dim3(256), 0, stream>>>(
      acc, t1, sDeg, WLv(35, 1), nullptr, acc, N_MD);
  do_pool(acc, b_md, N_MD, 4);
  // ---------- SEQ: SAGE(cd->seq) L1 then L2 ----------
  sage(x_cd, x_seq, ei_seq, E_seq, N_SEQ, WLm(16, 0), WLv(17, 0), WLm(18, 0), xoth);
  sage(xcd1, xoth, ei_seq, E_seq, N_SEQ, WLm(16, 1), WLv(17, 1), WLm(18, 1), acc);
  do_pool(acc, b_seq, N_SEQ, 1);
  // ---------- ANNO: SAGE(cd->anno) L1 then L2 ----------
  sage(x_cd, x_anno, ei_anno, E_anno, N_ANNO, WLm(19, 0), WLv(20, 0), WLm(21, 0), xoth);
  sage(xcd1, xoth, ei_anno, E_anno, N_ANNO, WLm(19, 1), WLv(20, 1), WLm(21, 1), acc);
  do_pool(acc, b_anno, N_ANNO, 2);
  // ---------- RANGE: GAT(cd->range) L1 then L2 ----------
  gat(x_cd, x_range, ei_range, E_range, N_CD, N_RANGE,
      WLm(27, 0), WLm(28, 0), WLv(29, 0), WLv(30, 0));
  k_combine_bias_relu<<<ew((size_t)N_RANGE * HD), dim3(256), 0, stream>>>(
      acc, WLv(31, 0), xoth, N_RANGE);
  gat(xcd1, xoth, ei_range, E_range, N_CD, N_RANGE,
      WLm(27, 1), WLm(28, 1), WLv(29, 1), WLv(30, 1));
  k_combine_bias_relu<<<ew((size_t)N_RANGE * HD), dim3(256), 0, stream>>>(
      acc, WLv(31, 1), acc, N_RANGE);
  do_pool(acc, b_range, N_RANGE, 3);

  k_mlp<<<dim3(GNUM), dim3(128), 0, stream>>>(
      pool, cntg, fin(36), fin(37), fin(38), fin(39), (float*)d_out);
}

// Round 3
// 2539.566 us; speedup vs baseline: 1.0763x; 1.0763x over previous
//
#include <hip/hip_runtime.h>

#define HD 128
#define GNUM 512

// ======================= GEMM: C[N,128] = A[N,128] @ W[128,128] (+Cadd +bias, relu) ===
// 32 rows/block, 256 threads, W staged in LDS in two 64-row K-halves. 48KB LDS.
// NOTE: C and Cadd may alias (element is read before written by the same thread).
__global__ __launch_bounds__(256) void k_gemm128(
    const float* __restrict__ A, const float* __restrict__ W,
    float* C, const float* Cadd,
    const float* __restrict__ bias, int N, int relu)
{
  __shared__ float As[32 * 128];   // 16 KB
  __shared__ float Wk[64 * 128];   // 32 KB
  const int t = threadIdx.x;
  const int row0 = blockIdx.x * 32;

  { // stage A tile (linear float4 copy, zero-pad beyond N)
    const float4* A4 = (const float4*)(A + (size_t)row0 * 128);
    float4* As4 = (float4*)As;
    const int nrow = min(N - row0, 32);
    const int maxf4 = nrow * 32;
#pragma unroll
    for (int i = 0; i < 4; ++i) {
      int f = t + i * 256;
      float4 v = make_float4(0.f, 0.f, 0.f, 0.f);
      if (f < maxf4) v = A4[f];
      As4[f] = v;
    }
  }

  const int tx = t & 31, ty = t >> 5;
  float acc[4][4];
#pragma unroll
  for (int i = 0; i < 4; ++i)
#pragma unroll
    for (int j = 0; j < 4; ++j) acc[i][j] = 0.f;

  for (int p = 0; p < 2; ++p) {
    __syncthreads();
    { // stage W K-half: 8192 floats
      const float4* W4 = (const float4*)(W + p * 64 * 128);
      float4* Wk4 = (float4*)Wk;
#pragma unroll
      for (int i = 0; i < 8; ++i) Wk4[t + i * 256] = W4[t + i * 256];
    }
    __syncthreads();
#pragma unroll 8
    for (int k = 0; k < 64; ++k) {
      const float4 b4 = *(const float4*)(Wk + k * 128 + tx * 4);
      const int kk = p * 64 + k;
      float a[4];
#pragma unroll
      for (int i = 0; i < 4; ++i) a[i] = As[(ty * 4 + i) * 128 + kk];
#pragma unroll
      for (int i = 0; i < 4; ++i) {
        acc[i][0] = fmaf(a[i], b4.x, acc[i][0]);
        acc[i][1] = fmaf(a[i], b4.y, acc[i][1]);
        acc[i][2] = fmaf(a[i], b4.z, acc[i][2]);
        acc[i][3] = fmaf(a[i], b4.w, acc[i][3]);
      }
    }
  }

  float4 bv = make_float4(0.f, 0.f, 0.f, 0.f);
  if (bias) bv = *(const float4*)(bias + tx * 4);
#pragma unroll
  for (int i = 0; i < 4; ++i) {
    int r = row0 + ty * 4 + i;
    if (r < N) {
      size_t base = (size_t)r * 128 + tx * 4;
      float4 v = make_float4(acc[i][0], acc[i][1], acc[i][2], acc[i][3]);
      if (Cadd) {
        float4 c4 = *(const float4*)(Cadd + base);
        v.x += c4.x; v.y += c4.y; v.z += c4.z; v.w += c4.w;
      }
      if (bias) { v.x += bv.x; v.y += bv.y; v.z += bv.z; v.w += bv.w; }
      if (relu) {
        v.x = fmaxf(v.x, 0.f); v.y = fmaxf(v.y, 0.f);
        v.z = fmaxf(v.z, 0.f); v.w = fmaxf(v.w, 0.f);
      }
      *(float4*)(C + base) = v;
    }
  }
}

// ======================= row dot: out[n] = x[n,:] . a  (one wave / node) ===========
__global__ void k_rowdot(const float* __restrict__ x, const float* __restrict__ a,
                         float* __restrict__ out, int N)
{
  int wid = blockIdx.x * 4 + (threadIdx.x >> 6);
  int lane = threadIdx.x & 63;
  if (wid >= N) return;
  const float* xr = x + (size_t)wid * 128;
  float v = xr[lane] * a[lane] + xr[64 + lane] * a[64 + lane];
#pragma unroll
  for (int o = 32; o > 0; o >>= 1) v += __shfl_down(v, o);
  if (lane == 0) out[wid] = v;
}

// ======================= wvec[i] = sum_j W[i,j]*a[j]  (one block, 128 thr) =========
__global__ void k_matvec_right(const float* __restrict__ W, const float* __restrict__ a,
                               float* __restrict__ wvec)
{
  __shared__ float as[128];
  int i = threadIdx.x;
  as[i] = a[i];
  __syncthreads();
  float v = 0.f;
  for (int j = 0; j < 128; ++j) v = fmaf(W[i * 128 + j], as[j], v);
  wvec[i] = v;
}

// ======================= CSR build =======================
__global__ void k_hist(const int* __restrict__ ed, int* __restrict__ cnt, int E) {
  int e = blockIdx.x * 256 + threadIdx.x;
  if (e < E) atomicAdd(&cnt[ed[e]], 1);
}

// in-place exclusive scan of rp[0..N-1]; rp[N] = total. One block, 1024 threads.
__global__ __launch_bounds__(1024) void k_scan(int* __restrict__ rp, int N) {
  __shared__ int sums[1024];
  const int t = threadIdx.x;
  const int chunk = (N + 1023) / 1024;
  const int i0 = min(t * chunk, N), i1 = min(i0 + chunk, N);
  int s = 0;
  for (int i = i0; i < i1; ++i) s += rp[i];
  sums[t] = s;
  __syncthreads();
  for (int ofs = 1; ofs < 1024; ofs <<= 1) {
    int v = 0;
    if (t >= ofs) v = sums[t - ofs];
    __syncthreads();
    if (t >= ofs) sums[t] += v;
    __syncthreads();
  }
  int pre = sums[t] - s;   // exclusive prefix of this chunk
  for (int i = i0; i < i1; ++i) { int v = rp[i]; rp[i] = pre; pre += v; }
  if (t == 1023) rp[N] = sums[1023];
}

__global__ void k_copyint(int* __restrict__ dst, const int* __restrict__ src, int N) {
  int i = blockIdx.x * 256 + threadIdx.x;
  if (i < N) dst[i] = src[i];
}

__global__ void k_fill(const int* __restrict__ es, const int* __restrict__ ed,
                       int* __restrict__ wp, int* __restrict__ col, int E) {
  int e = blockIdx.x * 256 + threadIdx.x;
  if (e >= E) return;
  int p = atomicAdd(&wp[ed[e]], 1);
  col[p] = es[e];
}

// ======================= gather kernels (one wave per dst node) =======================
// SAGE: out[n] = mean over incident src rows.
__global__ void k_sage_gather(const int* __restrict__ rp, const int* __restrict__ col,
                              const float* __restrict__ x, float* __restrict__ out, int N)
{
  int node = blockIdx.x * 4 + (threadIdx.x >> 6);
  if (node >= N) return;
  int lane = threadIdx.x & 63;
  int s0 = rp[node], s1 = rp[node + 1];
  float a0 = 0.f, a1 = 0.f;
  for (int e = s0; e < s1; ++e) {
    const float* xr = x + (size_t)col[e] * 128;
    a0 += xr[lane]; a1 += xr[64 + lane];
  }
  float inv = 1.f / fmaxf((float)(s1 - s0), 1.f);
  size_t base = (size_t)node * 128;
  out[base + lane] = a0 * inv;
  out[base + 64 + lane] = a1 * inv;
}

// GCN fused: out[n] = relu( sum_e nrm*h[s] + r^2*h[n] + b[c] + (addin?addin[n]:0) )
// out may alias addin (elementwise same-thread read->write).
__global__ void k_gcn_gather(const int* __restrict__ rp, const int* __restrict__ col,
                             const float* __restrict__ h, const float* addin,
                             const float* __restrict__ b, float* out, int N)
{
  int node = blockIdx.x * 4 + (threadIdx.x >> 6);
  if (node >= N) return;
  int lane = threadIdx.x & 63;
  int s0 = rp[node], s1 = rp[node + 1];
  float rd = rsqrtf((float)(s1 - s0) + 1.f);
  float a0 = 0.f, a1 = 0.f;
  for (int e = s0; e < s1; ++e) {
    int s = col[e];
    float ns = rsqrtf((float)(rp[s + 1] - rp[s]) + 1.f) * rd;
    const float* hr = h + (size_t)s * 128;
    a0 = fmaf(ns, hr[lane], a0);
    a1 = fmaf(ns, hr[64 + lane], a1);
  }
  size_t base = (size_t)node * 128;
  float rr = rd * rd;
  float v0 = a0 + rr * h[base + lane] + b[lane] + (addin ? addin[base + lane] : 0.f);
  float v1 = a1 + rr * h[base + 64 + lane] + b[64 + lane] + (addin ? addin[base + 64 + lane] : 0.f);
  out[base + lane] = fmaxf(v0, 0.f);
  out[base + 64 + lane] = fmaxf(v1, 0.f);
}

// GAT fused: segment softmax + weighted gather.  out[n] = (sum_e p_e*hs[s])/z + b  (opt relu)
__global__ void k_gat_gather(const int* __restrict__ rp, const int* __restrict__ col,
                             const float* __restrict__ hs, const float* __restrict__ as_,
                             const float* __restrict__ ad_, const float* __restrict__ b,
                             float* __restrict__ out, int N, int relu)
{
  int node = blockIdx.x * 4 + (threadIdx.x >> 6);
  if (node >= N) return;
  int lane = threadIdx.x & 63;
  int s0 = rp[node], s1 = rp[node + 1];
  float adn = ad_[node];
  // pass 1: max logit (lanes strided over edges)
  float m = -1e30f;
  for (int e = s0 + lane; e < s1; e += 64) {
    float v = as_[col[e]] + adn;
    v = v > 0.f ? v : 0.2f * v;
    m = fmaxf(m, v);
  }
#pragma unroll
  for (int o = 32; o > 0; o >>= 1) m = fmaxf(m, __shfl_xor(m, o));
  // pass 2: z
  float z = 0.f;
  for (int e = s0 + lane; e < s1; e += 64) {
    float v = as_[col[e]] + adn;
    v = v > 0.f ? v : 0.2f * v;
    z += expf(v - m);
  }
#pragma unroll
  for (int o = 32; o > 0; o >>= 1) z += __shfl_xor(z, o);
  // pass 3: accumulate p_e * hs[s]
  float a0 = 0.f, a1 = 0.f;
  for (int e = s0; e < s1; ++e) {
    int s = col[e];
    float v = as_[s] + adn;
    v = v > 0.f ? v : 0.2f * v;
    float p = expf(v - m);
    const float* hr = hs + (size_t)s * 128;
    a0 = fmaf(p, hr[lane], a0);
    a1 = fmaf(p, hr[64 + lane], a1);
  }
  float inv = z > 0.f ? 1.f / z : 0.f;   // z >= 1 whenever deg > 0
  float v0 = a0 * inv + b[lane];
  float v1 = a1 * inv + b[64 + lane];
  if (relu) { v0 = fmaxf(v0, 0.f); v1 = fmaxf(v1, 0.f); }
  size_t base = (size_t)node * 128;
  out[base + lane] = v0;
  out[base + 64 + lane] = v1;
}

// ======================= pooling (b sorted -> run-length + atomics) ================
__global__ void k_pool_scan(const float* __restrict__ x, const int* __restrict__ b,
                            float* __restrict__ pool, float* __restrict__ cntg,
                            int N, int col_off)
{
  const int t = threadIdx.x;
  const int c = t & 127;
  const int half = t >> 7;
  const int n0 = blockIdx.x * 256 + half * 128;
  if (n0 >= N) return;
  const int n1 = min(n0 + 128, N);
  float accum = 0.f;
  int cur = b[n0];
  int len = 0;
  for (int n = n0; n < n1; ++n) {
    int g = b[n];
    if (g != cur) {
      atomicAdd(&pool[(size_t)cur * 640 + col_off + c], accum);
      if (c == 0) atomicAdd(&cntg[cur], (float)len);
      accum = 0.f; len = 0; cur = g;
    }
    accum += x[(size_t)n * 128 + c];
    ++len;
  }
  atomicAdd(&pool[(size_t)cur * 640 + col_off + c], accum);
  if (c == 0) atomicAdd(&cntg[cur], (float)len);
}

// ======================= final MLP (one block per graph) =======================
__global__ void k_mlp(const float* __restrict__ pool, const float* __restrict__ cntg,
                      const float* __restrict__ W1, const float* __restrict__ b1,
                      const float* __restrict__ W2, const float* __restrict__ b2,
                      float* __restrict__ out)
{
  __shared__ float emb[640];
  __shared__ float red[128];
  const int g = blockIdx.x, t = threadIdx.x;
  for (int i = t; i < 640; i += 128) {
    int type = i >> 7;
    float cnt = cntg[type * GNUM + g];
    emb[i] = pool[(size_t)g * 640 + i] / fmaxf(cnt, 1.f);
  }
  __syncthreads();
  float acc = b1[t];
  for (int i = 0; i < 640; ++i) acc = fmaf(emb[i], W1[i * 128 + t], acc);
  float h = fmaxf(acc, 0.f);
  red[t] = h * W2[t];
  __syncthreads();
  for (int s = 64; s > 0; s >>= 1) {
    if (t < s) red[t] += red[t + s];
    __syncthreads();
  }
  if (t == 0) out[g] = red[0] + b2[0];
}

// ======================= host =======================
extern "C" void kernel_launch(void* const* d_in, const int* in_sizes, int n_in,
                              void* d_out, int out_size, void* d_ws, size_t ws_size,
                              hipStream_t stream)
{
  auto fin = [&](int i) { return (const float*)d_in[i]; };
  auto iin = [&](int i) { return (const int*)d_in[i]; };

  const float *x_cd = fin(0), *x_seq = fin(1), *x_anno = fin(2), *x_range = fin(3), *x_md = fin(4);
  const int *ei_seq = iin(5), *ei_anno = iin(6), *ei_range = iin(7),
            *ei_comp = iin(8), *ei_cc = iin(9), *ei_mm = iin(10);
  const int *b_cd = iin(11), *b_seq = iin(12), *b_anno = iin(13), *b_range = iin(14), *b_md = iin(15);

  const int N_CD = in_sizes[0] / HD, N_SEQ = in_sizes[1] / HD, N_ANNO = in_sizes[2] / HD,
            N_RANGE = in_sizes[3] / HD, N_MD = in_sizes[4] / HD;
  const int E_seq = in_sizes[5] / 2, E_anno = in_sizes[6] / 2, E_range = in_sizes[7] / 2,
            E_comp = in_sizes[8] / 2, E_cc = in_sizes[9] / 2, E_mm = in_sizes[10] / 2;
  const int N_OTH = max(max(N_SEQ, N_ANNO), N_RANGE);
  const int N_MAXD = max(N_CD, N_OTH);

  auto WLm = [&](int i, int l) { return fin(i) + (size_t)l * HD * HD; };
  auto WLv = [&](int i, int l) { return fin(i) + (size_t)l * HD; };

  // ---- workspace layout ----
  float* ws = (float*)d_ws;
  size_t off = 0;
  auto alloc = [&](size_t n) { float* p = ws + off; off += (n + 3) & ~(size_t)3; return p; };
  float* xcd1 = alloc((size_t)N_CD * HD);
  float* xmd1 = alloc((size_t)N_MD * HD);
  float* xoth = alloc((size_t)N_OTH * HD);
  float* acc  = alloc((size_t)N_CD * HD);
  float* t1   = alloc((size_t)N_CD * HD);
  float* sAs  = alloc((size_t)N_CD);
  float* sAd  = alloc((size_t)N_CD);
  float* wvec = alloc(HD);
  float* pool = alloc((size_t)GNUM * 5 * HD);
  float* cntg = alloc(5 * GNUM);
  // int region (CSR): 6 types
  auto alloci = [&](size_t n) { int* p = (int*)(ws + off); off += (n + 3) & ~(size_t)3; return p; };
  int* wp = alloci((size_t)N_MAXD);   // shared fill cursor
  int *rp_seq = alloci((size_t)N_SEQ + 1),  *col_seq = alloci((size_t)E_seq);
  int *rp_anno = alloci((size_t)N_ANNO + 1), *col_anno = alloci((size_t)E_anno);
  int *rp_range = alloci((size_t)N_RANGE + 1), *col_range = alloci((size_t)E_range);
  int *rp_comp = alloci((size_t)N_CD + 1),  *col_comp = alloci((size_t)E_comp);
  int *rp_cc = alloci((size_t)N_CD + 1),    *col_cc = alloci((size_t)E_cc);
  int *rp_mm = alloci((size_t)N_MD + 1),    *col_mm = alloci((size_t)E_mm);
  (void)n_in;

  if (off * sizeof(float) > ws_size) {
    hipMemsetAsync(d_out, 0, (size_t)out_size * sizeof(float), stream);
    return;
  }

  auto ew = [&](size_t elems) { return dim3((unsigned)((elems + 255) / 256)); };
  auto nw = [&](int N) { return dim3((unsigned)((N + 3) / 4)); };   // wave-per-node grids

  auto gemm = [&](const float* A, const float* W, float* C, const float* Cadd,
                  const float* b, int N, int relu) {
    k_gemm128<<<dim3((N + 31) / 32), dim3(256), 0, stream>>>(A, W, C, Cadd, b, N, relu);
  };
  auto rowdot = [&](const float* x, const float* a, float* o, int N) {
    k_rowdot<<<nw(N), dim3(256), 0, stream>>>(x, a, o, N);
  };
  auto do_pool = [&](const float* x, const int* b, int N, int type) {
    k_pool_scan<<<ew(N), dim3(256), 0, stream>>>(x, b, pool, cntg + type * GNUM, N, type * HD);
  };

  // ---- build all CSRs once ----
  auto build = [&](const int* ei, int E, int Nd, int* rp, int* col) {
    hipMemsetAsync(rp, 0, ((size_t)Nd + 1) * 4, stream);
    k_hist<<<ew(E), dim3(256), 0, stream>>>(ei + E, rp, E);
    k_scan<<<dim3(1), dim3(1024), 0, stream>>>(rp, Nd);
    k_copyint<<<ew(Nd), dim3(256), 0, stream>>>(wp, rp, Nd);
    k_fill<<<ew(E), dim3(256), 0, stream>>>(ei, ei + E, wp, col, E);
  };
  build(ei_seq, E_seq, N_SEQ, rp_seq, col_seq);
  build(ei_anno, E_anno, N_ANNO, rp_anno, col_anno);
  build(ei_range, E_range, N_RANGE, rp_range, col_range);
  build(ei_comp, E_comp, N_CD, rp_comp, col_comp);
  build(ei_cc, E_cc, N_CD, rp_cc, col_cc);
  build(ei_mm, E_mm, N_MD, rp_mm, col_mm);

  // GAT: hs -> t1, attention scalars -> sAs/sAd, fused gather -> out
  auto gat = [&](const float* xs, const float* xd, const int* rp, const int* col,
                 int Ns, int Nd, const float* Wsm, const float* Wdm,
                 const float* avs, const float* avd, const float* bias,
                 float* out, int relu) {
    gemm(xs, Wsm, t1, nullptr, nullptr, Ns, 0);          // hs
    rowdot(t1, avs, sAs, Ns);                            // hs . a_s
    k_matvec_right<<<dim3(1), dim3(128), 0, stream>>>(Wdm, avd, wvec);
    rowdot(xd, wvec, sAd, Nd);                           // x_dst . (Wd@a_d)
    k_gat_gather<<<nw(Nd), dim3(256), 0, stream>>>(rp, col, t1, sAs, sAd, bias, out, Nd, relu);
  };
  // GCN fused: h -> t1, gather(+self+bias+addin+relu) -> out
  auto gcn = [&](const float* x, const int* rp, const int* col, int N,
                 const float* W, const float* b, const float* addin, float* out) {
    gemm(x, W, t1, nullptr, nullptr, N, 0);
    k_gcn_gather<<<nw(N), dim3(256), 0, stream>>>(rp, col, t1, addin, b, out, N);
  };
  // SAGE: mean -> t1, out = relu(t1@Wl + bl + xself@Wr)
  auto sage = [&](const float* xsrc, const float* xself, const int* rp, const int* col,
                  int Nd, const float* Wl, const float* bl, const float* Wr, float* out) {
    k_sage_gather<<<nw(Nd), dim3(256), 0, stream>>>(rp, col, xsrc, t1, Nd);
    gemm(t1, Wl, out, nullptr, nullptr, Nd, 0);
    gemm(xself, Wr, out, out, bl, Nd, 1);
  };

  hipMemsetAsync(pool, 0, (size_t)GNUM * 5 * HD * 4, stream);
  hipMemsetAsync(cntg, 0, 5 * GNUM * 4, stream);

  // ---------- CD + MD, both layers ----------
  // L1 CD: GAT(md->cd) -> acc (bias, no relu), then GCN(cc) fused-add -> xcd1
  gat(x_md, x_cd, rp_comp, col_comp, N_MD, N_CD,
      WLm(22, 0), WLm(23, 0), WLv(24, 0), WLv(25, 0), WLv(26, 0), acc, 0);
  gcn(x_cd, rp_cc, col_cc, N_CD, WLm(32, 0), WLv(33, 0), acc, xcd1);
  // L1 MD: GCN(mm) -> xmd1
  gcn(x_md, rp_mm, col_mm, N_MD, WLm(34, 0), WLv(35, 0), nullptr, xmd1);
  // L2 CD
  gat(xmd1, xcd1, rp_comp, col_comp, N_MD, N_CD,
      WLm(22, 1), WLm(23, 1), WLv(24, 1), WLv(25, 1), WLv(26, 1), acc, 0);
  gcn(xcd1, rp_cc, col_cc, N_CD, WLm(32, 1), WLv(33, 1), acc, acc);
  do_pool(acc, b_cd, N_CD, 0);
  // L2 MD
  gcn(xmd1, rp_mm, col_mm, N_MD, WLm(34, 1), WLv(35, 1), nullptr, acc);
  do_pool(acc, b_md, N_MD, 4);

  // ---------- SEQ ----------
  sage(x_cd, x_seq, rp_seq, col_seq, N_SEQ, WLm(16, 0), WLv(17, 0), WLm(18, 0), xoth);
  sage(xcd1, xoth, rp_seq, col_seq, N_SEQ, WLm(16, 1), WLv(17, 1), WLm(18, 1), acc);
  do_pool(acc, b_seq, N_SEQ, 1);
  // ---------- ANNO ----------
  sage(x_cd, x_anno, rp_anno, col_anno, N_ANNO, WLm(19, 0), WLv(20, 0), WLm(21, 0), xoth);
  sage(xcd1, xoth, rp_anno, col_anno, N_ANNO, WLm(19, 1), WLv(20, 1), WLm(21, 1), acc);
  do_pool(acc, b_anno, N_ANNO, 2);
  // ---------- RANGE ----------
  gat(x_cd, x_range, rp_range, col_range, N_CD, N_RANGE,
      WLm(27, 0), WLm(28, 0), WLv(29, 0), WLv(30, 0), WLv(31, 0), xoth, 1);
  gat(xcd1, xoth, rp_range, col_range, N_CD, N_RANGE,
      WLm(27, 1), WLm(28, 1), WLv(29, 1), WLv(30, 1), WLv(31, 1), acc, 1);
  do_pool(acc, b_range, N_RANGE, 3);

  k_mlp<<<dim3(GNUM), dim3(128), 0, stream>>>(
      pool, cntg, fin(36), fin(37), fin(38), fin(39), (float*)d_out);
}

// Round 4
// 1856.406 us; speedup vs baseline: 1.4724x; 1.3680x over previous
//
#include <hip/hip_runtime.h>

#define HD 128
#define GNUM 512

// ======================= GEMM: C[N,128] = A[N,128] @ W[128,128] (+Cadd +bias, relu) ===
// 32 rows/block, 256 threads, W staged in LDS in two 64-row K-halves. 48KB LDS.
// NOTE: C and Cadd may alias (element is read before written by the same thread).
__global__ __launch_bounds__(256) void k_gemm128(
    const float* __restrict__ A, const float* __restrict__ W,
    float* C, const float* Cadd,
    const float* __restrict__ bias, int N, int relu)
{
  __shared__ float As[32 * 128];   // 16 KB
  __shared__ float Wk[64 * 128];   // 32 KB
  const int t = threadIdx.x;
  const int row0 = blockIdx.x * 32;

  { // stage A tile (linear float4 copy, zero-pad beyond N)
    const float4* A4 = (const float4*)(A + (size_t)row0 * 128);
    float4* As4 = (float4*)As;
    const int nrow = min(N - row0, 32);
    const int maxf4 = nrow * 32;
#pragma unroll
    for (int i = 0; i < 4; ++i) {
      int f = t + i * 256;
      float4 v = make_float4(0.f, 0.f, 0.f, 0.f);
      if (f < maxf4) v = A4[f];
      As4[f] = v;
    }
  }

  const int tx = t & 31, ty = t >> 5;
  float acc[4][4];
#pragma unroll
  for (int i = 0; i < 4; ++i)
#pragma unroll
    for (int j = 0; j < 4; ++j) acc[i][j] = 0.f;

  for (int p = 0; p < 2; ++p) {
    __syncthreads();
    { // stage W K-half: 8192 floats
      const float4* W4 = (const float4*)(W + p * 64 * 128);
      float4* Wk4 = (float4*)Wk;
#pragma unroll
      for (int i = 0; i < 8; ++i) Wk4[t + i * 256] = W4[t + i * 256];
    }
    __syncthreads();
#pragma unroll 8
    for (int k = 0; k < 64; ++k) {
      const float4 b4 = *(const float4*)(Wk + k * 128 + tx * 4);
      const int kk = p * 64 + k;
      float a[4];
#pragma unroll
      for (int i = 0; i < 4; ++i) a[i] = As[(ty * 4 + i) * 128 + kk];
#pragma unroll
      for (int i = 0; i < 4; ++i) {
        acc[i][0] = fmaf(a[i], b4.x, acc[i][0]);
        acc[i][1] = fmaf(a[i], b4.y, acc[i][1]);
        acc[i][2] = fmaf(a[i], b4.z, acc[i][2]);
        acc[i][3] = fmaf(a[i], b4.w, acc[i][3]);
      }
    }
  }

  float4 bv = make_float4(0.f, 0.f, 0.f, 0.f);
  if (bias) bv = *(const float4*)(bias + tx * 4);
#pragma unroll
  for (int i = 0; i < 4; ++i) {
    int r = row0 + ty * 4 + i;
    if (r < N) {
      size_t base = (size_t)r * 128 + tx * 4;
      float4 v = make_float4(acc[i][0], acc[i][1], acc[i][2], acc[i][3]);
      if (Cadd) {
        float4 c4 = *(const float4*)(Cadd + base);
        v.x += c4.x; v.y += c4.y; v.z += c4.z; v.w += c4.w;
      }
      if (bias) { v.x += bv.x; v.y += bv.y; v.z += bv.z; v.w += bv.w; }
      if (relu) {
        v.x = fmaxf(v.x, 0.f); v.y = fmaxf(v.y, 0.f);
        v.z = fmaxf(v.z, 0.f); v.w = fmaxf(v.w, 0.f);
      }
      *(float4*)(C + base) = v;
    }
  }
}

// ======================= row dot: out[n] = x[n,:] . a  (one wave / node) ===========
__global__ void k_rowdot(const float* __restrict__ x, const float* __restrict__ a,
                         float* __restrict__ out, int N)
{
  int wid = blockIdx.x * 4 + (threadIdx.x >> 6);
  int lane = threadIdx.x & 63;
  if (wid >= N) return;
  const float* xr = x + (size_t)wid * 128;
  float v = xr[lane] * a[lane] + xr[64 + lane] * a[64 + lane];
#pragma unroll
  for (int o = 32; o > 0; o >>= 1) v += __shfl_down(v, o);
  if (lane == 0) out[wid] = v;
}

// ======================= wvec[i] = sum_j W[i,j]*a[j]  (one block, 128 thr) =========
__global__ void k_matvec_right(const float* __restrict__ W, const float* __restrict__ a,
                               float* __restrict__ wvec)
{
  __shared__ float as[128];
  int i = threadIdx.x;
  as[i] = a[i];
  __syncthreads();
  float v = 0.f;
  for (int j = 0; j < 128; ++j) v = fmaf(W[i * 128 + j], as[j], v);
  wvec[i] = v;
}

// ======================= CSR build =======================
__global__ void k_hist(const int* __restrict__ ed, int* __restrict__ cnt, int E) {
  int e = blockIdx.x * 256 + threadIdx.x;
  if (e < E) atomicAdd(&cnt[ed[e]], 1);
}

// ---- 3-phase multi-block exclusive scan (tile = 4096 = 256 thr x 16) ----
__global__ __launch_bounds__(256) void k_scan_partial(
    const int* __restrict__ rp, int* __restrict__ bsums, int N)
{
  __shared__ int red[256];
  const int t = threadIdx.x, base = blockIdx.x * 4096;
  int s = 0;
  for (int i = t; i < 4096; i += 256) {
    int idx = base + i;
    if (idx < N) s += rp[idx];
  }
  red[t] = s;
  __syncthreads();
  for (int ofs = 128; ofs > 0; ofs >>= 1) {
    if (t < ofs) red[t] += red[t + ofs];
    __syncthreads();
  }
  if (t == 0) bsums[blockIdx.x] = red[0];
}

// single small block: exclusive-scan bsums[0..nb), write total to rpN.
__global__ __launch_bounds__(1024) void k_scan_bsums(
    int* __restrict__ bsums, int nb, int* __restrict__ rpN)
{
  __shared__ int sh[1024];
  const int t = threadIdx.x;
  int v = (t < nb) ? bsums[t] : 0;
  sh[t] = v;
  __syncthreads();
  for (int ofs = 1; ofs < 1024; ofs <<= 1) {
    int u = (t >= ofs) ? sh[t - ofs] : 0;
    __syncthreads();
    sh[t] += u;
    __syncthreads();
  }
  if (t < nb) bsums[t] = sh[t] - v;      // exclusive
  if (t == 1023) rpN[0] = sh[1023];      // total
}

__global__ __launch_bounds__(256) void k_scan_final(
    int* __restrict__ rp, const int* __restrict__ bsums, int N)
{
  __shared__ int sh[4096 + 256];         // padded: i -> i + (i>>4), conflict-free
  __shared__ int tsum[256];
  const int t = threadIdx.x, base = blockIdx.x * 4096;
  auto mp = [](int i) { return i + (i >> 4); };
#pragma unroll
  for (int i = 0; i < 16; ++i) {
    int idx = base + i * 256 + t;
    sh[mp(i * 256 + t)] = (idx < N) ? rp[idx] : 0;
  }
  __syncthreads();
  int s = 0;
#pragma unroll
  for (int j = 0; j < 16; ++j) s += sh[mp(t * 16 + j)];
  tsum[t] = s;
  __syncthreads();
  for (int ofs = 1; ofs < 256; ofs <<= 1) {
    int u = (t >= ofs) ? tsum[t - ofs] : 0;
    __syncthreads();
    tsum[t] += u;
    __syncthreads();
  }
  int pre = tsum[t] - s + bsums[blockIdx.x];
#pragma unroll
  for (int j = 0; j < 16; ++j) {
    int v = sh[mp(t * 16 + j)];
    sh[mp(t * 16 + j)] = pre;
    pre += v;
  }
  __syncthreads();
#pragma unroll
  for (int i = 0; i < 16; ++i) {
    int idx = base + i * 256 + t;
    if (idx < N) rp[idx] = sh[mp(i * 256 + t)];
  }
}

__global__ void k_copyint(int* __restrict__ dst, const int* __restrict__ src, int N) {
  int i = blockIdx.x * 256 + threadIdx.x;
  if (i < N) dst[i] = src[i];
}

__global__ void k_fill(const int* __restrict__ es, const int* __restrict__ ed,
                       int* __restrict__ wp, int* __restrict__ col, int E) {
  int e = blockIdx.x * 256 + threadIdx.x;
  if (e >= E) return;
  int p = atomicAdd(&wp[ed[e]], 1);
  col[p] = es[e];
}

// ======================= gather kernels (one wave per dst node) =======================
// SAGE: out[n] = mean over incident src rows.
__global__ void k_sage_gather(const int* __restrict__ rp, const int* __restrict__ col,
                              const float* __restrict__ x, float* __restrict__ out, int N)
{
  int node = blockIdx.x * 4 + (threadIdx.x >> 6);
  if (node >= N) return;
  int lane = threadIdx.x & 63;
  int s0 = rp[node], s1 = rp[node + 1];
  float a0 = 0.f, a1 = 0.f;
  for (int e = s0; e < s1; ++e) {
    const float* xr = x + (size_t)col[e] * 128;
    a0 += xr[lane]; a1 += xr[64 + lane];
  }
  float inv = 1.f / fmaxf((float)(s1 - s0), 1.f);
  size_t base = (size_t)node * 128;
  out[base + lane] = a0 * inv;
  out[base + 64 + lane] = a1 * inv;
}

// GCN fused: out[n] = relu( sum_e nrm*h[s] + r^2*h[n] + b[c] + (addin?addin[n]:0) )
// out may alias addin (elementwise same-thread read->write).
__global__ void k_gcn_gather(const int* __restrict__ rp, const int* __restrict__ col,
                             const float* __restrict__ h, const float* addin,
                             const float* __restrict__ b, float* out, int N)
{
  int node = blockIdx.x * 4 + (threadIdx.x >> 6);
  if (node >= N) return;
  int lane = threadIdx.x & 63;
  int s0 = rp[node], s1 = rp[node + 1];
  float rd = rsqrtf((float)(s1 - s0) + 1.f);
  float a0 = 0.f, a1 = 0.f;
  for (int e = s0; e < s1; ++e) {
    int s = col[e];
    float ns = rsqrtf((float)(rp[s + 1] - rp[s]) + 1.f) * rd;
    const float* hr = h + (size_t)s * 128;
    a0 = fmaf(ns, hr[lane], a0);
    a1 = fmaf(ns, hr[64 + lane], a1);
  }
  size_t base = (size_t)node * 128;
  float rr = rd * rd;
  float v0 = a0 + rr * h[base + lane] + b[lane] + (addin ? addin[base + lane] : 0.f);
  float v1 = a1 + rr * h[base + 64 + lane] + b[64 + lane] + (addin ? addin[base + 64 + lane] : 0.f);
  out[base + lane] = fmaxf(v0, 0.f);
  out[base + 64 + lane] = fmaxf(v1, 0.f);
}

// GAT fused: segment softmax + weighted gather.  out[n] = (sum_e p_e*hs[s])/z + b  (opt relu)
__global__ void k_gat_gather(const int* __restrict__ rp, const int* __restrict__ col,
                             const float* __restrict__ hs, const float* __restrict__ as_,
                             const float* __restrict__ ad_, const float* __restrict__ b,
                             float* __restrict__ out, int N, int relu)
{
  int node = blockIdx.x * 4 + (threadIdx.x >> 6);
  if (node >= N) return;
  int lane = threadIdx.x & 63;
  int s0 = rp[node], s1 = rp[node + 1];
  float adn = ad_[node];
  float m = -1e30f;
  for (int e = s0 + lane; e < s1; e += 64) {
    float v = as_[col[e]] + adn;
    v = v > 0.f ? v : 0.2f * v;
    m = fmaxf(m, v);
  }
#pragma unroll
  for (int o = 32; o > 0; o >>= 1) m = fmaxf(m, __shfl_xor(m, o));
  float z = 0.f;
  for (int e = s0 + lane; e < s1; e += 64) {
    float v = as_[col[e]] + adn;
    v = v > 0.f ? v : 0.2f * v;
    z += expf(v - m);
  }
#pragma unroll
  for (int o = 32; o > 0; o >>= 1) z += __shfl_xor(z, o);
  float a0 = 0.f, a1 = 0.f;
  for (int e = s0; e < s1; ++e) {
    int s = col[e];
    float v = as_[s] + adn;
    v = v > 0.f ? v : 0.2f * v;
    float p = expf(v - m);
    const float* hr = hs + (size_t)s * 128;
    a0 = fmaf(p, hr[lane], a0);
    a1 = fmaf(p, hr[64 + lane], a1);
  }
  float inv = z > 0.f ? 1.f / z : 0.f;
  float v0 = a0 * inv + b[lane];
  float v1 = a1 * inv + b[64 + lane];
  if (relu) { v0 = fmaxf(v0, 0.f); v1 = fmaxf(v1, 0.f); }
  size_t base = (size_t)node * 128;
  out[base + lane] = v0;
  out[base + 64 + lane] = v1;
}

// ======================= pooling (b sorted -> run-length + atomics) ================
__global__ void k_pool_scan(const float* __restrict__ x, const int* __restrict__ b,
                            float* __restrict__ pool, float* __restrict__ cntg,
                            int N, int col_off)
{
  const int t = threadIdx.x;
  const int c = t & 127;
  const int half = t >> 7;
  const int n0 = blockIdx.x * 256 + half * 128;
  if (n0 >= N) return;
  const int n1 = min(n0 + 128, N);
  float accum = 0.f;
  int cur = b[n0];
  int len = 0;
  for (int n = n0; n < n1; ++n) {
    int g = b[n];
    if (g != cur) {
      atomicAdd(&pool[(size_t)cur * 640 + col_off + c], accum);
      if (c == 0) atomicAdd(&cntg[cur], (float)len);
      accum = 0.f; len = 0; cur = g;
    }
    accum += x[(size_t)n * 128 + c];
    ++len;
  }
  atomicAdd(&pool[(size_t)cur * 640 + col_off + c], accum);
  if (c == 0) atomicAdd(&cntg[cur], (float)len);
}

// ======================= final MLP (one block per graph) =======================
__global__ void k_mlp(const float* __restrict__ pool, const float* __restrict__ cntg,
                      const float* __restrict__ W1, const float* __restrict__ b1,
                      const float* __restrict__ W2, const float* __restrict__ b2,
                      float* __restrict__ out)
{
  __shared__ float emb[640];
  __shared__ float red[128];
  const int g = blockIdx.x, t = threadIdx.x;
  for (int i = t; i < 640; i += 128) {
    int type = i >> 7;
    float cnt = cntg[type * GNUM + g];
    emb[i] = pool[(size_t)g * 640 + i] / fmaxf(cnt, 1.f);
  }
  __syncthreads();
  float acc = b1[t];
  for (int i = 0; i < 640; ++i) acc = fmaf(emb[i], W1[i * 128 + t], acc);
  float h = fmaxf(acc, 0.f);
  red[t] = h * W2[t];
  __syncthreads();
  for (int s = 64; s > 0; s >>= 1) {
    if (t < s) red[t] += red[t + s];
    __syncthreads();
  }
  if (t == 0) out[g] = red[0] + b2[0];
}

// ======================= host =======================
extern "C" void kernel_launch(void* const* d_in, const int* in_sizes, int n_in,
                              void* d_out, int out_size, void* d_ws, size_t ws_size,
                              hipStream_t stream)
{
  auto fin = [&](int i) { return (const float*)d_in[i]; };
  auto iin = [&](int i) { return (const int*)d_in[i]; };

  const float *x_cd = fin(0), *x_seq = fin(1), *x_anno = fin(2), *x_range = fin(3), *x_md = fin(4);
  const int *ei_seq = iin(5), *ei_anno = iin(6), *ei_range = iin(7),
            *ei_comp = iin(8), *ei_cc = iin(9), *ei_mm = iin(10);
  const int *b_cd = iin(11), *b_seq = iin(12), *b_anno = iin(13), *b_range = iin(14), *b_md = iin(15);

  const int N_CD = in_sizes[0] / HD, N_SEQ = in_sizes[1] / HD, N_ANNO = in_sizes[2] / HD,
            N_RANGE = in_sizes[3] / HD, N_MD = in_sizes[4] / HD;
  const int E_seq = in_sizes[5] / 2, E_anno = in_sizes[6] / 2, E_range = in_sizes[7] / 2,
            E_comp = in_sizes[8] / 2, E_cc = in_sizes[9] / 2, E_mm = in_sizes[10] / 2;
  const int N_OTH = max(max(N_SEQ, N_ANNO), N_RANGE);
  const int N_MAXD = max(N_CD, N_OTH);

  auto WLm = [&](int i, int l) { return fin(i) + (size_t)l * HD * HD; };
  auto WLv = [&](int i, int l) { return fin(i) + (size_t)l * HD; };

  // ---- workspace layout ----
  float* ws = (float*)d_ws;
  size_t off = 0;
  auto alloc = [&](size_t n) { float* p = ws + off; off += (n + 3) & ~(size_t)3; return p; };
  float* xcd1 = alloc((size_t)N_CD * HD);
  float* xmd1 = alloc((size_t)N_MD * HD);
  float* xoth = alloc((size_t)N_OTH * HD);
  float* acc  = alloc((size_t)N_CD * HD);
  float* t1   = alloc((size_t)N_CD * HD);
  float* sAs  = alloc((size_t)N_CD);
  float* sAd  = alloc((size_t)N_CD);
  float* wvec = alloc(HD);
  float* pool = alloc((size_t)GNUM * 5 * HD);
  float* cntg = alloc(5 * GNUM);
  auto alloci = [&](size_t n) { int* p = (int*)(ws + off); off += (n + 3) & ~(size_t)3; return p; };
  int* wp = alloci((size_t)N_MAXD);      // shared fill cursor
  int* bsums = alloci(1024);             // scan partials
  int *rp_seq = alloci((size_t)N_SEQ + 1),  *col_seq = alloci((size_t)E_seq);
  int *rp_anno = alloci((size_t)N_ANNO + 1), *col_anno = alloci((size_t)E_anno);
  int *rp_range = alloci((size_t)N_RANGE + 1), *col_range = alloci((size_t)E_range);
  int *rp_comp = alloci((size_t)N_CD + 1),  *col_comp = alloci((size_t)E_comp);
  int *rp_cc = alloci((size_t)N_CD + 1),    *col_cc = alloci((size_t)E_cc);
  int *rp_mm = alloci((size_t)N_MD + 1),    *col_mm = alloci((size_t)E_mm);
  (void)n_in;

  if (off * sizeof(float) > ws_size) {
    hipMemsetAsync(d_out, 0, (size_t)out_size * sizeof(float), stream);
    return;
  }

  auto ew = [&](size_t elems) { return dim3((unsigned)((elems + 255) / 256)); };
  auto nw = [&](int N) { return dim3((unsigned)((N + 3) / 4)); };   // wave-per-node grids

  auto gemm = [&](const float* A, const float* W, float* C, const float* Cadd,
                  const float* b, int N, int relu) {
    k_gemm128<<<dim3((N + 31) / 32), dim3(256), 0, stream>>>(A, W, C, Cadd, b, N, relu);
  };
  auto rowdot = [&](const float* x, const float* a, float* o, int N) {
    k_rowdot<<<nw(N), dim3(256), 0, stream>>>(x, a, o, N);
  };
  auto do_pool = [&](const float* x, const int* b, int N, int type) {
    k_pool_scan<<<ew(N), dim3(256), 0, stream>>>(x, b, pool, cntg + type * GNUM, N, type * HD);
  };

  // ---- build all CSRs once (multi-block scan) ----
  auto build = [&](const int* ei, int E, int Nd, int* rp, int* col) {
    hipMemsetAsync(rp, 0, ((size_t)Nd + 1) * 4, stream);
    k_hist<<<ew(E), dim3(256), 0, stream>>>(ei + E, rp, E);
    int nb = (Nd + 4095) / 4096;
    k_scan_partial<<<dim3(nb), dim3(256), 0, stream>>>(rp, bsums, Nd);
    k_scan_bsums<<<dim3(1), dim3(1024), 0, stream>>>(bsums, nb, rp + Nd);
    k_scan_final<<<dim3(nb), dim3(256), 0, stream>>>(rp, bsums, Nd);
    k_copyint<<<ew(Nd), dim3(256), 0, stream>>>(wp, rp, Nd);
    k_fill<<<ew(E), dim3(256), 0, stream>>>(ei, ei + E, wp, col, E);
  };
  build(ei_seq, E_seq, N_SEQ, rp_seq, col_seq);
  build(ei_anno, E_anno, N_ANNO, rp_anno, col_anno);
  build(ei_range, E_range, N_RANGE, rp_range, col_range);
  build(ei_comp, E_comp, N_CD, rp_comp, col_comp);
  build(ei_cc, E_cc, N_CD, rp_cc, col_cc);
  build(ei_mm, E_mm, N_MD, rp_mm, col_mm);

  // GAT: hs -> t1, attention scalars -> sAs/sAd, fused gather -> out
  auto gat = [&](const float* xs, const float* xd, const int* rp, const int* col,
                 int Ns, int Nd, const float* Wsm, const float* Wdm,
                 const float* avs, const float* avd, const float* bias,
                 float* out, int relu) {
    gemm(xs, Wsm, t1, nullptr, nullptr, Ns, 0);          // hs
    rowdot(t1, avs, sAs, Ns);                            // hs . a_s
    k_matvec_right<<<dim3(1), dim3(128), 0, stream>>>(Wdm, avd, wvec);
    rowdot(xd, wvec, sAd, Nd);                           // x_dst . (Wd@a_d)
    k_gat_gather<<<nw(Nd), dim3(256), 0, stream>>>(rp, col, t1, sAs, sAd, bias, out, Nd, relu);
  };
  // GCN fused: h -> t1, gather(+self+bias+addin+relu) -> out
  auto gcn = [&](const float* x, const int* rp, const int* col, int N,
                 const float* W, const float* b, const float* addin, float* out) {
    gemm(x, W, t1, nullptr, nullptr, N, 0);
    k_gcn_gather<<<nw(N), dim3(256), 0, stream>>>(rp, col, t1, addin, b, out, N);
  };
  // SAGE: mean -> t1, out = relu(t1@Wl + bl + xself@Wr)
  auto sage = [&](const float* xsrc, const float* xself, const int* rp, const int* col,
                  int Nd, const float* Wl, const float* bl, const float* Wr, float* out) {
    k_sage_gather<<<nw(Nd), dim3(256), 0, stream>>>(rp, col, xsrc, t1, Nd);
    gemm(t1, Wl, out, nullptr, nullptr, Nd, 0);
    gemm(xself, Wr, out, out, bl, Nd, 1);
  };

  hipMemsetAsync(pool, 0, (size_t)GNUM * 5 * HD * 4, stream);
  hipMemsetAsync(cntg, 0, 5 * GNUM * 4, stream);

  // ---------- CD + MD, both layers ----------
  gat(x_md, x_cd, rp_comp, col_comp, N_MD, N_CD,
      WLm(22, 0), WLm(23, 0), WLv(24, 0), WLv(25, 0), WLv(26, 0), acc, 0);
  gcn(x_cd, rp_cc, col_cc, N_CD, WLm(32, 0), WLv(33, 0), acc, xcd1);
  gcn(x_md, rp_mm, col_mm, N_MD, WLm(34, 0), WLv(35, 0), nullptr, xmd1);
  gat(xmd1, xcd1, rp_comp, col_comp, N_MD, N_CD,
      WLm(22, 1), WLm(23, 1), WLv(24, 1), WLv(25, 1), WLv(26, 1), acc, 0);
  gcn(xcd1, rp_cc, col_cc, N_CD, WLm(32, 1), WLv(33, 1), acc, acc);
  do_pool(acc, b_cd, N_CD, 0);
  gcn(xmd1, rp_mm, col_mm, N_MD, WLm(34, 1), WLv(35, 1), nullptr, acc);
  do_pool(acc, b_md, N_MD, 4);

  // ---------- SEQ ----------
  sage(x_cd, x_seq, rp_seq, col_seq, N_SEQ, WLm(16, 0), WLv(17, 0), WLm(18, 0), xoth);
  sage(xcd1, xoth, rp_seq, col_seq, N_SEQ, WLm(16, 1), WLv(17, 1), WLm(18, 1), acc);
  do_pool(acc, b_seq, N_SEQ, 1);
  // ---------- ANNO ----------
  sage(x_cd, x_anno, rp_anno, col_anno, N_ANNO, WLm(19, 0), WLv(20, 0), WLm(21, 0), xoth);
  sage(xcd1, xoth, rp_anno, col_anno, N_ANNO, WLm(19, 1), WLv(20, 1), WLm(21, 1), acc);
  do_pool(acc, b_anno, N_ANNO, 2);
  // ---------- RANGE ----------
  gat(x_cd, x_range, rp_range, col_range, N_CD, N_RANGE,
      WLm(27, 0), WLm(28, 0), WLv(29, 0), WLv(30, 0), WLv(31, 0), xoth, 1);
  gat(xcd1, xoth, rp_range, col_range, N_CD, N_RANGE,
      WLm(27, 1), WLm(28, 1), WLv(29, 1), WLv(30, 1), WLv(31, 1), acc, 1);
  do_pool(acc, b_range, N_RANGE, 3);

  k_mlp<<<dim3(GNUM), dim3(128), 0, stream>>>(
      pool, cntg, fin(36), fin(37), fin(38), fin(39), (float*)d_out);
}

// Round 5
// 1772.911 us; speedup vs baseline: 1.5418x; 1.0471x over previous
//
#include <hip/hip_runtime.h>

#define HD 128
#define GNUM 512

// ======================= GEMM: C[N,128] = A[N,128] @ W[128,128] (+Cadd +bias, relu) ===
// 32 rows/block, 256 threads, W staged in LDS in two 64-row K-halves. 48KB LDS.
// Optional fused row-dot: adot[r] = C_row[r] . avec (pre-bias/relu, raw A@W row).
// NOTE: C and Cadd may alias (element is read before written by the same thread).
__global__ __launch_bounds__(256) void k_gemm128(
    const float* __restrict__ A, const float* __restrict__ W,
    float* C, const float* Cadd,
    const float* __restrict__ bias, int N, int relu,
    const float* __restrict__ avec, float* __restrict__ adot)
{
  __shared__ float As[32 * 128];   // 16 KB
  __shared__ float Wk[64 * 128];   // 32 KB
  const int t = threadIdx.x;
  const int row0 = blockIdx.x * 32;

  { // stage A tile (linear float4 copy, zero-pad beyond N)
    const float4* A4 = (const float4*)(A + (size_t)row0 * 128);
    float4* As4 = (float4*)As;
    const int nrow = min(N - row0, 32);
    const int maxf4 = nrow * 32;
#pragma unroll
    for (int i = 0; i < 4; ++i) {
      int f = t + i * 256;
      float4 v = make_float4(0.f, 0.f, 0.f, 0.f);
      if (f < maxf4) v = A4[f];
      As4[f] = v;
    }
  }

  const int tx = t & 31, ty = t >> 5;
  float acc[4][4];
#pragma unroll
  for (int i = 0; i < 4; ++i)
#pragma unroll
    for (int j = 0; j < 4; ++j) acc[i][j] = 0.f;

  for (int p = 0; p < 2; ++p) {
    __syncthreads();
    { // stage W K-half: 8192 floats
      const float4* W4 = (const float4*)(W + p * 64 * 128);
      float4* Wk4 = (float4*)Wk;
#pragma unroll
      for (int i = 0; i < 8; ++i) Wk4[t + i * 256] = W4[t + i * 256];
    }
    __syncthreads();
#pragma unroll 4
    for (int k = 0; k < 64; k += 2) {
      const float4 b0 = *(const float4*)(Wk + k * 128 + tx * 4);
      const float4 b1 = *(const float4*)(Wk + (k + 1) * 128 + tx * 4);
      const int kk = p * 64 + k;
      float2 a01[4];
#pragma unroll
      for (int i = 0; i < 4; ++i)
        a01[i] = *(const float2*)(As + (ty * 4 + i) * 128 + kk);
#pragma unroll
      for (int i = 0; i < 4; ++i) {
        acc[i][0] = fmaf(a01[i].x, b0.x, acc[i][0]);
        acc[i][1] = fmaf(a01[i].x, b0.y, acc[i][1]);
        acc[i][2] = fmaf(a01[i].x, b0.z, acc[i][2]);
        acc[i][3] = fmaf(a01[i].x, b0.w, acc[i][3]);
        acc[i][0] = fmaf(a01[i].y, b1.x, acc[i][0]);
        acc[i][1] = fmaf(a01[i].y, b1.y, acc[i][1]);
        acc[i][2] = fmaf(a01[i].y, b1.z, acc[i][2]);
        acc[i][3] = fmaf(a01[i].y, b1.w, acc[i][3]);
      }
    }
  }

  // optional fused row-dot (raw A@W, before bias/relu/Cadd)
  if (avec) {
    const float4 av = *(const float4*)(avec + tx * 4);
#pragma unroll
    for (int i = 0; i < 4; ++i) {
      float d = acc[i][0] * av.x;
      d = fmaf(acc[i][1], av.y, d);
      d = fmaf(acc[i][2], av.z, d);
      d = fmaf(acc[i][3], av.w, d);
#pragma unroll
      for (int o = 16; o > 0; o >>= 1) d += __shfl_xor(d, o);
      int r = row0 + ty * 4 + i;
      if (tx == 0 && r < N) adot[r] = d;
    }
  }

  float4 bv = make_float4(0.f, 0.f, 0.f, 0.f);
  if (bias) bv = *(const float4*)(bias + tx * 4);
#pragma unroll
  for (int i = 0; i < 4; ++i) {
    int r = row0 + ty * 4 + i;
    if (r < N) {
      size_t base = (size_t)r * 128 + tx * 4;
      float4 v = make_float4(acc[i][0], acc[i][1], acc[i][2], acc[i][3]);
      if (Cadd) {
        float4 c4 = *(const float4*)(Cadd + base);
        v.x += c4.x; v.y += c4.y; v.z += c4.z; v.w += c4.w;
      }
      if (bias) { v.x += bv.x; v.y += bv.y; v.z += bv.z; v.w += bv.w; }
      if (relu) {
        v.x = fmaxf(v.x, 0.f); v.y = fmaxf(v.y, 0.f);
        v.z = fmaxf(v.z, 0.f); v.w = fmaxf(v.w, 0.f);
      }
      *(float4*)(C + base) = v;
    }
  }
}

// ======================= row dot: out[n] = x[n,:] . a  (one wave / node) ===========
__global__ void k_rowdot(const float* __restrict__ x, const float* __restrict__ a,
                         float* __restrict__ out, int N)
{
  int wid = blockIdx.x * 4 + (threadIdx.x >> 6);
  int lane = threadIdx.x & 63;
  if (wid >= N) return;
  float2 xv = ((const float2*)x)[(size_t)wid * 64 + lane];
  float2 av = ((const float2*)a)[lane];
  float v = fmaf(xv.y, av.y, xv.x * av.x);
#pragma unroll
  for (int o = 32; o > 0; o >>= 1) v += __shfl_down(v, o);
  if (lane == 0) out[wid] = v;
}

// ======================= wvec[i] = sum_j W[i,j]*a[j]  (one block, 128 thr) =========
__global__ void k_matvec_right(const float* __restrict__ W, const float* __restrict__ a,
                               float* __restrict__ wvec)
{
  __shared__ float as[128];
  int i = threadIdx.x;
  as[i] = a[i];
  __syncthreads();
  float v = 0.f;
  for (int j = 0; j < 128; ++j) v = fmaf(W[i * 128 + j], as[j], v);
  wvec[i] = v;
}

// ======================= CSR build =======================
__global__ void k_hist(const int* __restrict__ ed, int* __restrict__ cnt, int E) {
  int e = blockIdx.x * 256 + threadIdx.x;
  if (e < E) atomicAdd(&cnt[ed[e]], 1);
}

// ---- 3-phase multi-block exclusive scan (tile = 4096 = 256 thr x 16) ----
__global__ __launch_bounds__(256) void k_scan_partial(
    const int* __restrict__ rp, int* __restrict__ bsums, int N)
{
  __shared__ int red[256];
  const int t = threadIdx.x, base = blockIdx.x * 4096;
  int s = 0;
  for (int i = t; i < 4096; i += 256) {
    int idx = base + i;
    if (idx < N) s += rp[idx];
  }
  red[t] = s;
  __syncthreads();
  for (int ofs = 128; ofs > 0; ofs >>= 1) {
    if (t < ofs) red[t] += red[t + ofs];
    __syncthreads();
  }
  if (t == 0) bsums[blockIdx.x] = red[0];
}

__global__ __launch_bounds__(1024) void k_scan_bsums(
    int* __restrict__ bsums, int nb, int* __restrict__ rpN)
{
  __shared__ int sh[1024];
  const int t = threadIdx.x;
  int v = (t < nb) ? bsums[t] : 0;
  sh[t] = v;
  __syncthreads();
  for (int ofs = 1; ofs < 1024; ofs <<= 1) {
    int u = (t >= ofs) ? sh[t - ofs] : 0;
    __syncthreads();
    sh[t] += u;
    __syncthreads();
  }
  if (t < nb) bsums[t] = sh[t] - v;      // exclusive
  if (t == 1023) rpN[0] = sh[1023];      // total
}

__global__ __launch_bounds__(256) void k_scan_final(
    int* __restrict__ rp, const int* __restrict__ bsums, int N)
{
  __shared__ int sh[4096 + 256];         // padded: i -> i + (i>>4), conflict-free
  __shared__ int tsum[256];
  const int t = threadIdx.x, base = blockIdx.x * 4096;
  auto mp = [](int i) { return i + (i >> 4); };
#pragma unroll
  for (int i = 0; i < 16; ++i) {
    int idx = base + i * 256 + t;
    sh[mp(i * 256 + t)] = (idx < N) ? rp[idx] : 0;
  }
  __syncthreads();
  int s = 0;
#pragma unroll
  for (int j = 0; j < 16; ++j) s += sh[mp(t * 16 + j)];
  tsum[t] = s;
  __syncthreads();
  for (int ofs = 1; ofs < 256; ofs <<= 1) {
    int u = (t >= ofs) ? tsum[t - ofs] : 0;
    __syncthreads();
    tsum[t] += u;
    __syncthreads();
  }
  int pre = tsum[t] - s + bsums[blockIdx.x];
#pragma unroll
  for (int j = 0; j < 16; ++j) {
    int v = sh[mp(t * 16 + j)];
    sh[mp(t * 16 + j)] = pre;
    pre += v;
  }
  __syncthreads();
#pragma unroll
  for (int i = 0; i < 16; ++i) {
    int idx = base + i * 256 + t;
    if (idx < N) rp[idx] = sh[mp(i * 256 + t)];
  }
}

__global__ void k_copyint(int* __restrict__ dst, const int* __restrict__ src, int N) {
  int i = blockIdx.x * 256 + threadIdx.x;
  if (i < N) dst[i] = src[i];
}

__global__ void k_fill(const int* __restrict__ es, const int* __restrict__ ed,
                       int* __restrict__ wp, int* __restrict__ col, int E) {
  int e = blockIdx.x * 256 + threadIdx.x;
  if (e >= E) return;
  int p = atomicAdd(&wp[ed[e]], 1);
  col[p] = es[e];
}

__global__ void k_dis(const int* __restrict__ rp, float* __restrict__ dis, int N) {
  int n = blockIdx.x * 256 + threadIdx.x;
  if (n < N) dis[n] = rsqrtf((float)(rp[n + 1] - rp[n]) + 1.f);
}

// ======================= gather kernels (one wave per dst node, float2 lanes) ========
// SAGE: out[n] = mean over incident src rows.
__global__ void k_sage_gather(const int* __restrict__ rp, const int* __restrict__ col,
                              const float* __restrict__ x, float* __restrict__ out, int N)
{
  int node = blockIdx.x * 4 + (threadIdx.x >> 6);
  if (node >= N) return;
  int lane = threadIdx.x & 63;
  int s0 = rp[node], s1 = rp[node + 1];
  const float2* x2 = (const float2*)x;
  float a0 = 0.f, a1 = 0.f;
  for (int e = s0; e < s1; ++e) {
    float2 v = x2[(size_t)col[e] * 64 + lane];
    a0 += v.x; a1 += v.y;
  }
  float inv = 1.f / fmaxf((float)(s1 - s0), 1.f);
  ((float2*)out)[(size_t)node * 64 + lane] = make_float2(a0 * inv, a1 * inv);
}

// GCN fused: out[n] = relu( sum_e dis[s]*dis[n]*h[s] + dis[n]^2*h[n] + b + addin )
// out may alias addin.
__global__ void k_gcn_gather(const int* __restrict__ rp, const int* __restrict__ col,
                             const float* __restrict__ dis, const float* __restrict__ h,
                             const float* addin, const float* __restrict__ b,
                             float* out, int N)
{
  int node = blockIdx.x * 4 + (threadIdx.x >> 6);
  if (node >= N) return;
  int lane = threadIdx.x & 63;
  int s0 = rp[node], s1 = rp[node + 1];
  float rd = dis[node];
  const float2* h2 = (const float2*)h;
  float a0 = 0.f, a1 = 0.f;
  for (int e = s0; e < s1; ++e) {
    int s = col[e];
    float ns = dis[s] * rd;
    float2 hv = h2[(size_t)s * 64 + lane];
    a0 = fmaf(ns, hv.x, a0);
    a1 = fmaf(ns, hv.y, a1);
  }
  float rr = rd * rd;
  float2 hself = h2[(size_t)node * 64 + lane];
  float2 bv = ((const float2*)b)[lane];
  float ad0 = 0.f, ad1 = 0.f;
  if (addin) {
    float2 a2 = ((const float2*)addin)[(size_t)node * 64 + lane];
    ad0 = a2.x; ad1 = a2.y;
  }
  float v0 = fmaf(rr, hself.x, a0) + bv.x + ad0;
  float v1 = fmaf(rr, hself.y, a1) + bv.y + ad1;
  ((float2*)out)[(size_t)node * 64 + lane] = make_float2(fmaxf(v0, 0.f), fmaxf(v1, 0.f));
}

// GAT fused, single edge-walk (no max subtraction: logits are O(1), exp-safe).
// out[n] = (sum_e exp(v_e)*hs[s]) / (sum_e exp(v_e)) + b   (opt relu)
__global__ void k_gat_gather(const int* __restrict__ rp, const int* __restrict__ col,
                             const float* __restrict__ hs, const float* __restrict__ as_,
                             const float* __restrict__ ad_, const float* __restrict__ b,
                             float* __restrict__ out, int N, int relu)
{
  int node = blockIdx.x * 4 + (threadIdx.x >> 6);
  if (node >= N) return;
  int lane = threadIdx.x & 63;
  int s0 = rp[node], s1 = rp[node + 1];
  float adn = ad_[node];
  const float2* hs2 = (const float2*)hs;
  float z = 0.f, a0 = 0.f, a1 = 0.f;
  for (int e = s0; e < s1; ++e) {
    int s = col[e];
    float v = as_[s] + adn;
    v = v > 0.f ? v : 0.2f * v;       // leaky_relu 0.2
    float p = __expf(v);
    z += p;                            // identical across lanes (no reduction needed)
    float2 hv = hs2[(size_t)s * 64 + lane];
    a0 = fmaf(p, hv.x, a0);
    a1 = fmaf(p, hv.y, a1);
  }
  float inv = (s1 > s0) ? 1.f / z : 0.f;
  float2 bv = ((const float2*)b)[lane];
  float v0 = fmaf(a0, inv, bv.x);
  float v1 = fmaf(a1, inv, bv.y);
  if (relu) { v0 = fmaxf(v0, 0.f); v1 = fmaxf(v1, 0.f); }
  ((float2*)out)[(size_t)node * 64 + lane] = make_float2(v0, v1);
}

// ======================= pooling (b sorted -> run-length + atomics) ================
__global__ void k_pool_scan(const float* __restrict__ x, const int* __restrict__ b,
                            float* __restrict__ pool, float* __restrict__ cntg,
                            int N, int col_off)
{
  const int t = threadIdx.x;
  const int c = t & 127;
  const int half = t >> 7;
  const int n0 = blockIdx.x * 256 + half * 128;
  if (n0 >= N) return;
  const int n1 = min(n0 + 128, N);
  float accum = 0.f;
  int cur = b[n0];
  int len = 0;
  for (int n = n0; n < n1; ++n) {
    int g = b[n];
    if (g != cur) {
      atomicAdd(&pool[(size_t)cur * 640 + col_off + c], accum);
      if (c == 0) atomicAdd(&cntg[cur], (float)len);
      accum = 0.f; len = 0; cur = g;
    }
    accum += x[(size_t)n * 128 + c];
    ++len;
  }
  atomicAdd(&pool[(size_t)cur * 640 + col_off + c], accum);
  if (c == 0) atomicAdd(&cntg[cur], (float)len);
}

// ======================= final MLP (one block per graph) =======================
__global__ void k_mlp(const float* __restrict__ pool, const float* __restrict__ cntg,
                      const float* __restrict__ W1, const float* __restrict__ b1,
                      const float* __restrict__ W2, const float* __restrict__ b2,
                      float* __restrict__ out)
{
  __shared__ float emb[640];
  __shared__ float red[128];
  const int g = blockIdx.x, t = threadIdx.x;
  for (int i = t; i < 640; i += 128) {
    int type = i >> 7;
    float cnt = cntg[type * GNUM + g];
    emb[i] = pool[(size_t)g * 640 + i] / fmaxf(cnt, 1.f);
  }
  __syncthreads();
  float acc = b1[t];
  for (int i = 0; i < 640; ++i) acc = fmaf(emb[i], W1[i * 128 + t], acc);
  float h = fmaxf(acc, 0.f);
  red[t] = h * W2[t];
  __syncthreads();
  for (int s = 64; s > 0; s >>= 1) {
    if (t < s) red[t] += red[t + s];
    __syncthreads();
  }
  if (t == 0) out[g] = red[0] + b2[0];
}

// ======================= host =======================
extern "C" void kernel_launch(void* const* d_in, const int* in_sizes, int n_in,
                              void* d_out, int out_size, void* d_ws, size_t ws_size,
                              hipStream_t stream)
{
  auto fin = [&](int i) { return (const float*)d_in[i]; };
  auto iin = [&](int i) { return (const int*)d_in[i]; };

  const float *x_cd = fin(0), *x_seq = fin(1), *x_anno = fin(2), *x_range = fin(3), *x_md = fin(4);
  const int *ei_seq = iin(5), *ei_anno = iin(6), *ei_range = iin(7),
            *ei_comp = iin(8), *ei_cc = iin(9), *ei_mm = iin(10);
  const int *b_cd = iin(11), *b_seq = iin(12), *b_anno = iin(13), *b_range = iin(14), *b_md = iin(15);

  const int N_CD = in_sizes[0] / HD, N_SEQ = in_sizes[1] / HD, N_ANNO = in_sizes[2] / HD,
            N_RANGE = in_sizes[3] / HD, N_MD = in_sizes[4] / HD;
  const int E_seq = in_sizes[5] / 2, E_anno = in_sizes[6] / 2, E_range = in_sizes[7] / 2,
            E_comp = in_sizes[8] / 2, E_cc = in_sizes[9] / 2, E_mm = in_sizes[10] / 2;
  const int N_OTH = max(max(N_SEQ, N_ANNO), N_RANGE);
  const int N_MAXD = max(N_CD, N_OTH);

  auto WLm = [&](int i, int l) { return fin(i) + (size_t)l * HD * HD; };
  auto WLv = [&](int i, int l) { return fin(i) + (size_t)l * HD; };

  // ---- workspace layout ----
  float* ws = (float*)d_ws;
  size_t off = 0;
  auto alloc = [&](size_t n) { float* p = ws + off; off += (n + 3) & ~(size_t)3; return p; };
  float* xcd1 = alloc((size_t)N_CD * HD);
  float* xmd1 = alloc((size_t)N_MD * HD);
  float* xoth = alloc((size_t)N_OTH * HD);
  float* acc  = alloc((size_t)N_CD * HD);
  float* t1   = alloc((size_t)N_CD * HD);
  float* sAs  = alloc((size_t)N_CD);
  float* sAd  = alloc((size_t)N_CD);
  float* dis_cc = alloc((size_t)N_CD);
  float* dis_mm = alloc((size_t)N_MD);
  float* wvec = alloc(HD);
  float* pool = alloc((size_t)GNUM * 5 * HD);
  float* cntg = alloc(5 * GNUM);
  auto alloci = [&](size_t n) { int* p = (int*)(ws + off); off += (n + 3) & ~(size_t)3; return p; };
  int* wp = alloci((size_t)N_MAXD);      // shared fill cursor
  int* bsums = alloci(1024);             // scan partials
  int *rp_seq = alloci((size_t)N_SEQ + 1),  *col_seq = alloci((size_t)E_seq);
  int *rp_anno = alloci((size_t)N_ANNO + 1), *col_anno = alloci((size_t)E_anno);
  int *rp_range = alloci((size_t)N_RANGE + 1), *col_range = alloci((size_t)E_range);
  int *rp_comp = alloci((size_t)N_CD + 1),  *col_comp = alloci((size_t)E_comp);
  int *rp_cc = alloci((size_t)N_CD + 1),    *col_cc = alloci((size_t)E_cc);
  int *rp_mm = alloci((size_t)N_MD + 1),    *col_mm = alloci((size_t)E_mm);
  (void)n_in;

  if (off * sizeof(float) > ws_size) {
    hipMemsetAsync(d_out, 0, (size_t)out_size * sizeof(float), stream);
    return;
  }

  auto ew = [&](size_t elems) { return dim3((unsigned)((elems + 255) / 256)); };
  auto nw = [&](int N) { return dim3((unsigned)((N + 3) / 4)); };   // wave-per-node grids

  auto gemm = [&](const float* A, const float* W, float* C, const float* Cadd,
                  const float* b, int N, int relu, const float* avec, float* adot) {
    k_gemm128<<<dim3((N + 31) / 32), dim3(256), 0, stream>>>(A, W, C, Cadd, b, N, relu,
                                                             avec, adot);
  };
  auto do_pool = [&](const float* x, const int* b, int N, int type) {
    k_pool_scan<<<ew(N), dim3(256), 0, stream>>>(x, b, pool, cntg + type * GNUM, N, type * HD);
  };

  // ---- build all CSRs once (multi-block scan) ----
  auto build = [&](const int* ei, int E, int Nd, int* rp, int* col) {
    hipMemsetAsync(rp, 0, ((size_t)Nd + 1) * 4, stream);
    k_hist<<<ew(E), dim3(256), 0, stream>>>(ei + E, rp, E);
    int nb = (Nd + 4095) / 4096;
    k_scan_partial<<<dim3(nb), dim3(256), 0, stream>>>(rp, bsums, Nd);
    k_scan_bsums<<<dim3(1), dim3(1024), 0, stream>>>(bsums, nb, rp + Nd);
    k_scan_final<<<dim3(nb), dim3(256), 0, stream>>>(rp, bsums, Nd);
    k_copyint<<<ew(Nd), dim3(256), 0, stream>>>(wp, rp, Nd);
    k_fill<<<ew(E), dim3(256), 0, stream>>>(ei, ei + E, wp, col, E);
  };
  build(ei_seq, E_seq, N_SEQ, rp_seq, col_seq);
  build(ei_anno, E_anno, N_ANNO, rp_anno, col_anno);
  build(ei_range, E_range, N_RANGE, rp_range, col_range);
  build(ei_comp, E_comp, N_CD, rp_comp, col_comp);
  build(ei_cc, E_cc, N_CD, rp_cc, col_cc);
  build(ei_mm, E_mm, N_MD, rp_mm, col_mm);
  k_dis<<<ew(N_CD), dim3(256), 0, stream>>>(rp_cc, dis_cc, N_CD);
  k_dis<<<ew(N_MD), dim3(256), 0, stream>>>(rp_mm, dis_mm, N_MD);

  // GAT: hs -> t1 with fused sAs dot; sAd via matvec+rowdot; fused gather -> out
  auto gat = [&](const float* xs, const float* xd, const int* rp, const int* col,
                 int Ns, int Nd, const float* Wsm, const float* Wdm,
                 const float* avs, const float* avd, const float* bias,
                 float* out, int relu) {
    gemm(xs, Wsm, t1, nullptr, nullptr, Ns, 0, avs, sAs);   // hs + fused hs.a_s
    k_matvec_right<<<dim3(1), dim3(128), 0, stream>>>(Wdm, avd, wvec);
    k_rowdot<<<nw(Nd), dim3(256), 0, stream>>>(xd, wvec, sAd, Nd);
    k_gat_gather<<<nw(Nd), dim3(256), 0, stream>>>(rp, col, t1, sAs, sAd, bias, out, Nd, relu);
  };
  // GCN fused: h -> t1, gather(+self+bias+addin+relu) -> out
  auto gcn = [&](const float* x, const int* rp, const int* col, const float* dis, int N,
                 const float* W, const float* b, const float* addin, float* out) {
    gemm(x, W, t1, nullptr, nullptr, N, 0, nullptr, nullptr);
    k_gcn_gather<<<nw(N), dim3(256), 0, stream>>>(rp, col, dis, t1, addin, b, out, N);
  };
  // SAGE: mean -> t1, out = relu(t1@Wl + bl + xself@Wr)
  auto sage = [&](const float* xsrc, const float* xself, const int* rp, const int* col,
                  int Nd, const float* Wl, const float* bl, const float* Wr, float* out) {
    k_sage_gather<<<nw(Nd), dim3(256), 0, stream>>>(rp, col, xsrc, t1, Nd);
    gemm(t1, Wl, out, nullptr, nullptr, Nd, 0, nullptr, nullptr);
    gemm(xself, Wr, out, out, bl, Nd, 1, nullptr, nullptr);
  };

  hipMemsetAsync(pool, 0, (size_t)GNUM * 5 * HD * 4, stream);
  hipMemsetAsync(cntg, 0, 5 * GNUM * 4, stream);

  // ---------- CD + MD, both layers ----------
  gat(x_md, x_cd, rp_comp, col_comp, N_MD, N_CD,
      WLm(22, 0), WLm(23, 0), WLv(24, 0), WLv(25, 0), WLv(26, 0), acc, 0);
  gcn(x_cd, rp_cc, col_cc, dis_cc, N_CD, WLm(32, 0), WLv(33, 0), acc, xcd1);
  gcn(x_md, rp_mm, col_mm, dis_mm, N_MD, WLm(34, 0), WLv(35, 0), nullptr, xmd1);
  gat(xmd1, xcd1, rp_comp, col_comp, N_MD, N_CD,
      WLm(22, 1), WLm(23, 1), WLv(24, 1), WLv(25, 1), WLv(26, 1), acc, 0);
  gcn(xcd1, rp_cc, col_cc, dis_cc, N_CD, WLm(32, 1), WLv(33, 1), acc, acc);
  do_pool(acc, b_cd, N_CD, 0);
  gcn(xmd1, rp_mm, col_mm, dis_mm, N_MD, WLm(34, 1), WLv(35, 1), nullptr, acc);
  do_pool(acc, b_md, N_MD, 4);

  // ---------- SEQ ----------
  sage(x_cd, x_seq, rp_seq, col_seq, N_SEQ, WLm(16, 0), WLv(17, 0), WLm(18, 0), xoth);
  sage(xcd1, xoth, rp_seq, col_seq, N_SEQ, WLm(16, 1), WLv(17, 1), WLm(18, 1), acc);
  do_pool(acc, b_seq, N_SEQ, 1);
  // ---------- ANNO ----------
  sage(x_cd, x_anno, rp_anno, col_anno, N_ANNO, WLm(19, 0), WLv(20, 0), WLm(21, 0), xoth);
  sage(xcd1, xoth, rp_anno, col_anno, N_ANNO, WLm(19, 1), WLv(20, 1), WLm(21, 1), acc);
  do_pool(acc, b_anno, N_ANNO, 2);
  // ---------- RANGE ----------
  gat(x_cd, x_range, rp_range, col_range, N_CD, N_RANGE,
      WLm(27, 0), WLm(28, 0), WLv(29, 0), WLv(30, 0), WLv(31, 0), xoth, 1);
  gat(xcd1, xoth, rp_range, col_range, N_CD, N_RANGE,
      WLm(27, 1), WLm(28, 1), WLv(29, 1), WLv(30, 1), WLv(31, 1), acc, 1);
  do_pool(acc, b_range, N_RANGE, 3);

  k_mlp<<<dim3(GNUM), dim3(128), 0, stream>>>(
      pool, cntg, fin(36), fin(37), fin(38), fin(39), (float*)d_out);
}

// Round 6
// 1721.240 us; speedup vs baseline: 1.5881x; 1.0300x over previous
//
#include <hip/hip_runtime.h>

#define HD 128
#define GNUM 512

typedef __attribute__((ext_vector_type(8))) short short8v;   // 8 bf16 = 4 VGPR
typedef __attribute__((ext_vector_type(4))) float f32x4;

// RNE split: a ~= hi + lo (both bf16), |residual| ~ 2^-17 |a|
__device__ __forceinline__ void split1(float a, short& h, short& l) {
  unsigned u = __float_as_uint(a);
  unsigned hb = (u + 0x7FFFu + ((u >> 16) & 1u)) & 0xFFFF0000u;
  h = (short)(hb >> 16);
  float rest = a - __uint_as_float(hb);
  unsigned u2 = __float_as_uint(rest);
  l = (short)((u2 + 0x7FFFu + ((u2 >> 16) & 1u)) >> 16);
}

// ============ W pre-split: fp32 [k][n] -> bf16 hi/lo TRANSPOSED [n][k] ============
struct WTab { const float* p[8]; };
__global__ __launch_bounds__(256) void k_split_w(WTab tab, short* __restrict__ whi,
                                                 short* __restrict__ wlo)
{
  int m = blockIdx.x >> 6;                       // 16 matrices, 64 blocks each
  int i = (blockIdx.x & 63) * 256 + threadIdx.x; // 0..16383
  const float* W = tab.p[m >> 1] + (m & 1) * 16384;
  int k = i >> 7, n = i & 127;
  short h, l;
  split1(W[k * 128 + n], h, l);
  whi[m * 16384 + n * 128 + k] = h;
  wlo[m * 16384 + n * 128 + k] = l;
}

// ============ MFMA GEMM: C[N,128] = A[N,128] @ W (+Cadd +bias, relu) ============
// Split-bf16: C = Ah@Wh + Al@Wh + Ah@Wl. 64 rows/block, 4 waves of 64rx32c.
// W given as pre-split bf16, transposed [col][k]. C may alias Cadd.
__global__ __launch_bounds__(256) void k_gemm_mfma(
    const float* __restrict__ A, const short* __restrict__ WH,
    const short* __restrict__ WL, float* C, const float* Cadd,
    const float* __restrict__ bias, int N, int relu)
{
  __shared__ short Ah[64 * 136];   // pad 128->136: 272B row stride (16B-aligned)
  __shared__ short Al[64 * 136];
  const int t = threadIdx.x;
  const int row0 = blockIdx.x * 64;
  const int lane = t & 63, wid = t >> 6;
  const int g = lane >> 4, cn = lane & 15;
  const int colbase = wid * 32;

  // B fragments to VGPR (hi+lo): lane cn = col-within-tile, g = k-chunk of 8
  short8v bhi[2][4], blo[2][4];
#pragma unroll
  for (int ct = 0; ct < 2; ++ct)
#pragma unroll
    for (int kg = 0; kg < 4; ++kg) {
      size_t o = (size_t)(colbase + ct * 16 + cn) * 128 + kg * 32 + g * 8;
      bhi[ct][kg] = *(const short8v*)(WH + o);
      blo[ct][kg] = *(const short8v*)(WL + o);
    }

  // stage + split A tile
  const float4* A4 = (const float4*)(A + (size_t)row0 * 128);
#pragma unroll
  for (int i = 0; i < 8; ++i) {
    int f4 = t + i * 256;                        // 2048 float4 = 64 rows
    int row = f4 >> 5, c4 = f4 & 31;
    float4 v = make_float4(0.f, 0.f, 0.f, 0.f);
    if (row0 + row < N) v = A4[f4];
    short4 h, l;
    split1(v.x, h.x, l.x); split1(v.y, h.y, l.y);
    split1(v.z, h.z, l.z); split1(v.w, h.w, l.w);
    *(short4*)(Ah + row * 136 + c4 * 4) = h;
    *(short4*)(Al + row * 136 + c4 * 4) = l;
  }
  __syncthreads();

  f32x4 zero = {0.f, 0.f, 0.f, 0.f};
  f32x4 acc[4][2];
#pragma unroll
  for (int rt = 0; rt < 4; ++rt) { acc[rt][0] = zero; acc[rt][1] = zero; }

#pragma unroll
  for (int kg = 0; kg < 4; ++kg) {
#pragma unroll
    for (int rt = 0; rt < 4; ++rt) {
      const int ao = (rt * 16 + cn) * 136 + kg * 32 + g * 8;
      const short8v ah = *(const short8v*)(Ah + ao);
      const short8v al = *(const short8v*)(Al + ao);
#pragma unroll
      for (int ct = 0; ct < 2; ++ct) {
        acc[rt][ct] = __builtin_amdgcn_mfma_f32_16x16x32_bf16(ah, bhi[ct][kg], acc[rt][ct], 0, 0, 0);
        acc[rt][ct] = __builtin_amdgcn_mfma_f32_16x16x32_bf16(al, bhi[ct][kg], acc[rt][ct], 0, 0, 0);
        acc[rt][ct] = __builtin_amdgcn_mfma_f32_16x16x32_bf16(ah, blo[ct][kg], acc[rt][ct], 0, 0, 0);
      }
    }
  }

  // epilogue: C/D layout col = lane&15, row = (lane>>4)*4 + reg  [HW-verified]
#pragma unroll
  for (int rt = 0; rt < 4; ++rt) {
#pragma unroll
    for (int r = 0; r < 4; ++r) {
      int row = row0 + rt * 16 + g * 4 + r;
      if (row < N) {
#pragma unroll
        for (int ct = 0; ct < 2; ++ct) {
          int cg = colbase + ct * 16 + cn;
          size_t idx = (size_t)row * 128 + cg;
          float v = acc[rt][ct][r];
          if (Cadd) v += Cadd[idx];
          if (bias) v += bias[cg];
          if (relu) v = fmaxf(v, 0.f);
          C[idx] = v;
        }
      }
    }
  }
}

// ======================= row dot: out[n] = x[n,:] . a  (one wave / node) ===========
__global__ void k_rowdot(const float* __restrict__ x, const float* __restrict__ a,
                         float* __restrict__ out, int N)
{
  int wid = blockIdx.x * 4 + (threadIdx.x >> 6);
  int lane = threadIdx.x & 63;
  if (wid >= N) return;
  float2 xv = ((const float2*)x)[(size_t)wid * 64 + lane];
  float2 av = ((const float2*)a)[lane];
  float v = fmaf(xv.y, av.y, xv.x * av.x);
#pragma unroll
  for (int o = 32; o > 0; o >>= 1) v += __shfl_down(v, o);
  if (lane == 0) out[wid] = v;
}

// ======================= wvec[i] = sum_j W[i,j]*a[j]  (one block, 128 thr) =========
__global__ void k_matvec_right(const float* __restrict__ W, const float* __restrict__ a,
                               float* __restrict__ wvec)
{
  __shared__ float as[128];
  int i = threadIdx.x;
  as[i] = a[i];
  __syncthreads();
  float v = 0.f;
  for (int j = 0; j < 128; ++j) v = fmaf(W[i * 128 + j], as[j], v);
  wvec[i] = v;
}

// ======================= CSR build =======================
__global__ void k_hist(const int* __restrict__ ed, int* __restrict__ cnt, int E) {
  int e = blockIdx.x * 256 + threadIdx.x;
  if (e < E) atomicAdd(&cnt[ed[e]], 1);
}

__global__ __launch_bounds__(256) void k_scan_partial(
    const int* __restrict__ rp, int* __restrict__ bsums, int N)
{
  __shared__ int red[256];
  const int t = threadIdx.x, base = blockIdx.x * 4096;
  int s = 0;
  for (int i = t; i < 4096; i += 256) {
    int idx = base + i;
    if (idx < N) s += rp[idx];
  }
  red[t] = s;
  __syncthreads();
  for (int ofs = 128; ofs > 0; ofs >>= 1) {
    if (t < ofs) red[t] += red[t + ofs];
    __syncthreads();
  }
  if (t == 0) bsums[blockIdx.x] = red[0];
}

__global__ __launch_bounds__(1024) void k_scan_bsums(
    int* __restrict__ bsums, int nb, int* __restrict__ rpN)
{
  __shared__ int sh[1024];
  const int t = threadIdx.x;
  int v = (t < nb) ? bsums[t] : 0;
  sh[t] = v;
  __syncthreads();
  for (int ofs = 1; ofs < 1024; ofs <<= 1) {
    int u = (t >= ofs) ? sh[t - ofs] : 0;
    __syncthreads();
    sh[t] += u;
    __syncthreads();
  }
  if (t < nb) bsums[t] = sh[t] - v;      // exclusive
  if (t == 1023) rpN[0] = sh[1023];      // total
}

__global__ __launch_bounds__(256) void k_scan_final(
    int* __restrict__ rp, const int* __restrict__ bsums, int N)
{
  __shared__ int sh[4096 + 256];         // padded: i -> i + (i>>4)
  __shared__ int tsum[256];
  const int t = threadIdx.x, base = blockIdx.x * 4096;
  auto mp = [](int i) { return i + (i >> 4); };
#pragma unroll
  for (int i = 0; i < 16; ++i) {
    int idx = base + i * 256 + t;
    sh[mp(i * 256 + t)] = (idx < N) ? rp[idx] : 0;
  }
  __syncthreads();
  int s = 0;
#pragma unroll
  for (int j = 0; j < 16; ++j) s += sh[mp(t * 16 + j)];
  tsum[t] = s;
  __syncthreads();
  for (int ofs = 1; ofs < 256; ofs <<= 1) {
    int u = (t >= ofs) ? tsum[t - ofs] : 0;
    __syncthreads();
    tsum[t] += u;
    __syncthreads();
  }
  int pre = tsum[t] - s + bsums[blockIdx.x];
#pragma unroll
  for (int j = 0; j < 16; ++j) {
    int v = sh[mp(t * 16 + j)];
    sh[mp(t * 16 + j)] = pre;
    pre += v;
  }
  __syncthreads();
#pragma unroll
  for (int i = 0; i < 16; ++i) {
    int idx = base + i * 256 + t;
    if (idx < N) rp[idx] = sh[mp(i * 256 + t)];
  }
}

__global__ void k_copyint(int* __restrict__ dst, const int* __restrict__ src, int N) {
  int i = blockIdx.x * 256 + threadIdx.x;
  if (i < N) dst[i] = src[i];
}

__global__ void k_fill(const int* __restrict__ es, const int* __restrict__ ed,
                       int* __restrict__ wp, int* __restrict__ col, int E) {
  int e = blockIdx.x * 256 + threadIdx.x;
  if (e >= E) return;
  int p = atomicAdd(&wp[ed[e]], 1);
  col[p] = es[e];
}

__global__ void k_dis(const int* __restrict__ rp, float* __restrict__ dis, int N) {
  int n = blockIdx.x * 256 + threadIdx.x;
  if (n < N) dis[n] = rsqrtf((float)(rp[n + 1] - rp[n]) + 1.f);
}

// ======================= gather kernels (one wave per dst node, float2 lanes) ========
__global__ void k_sage_gather(const int* __restrict__ rp, const int* __restrict__ col,
                              const float* __restrict__ x, float* __restrict__ out, int N)
{
  int node = blockIdx.x * 4 + (threadIdx.x >> 6);
  if (node >= N) return;
  int lane = threadIdx.x & 63;
  int s0 = rp[node], s1 = rp[node + 1];
  const float2* x2 = (const float2*)x;
  float a0 = 0.f, a1 = 0.f;
  for (int e = s0; e < s1; ++e) {
    float2 v = x2[(size_t)col[e] * 64 + lane];
    a0 += v.x; a1 += v.y;
  }
  float inv = 1.f / fmaxf((float)(s1 - s0), 1.f);
  ((float2*)out)[(size_t)node * 64 + lane] = make_float2(a0 * inv, a1 * inv);
}

__global__ void k_gcn_gather(const int* __restrict__ rp, const int* __restrict__ col,
                             const float* __restrict__ dis, const float* __restrict__ h,
                             const float* addin, const float* __restrict__ b,
                             float* out, int N)
{
  int node = blockIdx.x * 4 + (threadIdx.x >> 6);
  if (node >= N) return;
  int lane = threadIdx.x & 63;
  int s0 = rp[node], s1 = rp[node + 1];
  float rd = dis[node];
  const float2* h2 = (const float2*)h;
  float a0 = 0.f, a1 = 0.f;
  for (int e = s0; e < s1; ++e) {
    int s = col[e];
    float ns = dis[s] * rd;
    float2 hv = h2[(size_t)s * 64 + lane];
    a0 = fmaf(ns, hv.x, a0);
    a1 = fmaf(ns, hv.y, a1);
  }
  float rr = rd * rd;
  float2 hself = h2[(size_t)node * 64 + lane];
  float2 bv = ((const float2*)b)[lane];
  float ad0 = 0.f, ad1 = 0.f;
  if (addin) {
    float2 a2 = ((const float2*)addin)[(size_t)node * 64 + lane];
    ad0 = a2.x; ad1 = a2.y;
  }
  float v0 = fmaf(rr, hself.x, a0) + bv.x + ad0;
  float v1 = fmaf(rr, hself.y, a1) + bv.y + ad1;
  ((float2*)out)[(size_t)node * 64 + lane] = make_float2(fmaxf(v0, 0.f), fmaxf(v1, 0.f));
}

__global__ void k_gat_gather(const int* __restrict__ rp, const int* __restrict__ col,
                             const float* __restrict__ hs, const float* __restrict__ as_,
                             const float* __restrict__ ad_, const float* __restrict__ b,
                             float* __restrict__ out, int N, int relu)
{
  int node = blockIdx.x * 4 + (threadIdx.x >> 6);
  if (node >= N) return;
  int lane = threadIdx.x & 63;
  int s0 = rp[node], s1 = rp[node + 1];
  float adn = ad_[node];
  const float2* hs2 = (const float2*)hs;
  float z = 0.f, a0 = 0.f, a1 = 0.f;
  for (int e = s0; e < s1; ++e) {
    int s = col[e];
    float v = as_[s] + adn;
    v = v > 0.f ? v : 0.2f * v;       // leaky_relu 0.2
    float p = __expf(v);
    z += p;
    float2 hv = hs2[(size_t)s * 64 + lane];
    a0 = fmaf(p, hv.x, a0);
    a1 = fmaf(p, hv.y, a1);
  }
  float inv = (s1 > s0) ? 1.f / z : 0.f;
  float2 bv = ((const float2*)b)[lane];
  float v0 = fmaf(a0, inv, bv.x);
  float v1 = fmaf(a1, inv, bv.y);
  if (relu) { v0 = fmaxf(v0, 0.f); v1 = fmaxf(v1, 0.f); }
  ((float2*)out)[(size_t)node * 64 + lane] = make_float2(v0, v1);
}

// ======================= pooling (b sorted -> run-length + atomics) ================
__global__ void k_pool_scan(const float* __restrict__ x, const int* __restrict__ b,
                            float* __restrict__ pool, float* __restrict__ cntg,
                            int N, int col_off)
{
  const int t = threadIdx.x;
  const int c = t & 127;
  const int half = t >> 7;
  const int n0 = blockIdx.x * 256 + half * 128;
  if (n0 >= N) return;
  const int n1 = min(n0 + 128, N);
  float accum = 0.f;
  int cur = b[n0];
  int len = 0;
  for (int n = n0; n < n1; ++n) {
    int g = b[n];
    if (g != cur) {
      atomicAdd(&pool[(size_t)cur * 640 + col_off + c], accum);
      if (c == 0) atomicAdd(&cntg[cur], (float)len);
      accum = 0.f; len = 0; cur = g;
    }
    accum += x[(size_t)n * 128 + c];
    ++len;
  }
  atomicAdd(&pool[(size_t)cur * 640 + col_off + c], accum);
  if (c == 0) atomicAdd(&cntg[cur], (float)len);
}

// ======================= final MLP (one block per graph) =======================
__global__ void k_mlp(const float* __restrict__ pool, const float* __restrict__ cntg,
                      const float* __restrict__ W1, const float* __restrict__ b1,
                      const float* __restrict__ W2, const float* __restrict__ b2,
                      float* __restrict__ out)
{
  __shared__ float emb[640];
  __shared__ float red[128];
  const int g = blockIdx.x, t = threadIdx.x;
  for (int i = t; i < 640; i += 128) {
    int type = i >> 7;
    float cnt = cntg[type * GNUM + g];
    emb[i] = pool[(size_t)g * 640 + i] / fmaxf(cnt, 1.f);
  }
  __syncthreads();
  float acc = b1[t];
  for (int i = 0; i < 640; ++i) acc = fmaf(emb[i], W1[i * 128 + t], acc);
  float h = fmaxf(acc, 0.f);
  red[t] = h * W2[t];
  __syncthreads();
  for (int s = 64; s > 0; s >>= 1) {
    if (t < s) red[t] += red[t + s];
    __syncthreads();
  }
  if (t == 0) out[g] = red[0] + b2[0];
}

// ======================= host =======================
extern "C" void kernel_launch(void* const* d_in, const int* in_sizes, int n_in,
                              void* d_out, int out_size, void* d_ws, size_t ws_size,
                              hipStream_t stream)
{
  auto fin = [&](int i) { return (const float*)d_in[i]; };
  auto iin = [&](int i) { return (const int*)d_in[i]; };

  const float *x_cd = fin(0), *x_seq = fin(1), *x_anno = fin(2), *x_range = fin(3), *x_md = fin(4);
  const int *ei_seq = iin(5), *ei_anno = iin(6), *ei_range = iin(7),
            *ei_comp = iin(8), *ei_cc = iin(9), *ei_mm = iin(10);
  const int *b_cd = iin(11), *b_seq = iin(12), *b_anno = iin(13), *b_range = iin(14), *b_md = iin(15);

  const int N_CD = in_sizes[0] / HD, N_SEQ = in_sizes[1] / HD, N_ANNO = in_sizes[2] / HD,
            N_RANGE = in_sizes[3] / HD, N_MD = in_sizes[4] / HD;
  const int E_seq = in_sizes[5] / 2, E_anno = in_sizes[6] / 2, E_range = in_sizes[7] / 2,
            E_comp = in_sizes[8] / 2, E_cc = in_sizes[9] / 2, E_mm = in_sizes[10] / 2;
  const int N_OTH = max(max(N_SEQ, N_ANNO), N_RANGE);
  const int N_MAXD = max(N_CD, N_OTH);

  auto WLm = [&](int i, int l) { return fin(i) + (size_t)l * HD * HD; };
  auto WLv = [&](int i, int l) { return fin(i) + (size_t)l * HD; };

  // ---- workspace layout ----
  float* ws = (float*)d_ws;
  size_t off = 0;
  auto alloc = [&](size_t n) { float* p = ws + off; off += (n + 3) & ~(size_t)3; return p; };
  float* xcd1 = alloc((size_t)N_CD * HD);
  float* xmd1 = alloc((size_t)N_MD * HD);
  float* xoth = alloc((size_t)N_OTH * HD);
  float* acc  = alloc((size_t)N_CD * HD);
  float* t1   = alloc((size_t)N_CD * HD);
  float* sAs  = alloc((size_t)N_CD);
  float* sAd  = alloc((size_t)N_CD);
  float* dis_cc = alloc((size_t)N_CD);
  float* dis_mm = alloc((size_t)N_MD);
  float* wvecS = alloc(HD);
  float* wvecD = alloc(HD);
  float* pool = alloc((size_t)GNUM * 5 * HD);
  float* cntg = alloc(5 * GNUM);
  // bf16 pre-split weights: 16 slots (8 matrices x 2 layers), transposed [n][k]
  short* whi = (short*)(ws + off); off += (size_t)16 * 16384 / 2;
  short* wlo = (short*)(ws + off); off += (size_t)16 * 16384 / 2;
  auto alloci = [&](size_t n) { int* p = (int*)(ws + off); off += (n + 3) & ~(size_t)3; return p; };
  int* wp = alloci((size_t)N_MAXD);
  int* bsums = alloci(1024);
  int *rp_seq = alloci((size_t)N_SEQ + 1),  *col_seq = alloci((size_t)E_seq);
  int *rp_anno = alloci((size_t)N_ANNO + 1), *col_anno = alloci((size_t)E_anno);
  int *rp_range = alloci((size_t)N_RANGE + 1), *col_range = alloci((size_t)E_range);
  int *rp_comp = alloci((size_t)N_CD + 1),  *col_comp = alloci((size_t)E_comp);
  int *rp_cc = alloci((size_t)N_CD + 1),    *col_cc = alloci((size_t)E_cc);
  int *rp_mm = alloci((size_t)N_MD + 1),    *col_mm = alloci((size_t)E_mm);
  (void)n_in;

  if (off * sizeof(float) > ws_size) {
    hipMemsetAsync(d_out, 0, (size_t)out_size * sizeof(float), stream);
    return;
  }

  auto ew = [&](size_t elems) { return dim3((unsigned)((elems + 255) / 256)); };
  auto nw = [&](int N) { return dim3((unsigned)((N + 3) / 4)); };

  // ---- pre-split all GEMM weights (slots: 0:16 1:18 2:19 3:21 4:22 5:27 6:32 7:34)
  WTab tab;
  tab.p[0] = fin(16); tab.p[1] = fin(18); tab.p[2] = fin(19); tab.p[3] = fin(21);
  tab.p[4] = fin(22); tab.p[5] = fin(27); tab.p[6] = fin(32); tab.p[7] = fin(34);
  k_split_w<<<dim3(1024), dim3(256), 0, stream>>>(tab, whi, wlo);

  auto gemm = [&](const float* A, int sidx, int layer, float* C, const float* Cadd,
                  const float* b, int N, int relu) {
    const short* WH = whi + (size_t)(sidx * 2 + layer) * 16384;
    const short* WL = wlo + (size_t)(sidx * 2 + layer) * 16384;
    k_gemm_mfma<<<dim3((N + 63) / 64), dim3(256), 0, stream>>>(A, WH, WL, C, Cadd, b, N, relu);
  };
  auto do_pool = [&](const float* x, const int* b, int N, int type) {
    k_pool_scan<<<ew(N), dim3(256), 0, stream>>>(x, b, pool, cntg + type * GNUM, N, type * HD);
  };

  // ---- build all CSRs (multi-block scan) ----
  auto build = [&](const int* ei, int E, int Nd, int* rp, int* col) {
    hipMemsetAsync(rp, 0, ((size_t)Nd + 1) * 4, stream);
    k_hist<<<ew(E), dim3(256), 0, stream>>>(ei + E, rp, E);
    int nb = (Nd + 4095) / 4096;
    k_scan_partial<<<dim3(nb), dim3(256), 0, stream>>>(rp, bsums, Nd);
    k_scan_bsums<<<dim3(1), dim3(1024), 0, stream>>>(bsums, nb, rp + Nd);
    k_scan_final<<<dim3(nb), dim3(256), 0, stream>>>(rp, bsums, Nd);
    k_copyint<<<ew(Nd), dim3(256), 0, stream>>>(wp, rp, Nd);
    k_fill<<<ew(E), dim3(256), 0, stream>>>(ei, ei + E, wp, col, E);
  };
  build(ei_seq, E_seq, N_SEQ, rp_seq, col_seq);
  build(ei_anno, E_anno, N_ANNO, rp_anno, col_anno);
  build(ei_range, E_range, N_RANGE, rp_range, col_range);
  build(ei_comp, E_comp, N_CD, rp_comp, col_comp);
  build(ei_cc, E_cc, N_CD, rp_cc, col_cc);
  build(ei_mm, E_mm, N_MD, rp_mm, col_mm);
  k_dis<<<ew(N_CD), dim3(256), 0, stream>>>(rp_cc, dis_cc, N_CD);
  k_dis<<<ew(N_MD), dim3(256), 0, stream>>>(rp_mm, dis_mm, N_MD);

  // GAT: sAs = xs.(Ws@a_s), sAd = xd.(Wd@a_d); hs = xs@Ws (MFMA); fused gather.
  auto gat = [&](const float* xs, const float* xd, const int* rp, const int* col,
                 int Ns, int Nd, int sidx, int layer, const float* Wsm, const float* Wdm,
                 const float* avs, const float* avd, const float* bias,
                 float* out, int relu) {
    k_matvec_right<<<dim3(1), dim3(128), 0, stream>>>(Wsm, avs, wvecS);
    k_rowdot<<<nw(Ns), dim3(256), 0, stream>>>(xs, wvecS, sAs, Ns);
    k_matvec_right<<<dim3(1), dim3(128), 0, stream>>>(Wdm, avd, wvecD);
    k_rowdot<<<nw(Nd), dim3(256), 0, stream>>>(xd, wvecD, sAd, Nd);
    gemm(xs, sidx, layer, t1, nullptr, nullptr, Ns, 0);   // hs
    k_gat_gather<<<nw(Nd), dim3(256), 0, stream>>>(rp, col, t1, sAs, sAd, bias, out, Nd, relu);
  };
  auto gcn = [&](const float* x, const int* rp, const int* col, const float* dis, int N,
                 int sidx, int layer, const float* b, const float* addin, float* out) {
    gemm(x, sidx, layer, t1, nullptr, nullptr, N, 0);
    k_gcn_gather<<<nw(N), dim3(256), 0, stream>>>(rp, col, dis, t1, addin, b, out, N);
  };
  auto sage = [&](const float* xsrc, const float* xself, const int* rp, const int* col,
                  int Nd, int sl, int sr, int layer, const float* bl, float* out) {
    k_sage_gather<<<nw(Nd), dim3(256), 0, stream>>>(rp, col, xsrc, t1, Nd);
    gemm(t1, sl, layer, out, nullptr, nullptr, Nd, 0);
    gemm(xself, sr, layer, out, out, bl, Nd, 1);
  };

  hipMemsetAsync(pool, 0, (size_t)GNUM * 5 * HD * 4, stream);
  hipMemsetAsync(cntg, 0, 5 * GNUM * 4, stream);

  // ---------- CD + MD, both layers ----------
  gat(x_md, x_cd, rp_comp, col_comp, N_MD, N_CD, 4, 0,
      WLm(22, 0), WLm(23, 0), WLv(24, 0), WLv(25, 0), WLv(26, 0), acc, 0);
  gcn(x_cd, rp_cc, col_cc, dis_cc, N_CD, 6, 0, WLv(33, 0), acc, xcd1);
  gcn(x_md, rp_mm, col_mm, dis_mm, N_MD, 7, 0, WLv(35, 0), nullptr, xmd1);
  gat(xmd1, xcd1, rp_comp, col_comp, N_MD, N_CD, 4, 1,
      WLm(22, 1), WLm(23, 1), WLv(24, 1), WLv(25, 1), WLv(26, 1), acc, 0);
  gcn(xcd1, rp_cc, col_cc, dis_cc, N_CD, 6, 1, WLv(33, 1), acc, acc);
  do_pool(acc, b_cd, N_CD, 0);
  gcn(xmd1, rp_mm, col_mm, dis_mm, N_MD, 7, 1, WLv(35, 1), nullptr, acc);
  do_pool(acc, b_md, N_MD, 4);

  // ---------- SEQ ----------
  sage(x_cd, x_seq, rp_seq, col_seq, N_SEQ, 0, 1, 0, WLv(17, 0), xoth);
  sage(xcd1, xoth, rp_seq, col_seq, N_SEQ, 0, 1, 1, WLv(17, 1), acc);
  do_pool(acc, b_seq, N_SEQ, 1);
  // ---------- ANNO ----------
  sage(x_cd, x_anno, rp_anno, col_anno, N_ANNO, 2, 3, 0, WLv(20, 0), xoth);
  sage(xcd1, xoth, rp_anno, col_anno, N_ANNO, 2, 3, 1, WLv(20, 1), acc);
  do_pool(acc, b_anno, N_ANNO, 2);
  // ---------- RANGE ----------
  gat(x_cd, x_range, rp_range, col_range, N_CD, N_RANGE, 5, 0,
      WLm(27, 0), WLm(28, 0), WLv(29, 0), WLv(30, 0), WLv(31, 0), xoth, 1);
  gat(xcd1, xoth, rp_range, col_range, N_CD, N_RANGE, 5, 1,
      WLm(27, 1), WLm(28, 1), WLv(29, 1), WLv(30, 1), WLv(31, 1), acc, 1);
  do_pool(acc, b_range, N_RANGE, 3);

  k_mlp<<<dim3(GNUM), dim3(128), 0, stream>>>(
      pool, cntg, fin(36), fin(37), fin(38), fin(39), (float*)d_out);
}

// Round 7
// 1546.948 us; speedup vs baseline: 1.7670x; 1.1127x over previous
//
#include <hip/hip_runtime.h>

#define HD 128
#define GNUM 512

typedef __attribute__((ext_vector_type(8))) short short8v;   // 8 bf16 = 4 VGPR
typedef __attribute__((ext_vector_type(4))) float f32x4;

// RNE split: a ~= hi + lo (both bf16), |residual| ~ 2^-17 |a|
__device__ __forceinline__ void split1(float a, short& h, short& l) {
  unsigned u = __float_as_uint(a);
  unsigned hb = (u + 0x7FFFu + ((u >> 16) & 1u)) & 0xFFFF0000u;
  h = (short)(hb >> 16);
  float rest = a - __uint_as_float(hb);
  unsigned u2 = __float_as_uint(rest);
  l = (short)((u2 + 0x7FFFu + ((u2 >> 16) & 1u)) >> 16);
}

// ============ W pre-split: fp32 [k][n] -> bf16 hi/lo TRANSPOSED [n][k] ============
struct WTab { const float* p[8]; };
__global__ __launch_bounds__(256) void k_split_w(WTab tab, short* __restrict__ whi,
                                                 short* __restrict__ wlo)
{
  int m = blockIdx.x >> 6;                       // 16 matrices, 64 blocks each
  int i = (blockIdx.x & 63) * 256 + threadIdx.x; // 0..16383
  const float* W = tab.p[m >> 1] + (m & 1) * 16384;
  int k = i >> 7, n = i & 127;
  short h, l;
  split1(W[k * 128 + n], h, l);
  whi[m * 16384 + n * 128 + k] = h;
  wlo[m * 16384 + n * 128 + k] = l;
}

// ============ MFMA GEMM: C = A1@W1 (+ A2@W2) (+bias, relu) ====================
// Split-bf16: A@W = Ah@Wh + Al@Wh + Ah@Wl. 64 rows/block, 4 waves of 64r x 32c.
// W pre-split bf16, transposed [col][k]. Epilogue goes through LDS for coalesced
// float4 stores (raw fragment layout would be 32 scalar stride-512B stores).
#define CF_LD 132   // fp32 LDS C-tile stride (2-way bank alias max)
__global__ __launch_bounds__(256) void k_gemm_mfma(
    const float* __restrict__ A1, const short* __restrict__ WH1, const short* __restrict__ WL1,
    const float* __restrict__ A2, const short* __restrict__ WH2, const short* __restrict__ WL2,
    float* __restrict__ C, const float* __restrict__ bias, int N, int relu)
{
  __shared__ char smem[64 * 136 * 2 * 2];        // 34816 B (>= 64*132*4 = 33792)
  short* Ah = (short*)smem;
  short* Al = Ah + 64 * 136;
  float* Cf = (float*)smem;

  const int t = threadIdx.x;
  const int row0 = blockIdx.x * 64;
  const int lane = t & 63, wid = t >> 6;
  const int g = lane >> 4, cn = lane & 15;
  const int colbase = wid * 32;

  f32x4 zero = {0.f, 0.f, 0.f, 0.f};
  f32x4 acc[4][2];
#pragma unroll
  for (int rt = 0; rt < 4; ++rt) { acc[rt][0] = zero; acc[rt][1] = zero; }

  auto stageA = [&](const float* __restrict__ A) {
    const float4* A4 = (const float4*)(A + (size_t)row0 * 128);
#pragma unroll
    for (int i = 0; i < 8; ++i) {
      int f4 = t + i * 256;                      // 2048 float4 = 64 rows
      int row = f4 >> 5, c4 = f4 & 31;
      float4 v = make_float4(0.f, 0.f, 0.f, 0.f);
      if (row0 + row < N) v = A4[f4];
      short4 h, l;
      split1(v.x, h.x, l.x); split1(v.y, h.y, l.y);
      split1(v.z, h.z, l.z); split1(v.w, h.w, l.w);
      *(short4*)(Ah + row * 136 + c4 * 4) = h;
      *(short4*)(Al + row * 136 + c4 * 4) = l;
    }
  };

  auto accum = [&](const short* __restrict__ WH, const short* __restrict__ WL) {
    // B fragments: lane cn = col-within-16, g = k-chunk of 8 (uncoalesced, L2-hot)
    short8v bhi[2][4], blo[2][4];
#pragma unroll
    for (int ct = 0; ct < 2; ++ct)
#pragma unroll
      for (int kg = 0; kg < 4; ++kg) {
        size_t o = (size_t)(colbase + ct * 16 + cn) * 128 + kg * 32 + g * 8;
        bhi[ct][kg] = *(const short8v*)(WH + o);
        blo[ct][kg] = *(const short8v*)(WL + o);
      }
#pragma unroll
    for (int kg = 0; kg < 4; ++kg) {
#pragma unroll
      for (int rt = 0; rt < 4; ++rt) {
        const int ao = (rt * 16 + cn) * 136 + kg * 32 + g * 8;
        const short8v ah = *(const short8v*)(Ah + ao);
        const short8v al = *(const short8v*)(Al + ao);
#pragma unroll
        for (int ct = 0; ct < 2; ++ct) {
          acc[rt][ct] = __builtin_amdgcn_mfma_f32_16x16x32_bf16(ah, bhi[ct][kg], acc[rt][ct], 0, 0, 0);
          acc[rt][ct] = __builtin_amdgcn_mfma_f32_16x16x32_bf16(al, bhi[ct][kg], acc[rt][ct], 0, 0, 0);
          acc[rt][ct] = __builtin_amdgcn_mfma_f32_16x16x32_bf16(ah, blo[ct][kg], acc[rt][ct], 0, 0, 0);
        }
      }
    }
  };

  stageA(A1);
  __syncthreads();
  accum(WH1, WL1);
  if (A2) {
    __syncthreads();                 // all waves done reading A1 LDS
    stageA(A2);
    __syncthreads();
    accum(WH2, WL2);
  }
  __syncthreads();                   // done with Ah/Al; reuse as Cf

  // scatter acc into LDS C-tile: C/D layout col = lane&15, row = (lane>>4)*4 + reg
#pragma unroll
  for (int rt = 0; rt < 4; ++rt)
#pragma unroll
    for (int ct = 0; ct < 2; ++ct)
#pragma unroll
      for (int r = 0; r < 4; ++r)
        Cf[(rt * 16 + g * 4 + r) * CF_LD + colbase + ct * 16 + cn] = acc[rt][ct][r];
  __syncthreads();

  // linear coalesced pass: LDS float4 -> (+bias, relu) -> global float4
  float4* C4 = (float4*)(C + (size_t)row0 * 128);
#pragma unroll
  for (int i = 0; i < 8; ++i) {
    int f4 = t + i * 256;
    int row = f4 >> 5, c4 = f4 & 31;
    if (row0 + row < N) {
      float4 v = *(const float4*)(Cf + row * CF_LD + c4 * 4);
      if (bias) {
        float4 bv = *(const float4*)(bias + c4 * 4);
        v.x += bv.x; v.y += bv.y; v.z += bv.z; v.w += bv.w;
      }
      if (relu) {
        v.x = fmaxf(v.x, 0.f); v.y = fmaxf(v.y, 0.f);
        v.z = fmaxf(v.z, 0.f); v.w = fmaxf(v.w, 0.f);
      }
      C4[f4] = v;
    }
  }
}

// ======================= row dot: out[n] = x[n,:] . a  (one wave / node) ===========
__global__ void k_rowdot(const float* __restrict__ x, const float* __restrict__ a,
                         float* __restrict__ out, int N)
{
  int wid = blockIdx.x * 4 + (threadIdx.x >> 6);
  int lane = threadIdx.x & 63;
  if (wid >= N) return;
  float2 xv = ((const float2*)x)[(size_t)wid * 64 + lane];
  float2 av = ((const float2*)a)[lane];
  float v = fmaf(xv.y, av.y, xv.x * av.x);
#pragma unroll
  for (int o = 32; o > 0; o >>= 1) v += __shfl_down(v, o);
  if (lane == 0) out[wid] = v;
}

// ======================= wvec[i] = sum_j W[i,j]*a[j]  (one block, 128 thr) =========
__global__ void k_matvec_right(const float* __restrict__ W, const float* __restrict__ a,
                               float* __restrict__ wvec)
{
  __shared__ float as[128];
  int i = threadIdx.x;
  as[i] = a[i];
  __syncthreads();
  float v = 0.f;
  for (int j = 0; j < 128; ++j) v = fmaf(W[i * 128 + j], as[j], v);
  wvec[i] = v;
}

// ======================= CSR build =======================
__global__ void k_hist(const int* __restrict__ ed, int* __restrict__ cnt, int E) {
  int e = blockIdx.x * 256 + threadIdx.x;
  if (e < E) atomicAdd(&cnt[ed[e]], 1);
}

__global__ __launch_bounds__(256) void k_scan_partial(
    const int* __restrict__ rp, int* __restrict__ bsums, int N)
{
  __shared__ int red[256];
  const int t = threadIdx.x, base = blockIdx.x * 4096;
  int s = 0;
  for (int i = t; i < 4096; i += 256) {
    int idx = base + i;
    if (idx < N) s += rp[idx];
  }
  red[t] = s;
  __syncthreads();
  for (int ofs = 128; ofs > 0; ofs >>= 1) {
    if (t < ofs) red[t] += red[t + ofs];
    __syncthreads();
  }
  if (t == 0) bsums[blockIdx.x] = red[0];
}

__global__ __launch_bounds__(1024) void k_scan_bsums(
    int* __restrict__ bsums, int nb, int* __restrict__ rpN)
{
  __shared__ int sh[1024];
  const int t = threadIdx.x;
  int v = (t < nb) ? bsums[t] : 0;
  sh[t] = v;
  __syncthreads();
  for (int ofs = 1; ofs < 1024; ofs <<= 1) {
    int u = (t >= ofs) ? sh[t - ofs] : 0;
    __syncthreads();
    sh[t] += u;
    __syncthreads();
  }
  if (t < nb) bsums[t] = sh[t] - v;      // exclusive
  if (t == 1023) rpN[0] = sh[1023];      // total
}

__global__ __launch_bounds__(256) void k_scan_final(
    int* __restrict__ rp, const int* __restrict__ bsums, int N)
{
  __shared__ int sh[4096 + 256];         // padded: i -> i + (i>>4)
  __shared__ int tsum[256];
  const int t = threadIdx.x, base = blockIdx.x * 4096;
  auto mp = [](int i) { return i + (i >> 4); };
#pragma unroll
  for (int i = 0; i < 16; ++i) {
    int idx = base + i * 256 + t;
    sh[mp(i * 256 + t)] = (idx < N) ? rp[idx] : 0;
  }
  __syncthreads();
  int s = 0;
#pragma unroll
  for (int j = 0; j < 16; ++j) s += sh[mp(t * 16 + j)];
  tsum[t] = s;
  __syncthreads();
  for (int ofs = 1; ofs < 256; ofs <<= 1) {
    int u = (t >= ofs) ? tsum[t - ofs] : 0;
    __syncthreads();
    tsum[t] += u;
    __syncthreads();
  }
  int pre = tsum[t] - s + bsums[blockIdx.x];
#pragma unroll
  for (int j = 0; j < 16; ++j) {
    int v = sh[mp(t * 16 + j)];
    sh[mp(t * 16 + j)] = pre;
    pre += v;
  }
  __syncthreads();
#pragma unroll
  for (int i = 0; i < 16; ++i) {
    int idx = base + i * 256 + t;
    if (idx < N) rp[idx] = sh[mp(i * 256 + t)];
  }
}

__global__ void k_copyint(int* __restrict__ dst, const int* __restrict__ src, int N) {
  int i = blockIdx.x * 256 + threadIdx.x;
  if (i < N) dst[i] = src[i];
}

__global__ void k_fill(const int* __restrict__ es, const int* __restrict__ ed,
                       int* __restrict__ wp, int* __restrict__ col, int E) {
  int e = blockIdx.x * 256 + threadIdx.x;
  if (e >= E) return;
  int p = atomicAdd(&wp[ed[e]], 1);
  col[p] = es[e];
}

__global__ void k_dis(const int* __restrict__ rp, float* __restrict__ dis, int N) {
  int n = blockIdx.x * 256 + threadIdx.x;
  if (n < N) dis[n] = rsqrtf((float)(rp[n + 1] - rp[n]) + 1.f);
}

// ======================= gather kernels (one wave per dst node, float2 lanes) ========
__global__ void k_sage_gather(const int* __restrict__ rp, const int* __restrict__ col,
                              const float* __restrict__ x, float* __restrict__ out, int N)
{
  int node = blockIdx.x * 4 + (threadIdx.x >> 6);
  if (node >= N) return;
  int lane = threadIdx.x & 63;
  int s0 = rp[node], s1 = rp[node + 1];
  const float2* x2 = (const float2*)x;
  float a0 = 0.f, a1 = 0.f;
  for (int e = s0; e < s1; ++e) {
    float2 v = x2[(size_t)col[e] * 64 + lane];
    a0 += v.x; a1 += v.y;
  }
  float inv = 1.f / fmaxf((float)(s1 - s0), 1.f);
  ((float2*)out)[(size_t)node * 64 + lane] = make_float2(a0 * inv, a1 * inv);
}

__global__ void k_gcn_gather(const int* __restrict__ rp, const int* __restrict__ col,
                             const float* __restrict__ dis, const float* __restrict__ h,
                             const float* addin, const float* __restrict__ b,
                             float* out, int N)
{
  int node = blockIdx.x * 4 + (threadIdx.x >> 6);
  if (node >= N) return;
  int lane = threadIdx.x & 63;
  int s0 = rp[node], s1 = rp[node + 1];
  float rd = dis[node];
  const float2* h2 = (const float2*)h;
  float a0 = 0.f, a1 = 0.f;
  for (int e = s0; e < s1; ++e) {
    int s = col[e];
    float ns = dis[s] * rd;
    float2 hv = h2[(size_t)s * 64 + lane];
    a0 = fmaf(ns, hv.x, a0);
    a1 = fmaf(ns, hv.y, a1);
  }
  float rr = rd * rd;
  float2 hself = h2[(size_t)node * 64 + lane];
  float2 bv = ((const float2*)b)[lane];
  float ad0 = 0.f, ad1 = 0.f;
  if (addin) {
    float2 a2 = ((const float2*)addin)[(size_t)node * 64 + lane];
    ad0 = a2.x; ad1 = a2.y;
  }
  float v0 = fmaf(rr, hself.x, a0) + bv.x + ad0;
  float v1 = fmaf(rr, hself.y, a1) + bv.y + ad1;
  ((float2*)out)[(size_t)node * 64 + lane] = make_float2(fmaxf(v0, 0.f), fmaxf(v1, 0.f));
}

__global__ void k_gat_gather(const int* __restrict__ rp, const int* __restrict__ col,
                             const float* __restrict__ hs, const float* __restrict__ as_,
                             const float* __restrict__ ad_, const float* __restrict__ b,
                             float* __restrict__ out, int N, int relu)
{
  int node = blockIdx.x * 4 + (threadIdx.x >> 6);
  if (node >= N) return;
  int lane = threadIdx.x & 63;
  int s0 = rp[node], s1 = rp[node + 1];
  float adn = ad_[node];
  const float2* hs2 = (const float2*)hs;
  float z = 0.f, a0 = 0.f, a1 = 0.f;
  for (int e = s0; e < s1; ++e) {
    int s = col[e];
    float v = as_[s] + adn;
    v = v > 0.f ? v : 0.2f * v;       // leaky_relu 0.2
    float p = __expf(v);
    z += p;
    float2 hv = hs2[(size_t)s * 64 + lane];
    a0 = fmaf(p, hv.x, a0);
    a1 = fmaf(p, hv.y, a1);
  }
  float inv = (s1 > s0) ? 1.f / z : 0.f;
  float2 bv = ((const float2*)b)[lane];
  float v0 = fmaf(a0, inv, bv.x);
  float v1 = fmaf(a1, inv, bv.y);
  if (relu) { v0 = fmaxf(v0, 0.f); v1 = fmaxf(v1, 0.f); }
  ((float2*)out)[(size_t)node * 64 + lane] = make_float2(v0, v1);
}

// ======================= pooling (b sorted -> run-length + atomics) ================
__global__ void k_pool_scan(const float* __restrict__ x, const int* __restrict__ b,
                            float* __restrict__ pool, float* __restrict__ cntg,
                            int N, int col_off)
{
  const int t = threadIdx.x;
  const int c = t & 127;
  const int half = t >> 7;
  const int n0 = blockIdx.x * 256 + half * 128;
  if (n0 >= N) return;
  const int n1 = min(n0 + 128, N);
  float accum = 0.f;
  int cur = b[n0];
  int len = 0;
  for (int n = n0; n < n1; ++n) {
    int g = b[n];
    if (g != cur) {
      atomicAdd(&pool[(size_t)cur * 640 + col_off + c], accum);
      if (c == 0) atomicAdd(&cntg[cur], (float)len);
      accum = 0.f; len = 0; cur = g;
    }
    accum += x[(size_t)n * 128 + c];
    ++len;
  }
  atomicAdd(&pool[(size_t)cur * 640 + col_off + c], accum);
  if (c == 0) atomicAdd(&cntg[cur], (float)len);
}

// ======================= final MLP (one block per graph) =======================
__global__ void k_mlp(const float* __restrict__ pool, const float* __restrict__ cntg,
                      const float* __restrict__ W1, const float* __restrict__ b1,
                      const float* __restrict__ W2, const float* __restrict__ b2,
                      float* __restrict__ out)
{
  __shared__ float emb[640];
  __shared__ float red[128];
  const int g = blockIdx.x, t = threadIdx.x;
  for (int i = t; i < 640; i += 128) {
    int type = i >> 7;
    float cnt = cntg[type * GNUM + g];
    emb[i] = pool[(size_t)g * 640 + i] / fmaxf(cnt, 1.f);
  }
  __syncthreads();
  float acc = b1[t];
  for (int i = 0; i < 640; ++i) acc = fmaf(emb[i], W1[i * 128 + t], acc);
  float h = fmaxf(acc, 0.f);
  red[t] = h * W2[t];
  __syncthreads();
  for (int s = 64; s > 0; s >>= 1) {
    if (t < s) red[t] += red[t + s];
    __syncthreads();
  }
  if (t == 0) out[g] = red[0] + b2[0];
}

// ======================= host =======================
extern "C" void kernel_launch(void* const* d_in, const int* in_sizes, int n_in,
                              void* d_out, int out_size, void* d_ws, size_t ws_size,
                              hipStream_t stream)
{
  auto fin = [&](int i) { return (const float*)d_in[i]; };
  auto iin = [&](int i) { return (const int*)d_in[i]; };

  const float *x_cd = fin(0), *x_seq = fin(1), *x_anno = fin(2), *x_range = fin(3), *x_md = fin(4);
  const int *ei_seq = iin(5), *ei_anno = iin(6), *ei_range = iin(7),
            *ei_comp = iin(8), *ei_cc = iin(9), *ei_mm = iin(10);
  const int *b_cd = iin(11), *b_seq = iin(12), *b_anno = iin(13), *b_range = iin(14), *b_md = iin(15);

  const int N_CD = in_sizes[0] / HD, N_SEQ = in_sizes[1] / HD, N_ANNO = in_sizes[2] / HD,
            N_RANGE = in_sizes[3] / HD, N_MD = in_sizes[4] / HD;
  const int E_seq = in_sizes[5] / 2, E_anno = in_sizes[6] / 2, E_range = in_sizes[7] / 2,
            E_comp = in_sizes[8] / 2, E_cc = in_sizes[9] / 2, E_mm = in_sizes[10] / 2;
  const int N_OTH = max(max(N_SEQ, N_ANNO), N_RANGE);
  const int N_MAXD = max(N_CD, N_OTH);

  auto WLm = [&](int i, int l) { return fin(i) + (size_t)l * HD * HD; };
  auto WLv = [&](int i, int l) { return fin(i) + (size_t)l * HD; };

  // ---- workspace layout ----
  float* ws = (float*)d_ws;
  size_t off = 0;
  auto alloc = [&](size_t n) { float* p = ws + off; off += (n + 3) & ~(size_t)3; return p; };
  float* xcd1 = alloc((size_t)N_CD * HD);
  float* xmd1 = alloc((size_t)N_MD * HD);
  float* xoth = alloc((size_t)N_OTH * HD);
  float* acc  = alloc((size_t)N_CD * HD);
  float* t1   = alloc((size_t)N_CD * HD);
  float* sAs  = alloc((size_t)N_CD);
  float* sAd  = alloc((size_t)N_CD);
  float* dis_cc = alloc((size_t)N_CD);
  float* dis_mm = alloc((size_t)N_MD);
  float* wvecS = alloc(HD);
  float* wvecD = alloc(HD);
  float* pool = alloc((size_t)GNUM * 5 * HD);
  float* cntg = alloc(5 * GNUM);
  // bf16 pre-split weights: 16 slots (8 matrices x 2 layers), transposed [n][k]
  short* whi = (short*)(ws + off); off += (size_t)16 * 16384 / 2;
  short* wlo = (short*)(ws + off); off += (size_t)16 * 16384 / 2;
  auto alloci = [&](size_t n) { int* p = (int*)(ws + off); off += (n + 3) & ~(size_t)3; return p; };
  int* wp = alloci((size_t)N_MAXD);
  int* bsums = alloci(1024);
  int *rp_seq = alloci((size_t)N_SEQ + 1),  *col_seq = alloci((size_t)E_seq);
  int *rp_anno = alloci((size_t)N_ANNO + 1), *col_anno = alloci((size_t)E_anno);
  int *rp_range = alloci((size_t)N_RANGE + 1), *col_range = alloci((size_t)E_range);
  int *rp_comp = alloci((size_t)N_CD + 1),  *col_comp = alloci((size_t)E_comp);
  int *rp_cc = alloci((size_t)N_CD + 1),    *col_cc = alloci((size_t)E_cc);
  int *rp_mm = alloci((size_t)N_MD + 1),    *col_mm = alloci((size_t)E_mm);
  (void)n_in;

  if (off * sizeof(float) > ws_size) {
    hipMemsetAsync(d_out, 0, (size_t)out_size * sizeof(float), stream);
    return;
  }

  auto ew = [&](size_t elems) { return dim3((unsigned)((elems + 255) / 256)); };
  auto nw = [&](int N) { return dim3((unsigned)((N + 3) / 4)); };

  // ---- pre-split all GEMM weights (slots: 0:16 1:18 2:19 3:21 4:22 5:27 6:32 7:34)
  WTab tab;
  tab.p[0] = fin(16); tab.p[1] = fin(18); tab.p[2] = fin(19); tab.p[3] = fin(21);
  tab.p[4] = fin(22); tab.p[5] = fin(27); tab.p[6] = fin(32); tab.p[7] = fin(34);
  k_split_w<<<dim3(1024), dim3(256), 0, stream>>>(tab, whi, wlo);

  auto WH = [&](int sidx, int layer) { return whi + (size_t)(sidx * 2 + layer) * 16384; };
  auto WL = [&](int sidx, int layer) { return wlo + (size_t)(sidx * 2 + layer) * 16384; };
  auto gemm = [&](const float* A, int sidx, int layer, float* C, const float* b,
                  int N, int relu) {
    k_gemm_mfma<<<dim3((N + 63) / 64), dim3(256), 0, stream>>>(
        A, WH(sidx, layer), WL(sidx, layer), nullptr, nullptr, nullptr, C, b, N, relu);
  };
  auto gemm2 = [&](const float* A1, int s1, const float* A2, int s2, int layer,
                   float* C, const float* b, int N, int relu) {
    k_gemm_mfma<<<dim3((N + 63) / 64), dim3(256), 0, stream>>>(
        A1, WH(s1, layer), WL(s1, layer), A2, WH(s2, layer), WL(s2, layer), C, b, N, relu);
  };
  auto do_pool = [&](const float* x, const int* b, int N, int type) {
    k_pool_scan<<<ew(N), dim3(256), 0, stream>>>(x, b, pool, cntg + type * GNUM, N, type * HD);
  };

  // ---- build all CSRs (multi-block scan) ----
  auto build = [&](const int* ei, int E, int Nd, int* rp, int* col) {
    hipMemsetAsync(rp, 0, ((size_t)Nd + 1) * 4, stream);
    k_hist<<<ew(E), dim3(256), 0, stream>>>(ei + E, rp, E);
    int nb = (Nd + 4095) / 4096;
    k_scan_partial<<<dim3(nb), dim3(256), 0, stream>>>(rp, bsums, Nd);
    k_scan_bsums<<<dim3(1), dim3(1024), 0, stream>>>(bsums, nb, rp + Nd);
    k_scan_final<<<dim3(nb), dim3(256), 0, stream>>>(rp, bsums, Nd);
    k_copyint<<<ew(Nd), dim3(256), 0, stream>>>(wp, rp, Nd);
    k_fill<<<ew(E), dim3(256), 0, stream>>>(ei, ei + E, wp, col, E);
  };
  build(ei_seq, E_seq, N_SEQ, rp_seq, col_seq);
  build(ei_anno, E_anno, N_ANNO, rp_anno, col_anno);
  build(ei_range, E_range, N_RANGE, rp_range, col_range);
  build(ei_comp, E_comp, N_CD, rp_comp, col_comp);
  build(ei_cc, E_cc, N_CD, rp_cc, col_cc);
  build(ei_mm, E_mm, N_MD, rp_mm, col_mm);
  k_dis<<<ew(N_CD), dim3(256), 0, stream>>>(rp_cc, dis_cc, N_CD);
  k_dis<<<ew(N_MD), dim3(256), 0, stream>>>(rp_mm, dis_mm, N_MD);

  // GAT: sAs = xs.(Ws@a_s), sAd = xd.(Wd@a_d); hs = xs@Ws (MFMA); fused gather.
  auto gat = [&](const float* xs, const float* xd, const int* rp, const int* col,
                 int Ns, int Nd, int sidx, int layer, const float* Wsm, const float* Wdm,
                 const float* avs, const float* avd, const float* bias,
                 float* out, int relu) {
    k_matvec_right<<<dim3(1), dim3(128), 0, stream>>>(Wsm, avs, wvecS);
    k_rowdot<<<nw(Ns), dim3(256), 0, stream>>>(xs, wvecS, sAs, Ns);
    k_matvec_right<<<dim3(1), dim3(128), 0, stream>>>(Wdm, avd, wvecD);
    k_rowdot<<<nw(Nd), dim3(256), 0, stream>>>(xd, wvecD, sAd, Nd);
    gemm(xs, sidx, layer, t1, nullptr, Ns, 0);   // hs
    k_gat_gather<<<nw(Nd), dim3(256), 0, stream>>>(rp, col, t1, sAs, sAd, bias, out, Nd, relu);
  };
  auto gcn = [&](const float* x, const int* rp, const int* col, const float* dis, int N,
                 int sidx, int layer, const float* b, const float* addin, float* out) {
    gemm(x, sidx, layer, t1, nullptr, N, 0);
    k_gcn_gather<<<nw(N), dim3(256), 0, stream>>>(rp, col, dis, t1, addin, b, out, N);
  };
  // SAGE: mean -> t1, out = relu(t1@Wl + xself@Wr + bl)  (single fused dual-A GEMM)
  auto sage = [&](const float* xsrc, const float* xself, const int* rp, const int* col,
                  int Nd, int sl, int sr, int layer, const float* bl, float* out) {
    k_sage_gather<<<nw(Nd), dim3(256), 0, stream>>>(rp, col, xsrc, t1, Nd);
    gemm2(t1, sl, xself, sr, layer, out, bl, Nd, 1);
  };

  hipMemsetAsync(pool, 0, (size_t)GNUM * 5 * HD * 4, stream);
  hipMemsetAsync(cntg, 0, 5 * GNUM * 4, stream);

  // ---------- CD + MD, both layers ----------
  gat(x_md, x_cd, rp_comp, col_comp, N_MD, N_CD, 4, 0,
      WLm(22, 0), WLm(23, 0), WLv(24, 0), WLv(25, 0), WLv(26, 0), acc, 0);
  gcn(x_cd, rp_cc, col_cc, dis_cc, N_CD, 6, 0, WLv(33, 0), acc, xcd1);
  gcn(x_md, rp_mm, col_mm, dis_mm, N_MD, 7, 0, WLv(35, 0), nullptr, xmd1);
  gat(xmd1, xcd1, rp_comp, col_comp, N_MD, N_CD, 4, 1,
      WLm(22, 1), WLm(23, 1), WLv(24, 1), WLv(25, 1), WLv(26, 1), acc, 0);
  gcn(xcd1, rp_cc, col_cc, dis_cc, N_CD, 6, 1, WLv(33, 1), acc, acc);
  do_pool(acc, b_cd, N_CD, 0);
  gcn(xmd1, rp_mm, col_mm, dis_mm, N_MD, 7, 1, WLv(35, 1), nullptr, acc);
  do_pool(acc, b_md, N_MD, 4);

  // ---------- SEQ ----------
  sage(x_cd, x_seq, rp_seq, col_seq, N_SEQ, 0, 1, 0, WLv(17, 0), xoth);
  sage(xcd1, xoth, rp_seq, col_seq, N_SEQ, 0, 1, 1, WLv(17, 1), acc);
  do_pool(acc, b_seq, N_SEQ, 1);
  // ---------- ANNO ----------
  sage(x_cd, x_anno, rp_anno, col_anno, N_ANNO, 2, 3, 0, WLv(20, 0), xoth);
  sage(xcd1, xoth, rp_anno, col_anno, N_ANNO, 2, 3, 1, WLv(20, 1), acc);
  do_pool(acc, b_anno, N_ANNO, 2);
  // ---------- RANGE ----------
  gat(x_cd, x_range, rp_range, col_range, N_CD, N_RANGE, 5, 0,
      WLm(27, 0), WLm(28, 0), WLv(29, 0), WLv(30, 0), WLv(31, 0), xoth, 1);
  gat(xcd1, xoth, rp_range, col_range, N_CD, N_RANGE, 5, 1,
      WLm(27, 1), WLm(28, 1), WLv(29, 1), WLv(30, 1), WLv(31, 1), acc, 1);
  do_pool(acc, b_range, N_RANGE, 3);

  k_mlp<<<dim3(GNUM), dim3(128), 0, stream>>>(
      pool, cntg, fin(36), fin(37), fin(38), fin(39), (float*)d_out);
}

// Round 8
// 1467.889 us; speedup vs baseline: 1.8622x; 1.0539x over previous
//
#include <hip/hip_runtime.h>

#define HD 128
#define GNUM 512

typedef __attribute__((ext_vector_type(8))) short short8v;   // 8 bf16 = 4 VGPR
typedef __attribute__((ext_vector_type(4))) float f32x4;

// RNE split: a ~= hi + lo (both bf16), |residual| ~ 2^-17 |a|
__device__ __forceinline__ void split1(float a, short& h, short& l) {
  unsigned u = __float_as_uint(a);
  unsigned hb = (u + 0x7FFFu + ((u >> 16) & 1u)) & 0xFFFF0000u;
  h = (short)(hb >> 16);
  float rest = a - __uint_as_float(hb);
  unsigned u2 = __float_as_uint(rest);
  l = (short)((u2 + 0x7FFFu + ((u2 >> 16) & 1u)) >> 16);
}

// ============ W pre-split: fp32 [k][n] -> bf16 hi/lo TRANSPOSED [n][k] ============
struct WTab { const float* p[8]; };
__global__ __launch_bounds__(256) void k_split_w(WTab tab, short* __restrict__ whi,
                                                 short* __restrict__ wlo)
{
  int m = blockIdx.x >> 6;                       // 16 matrices, 64 blocks each
  int i = (blockIdx.x & 63) * 256 + threadIdx.x; // 0..16383
  const float* W = tab.p[m >> 1] + (m & 1) * 16384;
  int k = i >> 7, n = i & 127;
  short h, l;
  split1(W[k * 128 + n], h, l);
  whi[m * 16384 + n * 128 + k] = h;
  wlo[m * 16384 + n * 128 + k] = l;
}

// ============ MFMA GEMM: C = A1@W1 (+ A2@W2) (+bias, relu) ====================
// Split-bf16: A@W = Ah@Wh + Al@Wh + Ah@Wl. 64 rows/block, 4 waves of 64r x 32c.
// W pre-split bf16, transposed [col][k]. Epilogue goes through LDS for coalesced
// float4 stores.
#define CF_LD 132   // fp32 LDS C-tile stride (2-way bank alias max)
__global__ __launch_bounds__(256) void k_gemm_mfma(
    const float* __restrict__ A1, const short* __restrict__ WH1, const short* __restrict__ WL1,
    const float* __restrict__ A2, const short* __restrict__ WH2, const short* __restrict__ WL2,
    float* __restrict__ C, const float* __restrict__ bias, int N, int relu)
{
  __shared__ char smem[64 * 136 * 2 * 2];        // 34816 B (>= 64*132*4 = 33792)
  short* Ah = (short*)smem;
  short* Al = Ah + 64 * 136;
  float* Cf = (float*)smem;

  const int t = threadIdx.x;
  const int row0 = blockIdx.x * 64;
  const int lane = t & 63, wid = t >> 6;
  const int g = lane >> 4, cn = lane & 15;
  const int colbase = wid * 32;

  f32x4 zero = {0.f, 0.f, 0.f, 0.f};
  f32x4 acc[4][2];
#pragma unroll
  for (int rt = 0; rt < 4; ++rt) { acc[rt][0] = zero; acc[rt][1] = zero; }

  auto stageA = [&](const float* __restrict__ A) {
    const float4* A4 = (const float4*)(A + (size_t)row0 * 128);
#pragma unroll
    for (int i = 0; i < 8; ++i) {
      int f4 = t + i * 256;                      // 2048 float4 = 64 rows
      int row = f4 >> 5, c4 = f4 & 31;
      float4 v = make_float4(0.f, 0.f, 0.f, 0.f);
      if (row0 + row < N) v = A4[f4];
      short4 h, l;
      split1(v.x, h.x, l.x); split1(v.y, h.y, l.y);
      split1(v.z, h.z, l.z); split1(v.w, h.w, l.w);
      *(short4*)(Ah + row * 136 + c4 * 4) = h;
      *(short4*)(Al + row * 136 + c4 * 4) = l;
    }
  };

  auto accum = [&](const short* __restrict__ WH, const short* __restrict__ WL) {
    short8v bhi[2][4], blo[2][4];
#pragma unroll
    for (int ct = 0; ct < 2; ++ct)
#pragma unroll
      for (int kg = 0; kg < 4; ++kg) {
        size_t o = (size_t)(colbase + ct * 16 + cn) * 128 + kg * 32 + g * 8;
        bhi[ct][kg] = *(const short8v*)(WH + o);
        blo[ct][kg] = *(const short8v*)(WL + o);
      }
#pragma unroll
    for (int kg = 0; kg < 4; ++kg) {
#pragma unroll
      for (int rt = 0; rt < 4; ++rt) {
        const int ao = (rt * 16 + cn) * 136 + kg * 32 + g * 8;
        const short8v ah = *(const short8v*)(Ah + ao);
        const short8v al = *(const short8v*)(Al + ao);
#pragma unroll
        for (int ct = 0; ct < 2; ++ct) {
          acc[rt][ct] = __builtin_amdgcn_mfma_f32_16x16x32_bf16(ah, bhi[ct][kg], acc[rt][ct], 0, 0, 0);
          acc[rt][ct] = __builtin_amdgcn_mfma_f32_16x16x32_bf16(al, bhi[ct][kg], acc[rt][ct], 0, 0, 0);
          acc[rt][ct] = __builtin_amdgcn_mfma_f32_16x16x32_bf16(ah, blo[ct][kg], acc[rt][ct], 0, 0, 0);
        }
      }
    }
  };

  stageA(A1);
  __syncthreads();
  accum(WH1, WL1);
  if (A2) {
    __syncthreads();
    stageA(A2);
    __syncthreads();
    accum(WH2, WL2);
  }
  __syncthreads();

  // scatter acc into LDS C-tile: C/D layout col = lane&15, row = (lane>>4)*4 + reg
#pragma unroll
  for (int rt = 0; rt < 4; ++rt)
#pragma unroll
    for (int ct = 0; ct < 2; ++ct)
#pragma unroll
      for (int r = 0; r < 4; ++r)
        Cf[(rt * 16 + g * 4 + r) * CF_LD + colbase + ct * 16 + cn] = acc[rt][ct][r];
  __syncthreads();

  float4* C4 = (float4*)(C + (size_t)row0 * 128);
#pragma unroll
  for (int i = 0; i < 8; ++i) {
    int f4 = t + i * 256;
    int row = f4 >> 5, c4 = f4 & 31;
    if (row0 + row < N) {
      float4 v = *(const float4*)(Cf + row * CF_LD + c4 * 4);
      if (bias) {
        float4 bv = *(const float4*)(bias + c4 * 4);
        v.x += bv.x; v.y += bv.y; v.z += bv.z; v.w += bv.w;
      }
      if (relu) {
        v.x = fmaxf(v.x, 0.f); v.y = fmaxf(v.y, 0.f);
        v.z = fmaxf(v.z, 0.f); v.w = fmaxf(v.w, 0.f);
      }
      C4[f4] = v;
    }
  }
}

// ======================= row dot: out[n] = x[n,:] . a  (one wave / node) ===========
__global__ void k_rowdot(const float* __restrict__ x, const float* __restrict__ a,
                         float* __restrict__ out, int N)
{
  int wid = blockIdx.x * 4 + (threadIdx.x >> 6);
  int lane = threadIdx.x & 63;
  if (wid >= N) return;
  float2 xv = ((const float2*)x)[(size_t)wid * 64 + lane];
  float2 av = ((const float2*)a)[lane];
  float v = fmaf(xv.y, av.y, xv.x * av.x);
#pragma unroll
  for (int o = 32; o > 0; o >>= 1) v += __shfl_down(v, o);
  if (lane == 0) out[wid] = v;
}

// ======================= wvec[i] = sum_j W[i,j]*a[j]  (one block, 128 thr) =========
__global__ void k_matvec_right(const float* __restrict__ W, const float* __restrict__ a,
                               float* __restrict__ wvec)
{
  __shared__ float as[128];
  int i = threadIdx.x;
  as[i] = a[i];
  __syncthreads();
  float v = 0.f;
  for (int j = 0; j < 128; ++j) v = fmaf(W[i * 128 + j], as[j], v);
  wvec[i] = v;
}

// ======================= CSR build =======================
__global__ void k_hist(const int* __restrict__ ed, int* __restrict__ cnt, int E) {
  int e = blockIdx.x * 256 + threadIdx.x;
  if (e < E) atomicAdd(&cnt[ed[e]], 1);
}

__global__ __launch_bounds__(256) void k_scan_partial(
    const int* __restrict__ rp, int* __restrict__ bsums, int N)
{
  __shared__ int red[256];
  const int t = threadIdx.x, base = blockIdx.x * 4096;
  int s = 0;
  for (int i = t; i < 4096; i += 256) {
    int idx = base + i;
    if (idx < N) s += rp[idx];
  }
  red[t] = s;
  __syncthreads();
  for (int ofs = 128; ofs > 0; ofs >>= 1) {
    if (t < ofs) red[t] += red[t + ofs];
    __syncthreads();
  }
  if (t == 0) bsums[blockIdx.x] = red[0];
}

__global__ __launch_bounds__(1024) void k_scan_bsums(
    int* __restrict__ bsums, int nb, int* __restrict__ rpN)
{
  __shared__ int sh[1024];
  const int t = threadIdx.x;
  int v = (t < nb) ? bsums[t] : 0;
  sh[t] = v;
  __syncthreads();
  for (int ofs = 1; ofs < 1024; ofs <<= 1) {
    int u = (t >= ofs) ? sh[t - ofs] : 0;
    __syncthreads();
    sh[t] += u;
    __syncthreads();
  }
  if (t < nb) bsums[t] = sh[t] - v;      // exclusive
  if (t == 1023) rpN[0] = sh[1023];      // total
}

__global__ __launch_bounds__(256) void k_scan_final(
    int* __restrict__ rp, const int* __restrict__ bsums, int N)
{
  __shared__ int sh[4096 + 256];         // padded: i -> i + (i>>4)
  __shared__ int tsum[256];
  const int t = threadIdx.x, base = blockIdx.x * 4096;
  auto mp = [](int i) { return i + (i >> 4); };
#pragma unroll
  for (int i = 0; i < 16; ++i) {
    int idx = base + i * 256 + t;
    sh[mp(i * 256 + t)] = (idx < N) ? rp[idx] : 0;
  }
  __syncthreads();
  int s = 0;
#pragma unroll
  for (int j = 0; j < 16; ++j) s += sh[mp(t * 16 + j)];
  tsum[t] = s;
  __syncthreads();
  for (int ofs = 1; ofs < 256; ofs <<= 1) {
    int u = (t >= ofs) ? tsum[t - ofs] : 0;
    __syncthreads();
    tsum[t] += u;
    __syncthreads();
  }
  int pre = tsum[t] - s + bsums[blockIdx.x];
#pragma unroll
  for (int j = 0; j < 16; ++j) {
    int v = sh[mp(t * 16 + j)];
    sh[mp(t * 16 + j)] = pre;
    pre += v;
  }
  __syncthreads();
#pragma unroll
  for (int i = 0; i < 16; ++i) {
    int idx = base + i * 256 + t;
    if (idx < N) rp[idx] = sh[mp(i * 256 + t)];
  }
}

__global__ void k_copyint(int* __restrict__ dst, const int* __restrict__ src, int N) {
  int i = blockIdx.x * 256 + threadIdx.x;
  if (i < N) dst[i] = src[i];
}

__global__ void k_fill(const int* __restrict__ es, const int* __restrict__ ed,
                       int* __restrict__ wp, int* __restrict__ col, int E) {
  int e = blockIdx.x * 256 + threadIdx.x;
  if (e >= E) return;
  int p = atomicAdd(&wp[ed[e]], 1);
  col[p] = es[e];
}

__global__ void k_dis(const int* __restrict__ rp, float* __restrict__ dis, int N) {
  int n = blockIdx.x * 256 + threadIdx.x;
  if (n < N) dis[n] = rsqrtf((float)(rp[n + 1] - rp[n]) + 1.f);
}

// ======================= gather kernels =======================
// One wave per dst node. MLP pattern: 64 lanes coalesce-prefetch col[] (+ per-src
// scalar), shfl-broadcast, then 2-way unrolled independent row fetches.

__global__ void k_sage_gather(const int* __restrict__ rp, const int* __restrict__ col,
                              const float* __restrict__ x, float* __restrict__ out, int N)
{
  int node = blockIdx.x * 4 + (threadIdx.x >> 6);
  if (node >= N) return;
  int lane = threadIdx.x & 63;
  int s0 = rp[node], deg = rp[node + 1] - s0;
  const float2* x2 = (const float2*)x;
  float a0 = 0.f, a1 = 0.f, b0 = 0.f, b1 = 0.f;
  for (int base = 0; base < deg; base += 64) {
    int m = min(64, deg - base);
    int c = (lane < m) ? col[s0 + base + lane] : 0;
    int j = 0;
    for (; j + 1 < m; j += 2) {
      int sA = __shfl(c, j), sB = __shfl(c, j + 1);
      float2 vA = x2[(size_t)sA * 64 + lane];
      float2 vB = x2[(size_t)sB * 64 + lane];
      a0 += vA.x; a1 += vA.y; b0 += vB.x; b1 += vB.y;
    }
    if (j < m) {
      int sA = __shfl(c, j);
      float2 vA = x2[(size_t)sA * 64 + lane];
      a0 += vA.x; a1 += vA.y;
    }
  }
  float inv = 1.f / fmaxf((float)deg, 1.f);
  ((float2*)out)[(size_t)node * 64 + lane] = make_float2((a0 + b0) * inv, (a1 + b1) * inv);
}

__global__ void k_gcn_gather(const int* __restrict__ rp, const int* __restrict__ col,
                             const float* __restrict__ dis, const float* __restrict__ h,
                             const float* addin, const float* __restrict__ b,
                             float* out, int N)
{
  int node = blockIdx.x * 4 + (threadIdx.x >> 6);
  if (node >= N) return;
  int lane = threadIdx.x & 63;
  int s0 = rp[node], deg = rp[node + 1] - s0;
  float rd = dis[node];
  const float2* h2 = (const float2*)h;
  float a0 = 0.f, a1 = 0.f, b0 = 0.f, b1 = 0.f;
  for (int base = 0; base < deg; base += 64) {
    int m = min(64, deg - base);
    int c = 0; float dv = 0.f;
    if (lane < m) { c = col[s0 + base + lane]; dv = dis[c]; }
    int j = 0;
    for (; j + 1 < m; j += 2) {
      int sA = __shfl(c, j), sB = __shfl(c, j + 1);
      float nA = __shfl(dv, j) * rd, nB = __shfl(dv, j + 1) * rd;
      float2 vA = h2[(size_t)sA * 64 + lane];
      float2 vB = h2[(size_t)sB * 64 + lane];
      a0 = fmaf(nA, vA.x, a0); a1 = fmaf(nA, vA.y, a1);
      b0 = fmaf(nB, vB.x, b0); b1 = fmaf(nB, vB.y, b1);
    }
    if (j < m) {
      int sA = __shfl(c, j);
      float nA = __shfl(dv, j) * rd;
      float2 vA = h2[(size_t)sA * 64 + lane];
      a0 = fmaf(nA, vA.x, a0); a1 = fmaf(nA, vA.y, a1);
    }
  }
  float rr = rd * rd;
  float2 hself = h2[(size_t)node * 64 + lane];
  float2 bv = ((const float2*)b)[lane];
  float ad0 = 0.f, ad1 = 0.f;
  if (addin) {
    float2 a2 = ((const float2*)addin)[(size_t)node * 64 + lane];
    ad0 = a2.x; ad1 = a2.y;
  }
  float v0 = fmaf(rr, hself.x, a0 + b0) + bv.x + ad0;
  float v1 = fmaf(rr, hself.y, a1 + b1) + bv.y + ad1;
  ((float2*)out)[(size_t)node * 64 + lane] = make_float2(fmaxf(v0, 0.f), fmaxf(v1, 0.f));
}

// GAT fused, single edge-walk (no max subtraction: logits O(1), exp-safe).
__global__ void k_gat_gather(const int* __restrict__ rp, const int* __restrict__ col,
                             const float* __restrict__ hs, const float* __restrict__ as_,
                             const float* __restrict__ ad_, const float* __restrict__ b,
                             float* __restrict__ out, int N, int relu)
{
  int node = blockIdx.x * 4 + (threadIdx.x >> 6);
  if (node >= N) return;
  int lane = threadIdx.x & 63;
  int s0 = rp[node], deg = rp[node + 1] - s0;
  float adn = ad_[node];
  const float2* hs2 = (const float2*)hs;
  float z = 0.f, a0 = 0.f, a1 = 0.f, b0 = 0.f, b1 = 0.f;
  for (int base = 0; base < deg; base += 64) {
    int m = min(64, deg - base);
    int c = 0; float av = 0.f;
    if (lane < m) { c = col[s0 + base + lane]; av = as_[c]; }
    int j = 0;
    for (; j + 1 < m; j += 2) {
      int sA = __shfl(c, j), sB = __shfl(c, j + 1);
      float vA = __shfl(av, j) + adn, vB = __shfl(av, j + 1) + adn;
      vA = vA > 0.f ? vA : 0.2f * vA;
      vB = vB > 0.f ? vB : 0.2f * vB;
      float pA = __expf(vA), pB = __expf(vB);
      z += pA + pB;
      float2 hA = hs2[(size_t)sA * 64 + lane];
      float2 hB = hs2[(size_t)sB * 64 + lane];
      a0 = fmaf(pA, hA.x, a0); a1 = fmaf(pA, hA.y, a1);
      b0 = fmaf(pB, hB.x, b0); b1 = fmaf(pB, hB.y, b1);
    }
    if (j < m) {
      int sA = __shfl(c, j);
      float vA = __shfl(av, j) + adn;
      vA = vA > 0.f ? vA : 0.2f * vA;
      float pA = __expf(vA);
      z += pA;
      float2 hA = hs2[(size_t)sA * 64 + lane];
      a0 = fmaf(pA, hA.x, a0); a1 = fmaf(pA, hA.y, a1);
    }
  }
  float inv = (deg > 0) ? 1.f / z : 0.f;
  float2 bv = ((const float2*)b)[lane];
  float v0 = fmaf(a0 + b0, inv, bv.x);
  float v1 = fmaf(a1 + b1, inv, bv.y);
  if (relu) { v0 = fmaxf(v0, 0.f); v1 = fmaxf(v1, 0.f); }
  ((float2*)out)[(size_t)node * 64 + lane] = make_float2(v0, v1);
}

// ======================= pooling (b sorted -> run-length + atomics) ================
__global__ void k_pool_scan(const float* __restrict__ x, const int* __restrict__ b,
                            float* __restrict__ pool, float* __restrict__ cntg,
                            int N, int col_off)
{
  const int t = threadIdx.x;
  const int c = t & 127;
  const int half = t >> 7;
  const int n0 = blockIdx.x * 256 + half * 128;
  if (n0 >= N) return;
  const int n1 = min(n0 + 128, N);
  float accum = 0.f;
  int cur = b[n0];
  int len = 0;
  for (int n = n0; n < n1; ++n) {
    int g = b[n];
    if (g != cur) {
      atomicAdd(&pool[(size_t)cur * 640 + col_off + c], accum);
      if (c == 0) atomicAdd(&cntg[cur], (float)len);
      accum = 0.f; len = 0; cur = g;
    }
    accum += x[(size_t)n * 128 + c];
    ++len;
  }
  atomicAdd(&pool[(size_t)cur * 640 + col_off + c], accum);
  if (c == 0) atomicAdd(&cntg[cur], (float)len);
}

// ======================= final MLP (one block per graph) =======================
__global__ void k_mlp(const float* __restrict__ pool, const float* __restrict__ cntg,
                      const float* __restrict__ W1, const float* __restrict__ b1,
                      const float* __restrict__ W2, const float* __restrict__ b2,
                      float* __restrict__ out)
{
  __shared__ float emb[640];
  __shared__ float red[128];
  const int g = blockIdx.x, t = threadIdx.x;
  for (int i = t; i < 640; i += 128) {
    int type = i >> 7;
    float cnt = cntg[type * GNUM + g];
    emb[i] = pool[(size_t)g * 640 + i] / fmaxf(cnt, 1.f);
  }
  __syncthreads();
  float acc = b1[t];
  for (int i = 0; i < 640; ++i) acc = fmaf(emb[i], W1[i * 128 + t], acc);
  float h = fmaxf(acc, 0.f);
  red[t] = h * W2[t];
  __syncthreads();
  for (int s = 64; s > 0; s >>= 1) {
    if (t < s) red[t] += red[t + s];
    __syncthreads();
  }
  if (t == 0) out[g] = red[0] + b2[0];
}

// ======================= host =======================
extern "C" void kernel_launch(void* const* d_in, const int* in_sizes, int n_in,
                              void* d_out, int out_size, void* d_ws, size_t ws_size,
                              hipStream_t stream)
{
  auto fin = [&](int i) { return (const float*)d_in[i]; };
  auto iin = [&](int i) { return (const int*)d_in[i]; };

  const float *x_cd = fin(0), *x_seq = fin(1), *x_anno = fin(2), *x_range = fin(3), *x_md = fin(4);
  const int *ei_seq = iin(5), *ei_anno = iin(6), *ei_range = iin(7),
            *ei_comp = iin(8), *ei_cc = iin(9), *ei_mm = iin(10);
  const int *b_cd = iin(11), *b_seq = iin(12), *b_anno = iin(13), *b_range = iin(14), *b_md = iin(15);

  const int N_CD = in_sizes[0] / HD, N_SEQ = in_sizes[1] / HD, N_ANNO = in_sizes[2] / HD,
            N_RANGE = in_sizes[3] / HD, N_MD = in_sizes[4] / HD;
  const int E_seq = in_sizes[5] / 2, E_anno = in_sizes[6] / 2, E_range = in_sizes[7] / 2,
            E_comp = in_sizes[8] / 2, E_cc = in_sizes[9] / 2, E_mm = in_sizes[10] / 2;
  const int N_OTH = max(max(N_SEQ, N_ANNO), N_RANGE);
  const int N_MAXD = max(N_CD, N_OTH);

  auto WLm = [&](int i, int l) { return fin(i) + (size_t)l * HD * HD; };
  auto WLv = [&](int i, int l) { return fin(i) + (size_t)l * HD; };

  // ---- workspace layout ----
  float* ws = (float*)d_ws;
  size_t off = 0;
  auto alloc = [&](size_t n) { float* p = ws + off; off += (n + 3) & ~(size_t)3; return p; };
  float* xcd1 = alloc((size_t)N_CD * HD);
  float* xmd1 = alloc((size_t)N_MD * HD);
  float* xoth = alloc((size_t)N_OTH * HD);
  float* acc  = alloc((size_t)N_CD * HD);
  float* t1   = alloc((size_t)N_CD * HD);
  float* sAs  = alloc((size_t)N_CD);
  float* sAd  = alloc((size_t)N_CD);
  float* dis_cc = alloc((size_t)N_CD);
  float* dis_mm = alloc((size_t)N_MD);
  float* wvecS = alloc(HD);
  float* wvecD = alloc(HD);
  float* pool = alloc((size_t)GNUM * 5 * HD);
  float* cntg = alloc(5 * GNUM);
  short* whi = (short*)(ws + off); off += (size_t)16 * 16384 / 2;
  short* wlo = (short*)(ws + off); off += (size_t)16 * 16384 / 2;
  auto alloci = [&](size_t n) { int* p = (int*)(ws + off); off += (n + 3) & ~(size_t)3; return p; };
  int* wp = alloci((size_t)N_MAXD);
  int* bsums = alloci(1024);
  int *rp_seq = alloci((size_t)N_SEQ + 1),  *col_seq = alloci((size_t)E_seq);
  int *rp_anno = alloci((size_t)N_ANNO + 1), *col_anno = alloci((size_t)E_anno);
  int *rp_range = alloci((size_t)N_RANGE + 1), *col_range = alloci((size_t)E_range);
  int *rp_comp = alloci((size_t)N_CD + 1),  *col_comp = alloci((size_t)E_comp);
  int *rp_cc = alloci((size_t)N_CD + 1),    *col_cc = alloci((size_t)E_cc);
  int *rp_mm = alloci((size_t)N_MD + 1),    *col_mm = alloci((size_t)E_mm);
  (void)n_in;

  if (off * sizeof(float) > ws_size) {
    hipMemsetAsync(d_out, 0, (size_t)out_size * sizeof(float), stream);
    return;
  }

  auto ew = [&](size_t elems) { return dim3((unsigned)((elems + 255) / 256)); };
  auto nw = [&](int N) { return dim3((unsigned)((N + 3) / 4)); };

  // ---- pre-split all GEMM weights (slots: 0:16 1:18 2:19 3:21 4:22 5:27 6:32 7:34)
  WTab tab;
  tab.p[0] = fin(16); tab.p[1] = fin(18); tab.p[2] = fin(19); tab.p[3] = fin(21);
  tab.p[4] = fin(22); tab.p[5] = fin(27); tab.p[6] = fin(32); tab.p[7] = fin(34);
  k_split_w<<<dim3(1024), dim3(256), 0, stream>>>(tab, whi, wlo);

  auto WH = [&](int sidx, int layer) { return whi + (size_t)(sidx * 2 + layer) * 16384; };
  auto WL = [&](int sidx, int layer) { return wlo + (size_t)(sidx * 2 + layer) * 16384; };
  auto gemm = [&](const float* A, int sidx, int layer, float* C, const float* b,
                  int N, int relu) {
    k_gemm_mfma<<<dim3((N + 63) / 64), dim3(256), 0, stream>>>(
        A, WH(sidx, layer), WL(sidx, layer), nullptr, nullptr, nullptr, C, b, N, relu);
  };
  auto gemm2 = [&](const float* A1, int s1, const float* A2, int s2, int layer,
                   float* C, const float* b, int N, int relu) {
    k_gemm_mfma<<<dim3((N + 63) / 64), dim3(256), 0, stream>>>(
        A1, WH(s1, layer), WL(s1, layer), A2, WH(s2, layer), WL(s2, layer), C, b, N, relu);
  };
  auto do_pool = [&](const float* x, const int* b, int N, int type) {
    k_pool_scan<<<ew(N), dim3(256), 0, stream>>>(x, b, pool, cntg + type * GNUM, N, type * HD);
  };

  // ---- build all CSRs (multi-block scan) ----
  auto build = [&](const int* ei, int E, int Nd, int* rp, int* col) {
    hipMemsetAsync(rp, 0, ((size_t)Nd + 1) * 4, stream);
    k_hist<<<ew(E), dim3(256), 0, stream>>>(ei + E, rp, E);
    int nb = (Nd + 4095) / 4096;
    k_scan_partial<<<dim3(nb), dim3(256), 0, stream>>>(rp, bsums, Nd);
    k_scan_bsums<<<dim3(1), dim3(1024), 0, stream>>>(bsums, nb, rp + Nd);
    k_scan_final<<<dim3(nb), dim3(256), 0, stream>>>(rp, bsums, Nd);
    k_copyint<<<ew(Nd), dim3(256), 0, stream>>>(wp, rp, Nd);
    k_fill<<<ew(E), dim3(256), 0, stream>>>(ei, ei + E, wp, col, E);
  };
  build(ei_seq, E_seq, N_SEQ, rp_seq, col_seq);
  build(ei_anno, E_anno, N_ANNO, rp_anno, col_anno);
  build(ei_range, E_range, N_RANGE, rp_range, col_range);
  build(ei_comp, E_comp, N_CD, rp_comp, col_comp);
  build(ei_cc, E_cc, N_CD, rp_cc, col_cc);
  build(ei_mm, E_mm, N_MD, rp_mm, col_mm);
  k_dis<<<ew(N_CD), dim3(256), 0, stream>>>(rp_cc, dis_cc, N_CD);
  k_dis<<<ew(N_MD), dim3(256), 0, stream>>>(rp_mm, dis_mm, N_MD);

  // GAT: sAs = xs.(Ws@a_s), sAd = xd.(Wd@a_d); hs = xs@Ws (MFMA); fused gather.
  auto gat = [&](const float* xs, const float* xd, const int* rp, const int* col,
                 int Ns, int Nd, int sidx, int layer, const float* Wsm, const float* Wdm,
                 const float* avs, const float* avd, const float* bias,
                 float* out, int relu) {
    k_matvec_right<<<dim3(1), dim3(128), 0, stream>>>(Wsm, avs, wvecS);
    k_rowdot<<<nw(Ns), dim3(256), 0, stream>>>(xs, wvecS, sAs, Ns);
    k_matvec_right<<<dim3(1), dim3(128), 0, stream>>>(Wdm, avd, wvecD);
    k_rowdot<<<nw(Nd), dim3(256), 0, stream>>>(xd, wvecD, sAd, Nd);
    gemm(xs, sidx, layer, t1, nullptr, Ns, 0);   // hs
    k_gat_gather<<<nw(Nd), dim3(256), 0, stream>>>(rp, col, t1, sAs, sAd, bias, out, Nd, relu);
  };
  auto gcn = [&](const float* x, const int* rp, const int* col, const float* dis, int N,
                 int sidx, int layer, const float* b, const float* addin, float* out) {
    gemm(x, sidx, layer, t1, nullptr, N, 0);
    k_gcn_gather<<<nw(N), dim3(256), 0, stream>>>(rp, col, dis, t1, addin, b, out, N);
  };
  // SAGE: mean -> t1, out = relu(t1@Wl + xself@Wr + bl)  (single fused dual-A GEMM)
  auto sage = [&](const float* xsrc, const float* xself, const int* rp, const int* col,
                  int Nd, int sl, int sr, int layer, const float* bl, float* out) {
    k_sage_gather<<<nw(Nd), dim3(256), 0, stream>>>(rp, col, xsrc, t1, Nd);
    gemm2(t1, sl, xself, sr, layer, out, bl, Nd, 1);
  };

  hipMemsetAsync(pool, 0, (size_t)GNUM * 5 * HD * 4, stream);
  hipMemsetAsync(cntg, 0, 5 * GNUM * 4, stream);

  // ---------- CD + MD, both layers ----------
  gat(x_md, x_cd, rp_comp, col_comp, N_MD, N_CD, 4, 0,
      WLm(22, 0), WLm(23, 0), WLv(24, 0), WLv(25, 0), WLv(26, 0), acc, 0);
  gcn(x_cd, rp_cc, col_cc, dis_cc, N_CD, 6, 0, WLv(33, 0), acc, xcd1);
  gcn(x_md, rp_mm, col_mm, dis_mm, N_MD, 7, 0, WLv(35, 0), nullptr, xmd1);
  gat(xmd1, xcd1, rp_comp, col_comp, N_MD, N_CD, 4, 1,
      WLm(22, 1), WLm(23, 1), WLv(24, 1), WLv(25, 1), WLv(26, 1), acc, 0);
  gcn(xcd1, rp_cc, col_cc, dis_cc, N_CD, 6, 1, WLv(33, 1), acc, acc);
  do_pool(acc, b_cd, N_CD, 0);
  gcn(xmd1, rp_mm, col_mm, dis_mm, N_MD, 7, 1, WLv(35, 1), nullptr, acc);
  do_pool(acc, b_md, N_MD, 4);

  // ---------- SEQ ----------
  sage(x_cd, x_seq, rp_seq, col_seq, N_SEQ, 0, 1, 0, WLv(17, 0), xoth);
  sage(xcd1, xoth, rp_seq, col_seq, N_SEQ, 0, 1, 1, WLv(17, 1), acc);
  do_pool(acc, b_seq, N_SEQ, 1);
  // ---------- ANNO ----------
  sage(x_cd, x_anno, rp_anno, col_anno, N_ANNO, 2, 3, 0, WLv(20, 0), xoth);
  sage(xcd1, xoth, rp_anno, col_anno, N_ANNO, 2, 3, 1, WLv(20, 1), acc);
  do_pool(acc, b_anno, N_ANNO, 2);
  // ---------- RANGE ----------
  gat(x_cd, x_range, rp_range, col_range, N_CD, N_RANGE, 5, 0,
      WLm(27, 0), WLm(28, 0), WLv(29, 0), WLv(30, 0), WLv(31, 0), xoth, 1);
  gat(xcd1, xoth, rp_range, col_range, N_CD, N_RANGE, 5, 1,
      WLm(27, 1), WLm(28, 1), WLv(29, 1), WLv(30, 1), WLv(31, 1), acc, 1);
  do_pool(acc, b_range, N_RANGE, 3);

  k_mlp<<<dim3(GNUM), dim3(128), 0, stream>>>(
      pool, cntg, fin(36), fin(37), fin(38), fin(39), (float*)d_out);
}

// Round 9
// 1303.367 us; speedup vs baseline: 2.0972x; 1.1262x over previous
//
#include <hip/hip_runtime.h>

#define HD 128
#define GNUM 512
#define RPB 520   // per-type stride in rpb_all (>= GNUM+1)

typedef __attribute__((ext_vector_type(8))) short short8v;   // 8 bf16 = 4 VGPR
typedef __attribute__((ext_vector_type(4))) float f32x4;

// RNE split: a ~= hi + lo (both bf16), |residual| ~ 2^-17 |a|
__device__ __forceinline__ void split1(float a, short& h, short& l) {
  unsigned u = __float_as_uint(a);
  unsigned hb = (u + 0x7FFFu + ((u >> 16) & 1u)) & 0xFFFF0000u;
  h = (short)(hb >> 16);
  float rest = a - __uint_as_float(hb);
  unsigned u2 = __float_as_uint(rest);
  l = (short)((u2 + 0x7FFFu + ((u2 >> 16) & 1u)) >> 16);
}

// ============ W pre-split: fp32 [k][n] -> bf16 hi/lo TRANSPOSED [n][k] ============
struct WTab { const float* p[8]; };
__global__ __launch_bounds__(256) void k_split_w(WTab tab, short* __restrict__ whi,
                                                 short* __restrict__ wlo)
{
  int m = blockIdx.x >> 6;                       // 16 matrices, 64 blocks each
  int i = (blockIdx.x & 63) * 256 + threadIdx.x; // 0..16383
  const float* W = tab.p[m >> 1] + (m & 1) * 16384;
  int k = i >> 7, n = i & 127;
  short h, l;
  split1(W[k * 128 + n], h, l);
  whi[m * 16384 + n * 128 + k] = h;
  wlo[m * 16384 + n * 128 + k] = l;
}

// ============ MFMA GEMM: C = A1@W1 (+ A2@W2) (+bias, relu) ====================
#define CF_LD 132
__global__ __launch_bounds__(256) void k_gemm_mfma(
    const float* __restrict__ A1, const short* __restrict__ WH1, const short* __restrict__ WL1,
    const float* __restrict__ A2, const short* __restrict__ WH2, const short* __restrict__ WL2,
    float* __restrict__ C, const float* __restrict__ bias, int N, int relu)
{
  __shared__ char smem[64 * 136 * 2 * 2];        // 34816 B
  short* Ah = (short*)smem;
  short* Al = Ah + 64 * 136;
  float* Cf = (float*)smem;

  const int t = threadIdx.x;
  const int row0 = blockIdx.x * 64;
  const int lane = t & 63, wid = t >> 6;
  const int g = lane >> 4, cn = lane & 15;
  const int colbase = wid * 32;

  f32x4 zero = {0.f, 0.f, 0.f, 0.f};
  f32x4 acc[4][2];
#pragma unroll
  for (int rt = 0; rt < 4; ++rt) { acc[rt][0] = zero; acc[rt][1] = zero; }

  auto stageA = [&](const float* __restrict__ A) {
    const float4* A4 = (const float4*)(A + (size_t)row0 * 128);
#pragma unroll
    for (int i = 0; i < 8; ++i) {
      int f4 = t + i * 256;
      int row = f4 >> 5, c4 = f4 & 31;
      float4 v = make_float4(0.f, 0.f, 0.f, 0.f);
      if (row0 + row < N) v = A4[f4];
      short4 h, l;
      split1(v.x, h.x, l.x); split1(v.y, h.y, l.y);
      split1(v.z, h.z, l.z); split1(v.w, h.w, l.w);
      *(short4*)(Ah + row * 136 + c4 * 4) = h;
      *(short4*)(Al + row * 136 + c4 * 4) = l;
    }
  };

  auto accum = [&](const short* __restrict__ WH, const short* __restrict__ WL) {
    short8v bhi[2][4], blo[2][4];
#pragma unroll
    for (int ct = 0; ct < 2; ++ct)
#pragma unroll
      for (int kg = 0; kg < 4; ++kg) {
        size_t o = (size_t)(colbase + ct * 16 + cn) * 128 + kg * 32 + g * 8;
        bhi[ct][kg] = *(const short8v*)(WH + o);
        blo[ct][kg] = *(const short8v*)(WL + o);
      }
#pragma unroll
    for (int kg = 0; kg < 4; ++kg) {
#pragma unroll
      for (int rt = 0; rt < 4; ++rt) {
        const int ao = (rt * 16 + cn) * 136 + kg * 32 + g * 8;
        const short8v ah = *(const short8v*)(Ah + ao);
        const short8v al = *(const short8v*)(Al + ao);
#pragma unroll
        for (int ct = 0; ct < 2; ++ct) {
          acc[rt][ct] = __builtin_amdgcn_mfma_f32_16x16x32_bf16(ah, bhi[ct][kg], acc[rt][ct], 0, 0, 0);
          acc[rt][ct] = __builtin_amdgcn_mfma_f32_16x16x32_bf16(al, bhi[ct][kg], acc[rt][ct], 0, 0, 0);
          acc[rt][ct] = __builtin_amdgcn_mfma_f32_16x16x32_bf16(ah, blo[ct][kg], acc[rt][ct], 0, 0, 0);
        }
      }
    }
  };

  stageA(A1);
  __syncthreads();
  accum(WH1, WL1);
  if (A2) {
    __syncthreads();
    stageA(A2);
    __syncthreads();
    accum(WH2, WL2);
  }
  __syncthreads();

#pragma unroll
  for (int rt = 0; rt < 4; ++rt)
#pragma unroll
    for (int ct = 0; ct < 2; ++ct)
#pragma unroll
      for (int r = 0; r < 4; ++r)
        Cf[(rt * 16 + g * 4 + r) * CF_LD + colbase + ct * 16 + cn] = acc[rt][ct][r];
  __syncthreads();

  float4* C4 = (float4*)(C + (size_t)row0 * 128);
#pragma unroll
  for (int i = 0; i < 8; ++i) {
    int f4 = t + i * 256;
    int row = f4 >> 5, c4 = f4 & 31;
    if (row0 + row < N) {
      float4 v = *(const float4*)(Cf + row * CF_LD + c4 * 4);
      if (bias) {
        float4 bv = *(const float4*)(bias + c4 * 4);
        v.x += bv.x; v.y += bv.y; v.z += bv.z; v.w += bv.w;
      }
      if (relu) {
        v.x = fmaxf(v.x, 0.f); v.y = fmaxf(v.y, 0.f);
        v.z = fmaxf(v.z, 0.f); v.w = fmaxf(v.w, 0.f);
      }
      C4[f4] = v;
    }
  }
}

// ======================= row dot: out[n] = x[n,:] . a  (one wave / node) ===========
__global__ void k_rowdot(const float* __restrict__ x, const float* __restrict__ a,
                         float* __restrict__ out, int N)
{
  int wid = blockIdx.x * 4 + (threadIdx.x >> 6);
  int lane = threadIdx.x & 63;
  if (wid >= N) return;
  float2 xv = ((const float2*)x)[(size_t)wid * 64 + lane];
  float2 av = ((const float2*)a)[lane];
  float v = fmaf(xv.y, av.y, xv.x * av.x);
#pragma unroll
  for (int o = 32; o > 0; o >>= 1) v += __shfl_down(v, o);
  if (lane == 0) out[wid] = v;
}

// ================= batched matvec: wv[m][i] = sum_j W_m[i,j]*a_m[j] ==============
struct MTab { const float* W[8]; const float* a[8]; };
__global__ __launch_bounds__(128) void k_matvec8(MTab tb, float* __restrict__ wv)
{
  __shared__ float as[128];
  int m = blockIdx.x, i = threadIdx.x;
  as[i] = tb.a[m][i];
  __syncthreads();
  const float* W = tb.W[m];
  float v = 0.f;
  for (int j = 0; j < 128; ++j) v = fmaf(W[i * 128 + j], as[j], v);
  wv[m * 128 + i] = v;
}

// ======================= batched CSR build =======================
struct HTab { const int* key[6]; int* cnt[6]; int bo[7]; int n[6]; };
__global__ void k_hist_all(HTab tb) {
  int bi = blockIdx.x, ty = 0;
  while (ty < 5 && bi >= tb.bo[ty + 1]) ++ty;
  int i = (bi - tb.bo[ty]) * 256 + threadIdx.x;
  if (i < tb.n[ty]) atomicAdd(&tb.cnt[ty][tb.key[ty][i]], 1);
}

struct PTab { const int* src[6]; int* dst[6]; int bo[7]; int n[6]; };
__global__ void k_copy_all(PTab tb) {
  int bi = blockIdx.x, ty = 0;
  while (ty < 5 && bi >= tb.bo[ty + 1]) ++ty;
  int i = (bi - tb.bo[ty]) * 256 + threadIdx.x;
  if (i < tb.n[ty]) tb.dst[ty][i] = tb.src[ty][i];
}

struct FTab { const int* es[6]; const int* ed[6]; int* wp[6]; int* col[6]; int bo[7]; int n[6]; };
__global__ void k_fill_all(FTab tb) {
  int bi = blockIdx.x, ty = 0;
  while (ty < 5 && bi >= tb.bo[ty + 1]) ++ty;
  int e = (bi - tb.bo[ty]) * 256 + threadIdx.x;
  if (e >= tb.n[ty]) return;
  int p = atomicAdd(&tb.wp[ty][tb.ed[ty][e]], 1);
  tb.col[ty][p] = tb.es[ty][e];
}

// ---- 3-phase multi-block exclusive scan (tile = 4096) ----
__global__ __launch_bounds__(256) void k_scan_partial(
    const int* __restrict__ rp, int* __restrict__ bsums, int N)
{
  __shared__ int red[256];
  const int t = threadIdx.x, base = blockIdx.x * 4096;
  int s = 0;
  for (int i = t; i < 4096; i += 256) {
    int idx = base + i;
    if (idx < N) s += rp[idx];
  }
  red[t] = s;
  __syncthreads();
  for (int ofs = 128; ofs > 0; ofs >>= 1) {
    if (t < ofs) red[t] += red[t + ofs];
    __syncthreads();
  }
  if (t == 0) bsums[blockIdx.x] = red[0];
}

__global__ __launch_bounds__(1024) void k_scan_bsums(
    int* __restrict__ bsums, int nb, int* __restrict__ rpN)
{
  __shared__ int sh[1024];
  const int t = threadIdx.x;
  int v = (t < nb) ? bsums[t] : 0;
  sh[t] = v;
  __syncthreads();
  for (int ofs = 1; ofs < 1024; ofs <<= 1) {
    int u = (t >= ofs) ? sh[t - ofs] : 0;
    __syncthreads();
    sh[t] += u;
    __syncthreads();
  }
  if (t < nb) bsums[t] = sh[t] - v;      // exclusive
  if (t == 1023) rpN[0] = sh[1023];      // total
}

__global__ __launch_bounds__(256) void k_scan_final(
    int* __restrict__ rp, const int* __restrict__ bsums, int N)
{
  __shared__ int sh[4096 + 256];
  __shared__ int tsum[256];
  const int t = threadIdx.x, base = blockIdx.x * 4096;
  auto mp = [](int i) { return i + (i >> 4); };
#pragma unroll
  for (int i = 0; i < 16; ++i) {
    int idx = base + i * 256 + t;
    sh[mp(i * 256 + t)] = (idx < N) ? rp[idx] : 0;
  }
  __syncthreads();
  int s = 0;
#pragma unroll
  for (int j = 0; j < 16; ++j) s += sh[mp(t * 16 + j)];
  tsum[t] = s;
  __syncthreads();
  for (int ofs = 1; ofs < 256; ofs <<= 1) {
    int u = (t >= ofs) ? tsum[t - ofs] : 0;
    __syncthreads();
    tsum[t] += u;
    __syncthreads();
  }
  int pre = tsum[t] - s + bsums[blockIdx.x];
#pragma unroll
  for (int j = 0; j < 16; ++j) {
    int v = sh[mp(t * 16 + j)];
    sh[mp(t * 16 + j)] = pre;
    pre += v;
  }
  __syncthreads();
#pragma unroll
  for (int i = 0; i < 16; ++i) {
    int idx = base + i * 256 + t;
    if (idx < N) rp[idx] = sh[mp(i * 256 + t)];
  }
}

__global__ void k_dis(const int* __restrict__ rp, float* __restrict__ dis, int N) {
  int n = blockIdx.x * 256 + threadIdx.x;
  if (n < N) dis[n] = rsqrtf((float)(rp[n + 1] - rp[n]) + 1.f);
}

// ======================= gather kernels =======================
__global__ void k_sage_gather(const int* __restrict__ rp, const int* __restrict__ col,
                              const float* __restrict__ x, float* __restrict__ out, int N)
{
  int node = blockIdx.x * 4 + (threadIdx.x >> 6);
  if (node >= N) return;
  int lane = threadIdx.x & 63;
  int s0 = rp[node], deg = rp[node + 1] - s0;
  const float2* x2 = (const float2*)x;
  float a0 = 0.f, a1 = 0.f, b0 = 0.f, b1 = 0.f;
  for (int base = 0; base < deg; base += 64) {
    int m = min(64, deg - base);
    int c = (lane < m) ? col[s0 + base + lane] : 0;
    int j = 0;
    for (; j + 1 < m; j += 2) {
      int sA = __shfl(c, j), sB = __shfl(c, j + 1);
      float2 vA = x2[(size_t)sA * 64 + lane];
      float2 vB = x2[(size_t)sB * 64 + lane];
      a0 += vA.x; a1 += vA.y; b0 += vB.x; b1 += vB.y;
    }
    if (j < m) {
      int sA = __shfl(c, j);
      float2 vA = x2[(size_t)sA * 64 + lane];
      a0 += vA.x; a1 += vA.y;
    }
  }
  float inv = 1.f / fmaxf((float)deg, 1.f);
  ((float2*)out)[(size_t)node * 64 + lane] = make_float2((a0 + b0) * inv, (a1 + b1) * inv);
}

__global__ void k_gcn_gather(const int* __restrict__ rp, const int* __restrict__ col,
                             const float* __restrict__ dis, const float* __restrict__ h,
                             const float* addin, const float* __restrict__ b,
                             float* out, int N)
{
  int node = blockIdx.x * 4 + (threadIdx.x >> 6);
  if (node >= N) return;
  int lane = threadIdx.x & 63;
  int s0 = rp[node], deg = rp[node + 1] - s0;
  float rd = dis[node];
  const float2* h2 = (const float2*)h;
  float a0 = 0.f, a1 = 0.f, b0 = 0.f, b1 = 0.f;
  for (int base = 0; base < deg; base += 64) {
    int m = min(64, deg - base);
    int c = 0; float dv = 0.f;
    if (lane < m) { c = col[s0 + base + lane]; dv = dis[c]; }
    int j = 0;
    for (; j + 1 < m; j += 2) {
      int sA = __shfl(c, j), sB = __shfl(c, j + 1);
      float nA = __shfl(dv, j) * rd, nB = __shfl(dv, j + 1) * rd;
      float2 vA = h2[(size_t)sA * 64 + lane];
      float2 vB = h2[(size_t)sB * 64 + lane];
      a0 = fmaf(nA, vA.x, a0); a1 = fmaf(nA, vA.y, a1);
      b0 = fmaf(nB, vB.x, b0); b1 = fmaf(nB, vB.y, b1);
    }
    if (j < m) {
      int sA = __shfl(c, j);
      float nA = __shfl(dv, j) * rd;
      float2 vA = h2[(size_t)sA * 64 + lane];
      a0 = fmaf(nA, vA.x, a0); a1 = fmaf(nA, vA.y, a1);
    }
  }
  float rr = rd * rd;
  float2 hself = h2[(size_t)node * 64 + lane];
  float2 bv = ((const float2*)b)[lane];
  float ad0 = 0.f, ad1 = 0.f;
  if (addin) {
    float2 a2 = ((const float2*)addin)[(size_t)node * 64 + lane];
    ad0 = a2.x; ad1 = a2.y;
  }
  float v0 = fmaf(rr, hself.x, a0 + b0) + bv.x + ad0;
  float v1 = fmaf(rr, hself.y, a1 + b1) + bv.y + ad1;
  ((float2*)out)[(size_t)node * 64 + lane] = make_float2(fmaxf(v0, 0.f), fmaxf(v1, 0.f));
}

__global__ void k_gat_gather(const int* __restrict__ rp, const int* __restrict__ col,
                             const float* __restrict__ hs, const float* __restrict__ as_,
                             const float* __restrict__ ad_, const float* __restrict__ b,
                             float* __restrict__ out, int N, int relu)
{
  int node = blockIdx.x * 4 + (threadIdx.x >> 6);
  if (node >= N) return;
  int lane = threadIdx.x & 63;
  int s0 = rp[node], deg = rp[node + 1] - s0;
  float adn = ad_[node];
  const float2* hs2 = (const float2*)hs;
  float z = 0.f, a0 = 0.f, a1 = 0.f, b0 = 0.f, b1 = 0.f;
  for (int base = 0; base < deg; base += 64) {
    int m = min(64, deg - base);
    int c = 0; float av = 0.f;
    if (lane < m) { c = col[s0 + base + lane]; av = as_[c]; }
    int j = 0;
    for (; j + 1 < m; j += 2) {
      int sA = __shfl(c, j), sB = __shfl(c, j + 1);
      float vA = __shfl(av, j) + adn, vB = __shfl(av, j + 1) + adn;
      vA = vA > 0.f ? vA : 0.2f * vA;
      vB = vB > 0.f ? vB : 0.2f * vB;
      float pA = __expf(vA), pB = __expf(vB);
      z += pA + pB;
      float2 hA = hs2[(size_t)sA * 64 + lane];
      float2 hB = hs2[(size_t)sB * 64 + lane];
      a0 = fmaf(pA, hA.x, a0); a1 = fmaf(pA, hA.y, a1);
      b0 = fmaf(pB, hB.x, b0); b1 = fmaf(pB, hB.y, b1);
    }
    if (j < m) {
      int sA = __shfl(c, j);
      float vA = __shfl(av, j) + adn;
      vA = vA > 0.f ? vA : 0.2f * vA;
      float pA = __expf(vA);
      z += pA;
      float2 hA = hs2[(size_t)sA * 64 + lane];
      a0 = fmaf(pA, hA.x, a0); a1 = fmaf(pA, hA.y, a1);
    }
  }
  float inv = (deg > 0) ? 1.f / z : 0.f;
  float2 bv = ((const float2*)b)[lane];
  float v0 = fmaf(a0 + b0, inv, bv.x);
  float v1 = fmaf(a1 + b1, inv, bv.y);
  if (relu) { v0 = fmaxf(v0, 0.f); v1 = fmaxf(v1, 0.f); }
  ((float2*)out)[(size_t)node * 64 + lane] = make_float2(v0, v1);
}

// ============ segment pooling: one block per graph, contiguous rows ============
__global__ __launch_bounds__(256) void k_pool_seg(
    const float* __restrict__ x, const int* __restrict__ rpb,
    float* __restrict__ pool, int col_off)
{
  __shared__ float2 red2[4][64];
  const int g = blockIdx.x;
  const int t = threadIdx.x, w = t >> 6, lane = t & 63;
  const int n0 = rpb[g], n1 = rpb[g + 1];
  const float2* x2 = (const float2*)x;
  float a0 = 0.f, a1 = 0.f, b0 = 0.f, b1 = 0.f;
  int n = n0 + w;
  for (; n + 4 < n1; n += 8) {
    float2 vA = x2[(size_t)n * 64 + lane];
    float2 vB = x2[(size_t)(n + 4) * 64 + lane];
    a0 += vA.x; a1 += vA.y; b0 += vB.x; b1 += vB.y;
  }
  if (n < n1) { float2 vA = x2[(size_t)n * 64 + lane]; a0 += vA.x; a1 += vA.y; }
  red2[w][lane] = make_float2(a0 + b0, a1 + b1);
  __syncthreads();
  if (t < 64) {
    float2 r0 = red2[0][t], r1 = red2[1][t], r2 = red2[2][t], r3 = red2[3][t];
    float inv = 1.f / fmaxf((float)(n1 - n0), 1.f);
    ((float2*)(pool + (size_t)g * 640 + col_off))[t] =
        make_float2((r0.x + r1.x + r2.x + r3.x) * inv,
                    (r0.y + r1.y + r2.y + r3.y) * inv);
  }
}

// ======================= final MLP (one block per graph) =======================
__global__ void k_mlp(const float* __restrict__ pool, const int* __restrict__ rpb,
                      const float* __restrict__ W1, const float* __restrict__ b1,
                      const float* __restrict__ W2, const float* __restrict__ b2,
                      float* __restrict__ out)
{
  __shared__ float emb[640];
  __shared__ float red[128];
  const int g = blockIdx.x, t = threadIdx.x;
  for (int i = t; i < 640; i += 128) emb[i] = pool[(size_t)g * 640 + i];
  __syncthreads();
  float acc = b1[t];
  for (int i = 0; i < 640; ++i) acc = fmaf(emb[i], W1[i * 128 + t], acc);
  float h = fmaxf(acc, 0.f);
  red[t] = h * W2[t];
  __syncthreads();
  for (int s = 64; s > 0; s >>= 1) {
    if (t < s) red[t] += red[t + s];
    __syncthreads();
  }
  if (t == 0) out[g] = red[0] + b2[0];
}

// ======================= host =======================
extern "C" void kernel_launch(void* const* d_in, const int* in_sizes, int n_in,
                              void* d_out, int out_size, void* d_ws, size_t ws_size,
                              hipStream_t stream)
{
  auto fin = [&](int i) { return (const float*)d_in[i]; };
  auto iin = [&](int i) { return (const int*)d_in[i]; };

  const float *x_cd = fin(0), *x_seq = fin(1), *x_anno = fin(2), *x_range = fin(3), *x_md = fin(4);
  const int *ei_seq = iin(5), *ei_anno = iin(6), *ei_range = iin(7),
            *ei_comp = iin(8), *ei_cc = iin(9), *ei_mm = iin(10);
  const int *b_cd = iin(11), *b_seq = iin(12), *b_anno = iin(13), *b_range = iin(14), *b_md = iin(15);

  const int N_CD = in_sizes[0] / HD, N_SEQ = in_sizes[1] / HD, N_ANNO = in_sizes[2] / HD,
            N_RANGE = in_sizes[3] / HD, N_MD = in_sizes[4] / HD;
  const int E_seq = in_sizes[5] / 2, E_anno = in_sizes[6] / 2, E_range = in_sizes[7] / 2,
            E_comp = in_sizes[8] / 2, E_cc = in_sizes[9] / 2, E_mm = in_sizes[10] / 2;
  const int N_OTH = max(max(N_SEQ, N_ANNO), N_RANGE);

  auto WLm = [&](int i, int l) { return fin(i) + (size_t)l * HD * HD; };
  auto WLv = [&](int i, int l) { return fin(i) + (size_t)l * HD; };

  // ---- workspace layout ----
  float* ws = (float*)d_ws;
  size_t off = 0;
  auto alloc = [&](size_t n) { float* p = ws + off; off += (n + 3) & ~(size_t)3; return p; };
  float* xcd1 = alloc((size_t)N_CD * HD);
  float* xmd1 = alloc((size_t)N_MD * HD);
  float* xoth = alloc((size_t)N_OTH * HD);
  float* acc  = alloc((size_t)N_CD * HD);
  float* t1   = alloc((size_t)N_CD * HD);
  float* sAs  = alloc((size_t)N_CD);
  float* sAd  = alloc((size_t)N_CD);
  float* dis_cc = alloc((size_t)N_CD);
  float* dis_mm = alloc((size_t)N_MD);
  float* wvall = alloc(8 * HD);
  float* pool = alloc((size_t)GNUM * 5 * HD);
  short* whi = (short*)(ws + off); off += (size_t)16 * 16384 / 2;
  short* wlo = (short*)(ws + off); off += (size_t)16 * 16384 / 2;
  auto alloci = [&](size_t n) { int* p = (int*)(ws + off); off += (n + 3) & ~(size_t)3; return p; };
  int* bsums = alloci(1024);
  int* rpb_all = alloci(5 * RPB);
  // rp arrays: CONTIGUOUS (one memset covers all)
  int Nds[6] = {N_SEQ, N_ANNO, N_RANGE, N_CD, N_CD, N_MD};
  int Es[6]  = {E_seq, E_anno, E_range, E_comp, E_cc, E_mm};
  int* rps[6];
  int* rp0 = alloci(0);
  { size_t tot = 0; for (int i = 0; i < 6; ++i) tot += (size_t)Nds[i] + 1;
    int* p = alloci(tot); rp0 = p;
    for (int i = 0; i < 6; ++i) { rps[i] = p; p += Nds[i] + 1; } }
  size_t rp_tot_bytes = 0; for (int i = 0; i < 6; ++i) rp_tot_bytes += ((size_t)Nds[i] + 1) * 4;
  int* wps[6]; for (int i = 0; i < 6; ++i) wps[i] = alloci((size_t)Nds[i]);
  int* cols[6]; for (int i = 0; i < 6; ++i) cols[i] = alloci((size_t)Es[i]);
  (void)n_in;

  if (off * sizeof(float) > ws_size) {
    hipMemsetAsync(d_out, 0, (size_t)out_size * sizeof(float), stream);
    return;
  }

  auto ew = [&](size_t elems) { return dim3((unsigned)((elems + 255) / 256)); };
  auto nw = [&](int N) { return dim3((unsigned)((N + 3) / 4)); };

  // ---- pre-split all GEMM weights (slots: 0:16 1:18 2:19 3:21 4:22 5:27 6:32 7:34)
  WTab tab;
  tab.p[0] = fin(16); tab.p[1] = fin(18); tab.p[2] = fin(19); tab.p[3] = fin(21);
  tab.p[4] = fin(22); tab.p[5] = fin(27); tab.p[6] = fin(32); tab.p[7] = fin(34);
  k_split_w<<<dim3(1024), dim3(256), 0, stream>>>(tab, whi, wlo);

  // ---- all 8 GAT matvecs in one launch: slots {comp: s0,d1,s2,d3 | range: s4,d5,s6,d7}
  MTab mt;
  mt.W[0] = WLm(22, 0); mt.a[0] = WLv(24, 0);  mt.W[1] = WLm(23, 0); mt.a[1] = WLv(25, 0);
  mt.W[2] = WLm(22, 1); mt.a[2] = WLv(24, 1);  mt.W[3] = WLm(23, 1); mt.a[3] = WLv(25, 1);
  mt.W[4] = WLm(27, 0); mt.a[4] = WLv(29, 0);  mt.W[5] = WLm(28, 0); mt.a[5] = WLv(30, 0);
  mt.W[6] = WLm(27, 1); mt.a[6] = WLv(29, 1);  mt.W[7] = WLm(28, 1); mt.a[7] = WLv(30, 1);
  k_matvec8<<<dim3(8), dim3(128), 0, stream>>>(mt, wvall);

  // ---- batched CSR build ----
  const int* ess[6] = {ei_seq, ei_anno, ei_range, ei_comp, ei_cc, ei_mm};
  const int* eds[6] = {ei_seq + E_seq, ei_anno + E_anno, ei_range + E_range,
                       ei_comp + E_comp, ei_cc + E_cc, ei_mm + E_mm};
  hipMemsetAsync(rp0, 0, rp_tot_bytes, stream);
  {
    HTab ht; int b = 0;
    for (int i = 0; i < 6; ++i) { ht.key[i] = eds[i]; ht.cnt[i] = rps[i]; ht.bo[i] = b; b += (Es[i] + 255) / 256; ht.n[i] = Es[i]; }
    ht.bo[6] = b;
    k_hist_all<<<dim3(b), dim3(256), 0, stream>>>(ht);
  }
  for (int i = 0; i < 6; ++i) {
    int nb = (Nds[i] + 4095) / 4096;
    k_scan_partial<<<dim3(nb), dim3(256), 0, stream>>>(rps[i], bsums, Nds[i]);
    k_scan_bsums<<<dim3(1), dim3(1024), 0, stream>>>(bsums, nb, rps[i] + Nds[i]);
    k_scan_final<<<dim3(nb), dim3(256), 0, stream>>>(rps[i], bsums, Nds[i]);
  }
  {
    PTab pt; int b = 0;
    for (int i = 0; i < 6; ++i) { pt.src[i] = rps[i]; pt.dst[i] = wps[i]; pt.bo[i] = b; b += (Nds[i] + 255) / 256; pt.n[i] = Nds[i]; }
    pt.bo[6] = b;
    k_copy_all<<<dim3(b), dim3(256), 0, stream>>>(pt);
  }
  {
    FTab ft; int b = 0;
    for (int i = 0; i < 6; ++i) { ft.es[i] = ess[i]; ft.ed[i] = eds[i]; ft.wp[i] = wps[i]; ft.col[i] = cols[i]; ft.bo[i] = b; b += (Es[i] + 255) / 256; ft.n[i] = Es[i]; }
    ft.bo[6] = b;
    k_fill_all<<<dim3(b), dim3(256), 0, stream>>>(ft);
  }
  int *rp_seq = rps[0], *rp_anno = rps[1], *rp_range = rps[2],
      *rp_comp = rps[3], *rp_cc = rps[4], *rp_mm = rps[5];
  int *col_seq = cols[0], *col_anno = cols[1], *col_range = cols[2],
      *col_comp = cols[3], *col_cc = cols[4], *col_mm = cols[5];
  k_dis<<<ew(N_CD), dim3(256), 0, stream>>>(rp_cc, dis_cc, N_CD);
  k_dis<<<ew(N_MD), dim3(256), 0, stream>>>(rp_mm, dis_mm, N_MD);

  // ---- batch run-pointers (b arrays sorted): hist + 512-scan per type ----
  hipMemsetAsync(rpb_all, 0, 5 * RPB * 4, stream);
  {
    HTab ht; const int* bs[5] = {b_cd, b_seq, b_anno, b_range, b_md};
    int Nb[5] = {N_CD, N_SEQ, N_ANNO, N_RANGE, N_MD};
    int b = 0;
    for (int i = 0; i < 5; ++i) { ht.key[i] = bs[i]; ht.cnt[i] = rpb_all + i * RPB; ht.bo[i] = b; b += (Nb[i] + 255) / 256; ht.n[i] = Nb[i]; }
    ht.key[5] = bs[0]; ht.cnt[5] = rpb_all; ht.n[5] = 0; ht.bo[5] = b; ht.bo[6] = b;
    k_hist_all<<<dim3(b), dim3(256), 0, stream>>>(ht);
  }
  for (int i = 0; i < 5; ++i)
    k_scan_bsums<<<dim3(1), dim3(1024), 0, stream>>>(rpb_all + i * RPB, GNUM, rpb_all + i * RPB + GNUM);

  auto WHp = [&](int sidx, int layer) { return whi + (size_t)(sidx * 2 + layer) * 16384; };
  auto WLp = [&](int sidx, int layer) { return wlo + (size_t)(sidx * 2 + layer) * 16384; };
  auto gemm = [&](const float* A, int sidx, int layer, float* C, const float* b,
                  int N, int relu) {
    k_gemm_mfma<<<dim3((N + 63) / 64), dim3(256), 0, stream>>>(
        A, WHp(sidx, layer), WLp(sidx, layer), nullptr, nullptr, nullptr, C, b, N, relu);
  };
  auto gemm2 = [&](const float* A1, int s1, const float* A2, int s2, int layer,
                   float* C, const float* b, int N, int relu) {
    k_gemm_mfma<<<dim3((N + 63) / 64), dim3(256), 0, stream>>>(
        A1, WHp(s1, layer), WLp(s1, layer), A2, WHp(s2, layer), WLp(s2, layer), C, b, N, relu);
  };
  auto do_pool = [&](const float* x, int N, int type) {
    (void)N;
    k_pool_seg<<<dim3(GNUM), dim3(256), 0, stream>>>(x, rpb_all + type * RPB, pool, type * HD);
  };

  // GAT: sAs = xs.(Ws@a_s), sAd = xd.(Wd@a_d) via precomputed wvecs; hs = xs@Ws (MFMA)
  auto gat = [&](const float* xs, const float* xd, const int* rp, const int* col,
                 int Ns, int Nd, int sidx, int layer, int wvS, int wvD,
                 const float* bias, float* out, int relu) {
    k_rowdot<<<nw(Ns), dim3(256), 0, stream>>>(xs, wvall + wvS * 128, sAs, Ns);
    k_rowdot<<<nw(Nd), dim3(256), 0, stream>>>(xd, wvall + wvD * 128, sAd, Nd);
    gemm(xs, sidx, layer, t1, nullptr, Ns, 0);   // hs
    k_gat_gather<<<nw(Nd), dim3(256), 0, stream>>>(rp, col, t1, sAs, sAd, bias, out, Nd, relu);
  };
  auto gcn = [&](const float* x, const int* rp, const int* col, const float* dis, int N,
                 int sidx, int layer, const float* b, const float* addin, float* out) {
    gemm(x, sidx, layer, t1, nullptr, N, 0);
    k_gcn_gather<<<nw(N), dim3(256), 0, stream>>>(rp, col, dis, t1, addin, b, out, N);
  };
  auto sage = [&](const float* xsrc, const float* xself, const int* rp, const int* col,
                  int Nd, int sl, int sr, int layer, const float* bl, float* out) {
    k_sage_gather<<<nw(Nd), dim3(256), 0, stream>>>(rp, col, xsrc, t1, Nd);
    gemm2(t1, sl, xself, sr, layer, out, bl, Nd, 1);
  };

  // ---------- CD + MD, both layers ----------
  gat(x_md, x_cd, rp_comp, col_comp, N_MD, N_CD, 4, 0, 0, 1, WLv(26, 0), acc, 0);
  gcn(x_cd, rp_cc, col_cc, dis_cc, N_CD, 6, 0, WLv(33, 0), acc, xcd1);
  gcn(x_md, rp_mm, col_mm, dis_mm, N_MD, 7, 0, WLv(35, 0), nullptr, xmd1);
  gat(xmd1, xcd1, rp_comp, col_comp, N_MD, N_CD, 4, 1, 2, 3, WLv(26, 1), acc, 0);
  gcn(xcd1, rp_cc, col_cc, dis_cc, N_CD, 6, 1, WLv(33, 1), acc, acc);
  do_pool(acc, N_CD, 0);
  gcn(xmd1, rp_mm, col_mm, dis_mm, N_MD, 7, 1, WLv(35, 1), nullptr, acc);
  do_pool(acc, N_MD, 4);

  // ---------- SEQ ----------
  sage(x_cd, x_seq, rp_seq, col_seq, N_SEQ, 0, 1, 0, WLv(17, 0), xoth);
  sage(xcd1, xoth, rp_seq, col_seq, N_SEQ, 0, 1, 1, WLv(17, 1), acc);
  do_pool(acc, N_SEQ, 1);
  // ---------- ANNO ----------
  sage(x_cd, x_anno, rp_anno, col_anno, N_ANNO, 2, 3, 0, WLv(20, 0), xoth);
  sage(xcd1, xoth, rp_anno, col_anno, N_ANNO, 2, 3, 1, WLv(20, 1), acc);
  do_pool(acc, N_ANNO, 2);
  // ---------- RANGE ----------
  gat(x_cd, x_range, rp_range, col_range, N_CD, N_RANGE, 5, 0, 4, 5, WLv(31, 0), xoth, 1);
  gat(xcd1, xoth, rp_range, col_range, N_CD, N_RANGE, 5, 1, 6, 7, WLv(31, 1), acc, 1);
  do_pool(acc, N_RANGE, 3);

  k_mlp<<<dim3(GNUM), dim3(128), 0, stream>>>(
      pool, rpb_all, fin(36), fin(37), fin(38), fin(39), (float*)d_out);
}

// Round 10
// 1124.608 us; speedup vs baseline: 2.4306x; 1.1590x over previous
//
#include <hip/hip_runtime.h>

#define HD 128
#define GNUM 512
#define RPB 520   // per-type stride in rpb_all (>= GNUM+1)

typedef __attribute__((ext_vector_type(8))) short short8v;   // 8 bf16 = 4 VGPR
typedef __attribute__((ext_vector_type(4))) float f32x4;

// RNE split: a ~= hi + lo (both bf16), |residual| ~ 2^-17 |a|
__device__ __forceinline__ void split1(float a, short& h, short& l) {
  unsigned u = __float_as_uint(a);
  unsigned hb = (u + 0x7FFFu + ((u >> 16) & 1u)) & 0xFFFF0000u;
  h = (short)(hb >> 16);
  float rest = a - __uint_as_float(hb);
  unsigned u2 = __float_as_uint(rest);
  l = (short)((u2 + 0x7FFFu + ((u2 >> 16) & 1u)) >> 16);
}

// ============ W pre-split: fp32 [k][n] -> bf16 hi/lo TRANSPOSED [n][k] ============
struct WTab { const float* p[8]; };
__global__ __launch_bounds__(256) void k_split_w(WTab tab, short* __restrict__ whi,
                                                 short* __restrict__ wlo)
{
  int m = blockIdx.x >> 6;                       // 16 matrices, 64 blocks each
  int i = (blockIdx.x & 63) * 256 + threadIdx.x; // 0..16383
  const float* W = tab.p[m >> 1] + (m & 1) * 16384;
  int k = i >> 7, n = i & 127;
  short h, l;
  split1(W[k * 128 + n], h, l);
  whi[m * 16384 + n * 128 + k] = h;
  wlo[m * 16384 + n * 128 + k] = l;
}

// ============ MFMA GEMM: C = A1@W1 (+ A2@W2) (+bias, relu) ====================
#define CF_LD 132
__global__ __launch_bounds__(256) void k_gemm_mfma(
    const float* __restrict__ A1, const short* __restrict__ WH1, const short* __restrict__ WL1,
    const float* __restrict__ A2, const short* __restrict__ WH2, const short* __restrict__ WL2,
    float* __restrict__ C, const float* __restrict__ bias, int N, int relu)
{
  __shared__ char smem[64 * 136 * 2 * 2];        // 34816 B
  short* Ah = (short*)smem;
  short* Al = Ah + 64 * 136;
  float* Cf = (float*)smem;

  const int t = threadIdx.x;
  const int row0 = blockIdx.x * 64;
  const int lane = t & 63, wid = t >> 6;
  const int g = lane >> 4, cn = lane & 15;
  const int colbase = wid * 32;

  f32x4 zero = {0.f, 0.f, 0.f, 0.f};
  f32x4 acc[4][2];
#pragma unroll
  for (int rt = 0; rt < 4; ++rt) { acc[rt][0] = zero; acc[rt][1] = zero; }

  auto stageA = [&](const float* __restrict__ A) {
    const float4* A4 = (const float4*)(A + (size_t)row0 * 128);
#pragma unroll
    for (int i = 0; i < 8; ++i) {
      int f4 = t + i * 256;
      int row = f4 >> 5, c4 = f4 & 31;
      float4 v = make_float4(0.f, 0.f, 0.f, 0.f);
      if (row0 + row < N) v = A4[f4];
      short4 h, l;
      split1(v.x, h.x, l.x); split1(v.y, h.y, l.y);
      split1(v.z, h.z, l.z); split1(v.w, h.w, l.w);
      *(short4*)(Ah + row * 136 + c4 * 4) = h;
      *(short4*)(Al + row * 136 + c4 * 4) = l;
    }
  };

  auto accum = [&](const short* __restrict__ WH, const short* __restrict__ WL) {
    short8v bhi[2][4], blo[2][4];
#pragma unroll
    for (int ct = 0; ct < 2; ++ct)
#pragma unroll
      for (int kg = 0; kg < 4; ++kg) {
        size_t o = (size_t)(colbase + ct * 16 + cn) * 128 + kg * 32 + g * 8;
        bhi[ct][kg] = *(const short8v*)(WH + o);
        blo[ct][kg] = *(const short8v*)(WL + o);
      }
#pragma unroll
    for (int kg = 0; kg < 4; ++kg) {
#pragma unroll
      for (int rt = 0; rt < 4; ++rt) {
        const int ao = (rt * 16 + cn) * 136 + kg * 32 + g * 8;
        const short8v ah = *(const short8v*)(Ah + ao);
        const short8v al = *(const short8v*)(Al + ao);
#pragma unroll
        for (int ct = 0; ct < 2; ++ct) {
          acc[rt][ct] = __builtin_amdgcn_mfma_f32_16x16x32_bf16(ah, bhi[ct][kg], acc[rt][ct], 0, 0, 0);
          acc[rt][ct] = __builtin_amdgcn_mfma_f32_16x16x32_bf16(al, bhi[ct][kg], acc[rt][ct], 0, 0, 0);
          acc[rt][ct] = __builtin_amdgcn_mfma_f32_16x16x32_bf16(ah, blo[ct][kg], acc[rt][ct], 0, 0, 0);
        }
      }
    }
  };

  stageA(A1);
  __syncthreads();
  accum(WH1, WL1);
  if (A2) {
    __syncthreads();
    stageA(A2);
    __syncthreads();
    accum(WH2, WL2);
  }
  __syncthreads();

#pragma unroll
  for (int rt = 0; rt < 4; ++rt)
#pragma unroll
    for (int ct = 0; ct < 2; ++ct)
#pragma unroll
      for (int r = 0; r < 4; ++r)
        Cf[(rt * 16 + g * 4 + r) * CF_LD + colbase + ct * 16 + cn] = acc[rt][ct][r];
  __syncthreads();

  float4* C4 = (float4*)(C + (size_t)row0 * 128);
#pragma unroll
  for (int i = 0; i < 8; ++i) {
    int f4 = t + i * 256;
    int row = f4 >> 5, c4 = f4 & 31;
    if (row0 + row < N) {
      float4 v = *(const float4*)(Cf + row * CF_LD + c4 * 4);
      if (bias) {
        float4 bv = *(const float4*)(bias + c4 * 4);
        v.x += bv.x; v.y += bv.y; v.z += bv.z; v.w += bv.w;
      }
      if (relu) {
        v.x = fmaxf(v.x, 0.f); v.y = fmaxf(v.y, 0.f);
        v.z = fmaxf(v.z, 0.f); v.w = fmaxf(v.w, 0.f);
      }
      C4[f4] = v;
    }
  }
}

// ======================= row dot: out[n] = x[n,:] . a  (one wave / node) ===========
__global__ void k_rowdot(const float* __restrict__ x, const float* __restrict__ a,
                         float* __restrict__ out, int N)
{
  int wid = blockIdx.x * 4 + (threadIdx.x >> 6);
  int lane = threadIdx.x & 63;
  if (wid >= N) return;
  float2 xv = ((const float2*)x)[(size_t)wid * 64 + lane];
  float2 av = ((const float2*)a)[lane];
  float v = fmaf(xv.y, av.y, xv.x * av.x);
#pragma unroll
  for (int o = 32; o > 0; o >>= 1) v += __shfl_down(v, o);
  if (lane == 0) out[wid] = v;
}

// ================= batched matvec: wv[m][i] = sum_j W_m[i,j]*a_m[j] ==============
struct MTab { const float* W[8]; const float* a[8]; };
__global__ __launch_bounds__(128) void k_matvec8(MTab tb, float* __restrict__ wv)
{
  __shared__ float as[128];
  int m = blockIdx.x, i = threadIdx.x;
  as[i] = tb.a[m][i];
  __syncthreads();
  const float* W = tb.W[m];
  float v = 0.f;
  for (int j = 0; j < 128; ++j) v = fmaf(W[i * 128 + j], as[j], v);
  wv[m * 128 + i] = v;
}

// ======================= batched CSR build =======================
struct HTab { const int* key[6]; int* cnt[6]; int bo[7]; int n[6]; };
__global__ void k_hist_all(HTab tb) {
  int bi = blockIdx.x, ty = 0;
  while (ty < 5 && bi >= tb.bo[ty + 1]) ++ty;
  int i = (bi - tb.bo[ty]) * 256 + threadIdx.x;
  if (i < tb.n[ty]) atomicAdd(&tb.cnt[ty][tb.key[ty][i]], 1);
}

struct FTab { const int* es[6]; const int* ed[6]; int* wp[6]; int* col[6]; int bo[7]; int n[6]; };
__global__ void k_fill_all(FTab tb) {
  int bi = blockIdx.x, ty = 0;
  while (ty < 5 && bi >= tb.bo[ty + 1]) ++ty;
  int e = (bi - tb.bo[ty]) * 256 + threadIdx.x;
  if (e >= tb.n[ty]) return;
  int p = atomicAdd(&tb.wp[ty][tb.ed[ty][e]], 1);
  tb.col[ty][p] = tb.es[ty][e];
}

// ---- batched 3-phase exclusive scan over 6 arrays (tile = 4096) ----
// final pass writes the scan to BOTH rp (row pointers) and wp (fill cursors).
struct STab { int* rp[6]; int* wp[6]; int* bs[6]; int n[6]; int bo[7]; };

__global__ __launch_bounds__(256) void k_scan_partial_all(STab tb) {
  __shared__ int red[256];
  int bi = blockIdx.x, ty = 0;
  while (ty < 5 && bi >= tb.bo[ty + 1]) ++ty;
  int lb = bi - tb.bo[ty];
  const int* rp = tb.rp[ty];
  const int N = tb.n[ty];
  const int t = threadIdx.x, base = lb * 4096;
  int s = 0;
  for (int i = t; i < 4096; i += 256) {
    int idx = base + i;
    if (idx < N) s += rp[idx];
  }
  red[t] = s;
  __syncthreads();
  for (int ofs = 128; ofs > 0; ofs >>= 1) {
    if (t < ofs) red[t] += red[t + ofs];
    __syncthreads();
  }
  if (t == 0) tb.bs[ty][lb] = red[0];
}

__global__ __launch_bounds__(256) void k_scan_bsums_all(STab tb) {
  __shared__ int sh[256];
  const int ty = blockIdx.x;
  const int nb = (tb.n[ty] + 4095) / 4096;   // <= 25
  const int t = threadIdx.x;
  int v = (t < nb) ? tb.bs[ty][t] : 0;
  sh[t] = v;
  __syncthreads();
  for (int ofs = 1; ofs < 256; ofs <<= 1) {
    int u = (t >= ofs) ? sh[t - ofs] : 0;
    __syncthreads();
    sh[t] += u;
    __syncthreads();
  }
  if (t < nb) tb.bs[ty][t] = sh[t] - v;      // exclusive
  if (t == 255) tb.rp[ty][tb.n[ty]] = sh[255];  // total
}

__global__ __launch_bounds__(256) void k_scan_final_all(STab tb) {
  __shared__ int sh[4096 + 256];             // padded: i -> i + (i>>4)
  __shared__ int tsum[256];
  int bi = blockIdx.x, ty = 0;
  while (ty < 5 && bi >= tb.bo[ty + 1]) ++ty;
  int lb = bi - tb.bo[ty];
  int* rp = tb.rp[ty];
  int* wp = tb.wp[ty];
  const int N = tb.n[ty];
  const int t = threadIdx.x, base = lb * 4096;
  auto mp = [](int i) { return i + (i >> 4); };
#pragma unroll
  for (int i = 0; i < 16; ++i) {
    int idx = base + i * 256 + t;
    sh[mp(i * 256 + t)] = (idx < N) ? rp[idx] : 0;
  }
  __syncthreads();
  int s = 0;
#pragma unroll
  for (int j = 0; j < 16; ++j) s += sh[mp(t * 16 + j)];
  tsum[t] = s;
  __syncthreads();
  for (int ofs = 1; ofs < 256; ofs <<= 1) {
    int u = (t >= ofs) ? tsum[t - ofs] : 0;
    __syncthreads();
    tsum[t] += u;
    __syncthreads();
  }
  int pre = tsum[t] - s + tb.bs[ty][lb];
#pragma unroll
  for (int j = 0; j < 16; ++j) {
    int v = sh[mp(t * 16 + j)];
    sh[mp(t * 16 + j)] = pre;
    pre += v;
  }
  __syncthreads();
#pragma unroll
  for (int i = 0; i < 16; ++i) {
    int idx = base + i * 256 + t;
    if (idx < N) {
      int v = sh[mp(i * 256 + t)];
      rp[idx] = v;
      wp[idx] = v;
    }
  }
}

// ---- run-pointers for SORTED batch vectors via binary search (no atomics) ----
struct BTab { const int* b[5]; int n[5]; };
__global__ __launch_bounds__(512) void k_runptr(BTab tb, int* __restrict__ rpb_all) {
  const int ty = blockIdx.x;
  const int* b = tb.b[ty];
  const int N = tb.n[ty];
  const int t = threadIdx.x;                 // 0..511 = graph id
  int lo = 0, hi = N;
  while (lo < hi) {                          // lower_bound(b, t)
    int mid = (lo + hi) >> 1;
    if (b[mid] < t) lo = mid + 1; else hi = mid;
  }
  rpb_all[ty * RPB + t] = lo;
  if (t == 0) rpb_all[ty * RPB + GNUM] = N;
}

__global__ void k_dis(const int* __restrict__ rp, float* __restrict__ dis, int N) {
  int n = blockIdx.x * 256 + threadIdx.x;
  if (n < N) dis[n] = rsqrtf((float)(rp[n + 1] - rp[n]) + 1.f);
}

// ======================= gather kernels =======================
__global__ void k_sage_gather(const int* __restrict__ rp, const int* __restrict__ col,
                              const float* __restrict__ x, float* __restrict__ out, int N)
{
  int node = blockIdx.x * 4 + (threadIdx.x >> 6);
  if (node >= N) return;
  int lane = threadIdx.x & 63;
  int s0 = rp[node], deg = rp[node + 1] - s0;
  const float2* x2 = (const float2*)x;
  float a0 = 0.f, a1 = 0.f, b0 = 0.f, b1 = 0.f;
  for (int base = 0; base < deg; base += 64) {
    int m = min(64, deg - base);
    int c = (lane < m) ? col[s0 + base + lane] : 0;
    int j = 0;
    for (; j + 1 < m; j += 2) {
      int sA = __shfl(c, j), sB = __shfl(c, j + 1);
      float2 vA = x2[(size_t)sA * 64 + lane];
      float2 vB = x2[(size_t)sB * 64 + lane];
      a0 += vA.x; a1 += vA.y; b0 += vB.x; b1 += vB.y;
    }
    if (j < m) {
      int sA = __shfl(c, j);
      float2 vA = x2[(size_t)sA * 64 + lane];
      a0 += vA.x; a1 += vA.y;
    }
  }
  float inv = 1.f / fmaxf((float)deg, 1.f);
  ((float2*)out)[(size_t)node * 64 + lane] = make_float2((a0 + b0) * inv, (a1 + b1) * inv);
}

__global__ void k_gcn_gather(const int* __restrict__ rp, const int* __restrict__ col,
                             const float* __restrict__ dis, const float* __restrict__ h,
                             const float* addin, const float* __restrict__ b,
                             float* out, int N)
{
  int node = blockIdx.x * 4 + (threadIdx.x >> 6);
  if (node >= N) return;
  int lane = threadIdx.x & 63;
  int s0 = rp[node], deg = rp[node + 1] - s0;
  float rd = dis[node];
  const float2* h2 = (const float2*)h;
  float a0 = 0.f, a1 = 0.f, b0 = 0.f, b1 = 0.f;
  for (int base = 0; base < deg; base += 64) {
    int m = min(64, deg - base);
    int c = 0; float dv = 0.f;
    if (lane < m) { c = col[s0 + base + lane]; dv = dis[c]; }
    int j = 0;
    for (; j + 1 < m; j += 2) {
      int sA = __shfl(c, j), sB = __shfl(c, j + 1);
      float nA = __shfl(dv, j) * rd, nB = __shfl(dv, j + 1) * rd;
      float2 vA = h2[(size_t)sA * 64 + lane];
      float2 vB = h2[(size_t)sB * 64 + lane];
      a0 = fmaf(nA, vA.x, a0); a1 = fmaf(nA, vA.y, a1);
      b0 = fmaf(nB, vB.x, b0); b1 = fmaf(nB, vB.y, b1);
    }
    if (j < m) {
      int sA = __shfl(c, j);
      float nA = __shfl(dv, j) * rd;
      float2 vA = h2[(size_t)sA * 64 + lane];
      a0 = fmaf(nA, vA.x, a0); a1 = fmaf(nA, vA.y, a1);
    }
  }
  float rr = rd * rd;
  float2 hself = h2[(size_t)node * 64 + lane];
  float2 bv = ((const float2*)b)[lane];
  float ad0 = 0.f, ad1 = 0.f;
  if (addin) {
    float2 a2 = ((const float2*)addin)[(size_t)node * 64 + lane];
    ad0 = a2.x; ad1 = a2.y;
  }
  float v0 = fmaf(rr, hself.x, a0 + b0) + bv.x + ad0;
  float v1 = fmaf(rr, hself.y, a1 + b1) + bv.y + ad1;
  ((float2*)out)[(size_t)node * 64 + lane] = make_float2(fmaxf(v0, 0.f), fmaxf(v1, 0.f));
}

__global__ void k_gat_gather(const int* __restrict__ rp, const int* __restrict__ col,
                             const float* __restrict__ hs, const float* __restrict__ as_,
                             const float* __restrict__ ad_, const float* __restrict__ b,
                             float* __restrict__ out, int N, int relu)
{
  int node = blockIdx.x * 4 + (threadIdx.x >> 6);
  if (node >= N) return;
  int lane = threadIdx.x & 63;
  int s0 = rp[node], deg = rp[node + 1] - s0;
  float adn = ad_[node];
  const float2* hs2 = (const float2*)hs;
  float z = 0.f, a0 = 0.f, a1 = 0.f, b0 = 0.f, b1 = 0.f;
  for (int base = 0; base < deg; base += 64) {
    int m = min(64, deg - base);
    int c = 0; float av = 0.f;
    if (lane < m) { c = col[s0 + base + lane]; av = as_[c]; }
    int j = 0;
    for (; j + 1 < m; j += 2) {
      int sA = __shfl(c, j), sB = __shfl(c, j + 1);
      float vA = __shfl(av, j) + adn, vB = __shfl(av, j + 1) + adn;
      vA = vA > 0.f ? vA : 0.2f * vA;
      vB = vB > 0.f ? vB : 0.2f * vB;
      float pA = __expf(vA), pB = __expf(vB);
      z += pA + pB;
      float2 hA = hs2[(size_t)sA * 64 + lane];
      float2 hB = hs2[(size_t)sB * 64 + lane];
      a0 = fmaf(pA, hA.x, a0); a1 = fmaf(pA, hA.y, a1);
      b0 = fmaf(pB, hB.x, b0); b1 = fmaf(pB, hB.y, b1);
    }
    if (j < m) {
      int sA = __shfl(c, j);
      float vA = __shfl(av, j) + adn;
      vA = vA > 0.f ? vA : 0.2f * vA;
      float pA = __expf(vA);
      z += pA;
      float2 hA = hs2[(size_t)sA * 64 + lane];
      a0 = fmaf(pA, hA.x, a0); a1 = fmaf(pA, hA.y, a1);
    }
  }
  float inv = (deg > 0) ? 1.f / z : 0.f;
  float2 bv = ((const float2*)b)[lane];
  float v0 = fmaf(a0 + b0, inv, bv.x);
  float v1 = fmaf(a1 + b1, inv, bv.y);
  if (relu) { v0 = fmaxf(v0, 0.f); v1 = fmaxf(v1, 0.f); }
  ((float2*)out)[(size_t)node * 64 + lane] = make_float2(v0, v1);
}

// ============ segment pooling: one block per graph, contiguous rows ============
__global__ __launch_bounds__(256) void k_pool_seg(
    const float* __restrict__ x, const int* __restrict__ rpb,
    float* __restrict__ pool, int col_off)
{
  __shared__ float2 red2[4][64];
  const int g = blockIdx.x;
  const int t = threadIdx.x, w = t >> 6, lane = t & 63;
  const int n0 = rpb[g], n1 = rpb[g + 1];
  const float2* x2 = (const float2*)x;
  float a0 = 0.f, a1 = 0.f, b0 = 0.f, b1 = 0.f;
  int n = n0 + w;
  for (; n + 4 < n1; n += 8) {
    float2 vA = x2[(size_t)n * 64 + lane];
    float2 vB = x2[(size_t)(n + 4) * 64 + lane];
    a0 += vA.x; a1 += vA.y; b0 += vB.x; b1 += vB.y;
  }
  if (n < n1) { float2 vA = x2[(size_t)n * 64 + lane]; a0 += vA.x; a1 += vA.y; }
  red2[w][lane] = make_float2(a0 + b0, a1 + b1);
  __syncthreads();
  if (t < 64) {
    float2 r0 = red2[0][t], r1 = red2[1][t], r2 = red2[2][t], r3 = red2[3][t];
    float inv = 1.f / fmaxf((float)(n1 - n0), 1.f);
    ((float2*)(pool + (size_t)g * 640 + col_off))[t] =
        make_float2((r0.x + r1.x + r2.x + r3.x) * inv,
                    (r0.y + r1.y + r2.y + r3.y) * inv);
  }
}

// ======================= final MLP (one block per graph) =======================
__global__ void k_mlp(const float* __restrict__ pool,
                      const float* __restrict__ W1, const float* __restrict__ b1,
                      const float* __restrict__ W2, const float* __restrict__ b2,
                      float* __restrict__ out)
{
  __shared__ float emb[640];
  __shared__ float red[128];
  const int g = blockIdx.x, t = threadIdx.x;
  for (int i = t; i < 640; i += 128) emb[i] = pool[(size_t)g * 640 + i];
  __syncthreads();
  float acc = b1[t];
  for (int i = 0; i < 640; ++i) acc = fmaf(emb[i], W1[i * 128 + t], acc);
  float h = fmaxf(acc, 0.f);
  red[t] = h * W2[t];
  __syncthreads();
  for (int s = 64; s > 0; s >>= 1) {
    if (t < s) red[t] += red[t + s];
    __syncthreads();
  }
  if (t == 0) out[g] = red[0] + b2[0];
}

// ======================= host =======================
extern "C" void kernel_launch(void* const* d_in, const int* in_sizes, int n_in,
                              void* d_out, int out_size, void* d_ws, size_t ws_size,
                              hipStream_t stream)
{
  auto fin = [&](int i) { return (const float*)d_in[i]; };
  auto iin = [&](int i) { return (const int*)d_in[i]; };

  const float *x_cd = fin(0), *x_seq = fin(1), *x_anno = fin(2), *x_range = fin(3), *x_md = fin(4);
  const int *ei_seq = iin(5), *ei_anno = iin(6), *ei_range = iin(7),
            *ei_comp = iin(8), *ei_cc = iin(9), *ei_mm = iin(10);
  const int *b_cd = iin(11), *b_seq = iin(12), *b_anno = iin(13), *b_range = iin(14), *b_md = iin(15);

  const int N_CD = in_sizes[0] / HD, N_SEQ = in_sizes[1] / HD, N_ANNO = in_sizes[2] / HD,
            N_RANGE = in_sizes[3] / HD, N_MD = in_sizes[4] / HD;
  const int E_seq = in_sizes[5] / 2, E_anno = in_sizes[6] / 2, E_range = in_sizes[7] / 2,
            E_comp = in_sizes[8] / 2, E_cc = in_sizes[9] / 2, E_mm = in_sizes[10] / 2;
  const int N_OTH = max(max(N_SEQ, N_ANNO), N_RANGE);

  auto WLm = [&](int i, int l) { return fin(i) + (size_t)l * HD * HD; };
  auto WLv = [&](int i, int l) { return fin(i) + (size_t)l * HD; };

  // ---- workspace layout ----
  float* ws = (float*)d_ws;
  size_t off = 0;
  auto alloc = [&](size_t n) { float* p = ws + off; off += (n + 3) & ~(size_t)3; return p; };
  float* xcd1 = alloc((size_t)N_CD * HD);
  float* xmd1 = alloc((size_t)N_MD * HD);
  float* xoth = alloc((size_t)N_OTH * HD);
  float* acc  = alloc((size_t)N_CD * HD);
  float* t1   = alloc((size_t)N_CD * HD);
  float* sAs  = alloc((size_t)N_CD);
  float* sAd  = alloc((size_t)N_CD);
  float* dis_cc = alloc((size_t)N_CD);
  float* dis_mm = alloc((size_t)N_MD);
  float* wvall = alloc(8 * HD);
  float* pool = alloc((size_t)GNUM * 5 * HD);
  short* whi = (short*)(ws + off); off += (size_t)16 * 16384 / 2;
  short* wlo = (short*)(ws + off); off += (size_t)16 * 16384 / 2;
  auto alloci = [&](size_t n) { int* p = (int*)(ws + off); off += (n + 3) & ~(size_t)3; return p; };
  int* bsall = alloci(6 * 256);          // batched scan partials
  int* rpb_all = alloci(5 * RPB);
  int Nds[6] = {N_SEQ, N_ANNO, N_RANGE, N_CD, N_CD, N_MD};
  int Es[6]  = {E_seq, E_anno, E_range, E_comp, E_cc, E_mm};
  int* rps[6];
  int* rp0 = alloci(0);
  { size_t tot = 0; for (int i = 0; i < 6; ++i) tot += (size_t)Nds[i] + 1;
    int* p = alloci(tot); rp0 = p;
    for (int i = 0; i < 6; ++i) { rps[i] = p; p += Nds[i] + 1; } }
  size_t rp_tot_bytes = 0; for (int i = 0; i < 6; ++i) rp_tot_bytes += ((size_t)Nds[i] + 1) * 4;
  int* wps[6]; for (int i = 0; i < 6; ++i) wps[i] = alloci((size_t)Nds[i]);
  int* cols[6]; for (int i = 0; i < 6; ++i) cols[i] = alloci((size_t)Es[i]);
  (void)n_in;

  if (off * sizeof(float) > ws_size) {
    hipMemsetAsync(d_out, 0, (size_t)out_size * sizeof(float), stream);
    return;
  }

  auto ew = [&](size_t elems) { return dim3((unsigned)((elems + 255) / 256)); };
  auto nw = [&](int N) { return dim3((unsigned)((N + 3) / 4)); };

  // ---- pre-split all GEMM weights (slots: 0:16 1:18 2:19 3:21 4:22 5:27 6:32 7:34)
  WTab tab;
  tab.p[0] = fin(16); tab.p[1] = fin(18); tab.p[2] = fin(19); tab.p[3] = fin(21);
  tab.p[4] = fin(22); tab.p[5] = fin(27); tab.p[6] = fin(32); tab.p[7] = fin(34);
  k_split_w<<<dim3(1024), dim3(256), 0, stream>>>(tab, whi, wlo);

  // ---- all 8 GAT matvecs in one launch: slots {comp: s0,d1,s2,d3 | range: s4,d5,s6,d7}
  MTab mt;
  mt.W[0] = WLm(22, 0); mt.a[0] = WLv(24, 0);  mt.W[1] = WLm(23, 0); mt.a[1] = WLv(25, 0);
  mt.W[2] = WLm(22, 1); mt.a[2] = WLv(24, 1);  mt.W[3] = WLm(23, 1); mt.a[3] = WLv(25, 1);
  mt.W[4] = WLm(27, 0); mt.a[4] = WLv(29, 0);  mt.W[5] = WLm(28, 0); mt.a[5] = WLv(30, 0);
  mt.W[6] = WLm(27, 1); mt.a[6] = WLv(29, 1);  mt.W[7] = WLm(28, 1); mt.a[7] = WLv(30, 1);
  k_matvec8<<<dim3(8), dim3(128), 0, stream>>>(mt, wvall);

  // ---- run-pointers for sorted batch vectors (binary search, no atomics) ----
  {
    BTab bt;
    bt.b[0] = b_cd; bt.n[0] = N_CD;  bt.b[1] = b_seq; bt.n[1] = N_SEQ;
    bt.b[2] = b_anno; bt.n[2] = N_ANNO;  bt.b[3] = b_range; bt.n[3] = N_RANGE;
    bt.b[4] = b_md; bt.n[4] = N_MD;
    k_runptr<<<dim3(5), dim3(512), 0, stream>>>(bt, rpb_all);
  }

  // ---- batched CSR build ----
  const int* ess[6] = {ei_seq, ei_anno, ei_range, ei_comp, ei_cc, ei_mm};
  const int* eds[6] = {ei_seq + E_seq, ei_anno + E_anno, ei_range + E_range,
                       ei_comp + E_comp, ei_cc + E_cc, ei_mm + E_mm};
  hipMemsetAsync(rp0, 0, rp_tot_bytes, stream);
  {
    HTab ht; int b = 0;
    for (int i = 0; i < 6; ++i) { ht.key[i] = eds[i]; ht.cnt[i] = rps[i]; ht.bo[i] = b; b += (Es[i] + 255) / 256; ht.n[i] = Es[i]; }
    ht.bo[6] = b;
    k_hist_all<<<dim3(b), dim3(256), 0, stream>>>(ht);
  }
  {
    STab st; int b = 0;
    for (int i = 0; i < 6; ++i) {
      st.rp[i] = rps[i]; st.wp[i] = wps[i]; st.bs[i] = bsall + i * 256;
      st.n[i] = Nds[i]; st.bo[i] = b; b += (Nds[i] + 4095) / 4096;
    }
    st.bo[6] = b;
    k_scan_partial_all<<<dim3(b), dim3(256), 0, stream>>>(st);
    k_scan_bsums_all<<<dim3(6), dim3(256), 0, stream>>>(st);
    k_scan_final_all<<<dim3(b), dim3(256), 0, stream>>>(st);
  }
  {
    FTab ft; int b = 0;
    for (int i = 0; i < 6; ++i) { ft.es[i] = ess[i]; ft.ed[i] = eds[i]; ft.wp[i] = wps[i]; ft.col[i] = cols[i]; ft.bo[i] = b; b += (Es[i] + 255) / 256; ft.n[i] = Es[i]; }
    ft.bo[6] = b;
    k_fill_all<<<dim3(b), dim3(256), 0, stream>>>(ft);
  }
  int *rp_seq = rps[0], *rp_anno = rps[1], *rp_range = rps[2],
      *rp_comp = rps[3], *rp_cc = rps[4], *rp_mm = rps[5];
  int *col_seq = cols[0], *col_anno = cols[1], *col_range = cols[2],
      *col_comp = cols[3], *col_cc = cols[4], *col_mm = cols[5];
  k_dis<<<ew(N_CD), dim3(256), 0, stream>>>(rp_cc, dis_cc, N_CD);
  k_dis<<<ew(N_MD), dim3(256), 0, stream>>>(rp_mm, dis_mm, N_MD);

  auto WHp = [&](int sidx, int layer) { return whi + (size_t)(sidx * 2 + layer) * 16384; };
  auto WLp = [&](int sidx, int layer) { return wlo + (size_t)(sidx * 2 + layer) * 16384; };
  auto gemm = [&](const float* A, int sidx, int layer, float* C, const float* b,
                  int N, int relu) {
    k_gemm_mfma<<<dim3((N + 63) / 64), dim3(256), 0, stream>>>(
        A, WHp(sidx, layer), WLp(sidx, layer), nullptr, nullptr, nullptr, C, b, N, relu);
  };
  auto gemm2 = [&](const float* A1, int s1, const float* A2, int s2, int layer,
                   float* C, const float* b, int N, int relu) {
    k_gemm_mfma<<<dim3((N + 63) / 64), dim3(256), 0, stream>>>(
        A1, WHp(s1, layer), WLp(s1, layer), A2, WHp(s2, layer), WLp(s2, layer), C, b, N, relu);
  };
  auto do_pool = [&](const float* x, int type) {
    k_pool_seg<<<dim3(GNUM), dim3(256), 0, stream>>>(x, rpb_all + type * RPB, pool, type * HD);
  };

  auto gat = [&](const float* xs, const float* xd, const int* rp, const int* col,
                 int Ns, int Nd, int sidx, int layer, int wvS, int wvD,
                 const float* bias, float* out, int relu) {
    k_rowdot<<<nw(Ns), dim3(256), 0, stream>>>(xs, wvall + wvS * 128, sAs, Ns);
    k_rowdot<<<nw(Nd), dim3(256), 0, stream>>>(xd, wvall + wvD * 128, sAd, Nd);
    gemm(xs, sidx, layer, t1, nullptr, Ns, 0);   // hs
    k_gat_gather<<<nw(Nd), dim3(256), 0, stream>>>(rp, col, t1, sAs, sAd, bias, out, Nd, relu);
  };
  auto gcn = [&](const float* x, const int* rp, const int* col, const float* dis, int N,
                 int sidx, int layer, const float* b, const float* addin, float* out) {
    gemm(x, sidx, layer, t1, nullptr, N, 0);
    k_gcn_gather<<<nw(N), dim3(256), 0, stream>>>(rp, col, dis, t1, addin, b, out, N);
  };
  auto sage = [&](const float* xsrc, const float* xself, const int* rp, const int* col,
                  int Nd, int sl, int sr, int layer, const float* bl, float* out) {
    k_sage_gather<<<nw(Nd), dim3(256), 0, stream>>>(rp, col, xsrc, t1, Nd);
    gemm2(t1, sl, xself, sr, layer, out, bl, Nd, 1);
  };

  // ---------- CD + MD, both layers ----------
  gat(x_md, x_cd, rp_comp, col_comp, N_MD, N_CD, 4, 0, 0, 1, WLv(26, 0), acc, 0);
  gcn(x_cd, rp_cc, col_cc, dis_cc, N_CD, 6, 0, WLv(33, 0), acc, xcd1);
  gcn(x_md, rp_mm, col_mm, dis_mm, N_MD, 7, 0, WLv(35, 0), nullptr, xmd1);
  gat(xmd1, xcd1, rp_comp, col_comp, N_MD, N_CD, 4, 1, 2, 3, WLv(26, 1), acc, 0);
  gcn(xcd1, rp_cc, col_cc, dis_cc, N_CD, 6, 1, WLv(33, 1), acc, acc);
  do_pool(acc, 0);
  gcn(xmd1, rp_mm, col_mm, dis_mm, N_MD, 7, 1, WLv(35, 1), nullptr, acc);
  do_pool(acc, 4);

  // ---------- SEQ ----------
  sage(x_cd, x_seq, rp_seq, col_seq, N_SEQ, 0, 1, 0, WLv(17, 0), xoth);
  sage(xcd1, xoth, rp_seq, col_seq, N_SEQ, 0, 1, 1, WLv(17, 1), acc);
  do_pool(acc, 1);
  // ---------- ANNO ----------
  sage(x_cd, x_anno, rp_anno, col_anno, N_ANNO, 2, 3, 0, WLv(20, 0), xoth);
  sage(xcd1, xoth, rp_anno, col_anno, N_ANNO, 2, 3, 1, WLv(20, 1), acc);
  do_pool(acc, 2);
  // ---------- RANGE ----------
  gat(x_cd, x_range, rp_range, col_range, N_CD, N_RANGE, 5, 0, 4, 5, WLv(31, 0), xoth, 1);
  gat(xcd1, xoth, rp_range, col_range, N_CD, N_RANGE, 5, 1, 6, 7, WLv(31, 1), acc, 1);
  do_pool(acc, 3);

  k_mlp<<<dim3(GNUM), dim3(128), 0, stream>>>(
      pool, fin(36), fin(37), fin(38), fin(39), (float*)d_out);
}

// Round 12
// 1059.451 us; speedup vs baseline: 2.5801x; 1.0615x over previous
//
#include <hip/hip_runtime.h>

#define HD 128
#define GNUM 512
#define RPB 520   // per-type stride in rpb_all (>= GNUM+1)

typedef __attribute__((ext_vector_type(8))) short short8v;   // 8 bf16 = 4 VGPR
typedef __attribute__((ext_vector_type(4))) float f32x4;

// RNE split: a ~= hi + lo (both bf16), |residual| ~ 2^-17 |a|
__device__ __forceinline__ void split1(float a, short& h, short& l) {
  unsigned u = __float_as_uint(a);
  unsigned hb = (u + 0x7FFFu + ((u >> 16) & 1u)) & 0xFFFF0000u;
  h = (short)(hb >> 16);
  float rest = a - __uint_as_float(hb);
  unsigned u2 = __float_as_uint(rest);
  l = (short)((u2 + 0x7FFFu + ((u2 >> 16) & 1u)) >> 16);
}

// ============ W pre-split: fp32 [k][n] -> bf16 hi/lo TRANSPOSED [n][k] ============
struct WTab { const float* p[8]; };
__global__ __launch_bounds__(256) void k_split_w(WTab tab, short* __restrict__ whi,
                                                 short* __restrict__ wlo)
{
  int m = blockIdx.x >> 6;                       // 16 matrices, 64 blocks each
  int i = (blockIdx.x & 63) * 256 + threadIdx.x; // 0..16383
  const float* W = tab.p[m >> 1] + (m & 1) * 16384;
  int k = i >> 7, n = i & 127;
  short h, l;
  split1(W[k * 128 + n], h, l);
  whi[m * 16384 + n * 128 + k] = h;
  wlo[m * 16384 + n * 128 + k] = l;
}

// ============ MFMA GEMM: C = A1@W1 (+ A2@W2) (+bias, relu) ====================
// Optional fused row-dot: adot[r] = (A1@W1)_row[r] . avec  (avec in OUTPUT space,
// i.e. the raw attention vector a_s — NOT the matvec'd W@a).
#define CF_LD 132
__global__ __launch_bounds__(256) void k_gemm_mfma(
    const float* __restrict__ A1, const short* __restrict__ WH1, const short* __restrict__ WL1,
    const float* __restrict__ A2, const short* __restrict__ WH2, const short* __restrict__ WL2,
    float* __restrict__ C, const float* __restrict__ bias, int N, int relu,
    const float* __restrict__ avec, float* __restrict__ adot)
{
  __shared__ char smem[64 * 136 * 2 * 2];        // 34816 B
  short* Ah = (short*)smem;
  short* Al = Ah + 64 * 136;
  float* Cf = (float*)smem;

  const int t = threadIdx.x;
  const int row0 = blockIdx.x * 64;
  const int lane = t & 63, wid = t >> 6;
  const int g = lane >> 4, cn = lane & 15;
  const int colbase = wid * 32;

  f32x4 zero = {0.f, 0.f, 0.f, 0.f};
  f32x4 acc[4][2];
#pragma unroll
  for (int rt = 0; rt < 4; ++rt) { acc[rt][0] = zero; acc[rt][1] = zero; }

  auto stageA = [&](const float* __restrict__ A) {
    const float4* A4 = (const float4*)(A + (size_t)row0 * 128);
#pragma unroll
    for (int i = 0; i < 8; ++i) {
      int f4 = t + i * 256;
      int row = f4 >> 5, c4 = f4 & 31;
      float4 v = make_float4(0.f, 0.f, 0.f, 0.f);
      if (row0 + row < N) v = A4[f4];
      short4 h, l;
      split1(v.x, h.x, l.x); split1(v.y, h.y, l.y);
      split1(v.z, h.z, l.z); split1(v.w, h.w, l.w);
      *(short4*)(Ah + row * 136 + c4 * 4) = h;
      *(short4*)(Al + row * 136 + c4 * 4) = l;
    }
  };

  auto accum = [&](const short* __restrict__ WH, const short* __restrict__ WL) {
    short8v bhi[2][4], blo[2][4];
#pragma unroll
    for (int ct = 0; ct < 2; ++ct)
#pragma unroll
      for (int kg = 0; kg < 4; ++kg) {
        size_t o = (size_t)(colbase + ct * 16 + cn) * 128 + kg * 32 + g * 8;
        bhi[ct][kg] = *(const short8v*)(WH + o);
        blo[ct][kg] = *(const short8v*)(WL + o);
      }
#pragma unroll
    for (int kg = 0; kg < 4; ++kg) {
#pragma unroll
      for (int rt = 0; rt < 4; ++rt) {
        const int ao = (rt * 16 + cn) * 136 + kg * 32 + g * 8;
        const short8v ah = *(const short8v*)(Ah + ao);
        const short8v al = *(const short8v*)(Al + ao);
#pragma unroll
        for (int ct = 0; ct < 2; ++ct) {
          acc[rt][ct] = __builtin_amdgcn_mfma_f32_16x16x32_bf16(ah, bhi[ct][kg], acc[rt][ct], 0, 0, 0);
          acc[rt][ct] = __builtin_amdgcn_mfma_f32_16x16x32_bf16(al, bhi[ct][kg], acc[rt][ct], 0, 0, 0);
          acc[rt][ct] = __builtin_amdgcn_mfma_f32_16x16x32_bf16(ah, blo[ct][kg], acc[rt][ct], 0, 0, 0);
        }
      }
    }
  };

  stageA(A1);
  __syncthreads();
  accum(WH1, WL1);
  if (A2) {
    __syncthreads();
    stageA(A2);
    __syncthreads();
    accum(WH2, WL2);
  }
  __syncthreads();                   // Ah/Al dead past here; smem reusable

  // ---- fused row-dot (raw A@W): per-wave partial + cross-wave LDS reduce ----
  if (avec) {
    float* part = (float*)smem;      // [4 waves][64 rows]
    const float av0 = avec[colbase + cn];
    const float av1 = avec[colbase + 16 + cn];
#pragma unroll
    for (int rt = 0; rt < 4; ++rt)
#pragma unroll
      for (int r = 0; r < 4; ++r) {
        float p = fmaf(acc[rt][1][r], av1, acc[rt][0][r] * av0);
#pragma unroll
        for (int o = 1; o < 16; o <<= 1) p += __shfl_xor(p, o);
        if (cn == 0) part[wid * 64 + rt * 16 + g * 4 + r] = p;
      }
    __syncthreads();
    if (t < 64) {
      int row = row0 + t;
      if (row < N) adot[row] = part[t] + part[64 + t] + part[128 + t] + part[192 + t];
    }
    __syncthreads();
  }

  // scatter acc into LDS C-tile: C/D layout col = lane&15, row = (lane>>4)*4 + reg
#pragma unroll
  for (int rt = 0; rt < 4; ++rt)
#pragma unroll
    for (int ct = 0; ct < 2; ++ct)
#pragma unroll
      for (int r = 0; r < 4; ++r)
        Cf[(rt * 16 + g * 4 + r) * CF_LD + colbase + ct * 16 + cn] = acc[rt][ct][r];
  __syncthreads();

  float4* C4 = (float4*)(C + (size_t)row0 * 128);
#pragma unroll
  for (int i = 0; i < 8; ++i) {
    int f4 = t + i * 256;
    int row = f4 >> 5, c4 = f4 & 31;
    if (row0 + row < N) {
      float4 v = *(const float4*)(Cf + row * CF_LD + c4 * 4);
      if (bias) {
        float4 bv = *(const float4*)(bias + c4 * 4);
        v.x += bv.x; v.y += bv.y; v.z += bv.z; v.w += bv.w;
      }
      if (relu) {
        v.x = fmaxf(v.x, 0.f); v.y = fmaxf(v.y, 0.f);
        v.z = fmaxf(v.z, 0.f); v.w = fmaxf(v.w, 0.f);
      }
      C4[f4] = v;
    }
  }
}

// ======================= row dot: out[n] = x[n,:] . a  (one wave / node) ===========
__global__ void k_rowdot(const float* __restrict__ x, const float* __restrict__ a,
                         float* __restrict__ out, int N)
{
  int wid = blockIdx.x * 4 + (threadIdx.x >> 6);
  int lane = threadIdx.x & 63;
  if (wid >= N) return;
  float2 xv = ((const float2*)x)[(size_t)wid * 64 + lane];
  float2 av = ((const float2*)a)[lane];
  float v = fmaf(xv.y, av.y, xv.x * av.x);
#pragma unroll
  for (int o = 32; o > 0; o >>= 1) v += __shfl_down(v, o);
  if (lane == 0) out[wid] = v;
}

// ================= batched matvec: wv[m][i] = sum_j W_m[i,j]*a_m[j] ==============
struct MTab { const float* W[4]; const float* a[4]; };
__global__ __launch_bounds__(128) void k_matvec4(MTab tb, float* __restrict__ wv)
{
  __shared__ float as[128];
  int m = blockIdx.x, i = threadIdx.x;
  as[i] = tb.a[m][i];
  __syncthreads();
  const float* W = tb.W[m];
  float v = 0.f;
  for (int j = 0; j < 128; ++j) v = fmaf(W[i * 128 + j], as[j], v);
  wv[m * 128 + i] = v;
}

// ======================= batched CSR build =======================
// hist pass records per-edge rank (atomicAdd return) -> fill needs NO atomics.
struct HTab { const int* key[6]; int* cnt[6]; int* rank[6]; int bo[7]; int n[6]; };
__global__ void k_hist_rank_all(HTab tb) {
  int bi = blockIdx.x, ty = 0;
  while (ty < 5 && bi >= tb.bo[ty + 1]) ++ty;
  int i = (bi - tb.bo[ty]) * 256 + threadIdx.x;
  if (i < tb.n[ty]) tb.rank[ty][i] = atomicAdd(&tb.cnt[ty][tb.key[ty][i]], 1);
}

struct FTab { const int* es[6]; const int* ed[6]; const int* rp[6]; const int* rank[6];
              int* col[6]; int bo[7]; int n[6]; };
__global__ void k_fill_all(FTab tb) {
  int bi = blockIdx.x, ty = 0;
  while (ty < 5 && bi >= tb.bo[ty + 1]) ++ty;
  int e = (bi - tb.bo[ty]) * 256 + threadIdx.x;
  if (e >= tb.n[ty]) return;
  int p = tb.rp[ty][tb.ed[ty][e]] + tb.rank[ty][e];
  tb.col[ty][p] = tb.es[ty][e];
}

// ---- batched 3-phase exclusive scan over 6 arrays (tile = 4096) ----
struct STab { int* rp[6]; int* bs[6]; int n[6]; int bo[7]; };

__global__ __launch_bounds__(256) void k_scan_partial_all(STab tb) {
  __shared__ int red[256];
  int bi = blockIdx.x, ty = 0;
  while (ty < 5 && bi >= tb.bo[ty + 1]) ++ty;
  int lb = bi - tb.bo[ty];
  const int* rp = tb.rp[ty];
  const int N = tb.n[ty];
  const int t = threadIdx.x, base = lb * 4096;
  int s = 0;
  for (int i = t; i < 4096; i += 256) {
    int idx = base + i;
    if (idx < N) s += rp[idx];
  }
  red[t] = s;
  __syncthreads();
  for (int ofs = 128; ofs > 0; ofs >>= 1) {
    if (t < ofs) red[t] += red[t + ofs];
    __syncthreads();
  }
  if (t == 0) tb.bs[ty][lb] = red[0];
}

__global__ __launch_bounds__(256) void k_scan_bsums_all(STab tb) {
  __shared__ int sh[256];
  const int ty = blockIdx.x;
  const int nb = (tb.n[ty] + 4095) / 4096;   // <= 25
  const int t = threadIdx.x;
  int v = (t < nb) ? tb.bs[ty][t] : 0;
  sh[t] = v;
  __syncthreads();
  for (int ofs = 1; ofs < 256; ofs <<= 1) {
    int u = (t >= ofs) ? sh[t - ofs] : 0;
    __syncthreads();
    sh[t] += u;
    __syncthreads();
  }
  if (t < nb) tb.bs[ty][t] = sh[t] - v;      // exclusive
  if (t == 255) tb.rp[ty][tb.n[ty]] = sh[255];  // total
}

__global__ __launch_bounds__(256) void k_scan_final_all(STab tb) {
  __shared__ int sh[4096 + 256];             // padded: i -> i + (i>>4)
  __shared__ int tsum[256];
  int bi = blockIdx.x, ty = 0;
  while (ty < 5 && bi >= tb.bo[ty + 1]) ++ty;
  int lb = bi - tb.bo[ty];
  int* rp = tb.rp[ty];
  const int N = tb.n[ty];
  const int t = threadIdx.x, base = lb * 4096;
  auto mp = [](int i) { return i + (i >> 4); };
#pragma unroll
  for (int i = 0; i < 16; ++i) {
    int idx = base + i * 256 + t;
    sh[mp(i * 256 + t)] = (idx < N) ? rp[idx] : 0;
  }
  __syncthreads();
  int s = 0;
#pragma unroll
  for (int j = 0; j < 16; ++j) s += sh[mp(t * 16 + j)];
  tsum[t] = s;
  __syncthreads();
  for (int ofs = 1; ofs < 256; ofs <<= 1) {
    int u = (t >= ofs) ? tsum[t - ofs] : 0;
    __syncthreads();
    tsum[t] += u;
    __syncthreads();
  }
  int pre = tsum[t] - s + tb.bs[ty][lb];
#pragma unroll
  for (int j = 0; j < 16; ++j) {
    int v = sh[mp(t * 16 + j)];
    sh[mp(t * 16 + j)] = pre;
    pre += v;
  }
  __syncthreads();
#pragma unroll
  for (int i = 0; i < 16; ++i) {
    int idx = base + i * 256 + t;
    if (idx < N) rp[idx] = sh[mp(i * 256 + t)];
  }
}

// ---- run-pointers for SORTED batch vectors via binary search (no atomics) ----
struct BTab { const int* b[5]; int n[5]; };
__global__ __launch_bounds__(512) void k_runptr(BTab tb, int* __restrict__ rpb_all) {
  const int ty = blockIdx.x;
  const int* b = tb.b[ty];
  const int N = tb.n[ty];
  const int t = threadIdx.x;                 // 0..511 = graph id
  int lo = 0, hi = N;
  while (lo < hi) {                          // lower_bound(b, t)
    int mid = (lo + hi) >> 1;
    if (b[mid] < t) lo = mid + 1; else hi = mid;
  }
  rpb_all[ty * RPB + t] = lo;
  if (t == 0) rpb_all[ty * RPB + GNUM] = N;
}

// dis for both GCN types in one launch
struct DTab { const int* rp[2]; float* dis[2]; int n[2]; int bo[3]; };
__global__ void k_dis2(DTab tb) {
  int bi = blockIdx.x, ty = (bi >= tb.bo[1]) ? 1 : 0;
  int n = (bi - tb.bo[ty]) * 256 + threadIdx.x;
  if (n < tb.n[ty]) tb.dis[ty][n] = rsqrtf((float)(tb.rp[ty][n + 1] - tb.rp[ty][n]) + 1.f);
}

// ======================= gather kernels =======================
__global__ void k_sage_gather(const int* __restrict__ rp, const int* __restrict__ col,
                              const float* __restrict__ x, float* __restrict__ out, int N)
{
  int node = blockIdx.x * 4 + (threadIdx.x >> 6);
  if (node >= N) return;
  int lane = threadIdx.x & 63;
  int s0 = rp[node], deg = rp[node + 1] - s0;
  const float2* x2 = (const float2*)x;
  float a0 = 0.f, a1 = 0.f, b0 = 0.f, b1 = 0.f;
  for (int base = 0; base < deg; base += 64) {
    int m = min(64, deg - base);
    int c = (lane < m) ? col[s0 + base + lane] : 0;
    int j = 0;
    for (; j + 1 < m; j += 2) {
      int sA = __shfl(c, j), sB = __shfl(c, j + 1);
      float2 vA = x2[(size_t)sA * 64 + lane];
      float2 vB = x2[(size_t)sB * 64 + lane];
      a0 += vA.x; a1 += vA.y; b0 += vB.x; b1 += vB.y;
    }
    if (j < m) {
      int sA = __shfl(c, j);
      float2 vA = x2[(size_t)sA * 64 + lane];
      a0 += vA.x; a1 += vA.y;
    }
  }
  float inv = 1.f / fmaxf((float)deg, 1.f);
  ((float2*)out)[(size_t)node * 64 + lane] = make_float2((a0 + b0) * inv, (a1 + b1) * inv);
}

__global__ void k_gcn_gather(const int* __restrict__ rp, const int* __restrict__ col,
                             const float* __restrict__ dis, const float* __restrict__ h,
                             const float* addin, const float* __restrict__ b,
                             float* out, int N)
{
  int node = blockIdx.x * 4 + (threadIdx.x >> 6);
  if (node >= N) return;
  int lane = threadIdx.x & 63;
  int s0 = rp[node], deg = rp[node + 1] - s0;
  float rd = dis[node];
  const float2* h2 = (const float2*)h;
  float a0 = 0.f, a1 = 0.f, b0 = 0.f, b1 = 0.f;
  for (int base = 0; base < deg; base += 64) {
    int m = min(64, deg - base);
    int c = 0; float dv = 0.f;
    if (lane < m) { c = col[s0 + base + lane]; dv = dis[c]; }
    int j = 0;
    for (; j + 1 < m; j += 2) {
      int sA = __shfl(c, j), sB = __shfl(c, j + 1);
      float nA = __shfl(dv, j) * rd, nB = __shfl(dv, j + 1) * rd;
      float2 vA = h2[(size_t)sA * 64 + lane];
      float2 vB = h2[(size_t)sB * 64 + lane];
      a0 = fmaf(nA, vA.x, a0); a1 = fmaf(nA, vA.y, a1);
      b0 = fmaf(nB, vB.x, b0); b1 = fmaf(nB, vB.y, b1);
    }
    if (j < m) {
      int sA = __shfl(c, j);
      float nA = __shfl(dv, j) * rd;
      float2 vA = h2[(size_t)sA * 64 + lane];
      a0 = fmaf(nA, vA.x, a0); a1 = fmaf(nA, vA.y, a1);
    }
  }
  float rr = rd * rd;
  float2 hself = h2[(size_t)node * 64 + lane];
  float2 bv = ((const float2*)b)[lane];
  float ad0 = 0.f, ad1 = 0.f;
  if (addin) {
    float2 a2 = ((const float2*)addin)[(size_t)node * 64 + lane];
    ad0 = a2.x; ad1 = a2.y;
  }
  float v0 = fmaf(rr, hself.x, a0 + b0) + bv.x + ad0;
  float v1 = fmaf(rr, hself.y, a1 + b1) + bv.y + ad1;
  ((float2*)out)[(size_t)node * 64 + lane] = make_float2(fmaxf(v0, 0.f), fmaxf(v1, 0.f));
}

__global__ void k_gat_gather(const int* __restrict__ rp, const int* __restrict__ col,
                             const float* __restrict__ hs, const float* __restrict__ as_,
                             const float* __restrict__ ad_, const float* __restrict__ b,
                             float* __restrict__ out, int N, int relu)
{
  int node = blockIdx.x * 4 + (threadIdx.x >> 6);
  if (node >= N) return;
  int lane = threadIdx.x & 63;
  int s0 = rp[node], deg = rp[node + 1] - s0;
  float adn = ad_[node];
  const float2* hs2 = (const float2*)hs;
  float z = 0.f, a0 = 0.f, a1 = 0.f, b0 = 0.f, b1 = 0.f;
  for (int base = 0; base < deg; base += 64) {
    int m = min(64, deg - base);
    int c = 0; float av = 0.f;
    if (lane < m) { c = col[s0 + base + lane]; av = as_[c]; }
    int j = 0;
    for (; j + 1 < m; j += 2) {
      int sA = __shfl(c, j), sB = __shfl(c, j + 1);
      float vA = __shfl(av, j) + adn, vB = __shfl(av, j + 1) + adn;
      vA = vA > 0.f ? vA : 0.2f * vA;
      vB = vB > 0.f ? vB : 0.2f * vB;
      float pA = __expf(vA), pB = __expf(vB);
      z += pA + pB;
      float2 hA = hs2[(size_t)sA * 64 + lane];
      float2 hB = hs2[(size_t)sB * 64 + lane];
      a0 = fmaf(pA, hA.x, a0); a1 = fmaf(pA, hA.y, a1);
      b0 = fmaf(pB, hB.x, b0); b1 = fmaf(pB, hB.y, b1);
    }
    if (j < m) {
      int sA = __shfl(c, j);
      float vA = __shfl(av, j) + adn;
      vA = vA > 0.f ? vA : 0.2f * vA;
      float pA = __expf(vA);
      z += pA;
      float2 hA = hs2[(size_t)sA * 64 + lane];
      a0 = fmaf(pA, hA.x, a0); a1 = fmaf(pA, hA.y, a1);
    }
  }
  float inv = (deg > 0) ? 1.f / z : 0.f;
  float2 bv = ((const float2*)b)[lane];
  float v0 = fmaf(a0 + b0, inv, bv.x);
  float v1 = fmaf(a1 + b1, inv, bv.y);
  if (relu) { v0 = fmaxf(v0, 0.f); v1 = fmaxf(v1, 0.f); }
  ((float2*)out)[(size_t)node * 64 + lane] = make_float2(v0, v1);
}

// ============ segment pooling: one block per graph, contiguous rows ============
__global__ __launch_bounds__(256) void k_pool_seg(
    const float* __restrict__ x, const int* __restrict__ rpb,
    float* __restrict__ pool, int col_off)
{
  __shared__ float2 red2[4][64];
  const int g = blockIdx.x;
  const int t = threadIdx.x, w = t >> 6, lane = t & 63;
  const int n0 = rpb[g], n1 = rpb[g + 1];
  const float2* x2 = (const float2*)x;
  float a0 = 0.f, a1 = 0.f, b0 = 0.f, b1 = 0.f;
  int n = n0 + w;
  for (; n + 4 < n1; n += 8) {
    float2 vA = x2[(size_t)n * 64 + lane];
    float2 vB = x2[(size_t)(n + 4) * 64 + lane];
    a0 += vA.x; a1 += vA.y; b0 += vB.x; b1 += vB.y;
  }
  if (n < n1) { float2 vA = x2[(size_t)n * 64 + lane]; a0 += vA.x; a1 += vA.y; }
  red2[w][lane] = make_float2(a0 + b0, a1 + b1);
  __syncthreads();
  if (t < 64) {
    float2 r0 = red2[0][t], r1 = red2[1][t], r2 = red2[2][t], r3 = red2[3][t];
    float inv = 1.f / fmaxf((float)(n1 - n0), 1.f);
    ((float2*)(pool + (size_t)g * 640 + col_off))[t] =
        make_float2((r0.x + r1.x + r2.x + r3.x) * inv,
                    (r0.y + r1.y + r2.y + r3.y) * inv);
  }
}

// ======================= final MLP (one block per graph) =======================
__global__ void k_mlp(const float* __restrict__ pool,
                      const float* __restrict__ W1, const float* __restrict__ b1,
                      const float* __restrict__ W2, const float* __restrict__ b2,
                      float* __restrict__ out)
{
  __shared__ float emb[640];
  __shared__ float red[128];
  const int g = blockIdx.x, t = threadIdx.x;
  for (int i = t; i < 640; i += 128) emb[i] = pool[(size_t)g * 640 + i];
  __syncthreads();
  float acc = b1[t];
  for (int i = 0; i < 640; ++i) acc = fmaf(emb[i], W1[i * 128 + t], acc);
  float h = fmaxf(acc, 0.f);
  red[t] = h * W2[t];
  __syncthreads();
  for (int s = 64; s > 0; s >>= 1) {
    if (t < s) red[t] += red[t + s];
    __syncthreads();
  }
  if (t == 0) out[g] = red[0] + b2[0];
}

// ======================= host =======================
extern "C" void kernel_launch(void* const* d_in, const int* in_sizes, int n_in,
                              void* d_out, int out_size, void* d_ws, size_t ws_size,
                              hipStream_t stream)
{
  auto fin = [&](int i) { return (const float*)d_in[i]; };
  auto iin = [&](int i) { return (const int*)d_in[i]; };

  const float *x_cd = fin(0), *x_seq = fin(1), *x_anno = fin(2), *x_range = fin(3), *x_md = fin(4);
  const int *ei_seq = iin(5), *ei_anno = iin(6), *ei_range = iin(7),
            *ei_comp = iin(8), *ei_cc = iin(9), *ei_mm = iin(10);
  const int *b_cd = iin(11), *b_seq = iin(12), *b_anno = iin(13), *b_range = iin(14), *b_md = iin(15);

  const int N_CD = in_sizes[0] / HD, N_SEQ = in_sizes[1] / HD, N_ANNO = in_sizes[2] / HD,
            N_RANGE = in_sizes[3] / HD, N_MD = in_sizes[4] / HD;
  const int E_seq = in_sizes[5] / 2, E_anno = in_sizes[6] / 2, E_range = in_sizes[7] / 2,
            E_comp = in_sizes[8] / 2, E_cc = in_sizes[9] / 2, E_mm = in_sizes[10] / 2;
  const int N_OTH = max(max(N_SEQ, N_ANNO), N_RANGE);

  auto WLm = [&](int i, int l) { return fin(i) + (size_t)l * HD * HD; };
  auto WLv = [&](int i, int l) { return fin(i) + (size_t)l * HD; };

  // ---- workspace layout ----
  float* ws = (float*)d_ws;
  size_t off = 0;
  auto alloc = [&](size_t n) { float* p = ws + off; off += (n + 3) & ~(size_t)3; return p; };
  float* xcd1 = alloc((size_t)N_CD * HD);
  float* xmd1 = alloc((size_t)N_MD * HD);
  float* xoth = alloc((size_t)N_OTH * HD);
  float* acc  = alloc((size_t)N_CD * HD);
  float* t1   = alloc((size_t)N_CD * HD);
  float* sAs  = alloc((size_t)N_CD);
  float* sAd  = alloc((size_t)N_CD);
  float* dis_cc = alloc((size_t)N_CD);
  float* dis_mm = alloc((size_t)N_MD);
  float* wvall = alloc(4 * HD);
  float* pool = alloc((size_t)GNUM * 5 * HD);
  short* whi = (short*)(ws + off); off += (size_t)16 * 16384 / 2;
  short* wlo = (short*)(ws + off); off += (size_t)16 * 16384 / 2;
  auto alloci = [&](size_t n) { int* p = (int*)(ws + off); off += (n + 3) & ~(size_t)3; return p; };
  int* bsall = alloci(6 * 256);          // batched scan partials
  int* rpb_all = alloci(5 * RPB);
  int Nds[6] = {N_SEQ, N_ANNO, N_RANGE, N_CD, N_CD, N_MD};
  int Es[6]  = {E_seq, E_anno, E_range, E_comp, E_cc, E_mm};
  int* rps[6];
  int* rp0 = alloci(0);
  { size_t tot = 0; for (int i = 0; i < 6; ++i) tot += (size_t)Nds[i] + 1;
    int* p = alloci(tot); rp0 = p;
    for (int i = 0; i < 6; ++i) { rps[i] = p; p += Nds[i] + 1; } }
  size_t rp_tot_bytes = 0; for (int i = 0; i < 6; ++i) rp_tot_bytes += ((size_t)Nds[i] + 1) * 4;
  int* ranks[6]; for (int i = 0; i < 6; ++i) ranks[i] = alloci((size_t)Es[i]);
  int* cols[6];  for (int i = 0; i < 6; ++i) cols[i] = alloci((size_t)Es[i]);
  (void)n_in;

  if (off * sizeof(float) > ws_size) {
    hipMemsetAsync(d_out, 0, (size_t)out_size * sizeof(float), stream);
    return;
  }

  auto ew = [&](size_t elems) { return dim3((unsigned)((elems + 255) / 256)); };
  auto nw = [&](int N) { return dim3((unsigned)((N + 3) / 4)); };

  // ---- pre-split all GEMM weights (slots: 0:16 1:18 2:19 3:21 4:22 5:27 6:32 7:34)
  WTab tab;
  tab.p[0] = fin(16); tab.p[1] = fin(18); tab.p[2] = fin(19); tab.p[3] = fin(21);
  tab.p[4] = fin(22); tab.p[5] = fin(27); tab.p[6] = fin(32); tab.p[7] = fin(34);
  k_split_w<<<dim3(1024), dim3(256), 0, stream>>>(tab, whi, wlo);

  // ---- 4 DST-side GAT matvecs (Wd@a_d): comp L0/L1, range L0/L1 ----
  MTab mt;
  mt.W[0] = WLm(23, 0); mt.a[0] = WLv(25, 0);
  mt.W[1] = WLm(23, 1); mt.a[1] = WLv(25, 1);
  mt.W[2] = WLm(28, 0); mt.a[2] = WLv(30, 0);
  mt.W[3] = WLm(28, 1); mt.a[3] = WLv(30, 1);
  k_matvec4<<<dim3(4), dim3(128), 0, stream>>>(mt, wvall);

  // ---- run-pointers for sorted batch vectors (binary search, no atomics) ----
  {
    BTab bt;
    bt.b[0] = b_cd; bt.n[0] = N_CD;  bt.b[1] = b_seq; bt.n[1] = N_SEQ;
    bt.b[2] = b_anno; bt.n[2] = N_ANNO;  bt.b[3] = b_range; bt.n[3] = N_RANGE;
    bt.b[4] = b_md; bt.n[4] = N_MD;
    k_runptr<<<dim3(5), dim3(512), 0, stream>>>(bt, rpb_all);
  }

  // ---- batched CSR build (rank-recording: fill has no atomics) ----
  const int* ess[6] = {ei_seq, ei_anno, ei_range, ei_comp, ei_cc, ei_mm};
  const int* eds[6] = {ei_seq + E_seq, ei_anno + E_anno, ei_range + E_range,
                       ei_comp + E_comp, ei_cc + E_cc, ei_mm + E_mm};
  hipMemsetAsync(rp0, 0, rp_tot_bytes, stream);
  {
    HTab ht; int b = 0;
    for (int i = 0; i < 6; ++i) {
      ht.key[i] = eds[i]; ht.cnt[i] = rps[i]; ht.rank[i] = ranks[i];
      ht.bo[i] = b; b += (Es[i] + 255) / 256; ht.n[i] = Es[i];
    }
    ht.bo[6] = b;
    k_hist_rank_all<<<dim3(b), dim3(256), 0, stream>>>(ht);
  }
  {
    STab st; int b = 0;
    for (int i = 0; i < 6; ++i) {
      st.rp[i] = rps[i]; st.bs[i] = bsall + i * 256;
      st.n[i] = Nds[i]; st.bo[i] = b; b += (Nds[i] + 4095) / 4096;
    }
    st.bo[6] = b;
    k_scan_partial_all<<<dim3(b), dim3(256), 0, stream>>>(st);
    k_scan_bsums_all<<<dim3(6), dim3(256), 0, stream>>>(st);
    k_scan_final_all<<<dim3(b), dim3(256), 0, stream>>>(st);
  }
  {
    FTab ft; int b = 0;
    for (int i = 0; i < 6; ++i) {
      ft.es[i] = ess[i]; ft.ed[i] = eds[i]; ft.rp[i] = rps[i]; ft.rank[i] = ranks[i];
      ft.col[i] = cols[i]; ft.bo[i] = b; b += (Es[i] + 255) / 256; ft.n[i] = Es[i];
    }
    ft.bo[6] = b;
    k_fill_all<<<dim3(b), dim3(256), 0, stream>>>(ft);
  }
  int *rp_seq = rps[0], *rp_anno = rps[1], *rp_range = rps[2],
      *rp_comp = rps[3], *rp_cc = rps[4], *rp_mm = rps[5];
  int *col_seq = cols[0], *col_anno = cols[1], *col_range = cols[2],
      *col_comp = cols[3], *col_cc = cols[4], *col_mm = cols[5];
  {
    DTab dt;
    dt.rp[0] = rp_cc; dt.dis[0] = dis_cc; dt.n[0] = N_CD;
    dt.rp[1] = rp_mm; dt.dis[1] = dis_mm; dt.n[1] = N_MD;
    dt.bo[0] = 0; dt.bo[1] = (N_CD + 255) / 256;
    dt.bo[2] = dt.bo[1] + (N_MD + 255) / 256;
    k_dis2<<<dim3(dt.bo[2]), dim3(256), 0, stream>>>(dt);
  }

  auto WHp = [&](int sidx, int layer) { return whi + (size_t)(sidx * 2 + layer) * 16384; };
  auto WLp = [&](int sidx, int layer) { return wlo + (size_t)(sidx * 2 + layer) * 16384; };
  auto gemm = [&](const float* A, int sidx, int layer, float* C, const float* b,
                  int N, int relu, const float* avec = nullptr, float* adot = nullptr) {
    k_gemm_mfma<<<dim3((N + 63) / 64), dim3(256), 0, stream>>>(
        A, WHp(sidx, layer), WLp(sidx, layer), nullptr, nullptr, nullptr, C, b, N, relu,
        avec, adot);
  };
  auto gemm2 = [&](const float* A1, int s1, const float* A2, int s2, int layer,
                   float* C, const float* b, int N, int relu) {
    k_gemm_mfma<<<dim3((N + 63) / 64), dim3(256), 0, stream>>>(
        A1, WHp(s1, layer), WLp(s1, layer), A2, WHp(s2, layer), WLp(s2, layer), C, b, N, relu,
        nullptr, nullptr);
  };
  auto do_pool = [&](const float* x, int type) {
    k_pool_seg<<<dim3(GNUM), dim3(256), 0, stream>>>(x, rpb_all + type * RPB, pool, type * HD);
  };

  // GAT: hs = xs@Ws with FUSED sAs = hs.a_s (avec = RAW a_s, output space);
  // sAd = xd.(Wd@a_d) via precomputed matvec (hd never materialized).
  auto gat = [&](const float* xs, const float* xd, const int* rp, const int* col,
                 int Ns, int Nd, int sidx, int layer, const float* avs_raw, int wvD,
                 const float* bias, float* out, int relu) {
    k_rowdot<<<nw(Nd), dim3(256), 0, stream>>>(xd, wvall + wvD * 128, sAd, Nd);
    gemm(xs, sidx, layer, t1, nullptr, Ns, 0, avs_raw, sAs);   // hs + fused hs.a_s
    k_gat_gather<<<nw(Nd), dim3(256), 0, stream>>>(rp, col, t1, sAs, sAd, bias, out, Nd, relu);
  };
  auto gcn = [&](const float* x, const int* rp, const int* col, const float* dis, int N,
                 int sidx, int layer, const float* b, const float* addin, float* out) {
    gemm(x, sidx, layer, t1, nullptr, N, 0);
    k_gcn_gather<<<nw(N), dim3(256), 0, stream>>>(rp, col, dis, t1, addin, b, out, N);
  };
  auto sage = [&](const float* xsrc, const float* xself, const int* rp, const int* col,
                  int Nd, int sl, int sr, int layer, const float* bl, float* out) {
    k_sage_gather<<<nw(Nd), dim3(256), 0, stream>>>(rp, col, xsrc, t1, Nd);
    gemm2(t1, sl, xself, sr, layer, out, bl, Nd, 1);
  };

  // ---------- CD + MD, both layers ----------
  gat(x_md, x_cd, rp_comp, col_comp, N_MD, N_CD, 4, 0, WLv(24, 0), 0, WLv(26, 0), acc, 0);
  gcn(x_cd, rp_cc, col_cc, dis_cc, N_CD, 6, 0, WLv(33, 0), acc, xcd1);
  gcn(x_md, rp_mm, col_mm, dis_mm, N_MD, 7, 0, WLv(35, 0), nullptr, xmd1);
  gat(xmd1, xcd1, rp_comp, col_comp, N_MD, N_CD, 4, 1, WLv(24, 1), 1, WLv(26, 1), acc, 0);
  gcn(xcd1, rp_cc, col_cc, dis_cc, N_CD, 6, 1, WLv(33, 1), acc, acc);
  do_pool(acc, 0);
  gcn(xmd1, rp_mm, col_mm, dis_mm, N_MD, 7, 1, WLv(35, 1), nullptr, acc);
  do_pool(acc, 4);

  // ---------- SEQ ----------
  sage(x_cd, x_seq, rp_seq, col_seq, N_SEQ, 0, 1, 0, WLv(17, 0), xoth);
  sage(xcd1, xoth, rp_seq, col_seq, N_SEQ, 0, 1, 1, WLv(17, 1), acc);
  do_pool(acc, 1);
  // ---------- ANNO ----------
  sage(x_cd, x_anno, rp_anno, col_anno, N_ANNO, 2, 3, 0, WLv(20, 0), xoth);
  sage(xcd1, xoth, rp_anno, col_anno, N_ANNO, 2, 3, 1, WLv(20, 1), acc);
  do_pool(acc, 2);
  // ---------- RANGE ----------
  gat(x_cd, x_range, rp_range, col_range, N_CD, N_RANGE, 5, 0, WLv(29, 0), 2, WLv(31, 0), xoth, 1);
  gat(xcd1, xoth, rp_range, col_range, N_CD, N_RANGE, 5, 1, WLv(29, 1), 3, WLv(31, 1), acc, 1);
  do_pool(acc, 3);

  k_mlp<<<dim3(GNUM), dim3(128), 0, stream>>>(
      pool, fin(36), fin(37), fin(38), fin(39), (float*)d_out);
}

// Round 13
// 1054.516 us; speedup vs baseline: 2.5921x; 1.0047x over previous
//
#include <hip/hip_runtime.h>

#define HD 128
#define GNUM 512
#define RPB 520   // per-type stride in rpb_all (>= GNUM+1)

typedef __attribute__((ext_vector_type(8))) short short8v;   // 8 bf16 = 4 VGPR
typedef __attribute__((ext_vector_type(4))) float f32x4;

// RNE split: a ~= hi + lo (both bf16), |residual| ~ 2^-17 |a|
__device__ __forceinline__ void split1(float a, short& h, short& l) {
  unsigned u = __float_as_uint(a);
  unsigned hb = (u + 0x7FFFu + ((u >> 16) & 1u)) & 0xFFFF0000u;
  h = (short)(hb >> 16);
  float rest = a - __uint_as_float(hb);
  unsigned u2 = __float_as_uint(rest);
  l = (short)((u2 + 0x7FFFu + ((u2 >> 16) & 1u)) >> 16);
}

// ============ W pre-split: fp32 [k][n] -> bf16 hi/lo TRANSPOSED [n][k] ============
struct WTab { const float* p[8]; };
__global__ __launch_bounds__(256) void k_split_w(WTab tab, short* __restrict__ whi,
                                                 short* __restrict__ wlo)
{
  int m = blockIdx.x >> 6;                       // 16 matrices, 64 blocks each
  int i = (blockIdx.x & 63) * 256 + threadIdx.x; // 0..16383
  const float* W = tab.p[m >> 1] + (m & 1) * 16384;
  int k = i >> 7, n = i & 127;
  short h, l;
  split1(W[k * 128 + n], h, l);
  whi[m * 16384 + n * 128 + k] = h;
  wlo[m * 16384 + n * 128 + k] = l;
}

// ============ MFMA GEMM: C = A1@W1 (+ A2@W2) (+bias, relu) ====================
// Optional fused row-dot: adot[r] = (A1@W1)_row[r] . avec  (avec in OUTPUT space).
#define CF_LD 132
__global__ __launch_bounds__(256) void k_gemm_mfma(
    const float* __restrict__ A1, const short* __restrict__ WH1, const short* __restrict__ WL1,
    const float* __restrict__ A2, const short* __restrict__ WH2, const short* __restrict__ WL2,
    float* __restrict__ C, const float* __restrict__ bias, int N, int relu,
    const float* __restrict__ avec, float* __restrict__ adot)
{
  __shared__ char smem[64 * 136 * 2 * 2];        // 34816 B
  short* Ah = (short*)smem;
  short* Al = Ah + 64 * 136;
  float* Cf = (float*)smem;

  const int t = threadIdx.x;
  const int row0 = blockIdx.x * 64;
  const int lane = t & 63, wid = t >> 6;
  const int g = lane >> 4, cn = lane & 15;
  const int colbase = wid * 32;

  f32x4 zero = {0.f, 0.f, 0.f, 0.f};
  f32x4 acc[4][2];
#pragma unroll
  for (int rt = 0; rt < 4; ++rt) { acc[rt][0] = zero; acc[rt][1] = zero; }

  auto stageA = [&](const float* __restrict__ A) {
    const float4* A4 = (const float4*)(A + (size_t)row0 * 128);
#pragma unroll
    for (int i = 0; i < 8; ++i) {
      int f4 = t + i * 256;
      int row = f4 >> 5, c4 = f4 & 31;
      float4 v = make_float4(0.f, 0.f, 0.f, 0.f);
      if (row0 + row < N) v = A4[f4];
      short4 h, l;
      split1(v.x, h.x, l.x); split1(v.y, h.y, l.y);
      split1(v.z, h.z, l.z); split1(v.w, h.w, l.w);
      *(short4*)(Ah + row * 136 + c4 * 4) = h;
      *(short4*)(Al + row * 136 + c4 * 4) = l;
    }
  };

  auto accum = [&](const short* __restrict__ WH, const short* __restrict__ WL) {
    short8v bhi[2][4], blo[2][4];
#pragma unroll
    for (int ct = 0; ct < 2; ++ct)
#pragma unroll
      for (int kg = 0; kg < 4; ++kg) {
        size_t o = (size_t)(colbase + ct * 16 + cn) * 128 + kg * 32 + g * 8;
        bhi[ct][kg] = *(const short8v*)(WH + o);
        blo[ct][kg] = *(const short8v*)(WL + o);
      }
#pragma unroll
    for (int kg = 0; kg < 4; ++kg) {
#pragma unroll
      for (int rt = 0; rt < 4; ++rt) {
        const int ao = (rt * 16 + cn) * 136 + kg * 32 + g * 8;
        const short8v ah = *(const short8v*)(Ah + ao);
        const short8v al = *(const short8v*)(Al + ao);
#pragma unroll
        for (int ct = 0; ct < 2; ++ct) {
          acc[rt][ct] = __builtin_amdgcn_mfma_f32_16x16x32_bf16(ah, bhi[ct][kg], acc[rt][ct], 0, 0, 0);
          acc[rt][ct] = __builtin_amdgcn_mfma_f32_16x16x32_bf16(al, bhi[ct][kg], acc[rt][ct], 0, 0, 0);
          acc[rt][ct] = __builtin_amdgcn_mfma_f32_16x16x32_bf16(ah, blo[ct][kg], acc[rt][ct], 0, 0, 0);
        }
      }
    }
  };

  stageA(A1);
  __syncthreads();
  accum(WH1, WL1);
  if (A2) {
    __syncthreads();
    stageA(A2);
    __syncthreads();
    accum(WH2, WL2);
  }
  __syncthreads();                   // Ah/Al dead past here; smem reusable

  // ---- fused row-dot (raw A@W): per-wave partial + cross-wave LDS reduce ----
  if (avec) {
    float* part = (float*)smem;      // [4 waves][64 rows]
    const float av0 = avec[colbase + cn];
    const float av1 = avec[colbase + 16 + cn];
#pragma unroll
    for (int rt = 0; rt < 4; ++rt)
#pragma unroll
      for (int r = 0; r < 4; ++r) {
        float p = fmaf(acc[rt][1][r], av1, acc[rt][0][r] * av0);
#pragma unroll
        for (int o = 1; o < 16; o <<= 1) p += __shfl_xor(p, o);
        if (cn == 0) part[wid * 64 + rt * 16 + g * 4 + r] = p;
      }
    __syncthreads();
    if (t < 64) {
      int row = row0 + t;
      if (row < N) adot[row] = part[t] + part[64 + t] + part[128 + t] + part[192 + t];
    }
    __syncthreads();
  }

  // scatter acc into LDS C-tile: C/D layout col = lane&15, row = (lane>>4)*4 + reg
#pragma unroll
  for (int rt = 0; rt < 4; ++rt)
#pragma unroll
    for (int ct = 0; ct < 2; ++ct)
#pragma unroll
      for (int r = 0; r < 4; ++r)
        Cf[(rt * 16 + g * 4 + r) * CF_LD + colbase + ct * 16 + cn] = acc[rt][ct][r];
  __syncthreads();

  float4* C4 = (float4*)(C + (size_t)row0 * 128);
#pragma unroll
  for (int i = 0; i < 8; ++i) {
    int f4 = t + i * 256;
    int row = f4 >> 5, c4 = f4 & 31;
    if (row0 + row < N) {
      float4 v = *(const float4*)(Cf + row * CF_LD + c4 * 4);
      if (bias) {
        float4 bv = *(const float4*)(bias + c4 * 4);
        v.x += bv.x; v.y += bv.y; v.z += bv.z; v.w += bv.w;
      }
      if (relu) {
        v.x = fmaxf(v.x, 0.f); v.y = fmaxf(v.y, 0.f);
        v.z = fmaxf(v.z, 0.f); v.w = fmaxf(v.w, 0.f);
      }
      C4[f4] = v;
    }
  }
}

// ======================= row dot: out[n] = x[n,:] . a  (one wave / node) ===========
__global__ void k_rowdot(const float* __restrict__ x, const float* __restrict__ a,
                         float* __restrict__ out, int N)
{
  int wid = blockIdx.x * 4 + (threadIdx.x >> 6);
  int lane = threadIdx.x & 63;
  if (wid >= N) return;
  float2 xv = ((const float2*)x)[(size_t)wid * 64 + lane];
  float2 av = ((const float2*)a)[lane];
  float v = fmaf(xv.y, av.y, xv.x * av.x);
#pragma unroll
  for (int o = 32; o > 0; o >>= 1) v += __shfl_down(v, o);
  if (lane == 0) out[wid] = v;
}

// ================= batched matvec: wv[m][i] = sum_j W_m[i,j]*a_m[j] ==============
struct MTab { const float* W[4]; const float* a[4]; };
__global__ __launch_bounds__(128) void k_matvec4(MTab tb, float* __restrict__ wv)
{
  __shared__ float as[128];
  int m = blockIdx.x, i = threadIdx.x;
  as[i] = tb.a[m][i];
  __syncthreads();
  const float* W = tb.W[m];
  float v = 0.f;
  for (int j = 0; j < 128; ++j) v = fmaf(W[i * 128 + j], as[j], v);
  wv[m * 128 + i] = v;
}

// ======================= batched CSR build =======================
// hist pass records per-edge rank (atomicAdd return, ushort) -> fill has NO atomics.
struct HTab { const int* key[6]; int* cnt[6]; unsigned short* rank[6]; int bo[7]; int n[6]; };
__global__ void k_hist_rank_all(HTab tb) {
  int bi = blockIdx.x, ty = 0;
  while (ty < 5 && bi >= tb.bo[ty + 1]) ++ty;
  int i = (bi - tb.bo[ty]) * 256 + threadIdx.x;
  if (i < tb.n[ty])
    tb.rank[ty][i] = (unsigned short)atomicAdd(&tb.cnt[ty][tb.key[ty][i]], 1);
}

struct FTab { const int* es[6]; const int* ed[6]; const int* rp[6];
              const unsigned short* rank[6]; int* col[6]; int bo[7]; int n[6]; };
__global__ void k_fill_all(FTab tb) {
  int bi = blockIdx.x, ty = 0;
  while (ty < 5 && bi >= tb.bo[ty + 1]) ++ty;
  int e = (bi - tb.bo[ty]) * 256 + threadIdx.x;
  if (e >= tb.n[ty]) return;
  int p = tb.rp[ty][tb.ed[ty][e]] + (int)tb.rank[ty][e];
  tb.col[ty][p] = tb.es[ty][e];
}

// ---- batched 3-phase exclusive scan over 6 arrays (tile = 4096) ----
struct STab { int* rp[6]; int* bs[6]; int n[6]; int bo[7]; };

__global__ __launch_bounds__(256) void k_scan_partial_all(STab tb) {
  __shared__ int red[256];
  int bi = blockIdx.x, ty = 0;
  while (ty < 5 && bi >= tb.bo[ty + 1]) ++ty;
  int lb = bi - tb.bo[ty];
  const int* rp = tb.rp[ty];
  const int N = tb.n[ty];
  const int t = threadIdx.x, base = lb * 4096;
  int s = 0;
  for (int i = t; i < 4096; i += 256) {
    int idx = base + i;
    if (idx < N) s += rp[idx];
  }
  red[t] = s;
  __syncthreads();
  for (int ofs = 128; ofs > 0; ofs >>= 1) {
    if (t < ofs) red[t] += red[t + ofs];
    __syncthreads();
  }
  if (t == 0) tb.bs[ty][lb] = red[0];
}

__global__ __launch_bounds__(256) void k_scan_bsums_all(STab tb) {
  __shared__ int sh[256];
  const int ty = blockIdx.x;
  const int nb = (tb.n[ty] + 4095) / 4096;   // <= 25
  const int t = threadIdx.x;
  int v = (t < nb) ? tb.bs[ty][t] : 0;
  sh[t] = v;
  __syncthreads();
  for (int ofs = 1; ofs < 256; ofs <<= 1) {
    int u = (t >= ofs) ? sh[t - ofs] : 0;
    __syncthreads();
    sh[t] += u;
    __syncthreads();
  }
  if (t < nb) tb.bs[ty][t] = sh[t] - v;      // exclusive
  if (t == 255) tb.rp[ty][tb.n[ty]] = sh[255];  // total
}

__global__ __launch_bounds__(256) void k_scan_final_all(STab tb) {
  __shared__ int sh[4096 + 256];             // padded: i -> i + (i>>4)
  __shared__ int tsum[256];
  int bi = blockIdx.x, ty = 0;
  while (ty < 5 && bi >= tb.bo[ty + 1]) ++ty;
  int lb = bi - tb.bo[ty];
  int* rp = tb.rp[ty];
  const int N = tb.n[ty];
  const int t = threadIdx.x, base = lb * 4096;
  auto mp = [](int i) { return i + (i >> 4); };
#pragma unroll
  for (int i = 0; i < 16; ++i) {
    int idx = base + i * 256 + t;
    sh[mp(i * 256 + t)] = (idx < N) ? rp[idx] : 0;
  }
  __syncthreads();
  int s = 0;
#pragma unroll
  for (int j = 0; j < 16; ++j) s += sh[mp(t * 16 + j)];
  tsum[t] = s;
  __syncthreads();
  for (int ofs = 1; ofs < 256; ofs <<= 1) {
    int u = (t >= ofs) ? tsum[t - ofs] : 0;
    __syncthreads();
    tsum[t] += u;
    __syncthreads();
  }
  int pre = tsum[t] - s + tb.bs[ty][lb];
#pragma unroll
  for (int j = 0; j < 16; ++j) {
    int v = sh[mp(t * 16 + j)];
    sh[mp(t * 16 + j)] = pre;
    pre += v;
  }
  __syncthreads();
#pragma unroll
  for (int i = 0; i < 16; ++i) {
    int idx = base + i * 256 + t;
    if (idx < N) rp[idx] = sh[mp(i * 256 + t)];
  }
}

// ---- run-pointers for SORTED batch vectors via binary search (no atomics) ----
struct BTab { const int* b[5]; int n[5]; };
__global__ __launch_bounds__(512) void k_runptr(BTab tb, int* __restrict__ rpb_all) {
  const int ty = blockIdx.x;
  const int* b = tb.b[ty];
  const int N = tb.n[ty];
  const int t = threadIdx.x;                 // 0..511 = graph id
  int lo = 0, hi = N;
  while (lo < hi) {                          // lower_bound(b, t)
    int mid = (lo + hi) >> 1;
    if (b[mid] < t) lo = mid + 1; else hi = mid;
  }
  rpb_all[ty * RPB + t] = lo;
  if (t == 0) rpb_all[ty * RPB + GNUM] = N;
}

// dis for both GCN types in one launch
struct DTab { const int* rp[2]; float* dis[2]; int n[2]; int bo[3]; };
__global__ void k_dis2(DTab tb) {
  int bi = blockIdx.x, ty = (bi >= tb.bo[1]) ? 1 : 0;
  int n = (bi - tb.bo[ty]) * 256 + threadIdx.x;
  if (n < tb.n[ty]) tb.dis[ty][n] = rsqrtf((float)(tb.rp[ty][n + 1] - tb.rp[ty][n]) + 1.f);
}

// ======================= gather kernels =======================
// One wave per dst node; coalesced col[] prefetch + shfl broadcast; 4-way
// unrolled independent row fetches (4 chains in flight per wave).

__global__ void k_sage_gather(const int* __restrict__ rp, const int* __restrict__ col,
                              const float* __restrict__ x, float* __restrict__ out, int N)
{
  int node = blockIdx.x * 4 + (threadIdx.x >> 6);
  if (node >= N) return;
  int lane = threadIdx.x & 63;
  int s0 = rp[node], deg = rp[node + 1] - s0;
  const float2* x2 = (const float2*)x;
  float a0 = 0.f, a1 = 0.f, b0 = 0.f, b1 = 0.f;
  float c0 = 0.f, c1 = 0.f, d0 = 0.f, d1 = 0.f;
  for (int base = 0; base < deg; base += 64) {
    int m = min(64, deg - base);
    int c = (lane < m) ? col[s0 + base + lane] : 0;
    int j = 0;
    for (; j + 3 < m; j += 4) {
      int sA = __shfl(c, j), sB = __shfl(c, j + 1);
      int sC = __shfl(c, j + 2), sD = __shfl(c, j + 3);
      float2 vA = x2[(size_t)sA * 64 + lane];
      float2 vB = x2[(size_t)sB * 64 + lane];
      float2 vC = x2[(size_t)sC * 64 + lane];
      float2 vD = x2[(size_t)sD * 64 + lane];
      a0 += vA.x; a1 += vA.y; b0 += vB.x; b1 += vB.y;
      c0 += vC.x; c1 += vC.y; d0 += vD.x; d1 += vD.y;
    }
    for (; j < m; ++j) {
      int sA = __shfl(c, j);
      float2 vA = x2[(size_t)sA * 64 + lane];
      a0 += vA.x; a1 += vA.y;
    }
  }
  float inv = 1.f / fmaxf((float)deg, 1.f);
  ((float2*)out)[(size_t)node * 64 + lane] =
      make_float2((a0 + b0 + c0 + d0) * inv, (a1 + b1 + c1 + d1) * inv);
}

__global__ void k_gcn_gather(const int* __restrict__ rp, const int* __restrict__ col,
                             const float* __restrict__ dis, const float* __restrict__ h,
                             const float* addin, const float* __restrict__ b,
                             float* out, int N)
{
  int node = blockIdx.x * 4 + (threadIdx.x >> 6);
  if (node >= N) return;
  int lane = threadIdx.x & 63;
  int s0 = rp[node], deg = rp[node + 1] - s0;
  float rd = dis[node];
  const float2* h2 = (const float2*)h;
  // hoist independent tail loads: overlap with edge loop
  float2 hself = h2[(size_t)node * 64 + lane];
  float2 bv = ((const float2*)b)[lane];
  float ad0 = 0.f, ad1 = 0.f;
  if (addin) {
    float2 a2 = ((const float2*)addin)[(size_t)node * 64 + lane];
    ad0 = a2.x; ad1 = a2.y;
  }
  float a0 = 0.f, a1 = 0.f, b0 = 0.f, b1 = 0.f;
  float c0 = 0.f, c1 = 0.f, d0 = 0.f, d1 = 0.f;
  for (int base = 0; base < deg; base += 64) {
    int m = min(64, deg - base);
    int c = 0; float dv = 0.f;
    if (lane < m) { c = col[s0 + base + lane]; dv = dis[c]; }
    int j = 0;
    for (; j + 3 < m; j += 4) {
      int sA = __shfl(c, j), sB = __shfl(c, j + 1);
      int sC = __shfl(c, j + 2), sD = __shfl(c, j + 3);
      float nA = __shfl(dv, j) * rd, nB = __shfl(dv, j + 1) * rd;
      float nC = __shfl(dv, j + 2) * rd, nD = __shfl(dv, j + 3) * rd;
      float2 vA = h2[(size_t)sA * 64 + lane];
      float2 vB = h2[(size_t)sB * 64 + lane];
      float2 vC = h2[(size_t)sC * 64 + lane];
      float2 vD = h2[(size_t)sD * 64 + lane];
      a0 = fmaf(nA, vA.x, a0); a1 = fmaf(nA, vA.y, a1);
      b0 = fmaf(nB, vB.x, b0); b1 = fmaf(nB, vB.y, b1);
      c0 = fmaf(nC, vC.x, c0); c1 = fmaf(nC, vC.y, c1);
      d0 = fmaf(nD, vD.x, d0); d1 = fmaf(nD, vD.y, d1);
    }
    for (; j < m; ++j) {
      int sA = __shfl(c, j);
      float nA = __shfl(dv, j) * rd;
      float2 vA = h2[(size_t)sA * 64 + lane];
      a0 = fmaf(nA, vA.x, a0); a1 = fmaf(nA, vA.y, a1);
    }
  }
  float rr = rd * rd;
  float v0 = fmaf(rr, hself.x, a0 + b0 + c0 + d0) + bv.x + ad0;
  float v1 = fmaf(rr, hself.y, a1 + b1 + c1 + d1) + bv.y + ad1;
  ((float2*)out)[(size_t)node * 64 + lane] = make_float2(fmaxf(v0, 0.f), fmaxf(v1, 0.f));
}

__global__ void k_gat_gather(const int* __restrict__ rp, const int* __restrict__ col,
                             const float* __restrict__ hs, const float* __restrict__ as_,
                             const float* __restrict__ ad_, const float* __restrict__ b,
                             float* __restrict__ out, int N, int relu)
{
  int node = blockIdx.x * 4 + (threadIdx.x >> 6);
  if (node >= N) return;
  int lane = threadIdx.x & 63;
  int s0 = rp[node], deg = rp[node + 1] - s0;
  float adn = ad_[node];
  float2 bv = ((const float2*)b)[lane];        // hoisted
  const float2* hs2 = (const float2*)hs;
  float z = 0.f;
  float a0 = 0.f, a1 = 0.f, b0 = 0.f, b1 = 0.f;
  float c0 = 0.f, c1 = 0.f, d0 = 0.f, d1 = 0.f;
  for (int base = 0; base < deg; base += 64) {
    int m = min(64, deg - base);
    int c = 0; float av = 0.f;
    if (lane < m) { c = col[s0 + base + lane]; av = as_[c]; }
    int j = 0;
    for (; j + 3 < m; j += 4) {
      int sA = __shfl(c, j), sB = __shfl(c, j + 1);
      int sC = __shfl(c, j + 2), sD = __shfl(c, j + 3);
      float vA = __shfl(av, j) + adn, vB = __shfl(av, j + 1) + adn;
      float vC = __shfl(av, j + 2) + adn, vD = __shfl(av, j + 3) + adn;
      vA = vA > 0.f ? vA : 0.2f * vA;  vB = vB > 0.f ? vB : 0.2f * vB;
      vC = vC > 0.f ? vC : 0.2f * vC;  vD = vD > 0.f ? vD : 0.2f * vD;
      float pA = __expf(vA), pB = __expf(vB), pC = __expf(vC), pD = __expf(vD);
      z += (pA + pB) + (pC + pD);
      float2 hA = hs2[(size_t)sA * 64 + lane];
      float2 hB = hs2[(size_t)sB * 64 + lane];
      float2 hC = hs2[(size_t)sC * 64 + lane];
      float2 hD = hs2[(size_t)sD * 64 + lane];
      a0 = fmaf(pA, hA.x, a0); a1 = fmaf(pA, hA.y, a1);
      b0 = fmaf(pB, hB.x, b0); b1 = fmaf(pB, hB.y, b1);
      c0 = fmaf(pC, hC.x, c0); c1 = fmaf(pC, hC.y, c1);
      d0 = fmaf(pD, hD.x, d0); d1 = fmaf(pD, hD.y, d1);
    }
    for (; j < m; ++j) {
      int sA = __shfl(c, j);
      float vA = __shfl(av, j) + adn;
      vA = vA > 0.f ? vA : 0.2f * vA;
      float pA = __expf(vA);
      z += pA;
      float2 hA = hs2[(size_t)sA * 64 + lane];
      a0 = fmaf(pA, hA.x, a0); a1 = fmaf(pA, hA.y, a1);
    }
  }
  float inv = (deg > 0) ? 1.f / z : 0.f;
  float v0 = fmaf((a0 + b0) + (c0 + d0), inv, bv.x);
  float v1 = fmaf((a1 + b1) + (c1 + d1), inv, bv.y);
  if (relu) { v0 = fmaxf(v0, 0.f); v1 = fmaxf(v1, 0.f); }
  ((float2*)out)[(size_t)node * 64 + lane] = make_float2(v0, v1);
}

// ============ segment pooling: one block per graph, contiguous rows ============
__global__ __launch_bounds__(256) void k_pool_seg(
    const float* __restrict__ x, const int* __restrict__ rpb,
    float* __restrict__ pool, int col_off)
{
  __shared__ float2 red2[4][64];
  const int g = blockIdx.x;
  const int t = threadIdx.x, w = t >> 6, lane = t & 63;
  const int n0 = rpb[g], n1 = rpb[g + 1];
  const float2* x2 = (const float2*)x;
  float a0 = 0.f, a1 = 0.f, b0 = 0.f, b1 = 0.f;
  int n = n0 + w;
  for (; n + 4 < n1; n += 8) {
    float2 vA = x2[(size_t)n * 64 + lane];
    float2 vB = x2[(size_t)(n + 4) * 64 + lane];
    a0 += vA.x; a1 += vA.y; b0 += vB.x; b1 += vB.y;
  }
  if (n < n1) { float2 vA = x2[(size_t)n * 64 + lane]; a0 += vA.x; a1 += vA.y; }
  red2[w][lane] = make_float2(a0 + b0, a1 + b1);
  __syncthreads();
  if (t < 64) {
    float2 r0 = red2[0][t], r1 = red2[1][t], r2 = red2[2][t], r3 = red2[3][t];
    float inv = 1.f / fmaxf((float)(n1 - n0), 1.f);
    ((float2*)(pool + (size_t)g * 640 + col_off))[t] =
        make_float2((r0.x + r1.x + r2.x + r3.x) * inv,
                    (r0.y + r1.y + r2.y + r3.y) * inv);
  }
}

// ======================= final MLP (one block per graph) =======================
__global__ void k_mlp(const float* __restrict__ pool,
                      const float* __restrict__ W1, const float* __restrict__ b1,
                      const float* __restrict__ W2, const float* __restrict__ b2,
                      float* __restrict__ out)
{
  __shared__ float emb[640];
  __shared__ float red[128];
  const int g = blockIdx.x, t = threadIdx.x;
  for (int i = t; i < 640; i += 128) emb[i] = pool[(size_t)g * 640 + i];
  __syncthreads();
  float acc = b1[t];
  for (int i = 0; i < 640; ++i) acc = fmaf(emb[i], W1[i * 128 + t], acc);
  float h = fmaxf(acc, 0.f);
  red[t] = h * W2[t];
  __syncthreads();
  for (int s = 64; s > 0; s >>= 1) {
    if (t < s) red[t] += red[t + s];
    __syncthreads();
  }
  if (t == 0) out[g] = red[0] + b2[0];
}

// ======================= host =======================
extern "C" void kernel_launch(void* const* d_in, const int* in_sizes, int n_in,
                              void* d_out, int out_size, void* d_ws, size_t ws_size,
                              hipStream_t stream)
{
  auto fin = [&](int i) { return (const float*)d_in[i]; };
  auto iin = [&](int i) { return (const int*)d_in[i]; };

  const float *x_cd = fin(0), *x_seq = fin(1), *x_anno = fin(2), *x_range = fin(3), *x_md = fin(4);
  const int *ei_seq = iin(5), *ei_anno = iin(6), *ei_range = iin(7),
            *ei_comp = iin(8), *ei_cc = iin(9), *ei_mm = iin(10);
  const int *b_cd = iin(11), *b_seq = iin(12), *b_anno = iin(13), *b_range = iin(14), *b_md = iin(15);

  const int N_CD = in_sizes[0] / HD, N_SEQ = in_sizes[1] / HD, N_ANNO = in_sizes[2] / HD,
            N_RANGE = in_sizes[3] / HD, N_MD = in_sizes[4] / HD;
  const int E_seq = in_sizes[5] / 2, E_anno = in_sizes[6] / 2, E_range = in_sizes[7] / 2,
            E_comp = in_sizes[8] / 2, E_cc = in_sizes[9] / 2, E_mm = in_sizes[10] / 2;
  const int N_OTH = max(max(N_SEQ, N_ANNO), N_RANGE);

  auto WLm = [&](int i, int l) { return fin(i) + (size_t)l * HD * HD; };
  auto WLv = [&](int i, int l) { return fin(i) + (size_t)l * HD; };

  // ---- workspace layout ----
  float* ws = (float*)d_ws;
  size_t off = 0;
  auto alloc = [&](size_t n) { float* p = ws + off; off += (n + 3) & ~(size_t)3; return p; };
  float* xcd1 = alloc((size_t)N_CD * HD);
  float* xmd1 = alloc((size_t)N_MD * HD);
  float* xoth = alloc((size_t)N_OTH * HD);
  float* acc  = alloc((size_t)N_CD * HD);
  float* t1   = alloc((size_t)N_CD * HD);
  float* sAs  = alloc((size_t)N_CD);
  float* sAd  = alloc((size_t)N_CD);
  float* dis_cc = alloc((size_t)N_CD);
  float* dis_mm = alloc((size_t)N_MD);
  float* wvall = alloc(4 * HD);
  float* pool = alloc((size_t)GNUM * 5 * HD);
  short* whi = (short*)(ws + off); off += (size_t)16 * 16384 / 2;
  short* wlo = (short*)(ws + off); off += (size_t)16 * 16384 / 2;
  auto alloci = [&](size_t n) { int* p = (int*)(ws + off); off += (n + 3) & ~(size_t)3; return p; };
  int* bsall = alloci(6 * 256);          // batched scan partials
  int* rpb_all = alloci(5 * RPB);
  int Nds[6] = {N_SEQ, N_ANNO, N_RANGE, N_CD, N_CD, N_MD};
  int Es[6]  = {E_seq, E_anno, E_range, E_comp, E_cc, E_mm};
  int* rps[6];
  int* rp0 = alloci(0);
  { size_t tot = 0; for (int i = 0; i < 6; ++i) tot += (size_t)Nds[i] + 1;
    int* p = alloci(tot); rp0 = p;
    for (int i = 0; i < 6; ++i) { rps[i] = p; p += Nds[i] + 1; } }
  size_t rp_tot_bytes = 0; for (int i = 0; i < 6; ++i) rp_tot_bytes += ((size_t)Nds[i] + 1) * 4;
  unsigned short* ranks[6];
  for (int i = 0; i < 6; ++i) ranks[i] = (unsigned short*)alloci(((size_t)Es[i] + 1) / 2);
  int* cols[6];  for (int i = 0; i < 6; ++i) cols[i] = alloci((size_t)Es[i]);
  (void)n_in;

  if (off * sizeof(float) > ws_size) {
    hipMemsetAsync(d_out, 0, (size_t)out_size * sizeof(float), stream);
    return;
  }

  auto ew = [&](size_t elems) { return dim3((unsigned)((elems + 255) / 256)); };
  auto nw = [&](int N) { return dim3((unsigned)((N + 3) / 4)); };

  // ---- pre-split all GEMM weights (slots: 0:16 1:18 2:19 3:21 4:22 5:27 6:32 7:34)
  WTab tab;
  tab.p[0] = fin(16); tab.p[1] = fin(18); tab.p[2] = fin(19); tab.p[3] = fin(21);
  tab.p[4] = fin(22); tab.p[5] = fin(27); tab.p[6] = fin(32); tab.p[7] = fin(34);
  k_split_w<<<dim3(1024), dim3(256), 0, stream>>>(tab, whi, wlo);

  // ---- 4 DST-side GAT matvecs (Wd@a_d): comp L0/L1, range L0/L1 ----
  MTab mt;
  mt.W[0] = WLm(23, 0); mt.a[0] = WLv(25, 0);
  mt.W[1] = WLm(23, 1); mt.a[1] = WLv(25, 1);
  mt.W[2] = WLm(28, 0); mt.a[2] = WLv(30, 0);
  mt.W[3] = WLm(28, 1); mt.a[3] = WLv(30, 1);
  k_matvec4<<<dim3(4), dim3(128), 0, stream>>>(mt, wvall);

  // ---- run-pointers for sorted batch vectors (binary search, no atomics) ----
  {
    BTab bt;
    bt.b[0] = b_cd; bt.n[0] = N_CD;  bt.b[1] = b_seq; bt.n[1] = N_SEQ;
    bt.b[2] = b_anno; bt.n[2] = N_ANNO;  bt.b[3] = b_range; bt.n[3] = N_RANGE;
    bt.b[4] = b_md; bt.n[4] = N_MD;
    k_runptr<<<dim3(5), dim3(512), 0, stream>>>(bt, rpb_all);
  }

  // ---- batched CSR build (rank-recording: fill has no atomics) ----
  const int* ess[6] = {ei_seq, ei_anno, ei_range, ei_comp, ei_cc, ei_mm};
  const int* eds[6] = {ei_seq + E_seq, ei_anno + E_anno, ei_range + E_range,
                       ei_comp + E_comp, ei_cc + E_cc, ei_mm + E_mm};
  hipMemsetAsync(rp0, 0, rp_tot_bytes, stream);
  {
    HTab ht; int b = 0;
    for (int i = 0; i < 6; ++i) {
      ht.key[i] = eds[i]; ht.cnt[i] = rps[i]; ht.rank[i] = ranks[i];
      ht.bo[i] = b; b += (Es[i] + 255) / 256; ht.n[i] = Es[i];
    }
    ht.bo[6] = b;
    k_hist_rank_all<<<dim3(b), dim3(256), 0, stream>>>(ht);
  }
  {
    STab st; int b = 0;
    for (int i = 0; i < 6; ++i) {
      st.rp[i] = rps[i]; st.bs[i] = bsall + i * 256;
      st.n[i] = Nds[i]; st.bo[i] = b; b += (Nds[i] + 4095) / 4096;
    }
    st.bo[6] = b;
    k_scan_partial_all<<<dim3(b), dim3(256), 0, stream>>>(st);
    k_scan_bsums_all<<<dim3(6), dim3(256), 0, stream>>>(st);
    k_scan_final_all<<<dim3(b), dim3(256), 0, stream>>>(st);
  }
  {
    FTab ft; int b = 0;
    for (int i = 0; i < 6; ++i) {
      ft.es[i] = ess[i]; ft.ed[i] = eds[i]; ft.rp[i] = rps[i]; ft.rank[i] = ranks[i];
      ft.col[i] = cols[i]; ft.bo[i] = b; b += (Es[i] + 255) / 256; ft.n[i] = Es[i];
    }
    ft.bo[6] = b;
    k_fill_all<<<dim3(b), dim3(256), 0, stream>>>(ft);
  }
  int *rp_seq = rps[0], *rp_anno = rps[1], *rp_range = rps[2],
      *rp_comp = rps[3], *rp_cc = rps[4], *rp_mm = rps[5];
  int *col_seq = cols[0], *col_anno = cols[1], *col_range = cols[2],
      *col_comp = cols[3], *col_cc = cols[4], *col_mm = cols[5];
  {
    DTab dt;
    dt.rp[0] = rp_cc; dt.dis[0] = dis_cc; dt.n[0] = N_CD;
    dt.rp[1] = rp_mm; dt.dis[1] = dis_mm; dt.n[1] = N_MD;
    dt.bo[0] = 0; dt.bo[1] = (N_CD + 255) / 256;
    dt.bo[2] = dt.bo[1] + (N_MD + 255) / 256;
    k_dis2<<<dim3(dt.bo[2]), dim3(256), 0, stream>>>(dt);
  }

  auto WHp = [&](int sidx, int layer) { return whi + (size_t)(sidx * 2 + layer) * 16384; };
  auto WLp = [&](int sidx, int layer) { return wlo + (size_t)(sidx * 2 + layer) * 16384; };
  auto gemm = [&](const float* A, int sidx, int layer, float* C, const float* b,
                  int N, int relu, const float* avec = nullptr, float* adot = nullptr) {
    k_gemm_mfma<<<dim3((N + 63) / 64), dim3(256), 0, stream>>>(
        A, WHp(sidx, layer), WLp(sidx, layer), nullptr, nullptr, nullptr, C, b, N, relu,
        avec, adot);
  };
  auto gemm2 = [&](const float* A1, int s1, const float* A2, int s2, int layer,
                   float* C, const float* b, int N, int relu) {
    k_gemm_mfma<<<dim3((N + 63) / 64), dim3(256), 0, stream>>>(
        A1, WHp(s1, layer), WLp(s1, layer), A2, WHp(s2, layer), WLp(s2, layer), C, b, N, relu,
        nullptr, nullptr);
  };
  auto do_pool = [&](const float* x, int type) {
    k_pool_seg<<<dim3(GNUM), dim3(256), 0, stream>>>(x, rpb_all + type * RPB, pool, type * HD);
  };

  // GAT: hs = xs@Ws with FUSED sAs = hs.a_s (avec = RAW a_s, output space);
  // sAd = xd.(Wd@a_d) via precomputed matvec (hd never materialized).
  auto gat = [&](const float* xs, const float* xd, const int* rp, const int* col,
                 int Ns, int Nd, int sidx, int layer, const float* avs_raw, int wvD,
                 const float* bias, float* out, int relu) {
    k_rowdot<<<nw(Nd), dim3(256), 0, stream>>>(xd, wvall + wvD * 128, sAd, Nd);
    gemm(xs, sidx, layer, t1, nullptr, Ns, 0, avs_raw, sAs);   // hs + fused hs.a_s
    k_gat_gather<<<nw(Nd), dim3(256), 0, stream>>>(rp, col, t1, sAs, sAd, bias, out, Nd, relu);
  };
  auto gcn = [&](const float* x, const int* rp, const int* col, const float* dis, int N,
                 int sidx, int layer, const float* b, const float* addin, float* out) {
    gemm(x, sidx, layer, t1, nullptr, N, 0);
    k_gcn_gather<<<nw(N), dim3(256), 0, stream>>>(rp, col, dis, t1, addin, b, out, N);
  };
  auto sage = [&](const float* xsrc, const float* xself, const int* rp, const int* col,
                  int Nd, int sl, int sr, int layer, const float* bl, float* out) {
    k_sage_gather<<<nw(Nd), dim3(256), 0, stream>>>(rp, col, xsrc, t1, Nd);
    gemm2(t1, sl, xself, sr, layer, out, bl, Nd, 1);
  };

  // ---------- CD + MD, both layers ----------
  gat(x_md, x_cd, rp_comp, col_comp, N_MD, N_CD, 4, 0, WLv(24, 0), 0, WLv(26, 0), acc, 0);
  gcn(x_cd, rp_cc, col_cc, dis_cc, N_CD, 6, 0, WLv(33, 0), acc, xcd1);
  gcn(x_md, rp_mm, col_mm, dis_mm, N_MD, 7, 0, WLv(35, 0), nullptr, xmd1);
  gat(xmd1, xcd1, rp_comp, col_comp, N_MD, N_CD, 4, 1, WLv(24, 1), 1, WLv(26, 1), acc, 0);
  gcn(xcd1, rp_cc, col_cc, dis_cc, N_CD, 6, 1, WLv(33, 1), acc, acc);
  do_pool(acc, 0);
  gcn(xmd1, rp_mm, col_mm, dis_mm, N_MD, 7, 1, WLv(35, 1), nullptr, acc);
  do_pool(acc, 4);

  // ---------- SEQ ----------
  sage(x_cd, x_seq, rp_seq, col_seq, N_SEQ, 0, 1, 0, WLv(17, 0), xoth);
  sage(xcd1, xoth, rp_seq, col_seq, N_SEQ, 0, 1, 1, WLv(17, 1), acc);
  do_pool(acc, 1);
  // ---------- ANNO ----------
  sage(x_cd, x_anno, rp_anno, col_anno, N_ANNO, 2, 3, 0, WLv(20, 0), xoth);
  sage(xcd1, xoth, rp_anno, col_anno, N_ANNO, 2, 3, 1, WLv(20, 1), acc);
  do_pool(acc, 2);
  // ---------- RANGE ----------
  gat(x_cd, x_range, rp_range, col_range, N_CD, N_RANGE, 5, 0, WLv(29, 0), 2, WLv(31, 0), xoth, 1);
  gat(xcd1, xoth, rp_range, col_range, N_CD, N_RANGE, 5, 1, WLv(29, 1), 3, WLv(31, 1), acc, 1);
  do_pool(acc, 3);

  k_mlp<<<dim3(GNUM), dim3(128), 0, stream>>>(
      pool, fin(36), fin(37), fin(38), fin(39), (float*)d_out);
}

// Round 14
// 1053.153 us; speedup vs baseline: 2.5955x; 1.0013x over previous
//
#include <hip/hip_runtime.h>

#define HD 128
#define GNUM 512
#define RPB 520   // per-type stride in rpb_all (>= GNUM+1)

typedef __attribute__((ext_vector_type(8))) short short8v;   // 8 bf16 = 4 VGPR
typedef __attribute__((ext_vector_type(4))) float f32x4;

// RNE split: a ~= hi + lo (both bf16), |residual| ~ 2^-17 |a|
__device__ __forceinline__ void split1(float a, short& h, short& l) {
  unsigned u = __float_as_uint(a);
  unsigned hb = (u + 0x7FFFu + ((u >> 16) & 1u)) & 0xFFFF0000u;
  h = (short)(hb >> 16);
  float rest = a - __uint_as_float(hb);
  unsigned u2 = __float_as_uint(rest);
  l = (short)((u2 + 0x7FFFu + ((u2 >> 16) & 1u)) >> 16);
}

// ============ W pre-split: fp32 [k][n] -> bf16 hi/lo TRANSPOSED [n][k] ============
struct WTab { const float* p[8]; };
__global__ __launch_bounds__(256) void k_split_w(WTab tab, short* __restrict__ whi,
                                                 short* __restrict__ wlo)
{
  int m = blockIdx.x >> 6;                       // 16 matrices, 64 blocks each
  int i = (blockIdx.x & 63) * 256 + threadIdx.x; // 0..16383
  const float* W = tab.p[m >> 1] + (m & 1) * 16384;
  int k = i >> 7, n = i & 127;
  short h, l;
  split1(W[k * 128 + n], h, l);
  whi[m * 16384 + n * 128 + k] = h;
  wlo[m * 16384 + n * 128 + k] = l;
}

// ============ MFMA GEMM: C = A1@W1 (+ A2@W2) (+bias, relu) ====================
// If grp/gcol given: A1 rows are the CSR-MEAN over gcol of source matrix A1
// (SAGE fusion — the gather happens inside staging, no t1 round-trip).
// Optional fused row-dot: adot[r] = (A1@W1)_row[r] . avec  (avec in OUTPUT space).
#define CF_LD 132
__global__ __launch_bounds__(256) void k_gemm_mfma(
    const float* __restrict__ A1, const short* __restrict__ WH1, const short* __restrict__ WL1,
    const int* __restrict__ grp, const int* __restrict__ gcol,
    const float* __restrict__ A2, const short* __restrict__ WH2, const short* __restrict__ WL2,
    float* __restrict__ C, const float* __restrict__ bias, int N, int relu,
    const float* __restrict__ avec, float* __restrict__ adot)
{
  __shared__ char smem[64 * 136 * 2 * 2];        // 34816 B
  short* Ah = (short*)smem;
  short* Al = Ah + 64 * 136;
  float* Cf = (float*)smem;

  const int t = threadIdx.x;
  const int row0 = blockIdx.x * 64;
  const int lane = t & 63, wid = t >> 6;
  const int g = lane >> 4, cn = lane & 15;
  const int colbase = wid * 32;

  f32x4 zero = {0.f, 0.f, 0.f, 0.f};
  f32x4 acc[4][2];
#pragma unroll
  for (int rt = 0; rt < 4; ++rt) { acc[rt][0] = zero; acc[rt][1] = zero; }

  auto stageA = [&](const float* __restrict__ A) {
    const float4* A4 = (const float4*)(A + (size_t)row0 * 128);
#pragma unroll
    for (int i = 0; i < 8; ++i) {
      int f4 = t + i * 256;
      int row = f4 >> 5, c4 = f4 & 31;
      float4 v = make_float4(0.f, 0.f, 0.f, 0.f);
      if (row0 + row < N) v = A4[f4];
      short4 h, l;
      split1(v.x, h.x, l.x); split1(v.y, h.y, l.y);
      split1(v.z, h.z, l.z); split1(v.w, h.w, l.w);
      *(short4*)(Ah + row * 136 + c4 * 4) = h;
      *(short4*)(Al + row * 136 + c4 * 4) = l;
    }
  };

  // CSR-mean gather staging: 32-thread group per row, loop over its edges.
  auto stageA_gather = [&](const float* __restrict__ X) {
#pragma unroll
    for (int i = 0; i < 8; ++i) {
      int f4 = t + i * 256;
      int row = f4 >> 5, ln = f4 & 31;
      int r = row0 + row;
      float4 s = make_float4(0.f, 0.f, 0.f, 0.f);
      int e0 = 0, e1 = 0;
      if (r < N) { e0 = grp[r]; e1 = grp[r + 1]; }
      for (int e = e0; e < e1; ++e) {
        int c = gcol[e];                         // uniform in the 32-thread group
        float4 v = *(const float4*)(X + (size_t)c * 128 + ln * 4);
        s.x += v.x; s.y += v.y; s.z += v.z; s.w += v.w;
      }
      float inv = 1.f / fmaxf((float)(e1 - e0), 1.f);
      short4 h, l;
      split1(s.x * inv, h.x, l.x); split1(s.y * inv, h.y, l.y);
      split1(s.z * inv, h.z, l.z); split1(s.w * inv, h.w, l.w);
      *(short4*)(Ah + row * 136 + ln * 4) = h;
      *(short4*)(Al + row * 136 + ln * 4) = l;
    }
  };

  auto accum = [&](const short* __restrict__ WH, const short* __restrict__ WL) {
    short8v bhi[2][4], blo[2][4];
#pragma unroll
    for (int ct = 0; ct < 2; ++ct)
#pragma unroll
      for (int kg = 0; kg < 4; ++kg) {
        size_t o = (size_t)(colbase + ct * 16 + cn) * 128 + kg * 32 + g * 8;
        bhi[ct][kg] = *(const short8v*)(WH + o);
        blo[ct][kg] = *(const short8v*)(WL + o);
      }
#pragma unroll
    for (int kg = 0; kg < 4; ++kg) {
#pragma unroll
      for (int rt = 0; rt < 4; ++rt) {
        const int ao = (rt * 16 + cn) * 136 + kg * 32 + g * 8;
        const short8v ah = *(const short8v*)(Ah + ao);
        const short8v al = *(const short8v*)(Al + ao);
#pragma unroll
        for (int ct = 0; ct < 2; ++ct) {
          acc[rt][ct] = __builtin_amdgcn_mfma_f32_16x16x32_bf16(ah, bhi[ct][kg], acc[rt][ct], 0, 0, 0);
          acc[rt][ct] = __builtin_amdgcn_mfma_f32_16x16x32_bf16(al, bhi[ct][kg], acc[rt][ct], 0, 0, 0);
          acc[rt][ct] = __builtin_amdgcn_mfma_f32_16x16x32_bf16(ah, blo[ct][kg], acc[rt][ct], 0, 0, 0);
        }
      }
    }
  };

  if (grp) stageA_gather(A1); else stageA(A1);
  __syncthreads();
  accum(WH1, WL1);
  if (A2) {
    __syncthreads();
    stageA(A2);
    __syncthreads();
    accum(WH2, WL2);
  }
  __syncthreads();                   // Ah/Al dead past here; smem reusable

  // ---- fused row-dot (raw A@W): per-wave partial + cross-wave LDS reduce ----
  if (avec) {
    float* part = (float*)smem;      // [4 waves][64 rows]
    const float av0 = avec[colbase + cn];
    const float av1 = avec[colbase + 16 + cn];
#pragma unroll
    for (int rt = 0; rt < 4; ++rt)
#pragma unroll
      for (int r = 0; r < 4; ++r) {
        float p = fmaf(acc[rt][1][r], av1, acc[rt][0][r] * av0);
#pragma unroll
        for (int o = 1; o < 16; o <<= 1) p += __shfl_xor(p, o);
        if (cn == 0) part[wid * 64 + rt * 16 + g * 4 + r] = p;
      }
    __syncthreads();
    if (t < 64) {
      int row = row0 + t;
      if (row < N) adot[row] = part[t] + part[64 + t] + part[128 + t] + part[192 + t];
    }
    __syncthreads();
  }

  // scatter acc into LDS C-tile: C/D layout col = lane&15, row = (lane>>4)*4 + reg
#pragma unroll
  for (int rt = 0; rt < 4; ++rt)
#pragma unroll
    for (int ct = 0; ct < 2; ++ct)
#pragma unroll
      for (int r = 0; r < 4; ++r)
        Cf[(rt * 16 + g * 4 + r) * CF_LD + colbase + ct * 16 + cn] = acc[rt][ct][r];
  __syncthreads();

  float4* C4 = (float4*)(C + (size_t)row0 * 128);
#pragma unroll
  for (int i = 0; i < 8; ++i) {
    int f4 = t + i * 256;
    int row = f4 >> 5, c4 = f4 & 31;
    if (row0 + row < N) {
      float4 v = *(const float4*)(Cf + row * CF_LD + c4 * 4);
      if (bias) {
        float4 bv = *(const float4*)(bias + c4 * 4);
        v.x += bv.x; v.y += bv.y; v.z += bv.z; v.w += bv.w;
      }
      if (relu) {
        v.x = fmaxf(v.x, 0.f); v.y = fmaxf(v.y, 0.f);
        v.z = fmaxf(v.z, 0.f); v.w = fmaxf(v.w, 0.f);
      }
      C4[f4] = v;
    }
  }
}

// ======================= row dot: out[n] = x[n,:] . a  (one wave / node) ===========
__global__ void k_rowdot(const float* __restrict__ x, const float* __restrict__ a,
                         float* __restrict__ out, int N)
{
  int wid = blockIdx.x * 4 + (threadIdx.x >> 6);
  int lane = threadIdx.x & 63;
  if (wid >= N) return;
  float2 xv = ((const float2*)x)[(size_t)wid * 64 + lane];
  float2 av = ((const float2*)a)[lane];
  float v = fmaf(xv.y, av.y, xv.x * av.x);
#pragma unroll
  for (int o = 32; o > 0; o >>= 1) v += __shfl_down(v, o);
  if (lane == 0) out[wid] = v;
}

// ================= batched matvec: wv[m][i] = sum_j W_m[i,j]*a_m[j] ==============
struct MTab { const float* W[4]; const float* a[4]; };
__global__ __launch_bounds__(128) void k_matvec4(MTab tb, float* __restrict__ wv)
{
  __shared__ float as[128];
  int m = blockIdx.x, i = threadIdx.x;
  as[i] = tb.a[m][i];
  __syncthreads();
  const float* W = tb.W[m];
  float v = 0.f;
  for (int j = 0; j < 128; ++j) v = fmaf(W[i * 128 + j], as[j], v);
  wv[m * 128 + i] = v;
}

// ======================= batched CSR build =======================
struct HTab { const int* key[6]; int* cnt[6]; unsigned short* rank[6]; int bo[7]; int n[6]; };
__global__ void k_hist_rank_all(HTab tb) {
  int bi = blockIdx.x, ty = 0;
  while (ty < 5 && bi >= tb.bo[ty + 1]) ++ty;
  int i = (bi - tb.bo[ty]) * 256 + threadIdx.x;
  if (i < tb.n[ty])
    tb.rank[ty][i] = (unsigned short)atomicAdd(&tb.cnt[ty][tb.key[ty][i]], 1);
}

struct FTab { const int* es[6]; const int* ed[6]; const int* rp[6];
              const unsigned short* rank[6]; int* col[6]; int bo[7]; int n[6]; };
__global__ void k_fill_all(FTab tb) {
  int bi = blockIdx.x, ty = 0;
  while (ty < 5 && bi >= tb.bo[ty + 1]) ++ty;
  int e = (bi - tb.bo[ty]) * 256 + threadIdx.x;
  if (e >= tb.n[ty]) return;
  int p = tb.rp[ty][tb.ed[ty][e]] + (int)tb.rank[ty][e];
  tb.col[ty][p] = tb.es[ty][e];
}

// ---- batched 3-phase exclusive scan over 6 arrays (tile = 4096) ----
struct STab { int* rp[6]; int* bs[6]; int n[6]; int bo[7]; };

__global__ __launch_bounds__(256) void k_scan_partial_all(STab tb) {
  __shared__ int red[256];
  int bi = blockIdx.x, ty = 0;
  while (ty < 5 && bi >= tb.bo[ty + 1]) ++ty;
  int lb = bi - tb.bo[ty];
  const int* rp = tb.rp[ty];
  const int N = tb.n[ty];
  const int t = threadIdx.x, base = lb * 4096;
  int s = 0;
  for (int i = t; i < 4096; i += 256) {
    int idx = base + i;
    if (idx < N) s += rp[idx];
  }
  red[t] = s;
  __syncthreads();
  for (int ofs = 128; ofs > 0; ofs >>= 1) {
    if (t < ofs) red[t] += red[t + ofs];
    __syncthreads();
  }
  if (t == 0) tb.bs[ty][lb] = red[0];
}

__global__ __launch_bounds__(256) void k_scan_bsums_all(STab tb) {
  __shared__ int sh[256];
  const int ty = blockIdx.x;
  const int nb = (tb.n[ty] + 4095) / 4096;   // <= 25
  const int t = threadIdx.x;
  int v = (t < nb) ? tb.bs[ty][t] : 0;
  sh[t] = v;
  __syncthreads();
  for (int ofs = 1; ofs < 256; ofs <<= 1) {
    int u = (t >= ofs) ? sh[t - ofs] : 0;
    __syncthreads();
    sh[t] += u;
    __syncthreads();
  }
  if (t < nb) tb.bs[ty][t] = sh[t] - v;      // exclusive
  if (t == 255) tb.rp[ty][tb.n[ty]] = sh[255];  // total
}

__global__ __launch_bounds__(256) void k_scan_final_all(STab tb) {
  __shared__ int sh[4096 + 256];             // padded: i -> i + (i>>4)
  __shared__ int tsum[256];
  int bi = blockIdx.x, ty = 0;
  while (ty < 5 && bi >= tb.bo[ty + 1]) ++ty;
  int lb = bi - tb.bo[ty];
  int* rp = tb.rp[ty];
  const int N = tb.n[ty];
  const int t = threadIdx.x, base = lb * 4096;
  auto mp = [](int i) { return i + (i >> 4); };
#pragma unroll
  for (int i = 0; i < 16; ++i) {
    int idx = base + i * 256 + t;
    sh[mp(i * 256 + t)] = (idx < N) ? rp[idx] : 0;
  }
  __syncthreads();
  int s = 0;
#pragma unroll
  for (int j = 0; j < 16; ++j) s += sh[mp(t * 16 + j)];
  tsum[t] = s;
  __syncthreads();
  for (int ofs = 1; ofs < 256; ofs <<= 1) {
    int u = (t >= ofs) ? tsum[t - ofs] : 0;
    __syncthreads();
    tsum[t] += u;
    __syncthreads();
  }
  int pre = tsum[t] - s + tb.bs[ty][lb];
#pragma unroll
  for (int j = 0; j < 16; ++j) {
    int v = sh[mp(t * 16 + j)];
    sh[mp(t * 16 + j)] = pre;
    pre += v;
  }
  __syncthreads();
#pragma unroll
  for (int i = 0; i < 16; ++i) {
    int idx = base + i * 256 + t;
    if (idx < N) rp[idx] = sh[mp(i * 256 + t)];
  }
}

// ---- run-pointers for SORTED batch vectors via binary search (no atomics) ----
struct BTab { const int* b[5]; int n[5]; };
__global__ __launch_bounds__(512) void k_runptr(BTab tb, int* __restrict__ rpb_all) {
  const int ty = blockIdx.x;
  const int* b = tb.b[ty];
  const int N = tb.n[ty];
  const int t = threadIdx.x;                 // 0..511 = graph id
  int lo = 0, hi = N;
  while (lo < hi) {                          // lower_bound(b, t)
    int mid = (lo + hi) >> 1;
    if (b[mid] < t) lo = mid + 1; else hi = mid;
  }
  rpb_all[ty * RPB + t] = lo;
  if (t == 0) rpb_all[ty * RPB + GNUM] = N;
}

// dis for both GCN types in one launch
struct DTab { const int* rp[2]; float* dis[2]; int n[2]; int bo[3]; };
__global__ void k_dis2(DTab tb) {
  int bi = blockIdx.x, ty = (bi >= tb.bo[1]) ? 1 : 0;
  int n = (bi - tb.bo[ty]) * 256 + threadIdx.x;
  if (n < tb.n[ty]) tb.dis[ty][n] = rsqrtf((float)(tb.rp[ty][n + 1] - tb.rp[ty][n]) + 1.f);
}

// ======================= gather kernels =======================
// One wave per dst node; coalesced col[] prefetch + shfl broadcast; 2-way unroll.
// Optional fused output-dot: dout[node] = out_row . dvec (for the NEXT layer's sAd).

__global__ void k_gcn_gather(const int* __restrict__ rp, const int* __restrict__ col,
                             const float* __restrict__ dis, const float* __restrict__ h,
                             const float* addin, const float* __restrict__ b,
                             float* out, int N,
                             const float* __restrict__ dvec, float* __restrict__ dout)
{
  int node = blockIdx.x * 4 + (threadIdx.x >> 6);
  if (node >= N) return;
  int lane = threadIdx.x & 63;
  int s0 = rp[node], deg = rp[node + 1] - s0;
  float rd = dis[node];
  const float2* h2 = (const float2*)h;
  float2 hself = h2[(size_t)node * 64 + lane];
  float2 bv = ((const float2*)b)[lane];
  float ad0 = 0.f, ad1 = 0.f;
  if (addin) {
    float2 a2 = ((const float2*)addin)[(size_t)node * 64 + lane];
    ad0 = a2.x; ad1 = a2.y;
  }
  float a0 = 0.f, a1 = 0.f, b0 = 0.f, b1 = 0.f;
  for (int base = 0; base < deg; base += 64) {
    int m = min(64, deg - base);
    int c = 0; float dv = 0.f;
    if (lane < m) { c = col[s0 + base + lane]; dv = dis[c]; }
    int j = 0;
    for (; j + 1 < m; j += 2) {
      int sA = __shfl(c, j), sB = __shfl(c, j + 1);
      float nA = __shfl(dv, j) * rd, nB = __shfl(dv, j + 1) * rd;
      float2 vA = h2[(size_t)sA * 64 + lane];
      float2 vB = h2[(size_t)sB * 64 + lane];
      a0 = fmaf(nA, vA.x, a0); a1 = fmaf(nA, vA.y, a1);
      b0 = fmaf(nB, vB.x, b0); b1 = fmaf(nB, vB.y, b1);
    }
    if (j < m) {
      int sA = __shfl(c, j);
      float nA = __shfl(dv, j) * rd;
      float2 vA = h2[(size_t)sA * 64 + lane];
      a0 = fmaf(nA, vA.x, a0); a1 = fmaf(nA, vA.y, a1);
    }
  }
  float rr = rd * rd;
  float v0 = fmaf(rr, hself.x, a0 + b0) + bv.x + ad0;
  float v1 = fmaf(rr, hself.y, a1 + b1) + bv.y + ad1;
  v0 = fmaxf(v0, 0.f); v1 = fmaxf(v1, 0.f);
  ((float2*)out)[(size_t)node * 64 + lane] = make_float2(v0, v1);
  if (dvec) {
    float2 wv = ((const float2*)dvec)[lane];
    float p = fmaf(v1, wv.y, v0 * wv.x);
#pragma unroll
    for (int o = 32; o > 0; o >>= 1) p += __shfl_xor(p, o);
    if (lane == 0) dout[node] = p;
  }
}

__global__ void k_gat_gather(const int* __restrict__ rp, const int* __restrict__ col,
                             const float* __restrict__ hs, const float* __restrict__ as_,
                             const float* __restrict__ ad_, const float* __restrict__ b,
                             float* __restrict__ out, int N, int relu,
                             const float* __restrict__ dvec, float* __restrict__ dout)
{
  int node = blockIdx.x * 4 + (threadIdx.x >> 6);
  if (node >= N) return;
  int lane = threadIdx.x & 63;
  int s0 = rp[node], deg = rp[node + 1] - s0;
  float adn = ad_[node];
  float2 bv = ((const float2*)b)[lane];
  const float2* hs2 = (const float2*)hs;
  float z = 0.f, a0 = 0.f, a1 = 0.f, b0 = 0.f, b1 = 0.f;
  for (int base = 0; base < deg; base += 64) {
    int m = min(64, deg - base);
    int c = 0; float av = 0.f;
    if (lane < m) { c = col[s0 + base + lane]; av = as_[c]; }
    int j = 0;
    for (; j + 1 < m; j += 2) {
      int sA = __shfl(c, j), sB = __shfl(c, j + 1);
      float vA = __shfl(av, j) + adn, vB = __shfl(av, j + 1) + adn;
      vA = vA > 0.f ? vA : 0.2f * vA;
      vB = vB > 0.f ? vB : 0.2f * vB;
      float pA = __expf(vA), pB = __expf(vB);
      z += pA + pB;
      float2 hA = hs2[(size_t)sA * 64 + lane];
      float2 hB = hs2[(size_t)sB * 64 + lane];
      a0 = fmaf(pA, hA.x, a0); a1 = fmaf(pA, hA.y, a1);
      b0 = fmaf(pB, hB.x, b0); b1 = fmaf(pB, hB.y, b1);
    }
    if (j < m) {
      int sA = __shfl(c, j);
      float vA = __shfl(av, j) + adn;
      vA = vA > 0.f ? vA : 0.2f * vA;
      float pA = __expf(vA);
      z += pA;
      float2 hA = hs2[(size_t)sA * 64 + lane];
      a0 = fmaf(pA, hA.x, a0); a1 = fmaf(pA, hA.y, a1);
    }
  }
  float inv = (deg > 0) ? 1.f / z : 0.f;
  float v0 = fmaf(a0 + b0, inv, bv.x);
  float v1 = fmaf(a1 + b1, inv, bv.y);
  if (relu) { v0 = fmaxf(v0, 0.f); v1 = fmaxf(v1, 0.f); }
  ((float2*)out)[(size_t)node * 64 + lane] = make_float2(v0, v1);
  if (dvec) {
    float2 wv = ((const float2*)dvec)[lane];
    float p = fmaf(v1, wv.y, v0 * wv.x);
#pragma unroll
    for (int o = 32; o > 0; o >>= 1) p += __shfl_xor(p, o);
    if (lane == 0) dout[node] = p;
  }
}

// ============ segment pooling: one block per graph, contiguous rows ============
__global__ __launch_bounds__(256) void k_pool_seg(
    const float* __restrict__ x, const int* __restrict__ rpb,
    float* __restrict__ pool, int col_off)
{
  __shared__ float2 red2[4][64];
  const int g = blockIdx.x;
  const int t = threadIdx.x, w = t >> 6, lane = t & 63;
  const int n0 = rpb[g], n1 = rpb[g + 1];
  const float2* x2 = (const float2*)x;
  float a0 = 0.f, a1 = 0.f, b0 = 0.f, b1 = 0.f;
  int n = n0 + w;
  for (; n + 4 < n1; n += 8) {
    float2 vA = x2[(size_t)n * 64 + lane];
    float2 vB = x2[(size_t)(n + 4) * 64 + lane];
    a0 += vA.x; a1 += vA.y; b0 += vB.x; b1 += vB.y;
  }
  if (n < n1) { float2 vA = x2[(size_t)n * 64 + lane]; a0 += vA.x; a1 += vA.y; }
  red2[w][lane] = make_float2(a0 + b0, a1 + b1);
  __syncthreads();
  if (t < 64) {
    float2 r0 = red2[0][t], r1 = red2[1][t], r2 = red2[2][t], r3 = red2[3][t];
    float inv = 1.f / fmaxf((float)(n1 - n0), 1.f);
    ((float2*)(pool + (size_t)g * 640 + col_off))[t] =
        make_float2((r0.x + r1.x + r2.x + r3.x) * inv,
                    (r0.y + r1.y + r2.y + r3.y) * inv);
  }
}

// ======================= final MLP (one block per graph) =======================
__global__ void k_mlp(const float* __restrict__ pool,
                      const float* __restrict__ W1, const float* __restrict__ b1,
                      const float* __restrict__ W2, const float* __restrict__ b2,
                      float* __restrict__ out)
{
  __shared__ float emb[640];
  __shared__ float red[128];
  const int g = blockIdx.x, t = threadIdx.x;
  for (int i = t; i < 640; i += 128) emb[i] = pool[(size_t)g * 640 + i];
  __syncthreads();
  float acc = b1[t];
  for (int i = 0; i < 640; ++i) acc = fmaf(emb[i], W1[i * 128 + t], acc);
  float h = fmaxf(acc, 0.f);
  red[t] = h * W2[t];
  __syncthreads();
  for (int s = 64; s > 0; s >>= 1) {
    if (t < s) red[t] += red[t + s];
    __syncthreads();
  }
  if (t == 0) out[g] = red[0] + b2[0];
}

// ======================= host =======================
extern "C" void kernel_launch(void* const* d_in, const int* in_sizes, int n_in,
                              void* d_out, int out_size, void* d_ws, size_t ws_size,
                              hipStream_t stream)
{
  auto fin = [&](int i) { return (const float*)d_in[i]; };
  auto iin = [&](int i) { return (const int*)d_in[i]; };

  const float *x_cd = fin(0), *x_seq = fin(1), *x_anno = fin(2), *x_range = fin(3), *x_md = fin(4);
  const int *ei_seq = iin(5), *ei_anno = iin(6), *ei_range = iin(7),
            *ei_comp = iin(8), *ei_cc = iin(9), *ei_mm = iin(10);
  const int *b_cd = iin(11), *b_seq = iin(12), *b_anno = iin(13), *b_range = iin(14), *b_md = iin(15);

  const int N_CD = in_sizes[0] / HD, N_SEQ = in_sizes[1] / HD, N_ANNO = in_sizes[2] / HD,
            N_RANGE = in_sizes[3] / HD, N_MD = in_sizes[4] / HD;
  const int E_seq = in_sizes[5] / 2, E_anno = in_sizes[6] / 2, E_range = in_sizes[7] / 2,
            E_comp = in_sizes[8] / 2, E_cc = in_sizes[9] / 2, E_mm = in_sizes[10] / 2;
  const int N_OTH = max(max(N_SEQ, N_ANNO), N_RANGE);

  auto WLm = [&](int i, int l) { return fin(i) + (size_t)l * HD * HD; };
  auto WLv = [&](int i, int l) { return fin(i) + (size_t)l * HD; };

  // ---- workspace layout ----
  float* ws = (float*)d_ws;
  size_t off = 0;
  auto alloc = [&](size_t n) { float* p = ws + off; off += (n + 3) & ~(size_t)3; return p; };
  float* xcd1 = alloc((size_t)N_CD * HD);
  float* xmd1 = alloc((size_t)N_MD * HD);
  float* xoth = alloc((size_t)N_OTH * HD);
  float* acc  = alloc((size_t)N_CD * HD);
  float* t1   = alloc((size_t)N_CD * HD);
  float* sAs  = alloc((size_t)N_CD);
  float* sAd  = alloc((size_t)N_CD);
  float* sAd2 = alloc((size_t)N_CD);
  float* dis_cc = alloc((size_t)N_CD);
  float* dis_mm = alloc((size_t)N_MD);
  float* wvall = alloc(4 * HD);
  float* pool = alloc((size_t)GNUM * 5 * HD);
  short* whi = (short*)(ws + off); off += (size_t)16 * 16384 / 2;
  short* wlo = (short*)(ws + off); off += (size_t)16 * 16384 / 2;
  auto alloci = [&](size_t n) { int* p = (int*)(ws + off); off += (n + 3) & ~(size_t)3; return p; };
  int* bsall = alloci(6 * 256);          // batched scan partials
  int* rpb_all = alloci(5 * RPB);
  int Nds[6] = {N_SEQ, N_ANNO, N_RANGE, N_CD, N_CD, N_MD};
  int Es[6]  = {E_seq, E_anno, E_range, E_comp, E_cc, E_mm};
  int* rps[6];
  int* rp0 = alloci(0);
  { size_t tot = 0; for (int i = 0; i < 6; ++i) tot += (size_t)Nds[i] + 1;
    int* p = alloci(tot); rp0 = p;
    for (int i = 0; i < 6; ++i) { rps[i] = p; p += Nds[i] + 1; } }
  size_t rp_tot_bytes = 0; for (int i = 0; i < 6; ++i) rp_tot_bytes += ((size_t)Nds[i] + 1) * 4;
  unsigned short* ranks[6];
  for (int i = 0; i < 6; ++i) ranks[i] = (unsigned short*)alloci(((size_t)Es[i] + 1) / 2);
  int* cols[6];  for (int i = 0; i < 6; ++i) cols[i] = alloci((size_t)Es[i]);
  (void)n_in;

  if (off * sizeof(float) > ws_size) {
    hipMemsetAsync(d_out, 0, (size_t)out_size * sizeof(float), stream);
    return;
  }

  auto ew = [&](size_t elems) { return dim3((unsigned)((elems + 255) / 256)); };
  auto nw = [&](int N) { return dim3((unsigned)((N + 3) / 4)); };

  // ---- pre-split all GEMM weights (slots: 0:16 1:18 2:19 3:21 4:22 5:27 6:32 7:34)
  WTab tab;
  tab.p[0] = fin(16); tab.p[1] = fin(18); tab.p[2] = fin(19); tab.p[3] = fin(21);
  tab.p[4] = fin(22); tab.p[5] = fin(27); tab.p[6] = fin(32); tab.p[7] = fin(34);
  k_split_w<<<dim3(1024), dim3(256), 0, stream>>>(tab, whi, wlo);

  // ---- 4 DST-side GAT matvecs (Wd@a_d): comp L0/L1, range L0/L1 ----
  MTab mt;
  mt.W[0] = WLm(23, 0); mt.a[0] = WLv(25, 0);
  mt.W[1] = WLm(23, 1); mt.a[1] = WLv(25, 1);
  mt.W[2] = WLm(28, 0); mt.a[2] = WLv(30, 0);
  mt.W[3] = WLm(28, 1); mt.a[3] = WLv(30, 1);
  k_matvec4<<<dim3(4), dim3(128), 0, stream>>>(mt, wvall);

  // ---- run-pointers for sorted batch vectors (binary search, no atomics) ----
  {
    BTab bt;
    bt.b[0] = b_cd; bt.n[0] = N_CD;  bt.b[1] = b_seq; bt.n[1] = N_SEQ;
    bt.b[2] = b_anno; bt.n[2] = N_ANNO;  bt.b[3] = b_range; bt.n[3] = N_RANGE;
    bt.b[4] = b_md; bt.n[4] = N_MD;
    k_runptr<<<dim3(5), dim3(512), 0, stream>>>(bt, rpb_all);
  }

  // ---- batched CSR build (rank-recording: fill has no atomics) ----
  const int* ess[6] = {ei_seq, ei_anno, ei_range, ei_comp, ei_cc, ei_mm};
  const int* eds[6] = {ei_seq + E_seq, ei_anno + E_anno, ei_range + E_range,
                       ei_comp + E_comp, ei_cc + E_cc, ei_mm + E_mm};
  hipMemsetAsync(rp0, 0, rp_tot_bytes, stream);
  {
    HTab ht; int b = 0;
    for (int i = 0; i < 6; ++i) {
      ht.key[i] = eds[i]; ht.cnt[i] = rps[i]; ht.rank[i] = ranks[i];
      ht.bo[i] = b; b += (Es[i] + 255) / 256; ht.n[i] = Es[i];
    }
    ht.bo[6] = b;
    k_hist_rank_all<<<dim3(b), dim3(256), 0, stream>>>(ht);
  }
  {
    STab st; int b = 0;
    for (int i = 0; i < 6; ++i) {
      st.rp[i] = rps[i]; st.bs[i] = bsall + i * 256;
      st.n[i] = Nds[i]; st.bo[i] = b; b += (Nds[i] + 4095) / 4096;
    }
    st.bo[6] = b;
    k_scan_partial_all<<<dim3(b), dim3(256), 0, stream>>>(st);
    k_scan_bsums_all<<<dim3(6), dim3(256), 0, stream>>>(st);
    k_scan_final_all<<<dim3(b), dim3(256), 0, stream>>>(st);
  }
  {
    FTab ft; int b = 0;
    for (int i = 0; i < 6; ++i) {
      ft.es[i] = ess[i]; ft.ed[i] = eds[i]; ft.rp[i] = rps[i]; ft.rank[i] = ranks[i];
      ft.col[i] = cols[i]; ft.bo[i] = b; b += (Es[i] + 255) / 256; ft.n[i] = Es[i];
    }
    ft.bo[6] = b;
    k_fill_all<<<dim3(b), dim3(256), 0, stream>>>(ft);
  }
  int *rp_seq = rps[0], *rp_anno = rps[1], *rp_range = rps[2],
      *rp_comp = rps[3], *rp_cc = rps[4], *rp_mm = rps[5];
  int *col_seq = cols[0], *col_anno = cols[1], *col_range = cols[2],
      *col_comp = cols[3], *col_cc = cols[4], *col_mm = cols[5];
  {
    DTab dt;
    dt.rp[0] = rp_cc; dt.dis[0] = dis_cc; dt.n[0] = N_CD;
    dt.rp[1] = rp_mm; dt.dis[1] = dis_mm; dt.n[1] = N_MD;
    dt.bo[0] = 0; dt.bo[1] = (N_CD + 255) / 256;
    dt.bo[2] = dt.bo[1] + (N_MD + 255) / 256;
    k_dis2<<<dim3(dt.bo[2]), dim3(256), 0, stream>>>(dt);
  }

  auto WHp = [&](int sidx, int layer) { return whi + (size_t)(sidx * 2 + layer) * 16384; };
  auto WLp = [&](int sidx, int layer) { return wlo + (size_t)(sidx * 2 + layer) * 16384; };
  auto gemm = [&](const float* A, int sidx, int layer, float* C, const float* b,
                  int N, int relu, const float* avec = nullptr, float* adot = nullptr) {
    k_gemm_mfma<<<dim3((N + 63) / 64), dim3(256), 0, stream>>>(
        A, WHp(sidx, layer), WLp(sidx, layer), nullptr, nullptr,
        nullptr, nullptr, nullptr, C, b, N, relu, avec, adot);
  };
  // SAGE fused: A1 = CSR-mean of xsrc (gathered in staging), A2 = xself
  auto gemm2g = [&](const float* xsrc, const int* grp, const int* gcol, int s1,
                    const float* xself, int s2, int layer,
                    float* C, const float* b, int N) {
    k_gemm_mfma<<<dim3((N + 63) / 64), dim3(256), 0, stream>>>(
        xsrc, WHp(s1, layer), WLp(s1, layer), grp, gcol,
        xself, WHp(s2, layer), WLp(s2, layer), C, b, N, 1, nullptr, nullptr);
  };
  auto do_pool = [&](const float* x, int type) {
    k_pool_seg<<<dim3(GNUM), dim3(256), 0, stream>>>(x, rpb_all + type * RPB, pool, type * HD);
  };

  // GAT: hs = xs@Ws with FUSED sAs = hs.a_s; sAd either precomputed (sAd_src)
  // or via rowdot(xd, wv). Optional fused out-dot (dvec->dout) for next layer.
  auto gat = [&](const float* xs, const float* xd, const int* rp, const int* col,
                 int Ns, int Nd, int sidx, int layer, const float* avs_raw,
                 const float* sAd_src, int wvD,
                 const float* dvec, float* dout,
                 const float* bias, float* out, int relu) {
    if (wvD >= 0) {
      k_rowdot<<<nw(Nd), dim3(256), 0, stream>>>(xd, wvall + wvD * 128, sAd, Nd);
      sAd_src = sAd;
    }
    gemm(xs, sidx, layer, t1, nullptr, Ns, 0, avs_raw, sAs);   // hs + fused hs.a_s
    k_gat_gather<<<nw(Nd), dim3(256), 0, stream>>>(rp, col, t1, sAs, sAd_src, bias,
                                                   out, Nd, relu, dvec, dout);
  };
  auto gcn = [&](const float* x, const int* rp, const int* col, const float* dis, int N,
                 int sidx, int layer, const float* b, const float* addin, float* out,
                 const float* dvec, float* dout) {
    gemm(x, sidx, layer, t1, nullptr, N, 0);
    k_gcn_gather<<<nw(N), dim3(256), 0, stream>>>(rp, col, dis, t1, addin, b, out, N,
                                                  dvec, dout);
  };
  auto sage = [&](const float* xsrc, const float* xself, const int* rp, const int* col,
                  int Nd, int sl, int sr, int layer, const float* bl, float* out) {
    gemm2g(xsrc, rp, col, sl, xself, sr, layer, out, bl, Nd);
  };

  // ---------- CD + MD, both layers ----------
  gat(x_md, x_cd, rp_comp, col_comp, N_MD, N_CD, 4, 0, WLv(24, 0),
      nullptr, 0, nullptr, nullptr, WLv(26, 0), acc, 0);
  // cc L1: produces xcd1; fused dot with comp-L2 dst vec -> sAd2
  gcn(x_cd, rp_cc, col_cc, dis_cc, N_CD, 6, 0, WLv(33, 0), acc, xcd1,
      wvall + 1 * 128, sAd2);
  gcn(x_md, rp_mm, col_mm, dis_mm, N_MD, 7, 0, WLv(35, 0), nullptr, xmd1,
      nullptr, nullptr);
  gat(xmd1, xcd1, rp_comp, col_comp, N_MD, N_CD, 4, 1, WLv(24, 1),
      sAd2, -1, nullptr, nullptr, WLv(26, 1), acc, 0);
  gcn(xcd1, rp_cc, col_cc, dis_cc, N_CD, 6, 1, WLv(33, 1), acc, acc,
      nullptr, nullptr);
  do_pool(acc, 0);
  gcn(xmd1, rp_mm, col_mm, dis_mm, N_MD, 7, 1, WLv(35, 1), nullptr, acc,
      nullptr, nullptr);
  do_pool(acc, 4);

  // ---------- SEQ ----------
  sage(x_cd, x_seq, rp_seq, col_seq, N_SEQ, 0, 1, 0, WLv(17, 0), xoth);
  sage(xcd1, xoth, rp_seq, col_seq, N_SEQ, 0, 1, 1, WLv(17, 1), acc);
  do_pool(acc, 1);
  // ---------- ANNO ----------
  sage(x_cd, x_anno, rp_anno, col_anno, N_ANNO, 2, 3, 0, WLv(20, 0), xoth);
  sage(xcd1, xoth, rp_anno, col_anno, N_ANNO, 2, 3, 1, WLv(20, 1), acc);
  do_pool(acc, 2);
  // ---------- RANGE ----------
  // range L1: produces xoth; fused dot with range-L2 dst vec -> sAd2
  gat(x_cd, x_range, rp_range, col_range, N_CD, N_RANGE, 5, 0, WLv(29, 0),
      nullptr, 2, wvall + 3 * 128, sAd2, WLv(31, 0), xoth, 1);
  gat(xcd1, xoth, rp_range, col_range, N_CD, N_RANGE, 5, 1, WLv(29, 1),
      sAd2, -1, nullptr, nullptr, WLv(31, 1), acc, 1);
  do_pool(acc, 3);

  k_mlp<<<dim3(GNUM), dim3(128), 0, stream>>>(
      pool, fin(36), fin(37), fin(38), fin(39), (float*)d_out);
}

// Round 15
// 1017.123 us; speedup vs baseline: 2.6874x; 1.0354x over previous
//
#include <hip/hip_runtime.h>

#define HD 128
#define GNUM 512
#define RPB 520   // per-type stride in rpb_all (>= GNUM+1)
#define IDXCAP 1024

typedef __attribute__((ext_vector_type(8))) short short8v;   // 8 bf16 = 4 VGPR
typedef __attribute__((ext_vector_type(4))) float f32x4;

// RNE split: a ~= hi + lo (both bf16), |residual| ~ 2^-17 |a|
__device__ __forceinline__ void split1(float a, short& h, short& l) {
  unsigned u = __float_as_uint(a);
  unsigned hb = (u + 0x7FFFu + ((u >> 16) & 1u)) & 0xFFFF0000u;
  h = (short)(hb >> 16);
  float rest = a - __uint_as_float(hb);
  unsigned u2 = __float_as_uint(rest);
  l = (short)((u2 + 0x7FFFu + ((u2 >> 16) & 1u)) >> 16);
}

// ============ W pre-split: fp32 [k][n] -> bf16 hi/lo TRANSPOSED [n][k] ============
struct WTab { const float* p[8]; };
__global__ __launch_bounds__(256) void k_split_w(WTab tab, short* __restrict__ whi,
                                                 short* __restrict__ wlo)
{
  int m = blockIdx.x >> 6;                       // 16 matrices, 64 blocks each
  int i = (blockIdx.x & 63) * 256 + threadIdx.x; // 0..16383
  const float* W = tab.p[m >> 1] + (m & 1) * 16384;
  int k = i >> 7, n = i & 127;
  short h, l;
  split1(W[k * 128 + n], h, l);
  whi[m * 16384 + n * 128 + k] = h;
  wlo[m * 16384 + n * 128 + k] = l;
}

// ============ MFMA GEMM: C = A1@W1 (+ A2@W2) (+bias, relu) ====================
// If grp/gcol given: A1 rows are the CSR-MEAN over gcol of source matrix A1
// (SAGE fusion). Block's edge slice is prefetched into LDS (coalesced) so the
// per-edge chain is LDS-idx -> row-load instead of global-idx -> row-load.
// Optional fused row-dot: adot[r] = (A1@W1)_row[r] . avec  (avec in OUTPUT space).
#define CF_LD 132
__global__ __launch_bounds__(256) void k_gemm_mfma(
    const float* __restrict__ A1, const short* __restrict__ WH1, const short* __restrict__ WL1,
    const int* __restrict__ grp, const int* __restrict__ gcol,
    const float* __restrict__ A2, const short* __restrict__ WH2, const short* __restrict__ WL2,
    float* __restrict__ C, const float* __restrict__ bias, int N, int relu,
    const float* __restrict__ avec, float* __restrict__ adot)
{
  __shared__ char smem[64 * 136 * 2 * 2];        // 34816 B
  __shared__ int idxbuf[IDXCAP];                 // 4096 B (38912 total: still 4 blk/CU)
  short* Ah = (short*)smem;
  short* Al = Ah + 64 * 136;
  float* Cf = (float*)smem;

  const int t = threadIdx.x;
  const int row0 = blockIdx.x * 64;
  const int lane = t & 63, wid = t >> 6;
  const int g = lane >> 4, cn = lane & 15;
  const int colbase = wid * 32;

  f32x4 zero = {0.f, 0.f, 0.f, 0.f};
  f32x4 acc[4][2];
#pragma unroll
  for (int rt = 0; rt < 4; ++rt) { acc[rt][0] = zero; acc[rt][1] = zero; }

  auto stageA = [&](const float* __restrict__ A) {
    const float4* A4 = (const float4*)(A + (size_t)row0 * 128);
#pragma unroll
    for (int i = 0; i < 8; ++i) {
      int f4 = t + i * 256;
      int row = f4 >> 5, c4 = f4 & 31;
      float4 v = make_float4(0.f, 0.f, 0.f, 0.f);
      if (row0 + row < N) v = A4[f4];
      short4 h, l;
      split1(v.x, h.x, l.x); split1(v.y, h.y, l.y);
      split1(v.z, h.z, l.z); split1(v.w, h.w, l.w);
      *(short4*)(Ah + row * 136 + c4 * 4) = h;
      *(short4*)(Al + row * 136 + c4 * 4) = l;
    }
  };

  // CSR-mean gather staging: 32-thread group per row; indices come from LDS.
  auto stageA_gather = [&](const float* __restrict__ X, int e_lo) {
#pragma unroll
    for (int i = 0; i < 8; ++i) {
      int f4 = t + i * 256;
      int row = f4 >> 5, ln = f4 & 31;
      int r = row0 + row;
      float4 s = make_float4(0.f, 0.f, 0.f, 0.f);
      int e0 = 0, e1 = 0;
      if (r < N) { e0 = grp[r]; e1 = grp[r + 1]; }
      for (int e = e0; e < e1; ++e) {
        int off = e - e_lo;
        int c = (off < IDXCAP) ? idxbuf[off] : gcol[e];
        float4 v = *(const float4*)(X + (size_t)c * 128 + ln * 4);
        s.x += v.x; s.y += v.y; s.z += v.z; s.w += v.w;
      }
      float inv = 1.f / fmaxf((float)(e1 - e0), 1.f);
      short4 h, l;
      split1(s.x * inv, h.x, l.x); split1(s.y * inv, h.y, l.y);
      split1(s.z * inv, h.z, l.z); split1(s.w * inv, h.w, l.w);
      *(short4*)(Ah + row * 136 + ln * 4) = h;
      *(short4*)(Al + row * 136 + ln * 4) = l;
    }
  };

  auto accum = [&](const short* __restrict__ WH, const short* __restrict__ WL) {
    short8v bhi[2][4], blo[2][4];
#pragma unroll
    for (int ct = 0; ct < 2; ++ct)
#pragma unroll
      for (int kg = 0; kg < 4; ++kg) {
        size_t o = (size_t)(colbase + ct * 16 + cn) * 128 + kg * 32 + g * 8;
        bhi[ct][kg] = *(const short8v*)(WH + o);
        blo[ct][kg] = *(const short8v*)(WL + o);
      }
#pragma unroll
    for (int kg = 0; kg < 4; ++kg) {
#pragma unroll
      for (int rt = 0; rt < 4; ++rt) {
        const int ao = (rt * 16 + cn) * 136 + kg * 32 + g * 8;
        const short8v ah = *(const short8v*)(Ah + ao);
        const short8v al = *(const short8v*)(Al + ao);
#pragma unroll
        for (int ct = 0; ct < 2; ++ct) {
          acc[rt][ct] = __builtin_amdgcn_mfma_f32_16x16x32_bf16(ah, bhi[ct][kg], acc[rt][ct], 0, 0, 0);
          acc[rt][ct] = __builtin_amdgcn_mfma_f32_16x16x32_bf16(al, bhi[ct][kg], acc[rt][ct], 0, 0, 0);
          acc[rt][ct] = __builtin_amdgcn_mfma_f32_16x16x32_bf16(ah, blo[ct][kg], acc[rt][ct], 0, 0, 0);
        }
      }
    }
  };

  if (grp) {
    const int row_end = min(row0 + 64, N);
    const int e_lo = grp[row0];
    const int cnt = min(grp[row_end] - e_lo, IDXCAP);
    for (int k = t; k < cnt; k += 256) idxbuf[k] = gcol[e_lo + k];
    __syncthreads();
    stageA_gather(A1, e_lo);
  } else {
    stageA(A1);
  }
  __syncthreads();
  accum(WH1, WL1);
  if (A2) {
    __syncthreads();
    stageA(A2);
    __syncthreads();
    accum(WH2, WL2);
  }
  __syncthreads();                   // Ah/Al dead past here; smem reusable

  // ---- fused row-dot (raw A@W): per-wave partial + cross-wave LDS reduce ----
  if (avec) {
    float* part = (float*)smem;      // [4 waves][64 rows]
    const float av0 = avec[colbase + cn];
    const float av1 = avec[colbase + 16 + cn];
#pragma unroll
    for (int rt = 0; rt < 4; ++rt)
#pragma unroll
      for (int r = 0; r < 4; ++r) {
        float p = fmaf(acc[rt][1][r], av1, acc[rt][0][r] * av0);
#pragma unroll
        for (int o = 1; o < 16; o <<= 1) p += __shfl_xor(p, o);
        if (cn == 0) part[wid * 64 + rt * 16 + g * 4 + r] = p;
      }
    __syncthreads();
    if (t < 64) {
      int row = row0 + t;
      if (row < N) adot[row] = part[t] + part[64 + t] + part[128 + t] + part[192 + t];
    }
    __syncthreads();
  }

  // scatter acc into LDS C-tile: C/D layout col = lane&15, row = (lane>>4)*4 + reg
#pragma unroll
  for (int rt = 0; rt < 4; ++rt)
#pragma unroll
    for (int ct = 0; ct < 2; ++ct)
#pragma unroll
      for (int r = 0; r < 4; ++r)
        Cf[(rt * 16 + g * 4 + r) * CF_LD + colbase + ct * 16 + cn] = acc[rt][ct][r];
  __syncthreads();

  float4* C4 = (float4*)(C + (size_t)row0 * 128);
#pragma unroll
  for (int i = 0; i < 8; ++i) {
    int f4 = t + i * 256;
    int row = f4 >> 5, c4 = f4 & 31;
    if (row0 + row < N) {
      float4 v = *(const float4*)(Cf + row * CF_LD + c4 * 4);
      if (bias) {
        float4 bv = *(const float4*)(bias + c4 * 4);
        v.x += bv.x; v.y += bv.y; v.z += bv.z; v.w += bv.w;
      }
      if (relu) {
        v.x = fmaxf(v.x, 0.f); v.y = fmaxf(v.y, 0.f);
        v.z = fmaxf(v.z, 0.f); v.w = fmaxf(v.w, 0.f);
      }
      C4[f4] = v;
    }
  }
}

// ======================= row dot: out[n] = x[n,:] . a  (one wave / node) ===========
__global__ void k_rowdot(const float* __restrict__ x, const float* __restrict__ a,
                         float* __restrict__ out, int N)
{
  int wid = blockIdx.x * 4 + (threadIdx.x >> 6);
  int lane = threadIdx.x & 63;
  if (wid >= N) return;
  float2 xv = ((const float2*)x)[(size_t)wid * 64 + lane];
  float2 av = ((const float2*)a)[lane];
  float v = fmaf(xv.y, av.y, xv.x * av.x);
#pragma unroll
  for (int o = 32; o > 0; o >>= 1) v += __shfl_down(v, o);
  if (lane == 0) out[wid] = v;
}

// ================= batched matvec: wv[m][i] = sum_j W_m[i,j]*a_m[j] ==============
struct MTab { const float* W[4]; const float* a[4]; };
__global__ __launch_bounds__(128) void k_matvec4(MTab tb, float* __restrict__ wv)
{
  __shared__ float as[128];
  int m = blockIdx.x, i = threadIdx.x;
  as[i] = tb.a[m][i];
  __syncthreads();
  const float* W = tb.W[m];
  float v = 0.f;
  for (int j = 0; j < 128; ++j) v = fmaf(W[i * 128 + j], as[j], v);
  wv[m * 128 + i] = v;
}

// ======================= batched CSR build =======================
struct HTab { const int* key[6]; int* cnt[6]; unsigned short* rank[6]; int bo[7]; int n[6]; };
__global__ void k_hist_rank_all(HTab tb) {
  int bi = blockIdx.x, ty = 0;
  while (ty < 5 && bi >= tb.bo[ty + 1]) ++ty;
  int i = (bi - tb.bo[ty]) * 256 + threadIdx.x;
  if (i < tb.n[ty])
    tb.rank[ty][i] = (unsigned short)atomicAdd(&tb.cnt[ty][tb.key[ty][i]], 1);
}

struct FTab { const int* es[6]; const int* ed[6]; const int* rp[6];
              const unsigned short* rank[6]; int* col[6]; int bo[7]; int n[6]; };
__global__ void k_fill_all(FTab tb) {
  int bi = blockIdx.x, ty = 0;
  while (ty < 5 && bi >= tb.bo[ty + 1]) ++ty;
  int e = (bi - tb.bo[ty]) * 256 + threadIdx.x;
  if (e >= tb.n[ty]) return;
  int p = tb.rp[ty][tb.ed[ty][e]] + (int)tb.rank[ty][e];
  tb.col[ty][p] = tb.es[ty][e];
}

// ---- batched 3-phase exclusive scan over 6 arrays (tile = 4096) ----
struct STab { int* rp[6]; int* bs[6]; int n[6]; int bo[7]; };

__global__ __launch_bounds__(256) void k_scan_partial_all(STab tb) {
  __shared__ int red[256];
  int bi = blockIdx.x, ty = 0;
  while (ty < 5 && bi >= tb.bo[ty + 1]) ++ty;
  int lb = bi - tb.bo[ty];
  const int* rp = tb.rp[ty];
  const int N = tb.n[ty];
  const int t = threadIdx.x, base = lb * 4096;
  int s = 0;
  for (int i = t; i < 4096; i += 256) {
    int idx = base + i;
    if (idx < N) s += rp[idx];
  }
  red[t] = s;
  __syncthreads();
  for (int ofs = 128; ofs > 0; ofs >>= 1) {
    if (t < ofs) red[t] += red[t + ofs];
    __syncthreads();
  }
  if (t == 0) tb.bs[ty][lb] = red[0];
}

__global__ __launch_bounds__(256) void k_scan_bsums_all(STab tb) {
  __shared__ int sh[256];
  const int ty = blockIdx.x;
  const int nb = (tb.n[ty] + 4095) / 4096;   // <= 25
  const int t = threadIdx.x;
  int v = (t < nb) ? tb.bs[ty][t] : 0;
  sh[t] = v;
  __syncthreads();
  for (int ofs = 1; ofs < 256; ofs <<= 1) {
    int u = (t >= ofs) ? sh[t - ofs] : 0;
    __syncthreads();
    sh[t] += u;
    __syncthreads();
  }
  if (t < nb) tb.bs[ty][t] = sh[t] - v;      // exclusive
  if (t == 255) tb.rp[ty][tb.n[ty]] = sh[255];  // total
}

__global__ __launch_bounds__(256) void k_scan_final_all(STab tb) {
  __shared__ int sh[4096 + 256];             // padded: i -> i + (i>>4)
  __shared__ int tsum[256];
  int bi = blockIdx.x, ty = 0;
  while (ty < 5 && bi >= tb.bo[ty + 1]) ++ty;
  int lb = bi - tb.bo[ty];
  int* rp = tb.rp[ty];
  const int N = tb.n[ty];
  const int t = threadIdx.x, base = lb * 4096;
  auto mp = [](int i) { return i + (i >> 4); };
#pragma unroll
  for (int i = 0; i < 16; ++i) {
    int idx = base + i * 256 + t;
    sh[mp(i * 256 + t)] = (idx < N) ? rp[idx] : 0;
  }
  __syncthreads();
  int s = 0;
#pragma unroll
  for (int j = 0; j < 16; ++j) s += sh[mp(t * 16 + j)];
  tsum[t] = s;
  __syncthreads();
  for (int ofs = 1; ofs < 256; ofs <<= 1) {
    int u = (t >= ofs) ? tsum[t - ofs] : 0;
    __syncthreads();
    tsum[t] += u;
    __syncthreads();
  }
  int pre = tsum[t] - s + tb.bs[ty][lb];
#pragma unroll
  for (int j = 0; j < 16; ++j) {
    int v = sh[mp(t * 16 + j)];
    sh[mp(t * 16 + j)] = pre;
    pre += v;
  }
  __syncthreads();
#pragma unroll
  for (int i = 0; i < 16; ++i) {
    int idx = base + i * 256 + t;
    if (idx < N) rp[idx] = sh[mp(i * 256 + t)];
  }
}

// ---- run-pointers for SORTED batch vectors via binary search (no atomics) ----
struct BTab { const int* b[5]; int n[5]; };
__global__ __launch_bounds__(512) void k_runptr(BTab tb, int* __restrict__ rpb_all) {
  const int ty = blockIdx.x;
  const int* b = tb.b[ty];
  const int N = tb.n[ty];
  const int t = threadIdx.x;                 // 0..511 = graph id
  int lo = 0, hi = N;
  while (lo < hi) {                          // lower_bound(b, t)
    int mid = (lo + hi) >> 1;
    if (b[mid] < t) lo = mid + 1; else hi = mid;
  }
  rpb_all[ty * RPB + t] = lo;
  if (t == 0) rpb_all[ty * RPB + GNUM] = N;
}

// dis for both GCN types in one launch
struct DTab { const int* rp[2]; float* dis[2]; int n[2]; int bo[3]; };
__global__ void k_dis2(DTab tb) {
  int bi = blockIdx.x, ty = (bi >= tb.bo[1]) ? 1 : 0;
  int n = (bi - tb.bo[ty]) * 256 + threadIdx.x;
  if (n < tb.n[ty]) tb.dis[ty][n] = rsqrtf((float)(tb.rp[ty][n + 1] - tb.rp[ty][n]) + 1.f);
}

// ======================= gather kernels =======================
__global__ void k_gcn_gather(const int* __restrict__ rp, const int* __restrict__ col,
                             const float* __restrict__ dis, const float* __restrict__ h,
                             const float* addin, const float* __restrict__ b,
                             float* out, int N,
                             const float* __restrict__ dvec, float* __restrict__ dout)
{
  int node = blockIdx.x * 4 + (threadIdx.x >> 6);
  if (node >= N) return;
  int lane = threadIdx.x & 63;
  int s0 = rp[node], deg = rp[node + 1] - s0;
  float rd = dis[node];
  const float2* h2 = (const float2*)h;
  float2 hself = h2[(size_t)node * 64 + lane];
  float2 bv = ((const float2*)b)[lane];
  float ad0 = 0.f, ad1 = 0.f;
  if (addin) {
    float2 a2 = ((const float2*)addin)[(size_t)node * 64 + lane];
    ad0 = a2.x; ad1 = a2.y;
  }
  float a0 = 0.f, a1 = 0.f, b0 = 0.f, b1 = 0.f;
  for (int base = 0; base < deg; base += 64) {
    int m = min(64, deg - base);
    int c = 0; float dv = 0.f;
    if (lane < m) { c = col[s0 + base + lane]; dv = dis[c]; }
    int j = 0;
    for (; j + 1 < m; j += 2) {
      int sA = __shfl(c, j), sB = __shfl(c, j + 1);
      float nA = __shfl(dv, j) * rd, nB = __shfl(dv, j + 1) * rd;
      float2 vA = h2[(size_t)sA * 64 + lane];
      float2 vB = h2[(size_t)sB * 64 + lane];
      a0 = fmaf(nA, vA.x, a0); a1 = fmaf(nA, vA.y, a1);
      b0 = fmaf(nB, vB.x, b0); b1 = fmaf(nB, vB.y, b1);
    }
    if (j < m) {
      int sA = __shfl(c, j);
      float nA = __shfl(dv, j) * rd;
      float2 vA = h2[(size_t)sA * 64 + lane];
      a0 = fmaf(nA, vA.x, a0); a1 = fmaf(nA, vA.y, a1);
    }
  }
  float rr = rd * rd;
  float v0 = fmaf(rr, hself.x, a0 + b0) + bv.x + ad0;
  float v1 = fmaf(rr, hself.y, a1 + b1) + bv.y + ad1;
  v0 = fmaxf(v0, 0.f); v1 = fmaxf(v1, 0.f);
  ((float2*)out)[(size_t)node * 64 + lane] = make_float2(v0, v1);
  if (dvec) {
    float2 wv = ((const float2*)dvec)[lane];
    float p = fmaf(v1, wv.y, v0 * wv.x);
#pragma unroll
    for (int o = 32; o > 0; o >>= 1) p += __shfl_xor(p, o);
    if (lane == 0) dout[node] = p;
  }
}

__global__ void k_gat_gather(const int* __restrict__ rp, const int* __restrict__ col,
                             const float* __restrict__ hs, const float* __restrict__ as_,
                             const float* __restrict__ ad_, const float* __restrict__ b,
                             float* __restrict__ out, int N, int relu,
                             const float* __restrict__ dvec, float* __restrict__ dout)
{
  int node = blockIdx.x * 4 + (threadIdx.x >> 6);
  if (node >= N) return;
  int lane = threadIdx.x & 63;
  int s0 = rp[node], deg = rp[node + 1] - s0;
  float adn = ad_[node];
  float2 bv = ((const float2*)b)[lane];
  const float2* hs2 = (const float2*)hs;
  float z = 0.f, a0 = 0.f, a1 = 0.f, b0 = 0.f, b1 = 0.f;
  for (int base = 0; base < deg; base += 64) {
    int m = min(64, deg - base);
    int c = 0; float av = 0.f;
    if (lane < m) { c = col[s0 + base + lane]; av = as_[c]; }
    int j = 0;
    for (; j + 1 < m; j += 2) {
      int sA = __shfl(c, j), sB = __shfl(c, j + 1);
      float vA = __shfl(av, j) + adn, vB = __shfl(av, j + 1) + adn;
      vA = vA > 0.f ? vA : 0.2f * vA;
      vB = vB > 0.f ? vB : 0.2f * vB;
      float pA = __expf(vA), pB = __expf(vB);
      z += pA + pB;
      float2 hA = hs2[(size_t)sA * 64 + lane];
      float2 hB = hs2[(size_t)sB * 64 + lane];
      a0 = fmaf(pA, hA.x, a0); a1 = fmaf(pA, hA.y, a1);
      b0 = fmaf(pB, hB.x, b0); b1 = fmaf(pB, hB.y, b1);
    }
    if (j < m) {
      int sA = __shfl(c, j);
      float vA = __shfl(av, j) + adn;
      vA = vA > 0.f ? vA : 0.2f * vA;
      float pA = __expf(vA);
      z += pA;
      float2 hA = hs2[(size_t)sA * 64 + lane];
      a0 = fmaf(pA, hA.x, a0); a1 = fmaf(pA, hA.y, a1);
    }
  }
  float inv = (deg > 0) ? 1.f / z : 0.f;
  float v0 = fmaf(a0 + b0, inv, bv.x);
  float v1 = fmaf(a1 + b1, inv, bv.y);
  if (relu) { v0 = fmaxf(v0, 0.f); v1 = fmaxf(v1, 0.f); }
  ((float2*)out)[(size_t)node * 64 + lane] = make_float2(v0, v1);
  if (dvec) {
    float2 wv = ((const float2*)dvec)[lane];
    float p = fmaf(v1, wv.y, v0 * wv.x);
#pragma unroll
    for (int o = 32; o > 0; o >>= 1) p += __shfl_xor(p, o);
    if (lane == 0) dout[node] = p;
  }
}

// ============ segment pooling: one block per graph, contiguous rows ============
__global__ __launch_bounds__(256) void k_pool_seg(
    const float* __restrict__ x, const int* __restrict__ rpb,
    float* __restrict__ pool, int col_off)
{
  __shared__ float2 red2[4][64];
  const int g = blockIdx.x;
  const int t = threadIdx.x, w = t >> 6, lane = t & 63;
  const int n0 = rpb[g], n1 = rpb[g + 1];
  const float2* x2 = (const float2*)x;
  float a0 = 0.f, a1 = 0.f, b0 = 0.f, b1 = 0.f;
  int n = n0 + w;
  for (; n + 4 < n1; n += 8) {
    float2 vA = x2[(size_t)n * 64 + lane];
    float2 vB = x2[(size_t)(n + 4) * 64 + lane];
    a0 += vA.x; a1 += vA.y; b0 += vB.x; b1 += vB.y;
  }
  if (n < n1) { float2 vA = x2[(size_t)n * 64 + lane]; a0 += vA.x; a1 += vA.y; }
  red2[w][lane] = make_float2(a0 + b0, a1 + b1);
  __syncthreads();
  if (t < 64) {
    float2 r0 = red2[0][t], r1 = red2[1][t], r2 = red2[2][t], r3 = red2[3][t];
    float inv = 1.f / fmaxf((float)(n1 - n0), 1.f);
    ((float2*)(pool + (size_t)g * 640 + col_off))[t] =
        make_float2((r0.x + r1.x + r2.x + r3.x) * inv,
                    (r0.y + r1.y + r2.y + r3.y) * inv);
  }
}

// ======================= final MLP (one block per graph) =======================
__global__ void k_mlp(const float* __restrict__ pool,
                      const float* __restrict__ W1, const float* __restrict__ b1,
                      const float* __restrict__ W2, const float* __restrict__ b2,
                      float* __restrict__ out)
{
  __shared__ float emb[640];
  __shared__ float red[128];
  const int g = blockIdx.x, t = threadIdx.x;
  for (int i = t; i < 640; i += 128) emb[i] = pool[(size_t)g * 640 + i];
  __syncthreads();
  float acc = b1[t];
  for (int i = 0; i < 640; ++i) acc = fmaf(emb[i], W1[i * 128 + t], acc);
  float h = fmaxf(acc, 0.f);
  red[t] = h * W2[t];
  __syncthreads();
  for (int s = 64; s > 0; s >>= 1) {
    if (t < s) red[t] += red[t + s];
    __syncthreads();
  }
  if (t == 0) out[g] = red[0] + b2[0];
}

// ======================= host =======================
extern "C" void kernel_launch(void* const* d_in, const int* in_sizes, int n_in,
                              void* d_out, int out_size, void* d_ws, size_t ws_size,
                              hipStream_t stream)
{
  auto fin = [&](int i) { return (const float*)d_in[i]; };
  auto iin = [&](int i) { return (const int*)d_in[i]; };

  const float *x_cd = fin(0), *x_seq = fin(1), *x_anno = fin(2), *x_range = fin(3), *x_md = fin(4);
  const int *ei_seq = iin(5), *ei_anno = iin(6), *ei_range = iin(7),
            *ei_comp = iin(8), *ei_cc = iin(9), *ei_mm = iin(10);
  const int *b_cd = iin(11), *b_seq = iin(12), *b_anno = iin(13), *b_range = iin(14), *b_md = iin(15);

  const int N_CD = in_sizes[0] / HD, N_SEQ = in_sizes[1] / HD, N_ANNO = in_sizes[2] / HD,
            N_RANGE = in_sizes[3] / HD, N_MD = in_sizes[4] / HD;
  const int E_seq = in_sizes[5] / 2, E_anno = in_sizes[6] / 2, E_range = in_sizes[7] / 2,
            E_comp = in_sizes[8] / 2, E_cc = in_sizes[9] / 2, E_mm = in_sizes[10] / 2;
  const int N_OTH = max(max(N_SEQ, N_ANNO), N_RANGE);

  auto WLm = [&](int i, int l) { return fin(i) + (size_t)l * HD * HD; };
  auto WLv = [&](int i, int l) { return fin(i) + (size_t)l * HD; };

  // ---- workspace layout ----
  float* ws = (float*)d_ws;
  size_t off = 0;
  auto alloc = [&](size_t n) { float* p = ws + off; off += (n + 3) & ~(size_t)3; return p; };
  float* xcd1 = alloc((size_t)N_CD * HD);
  float* xmd1 = alloc((size_t)N_MD * HD);
  float* xoth = alloc((size_t)N_OTH * HD);
  float* acc  = alloc((size_t)N_CD * HD);
  float* t1   = alloc((size_t)N_CD * HD);
  float* sAs  = alloc((size_t)N_CD);
  float* sAd  = alloc((size_t)N_CD);
  float* sAd2 = alloc((size_t)N_CD);
  float* dis_cc = alloc((size_t)N_CD);
  float* dis_mm = alloc((size_t)N_MD);
  float* wvall = alloc(4 * HD);
  float* pool = alloc((size_t)GNUM * 5 * HD);
  short* whi = (short*)(ws + off); off += (size_t)16 * 16384 / 2;
  short* wlo = (short*)(ws + off); off += (size_t)16 * 16384 / 2;
  auto alloci = [&](size_t n) { int* p = (int*)(ws + off); off += (n + 3) & ~(size_t)3; return p; };
  int* bsall = alloci(6 * 256);          // batched scan partials
  int* rpb_all = alloci(5 * RPB);
  int Nds[6] = {N_SEQ, N_ANNO, N_RANGE, N_CD, N_CD, N_MD};
  int Es[6]  = {E_seq, E_anno, E_range, E_comp, E_cc, E_mm};
  int* rps[6];
  int* rp0 = alloci(0);
  { size_t tot = 0; for (int i = 0; i < 6; ++i) tot += (size_t)Nds[i] + 1;
    int* p = alloci(tot); rp0 = p;
    for (int i = 0; i < 6; ++i) { rps[i] = p; p += Nds[i] + 1; } }
  size_t rp_tot_bytes = 0; for (int i = 0; i < 6; ++i) rp_tot_bytes += ((size_t)Nds[i] + 1) * 4;
  unsigned short* ranks[6];
  for (int i = 0; i < 6; ++i) ranks[i] = (unsigned short*)alloci(((size_t)Es[i] + 1) / 2);
  int* cols[6];  for (int i = 0; i < 6; ++i) cols[i] = alloci((size_t)Es[i]);
  (void)n_in;

  if (off * sizeof(float) > ws_size) {
    hipMemsetAsync(d_out, 0, (size_t)out_size * sizeof(float), stream);
    return;
  }

  auto ew = [&](size_t elems) { return dim3((unsigned)((elems + 255) / 256)); };
  auto nw = [&](int N) { return dim3((unsigned)((N + 3) / 4)); };

  // ---- pre-split all GEMM weights (slots: 0:16 1:18 2:19 3:21 4:22 5:27 6:32 7:34)
  WTab tab;
  tab.p[0] = fin(16); tab.p[1] = fin(18); tab.p[2] = fin(19); tab.p[3] = fin(21);
  tab.p[4] = fin(22); tab.p[5] = fin(27); tab.p[6] = fin(32); tab.p[7] = fin(34);
  k_split_w<<<dim3(1024), dim3(256), 0, stream>>>(tab, whi, wlo);

  // ---- 4 DST-side GAT matvecs (Wd@a_d): comp L0/L1, range L0/L1 ----
  MTab mt;
  mt.W[0] = WLm(23, 0); mt.a[0] = WLv(25, 0);
  mt.W[1] = WLm(23, 1); mt.a[1] = WLv(25, 1);
  mt.W[2] = WLm(28, 0); mt.a[2] = WLv(30, 0);
  mt.W[3] = WLm(28, 1); mt.a[3] = WLv(30, 1);
  k_matvec4<<<dim3(4), dim3(128), 0, stream>>>(mt, wvall);

  // ---- run-pointers for sorted batch vectors (binary search, no atomics) ----
  {
    BTab bt;
    bt.b[0] = b_cd; bt.n[0] = N_CD;  bt.b[1] = b_seq; bt.n[1] = N_SEQ;
    bt.b[2] = b_anno; bt.n[2] = N_ANNO;  bt.b[3] = b_range; bt.n[3] = N_RANGE;
    bt.b[4] = b_md; bt.n[4] = N_MD;
    k_runptr<<<dim3(5), dim3(512), 0, stream>>>(bt, rpb_all);
  }

  // ---- batched CSR build (rank-recording: fill has no atomics) ----
  const int* ess[6] = {ei_seq, ei_anno, ei_range, ei_comp, ei_cc, ei_mm};
  const int* eds[6] = {ei_seq + E_seq, ei_anno + E_anno, ei_range + E_range,
                       ei_comp + E_comp, ei_cc + E_cc, ei_mm + E_mm};
  hipMemsetAsync(rp0, 0, rp_tot_bytes, stream);
  {
    HTab ht; int b = 0;
    for (int i = 0; i < 6; ++i) {
      ht.key[i] = eds[i]; ht.cnt[i] = rps[i]; ht.rank[i] = ranks[i];
      ht.bo[i] = b; b += (Es[i] + 255) / 256; ht.n[i] = Es[i];
    }
    ht.bo[6] = b;
    k_hist_rank_all<<<dim3(b), dim3(256), 0, stream>>>(ht);
  }
  {
    STab st; int b = 0;
    for (int i = 0; i < 6; ++i) {
      st.rp[i] = rps[i]; st.bs[i] = bsall + i * 256;
      st.n[i] = Nds[i]; st.bo[i] = b; b += (Nds[i] + 4095) / 4096;
    }
    st.bo[6] = b;
    k_scan_partial_all<<<dim3(b), dim3(256), 0, stream>>>(st);
    k_scan_bsums_all<<<dim3(6), dim3(256), 0, stream>>>(st);
    k_scan_final_all<<<dim3(b), dim3(256), 0, stream>>>(st);
  }
  {
    FTab ft; int b = 0;
    for (int i = 0; i < 6; ++i) {
      ft.es[i] = ess[i]; ft.ed[i] = eds[i]; ft.rp[i] = rps[i]; ft.rank[i] = ranks[i];
      ft.col[i] = cols[i]; ft.bo[i] = b; b += (Es[i] + 255) / 256; ft.n[i] = Es[i];
    }
    ft.bo[6] = b;
    k_fill_all<<<dim3(b), dim3(256), 0, stream>>>(ft);
  }
  int *rp_seq = rps[0], *rp_anno = rps[1], *rp_range = rps[2],
      *rp_comp = rps[3], *rp_cc = rps[4], *rp_mm = rps[5];
  int *col_seq = cols[0], *col_anno = cols[1], *col_range = cols[2],
      *col_comp = cols[3], *col_cc = cols[4], *col_mm = cols[5];
  {
    DTab dt;
    dt.rp[0] = rp_cc; dt.dis[0] = dis_cc; dt.n[0] = N_CD;
    dt.rp[1] = rp_mm; dt.dis[1] = dis_mm; dt.n[1] = N_MD;
    dt.bo[0] = 0; dt.bo[1] = (N_CD + 255) / 256;
    dt.bo[2] = dt.bo[1] + (N_MD + 255) / 256;
    k_dis2<<<dim3(dt.bo[2]), dim3(256), 0, stream>>>(dt);
  }

  auto WHp = [&](int sidx, int layer) { return whi + (size_t)(sidx * 2 + layer) * 16384; };
  auto WLp = [&](int sidx, int layer) { return wlo + (size_t)(sidx * 2 + layer) * 16384; };
  auto gemm = [&](const float* A, int sidx, int layer, float* C, const float* b,
                  int N, int relu, const float* avec = nullptr, float* adot = nullptr) {
    k_gemm_mfma<<<dim3((N + 63) / 64), dim3(256), 0, stream>>>(
        A, WHp(sidx, layer), WLp(sidx, layer), nullptr, nullptr,
        nullptr, nullptr, nullptr, C, b, N, relu, avec, adot);
  };
  // SAGE fused: A1 = CSR-mean of xsrc (LDS-index gather in staging), A2 = xself
  auto gemm2g = [&](const float* xsrc, const int* grp, const int* gcol, int s1,
                    const float* xself, int s2, int layer,
                    float* C, const float* b, int N) {
    k_gemm_mfma<<<dim3((N + 63) / 64), dim3(256), 0, stream>>>(
        xsrc, WHp(s1, layer), WLp(s1, layer), grp, gcol,
        xself, WHp(s2, layer), WLp(s2, layer), C, b, N, 1, nullptr, nullptr);
  };
  auto do_pool = [&](const float* x, int type) {
    k_pool_seg<<<dim3(GNUM), dim3(256), 0, stream>>>(x, rpb_all + type * RPB, pool, type * HD);
  };

  // GAT: hs = xs@Ws with FUSED sAs = hs.a_s; sAd either precomputed (sAd_src)
  // or via rowdot(xd, wv). Optional fused out-dot (dvec->dout) for next layer.
  auto gat = [&](const float* xs, const float* xd, const int* rp, const int* col,
                 int Ns, int Nd, int sidx, int layer, const float* avs_raw,
                 const float* sAd_src, int wvD,
                 const float* dvec, float* dout,
                 const float* bias, float* out, int relu) {
    if (wvD >= 0) {
      k_rowdot<<<nw(Nd), dim3(256), 0, stream>>>(xd, wvall + wvD * 128, sAd, Nd);
      sAd_src = sAd;
    }
    gemm(xs, sidx, layer, t1, nullptr, Ns, 0, avs_raw, sAs);   // hs + fused hs.a_s
    k_gat_gather<<<nw(Nd), dim3(256), 0, stream>>>(rp, col, t1, sAs, sAd_src, bias,
                                                   out, Nd, relu, dvec, dout);
  };
  auto gcn = [&](const float* x, const int* rp, const int* col, const float* dis, int N,
                 int sidx, int layer, const float* b, const float* addin, float* out,
                 const float* dvec, float* dout) {
    gemm(x, sidx, layer, t1, nullptr, N, 0);
    k_gcn_gather<<<nw(N), dim3(256), 0, stream>>>(rp, col, dis, t1, addin, b, out, N,
                                                  dvec, dout);
  };
  auto sage = [&](const float* xsrc, const float* xself, const int* rp, const int* col,
                  int Nd, int sl, int sr, int layer, const float* bl, float* out) {
    gemm2g(xsrc, rp, col, sl, xself, sr, layer, out, bl, Nd);
  };

  // ---------- CD + MD, both layers ----------
  gat(x_md, x_cd, rp_comp, col_comp, N_MD, N_CD, 4, 0, WLv(24, 0),
      nullptr, 0, nullptr, nullptr, WLv(26, 0), acc, 0);
  gcn(x_cd, rp_cc, col_cc, dis_cc, N_CD, 6, 0, WLv(33, 0), acc, xcd1,
      wvall + 1 * 128, sAd2);
  gcn(x_md, rp_mm, col_mm, dis_mm, N_MD, 7, 0, WLv(35, 0), nullptr, xmd1,
      nullptr, nullptr);
  gat(xmd1, xcd1, rp_comp, col_comp, N_MD, N_CD, 4, 1, WLv(24, 1),
      sAd2, -1, nullptr, nullptr, WLv(26, 1), acc, 0);
  gcn(xcd1, rp_cc, col_cc, dis_cc, N_CD, 6, 1, WLv(33, 1), acc, acc,
      nullptr, nullptr);
  do_pool(acc, 0);
  gcn(xmd1, rp_mm, col_mm, dis_mm, N_MD, 7, 1, WLv(35, 1), nullptr, acc,
      nullptr, nullptr);
  do_pool(acc, 4);

  // ---------- SEQ ----------
  sage(x_cd, x_seq, rp_seq, col_seq, N_SEQ, 0, 1, 0, WLv(17, 0), xoth);
  sage(xcd1, xoth, rp_seq, col_seq, N_SEQ, 0, 1, 1, WLv(17, 1), acc);
  do_pool(acc, 1);
  // ---------- ANNO ----------
  sage(x_cd, x_anno, rp_anno, col_anno, N_ANNO, 2, 3, 0, WLv(20, 0), xoth);
  sage(xcd1, xoth, rp_anno, col_anno, N_ANNO, 2, 3, 1, WLv(20, 1), acc);
  do_pool(acc, 2);
  // ---------- RANGE ----------
  gat(x_cd, x_range, rp_range, col_range, N_CD, N_RANGE, 5, 0, WLv(29, 0),
      nullptr, 2, wvall + 3 * 128, sAd2, WLv(31, 0), xoth, 1);
  gat(xcd1, xoth, rp_range, col_range, N_CD, N_RANGE, 5, 1, WLv(29, 1),
      sAd2, -1, nullptr, nullptr, WLv(31, 1), acc, 1);
  do_pool(acc, 3);

  k_mlp<<<dim3(GNUM), dim3(128), 0, stream>>>(
      pool, fin(36), fin(37), fin(38), fin(39), (float*)d_out);
}